// Round 12
// baseline (906.236 us; speedup 1.0000x reference)
//
#include <hip/hip_runtime.h>
#include <math.h>

// ---- problem constants ----
constexpr int BB   = 32;    // batch
constexpr int L    = 336;   // seq_len
constexpr int CIN  = 7;
constexpr int MARK = 4;
constexpr int D    = 512;   // d_model
constexpr int DFF  = 2048;
constexpr int NH   = 8;
constexpr int HD   = 64;    // dk = dv
constexpr int S    = 446;   // 336+84+21+5
constexpr int DBOT = 128;
constexpr int L1 = 84, L2 = 21, L3 = 5;
constexpr int LC = 110;     // 84+21+5
constexpr int NLAYER = 3;
constexpr int PRED_N = 672; // 96*7
constexpr int MP   = 14336; // BB*S=14272 padded to multiple of 256
constexpr int NMAX = 12;    // max sparse neighbors (real max 10)
constexpr int MCONV1 = BB * L1;          // 2688 = 21*128 (exact)
constexpr int MCONV2P = 768;             // BB*L2=672 padded to 6*128
constexpr int MCAT  = 3584;              // BB*LC=3520 padded to 28*128

using short8  = __attribute__((ext_vector_type(8))) short;
using float4v = __attribute__((ext_vector_type(4))) float;

__device__ inline short f2bf(float f) {
    union { float f; unsigned u; } v; v.f = f;
    unsigned r = v.u + 0x7fffu + ((v.u >> 16) & 1u);
    return (short)(r >> 16);
}
__device__ inline float bf2f(short h) {
    union { unsigned u; float f; } v; v.u = ((unsigned)(unsigned short)h) << 16;
    return v.f;
}

// async global->LDS, 16B per lane, wave-uniform LDS base + lane*16
__device__ inline void gload_lds16(const void* g, void* l) {
    __builtin_amdgcn_global_load_lds(
        (const __attribute__((address_space(1))) void*)g,
        (__attribute__((address_space(3))) void*)l, 16, 0, 0);
}

// Staging map (both GEMM kernels), conflict-free + coalesced (round-11,
// verified 0 bank conflicts): LDS 16B-chunk u encodes
// row = ((u>>3)<<1)|((u>>2)&1), k-slot s=u&3 holding global kseg
// kg = s ^ ((u>>3)&3). Reader: rh=row>>1, s=lk^(rh&3),
// chunk = rh*8+(row&1)*4+s.
//
// Sparse-row support: amap (A row gather) / cmap (C row scatter) are
// position lists (pos-major compact rows: compact m -> batch b=m&31,
// list slot j=m>>5, orig row b*S+map[j]). cntp = active position count;
// blocks with m0 >= 32*cnt exit; boundary rows clamp j -> duplicate
// identical writes (benign).

// ---------------------------------------------------------------------------
// 128x128 bf16 MFMA GEMM, BK=32, double-buffered, counted vmcnt(4) pipeline.
// EPI: 0 f32; 1 f32+bias; 2 bf16; 3 bf16+bias+gelu; 4 bf16+bias;
//      5 bf16, v = acc*bias[gn] + bias2[gn] then ELU  (fused conv BN+ELU)
// ---------------------------------------------------------------------------
template<int EPI>
__launch_bounds__(256, 4)
__global__ void mfma_gemm(const short* __restrict__ A, const short* __restrict__ Bt,
                          const float* __restrict__ bias, const float* __restrict__ bias2,
                          void* __restrict__ Cout, int Kd, int Nd,
                          const int* __restrict__ amap, const int* __restrict__ cmap,
                          const int* __restrict__ cntp) {
    __shared__ short As[2][128 * 32];
    __shared__ short Bs[2][128 * 32];
    int tid = threadIdx.x;
    int nwg  = gridDim.x * gridDim.y;
    int orig = blockIdx.y * gridDim.x + blockIdx.x;
    int qq = nwg >> 3, rr = nwg & 7;
    int xcd = orig & 7, idx = orig >> 3;
    int wgid = (xcd < rr ? xcd * (qq + 1) : rr * (qq + 1) + (xcd - rr) * qq) + idx;
    int m0 = (wgid / gridDim.x) * 128, n0 = (wgid % gridDim.x) * 128;

    int cntA = 1 << 24;
    if (cntp) { cntA = *cntp; if (m0 >= cntA * 32) return; }

    int lane = tid & 63, wid = tid >> 6;
    int wm = wid >> 1, wn = wid & 1;
    int lr = lane & 15, lk = lane >> 4;

    size_t abase[2], bbase[2];
#pragma unroll
    for (int r = 0; r < 2; ++r) {
        int u = r * 256 + tid;
        int row = ((u >> 3) << 1) | ((u >> 2) & 1);
        int kg  = (u & 3) ^ ((u >> 3) & 3);
        int rm = m0 + row, ga;
        if (amap) { int j = rm >> 5; if (j > cntA - 1) j = cntA - 1; ga = (rm & 31) * S + amap[j]; }
        else ga = rm;
        abase[r] = (size_t)ga * Kd + kg * 8;
        bbase[r] = (size_t)(n0 + row) * Kd + kg * 8;
    }
    auto stage = [&](int buf, int k0) {
#pragma unroll
        for (int r = 0; r < 2; ++r) {
            short* la = As[buf] + (size_t)(r * 256 + wid * 64) * 8;
            short* lb = Bs[buf] + (size_t)(r * 256 + wid * 64) * 8;
            gload_lds16(A + abase[r] + k0, la);
            gload_lds16(Bt + bbase[r] + k0, lb);
        }
    };
    auto rd_off = [&](int row_) {
        int rh = row_ >> 1;
        int s  = lk ^ (rh & 3);
        return (size_t)(rh * 8 + (row_ & 1) * 4 + s) * 8;
    };

    float4v acc[4][4];
#pragma unroll
    for (int i = 0; i < 4; ++i)
#pragma unroll
        for (int j = 0; j < 4; ++j) acc[i][j] = 0;

    const int nt = Kd >> 5;
    stage(0, 0);
    for (int t = 0; t < nt; ++t) {
        int cur = t & 1;
        if (t + 1 < nt) {
            stage(cur ^ 1, (t + 1) * 32);
            asm volatile("s_waitcnt vmcnt(4)" ::: "memory");
        } else {
            asm volatile("s_waitcnt vmcnt(0)" ::: "memory");
        }
        __builtin_amdgcn_s_barrier();
        short8 af[4], bfv[4];
#pragma unroll
        for (int mi = 0; mi < 4; ++mi)
            af[mi] = *(const short8*)(As[cur] + rd_off(wm * 64 + mi * 16 + lr));
#pragma unroll
        for (int ni = 0; ni < 4; ++ni)
            bfv[ni] = *(const short8*)(Bs[cur] + rd_off(wn * 64 + ni * 16 + lr));
        __builtin_amdgcn_s_setprio(1);
#pragma unroll
        for (int mi = 0; mi < 4; ++mi)
#pragma unroll
            for (int ni = 0; ni < 4; ++ni)
                acc[mi][ni] = __builtin_amdgcn_mfma_f32_16x16x32_bf16(
                    af[mi], bfv[ni], acc[mi][ni], 0, 0, 0);
        __builtin_amdgcn_s_setprio(0);
        __builtin_amdgcn_s_barrier();
    }

#pragma unroll
    for (int mi = 0; mi < 4; ++mi) {
        int gmc = m0 + wm * 64 + mi * 16 + lk * 4;
#pragma unroll
        for (int ni = 0; ni < 4; ++ni) {
            int gn = n0 + wn * 64 + ni * 16 + lr;
            float bsv = (EPI == 1 || EPI == 3 || EPI == 4) ? bias[gn] : 0.0f;
            float sc = (EPI == 5) ? bias[gn]  : 0.0f;
            float sh = (EPI == 5) ? bias2[gn] : 0.0f;
#pragma unroll
            for (int e = 0; e < 4; ++e) {
                int rm = gmc + e, grow;
                if (cmap) { int j = rm >> 5; if (j > cntA - 1) j = cntA - 1; grow = (rm & 31) * S + cmap[j]; }
                else grow = rm;
                float v = acc[mi][ni][e] + bsv;
                if (EPI == 3) v = 0.5f * v * (1.0f + erff(v * 0.70710678118654752f));
                if (EPI == 5) { v = v * sc + sh; v = v > 0.0f ? v : (expf(v) - 1.0f); }
                if (EPI <= 1) ((float*)Cout)[(size_t)grow * Nd + gn] = v;
                else          ((short*)Cout)[(size_t)grow * Nd + gn] = f2bf(v);
            }
        }
    }
}

// ---------------------------------------------------------------------------
// 256x256 bf16 MFMA GEMM (wide-N shapes: FFN1, QKV). Same structure.
// ---------------------------------------------------------------------------
template<int EPI>
__launch_bounds__(512, 2)
__global__ void mfma_gemm256(const short* __restrict__ A, const short* __restrict__ Bt,
                             const float* __restrict__ bias, void* __restrict__ Cout,
                             int Kd, int Nd,
                             const int* __restrict__ amap, const int* __restrict__ cmap,
                             const int* __restrict__ cntp) {
    __shared__ short As[2][256 * 32];
    __shared__ short Bs[2][256 * 32];
    int tid = threadIdx.x;
    int nwg  = gridDim.x * gridDim.y;
    int orig = blockIdx.y * gridDim.x + blockIdx.x;
    int qq = nwg >> 3, rr = nwg & 7;
    int xcd = orig & 7, idx = orig >> 3;
    int wgid = (xcd < rr ? xcd * (qq + 1) : rr * (qq + 1) + (xcd - rr) * qq) + idx;
    int m0 = (wgid / gridDim.x) * 256, n0 = (wgid % gridDim.x) * 256;

    int cntA = 1 << 24;
    if (cntp) { cntA = *cntp; if (m0 >= cntA * 32) return; }

    int lane = tid & 63, wid = tid >> 6;
    int wm = wid >> 2, wn = wid & 3;
    int lr = lane & 15, lk = lane >> 4;

    size_t abase[2], bbase[2];
#pragma unroll
    for (int r = 0; r < 2; ++r) {
        int u = r * 512 + tid;
        int row = ((u >> 3) << 1) | ((u >> 2) & 1);
        int kg  = (u & 3) ^ ((u >> 3) & 3);
        int rm = m0 + row, ga;
        if (amap) { int j = rm >> 5; if (j > cntA - 1) j = cntA - 1; ga = (rm & 31) * S + amap[j]; }
        else ga = rm;
        abase[r] = (size_t)ga * Kd + kg * 8;
        bbase[r] = (size_t)(n0 + row) * Kd + kg * 8;
    }
    auto stage = [&](int buf, int k0) {
#pragma unroll
        for (int r = 0; r < 2; ++r) {
            short* la = As[buf] + (size_t)(r * 512 + wid * 64) * 8;
            short* lb = Bs[buf] + (size_t)(r * 512 + wid * 64) * 8;
            gload_lds16(A + abase[r] + k0, la);
            gload_lds16(Bt + bbase[r] + k0, lb);
        }
    };
    auto rd_off = [&](int row_) {
        int rh = row_ >> 1;
        int s  = lk ^ (rh & 3);
        return (size_t)(rh * 8 + (row_ & 1) * 4 + s) * 8;
    };

    float4v acc[8][4];
#pragma unroll
    for (int i = 0; i < 8; ++i)
#pragma unroll
        for (int j = 0; j < 4; ++j) acc[i][j] = 0;

    const int nt = Kd >> 5;
    stage(0, 0);
    for (int t = 0; t < nt; ++t) {
        int cur = t & 1;
        if (t + 1 < nt) {
            stage(cur ^ 1, (t + 1) * 32);
            asm volatile("s_waitcnt vmcnt(4)" ::: "memory");
        } else {
            asm volatile("s_waitcnt vmcnt(0)" ::: "memory");
        }
        __builtin_amdgcn_s_barrier();
        short8 af[8], bfv[4];
#pragma unroll
        for (int mi = 0; mi < 8; ++mi)
            af[mi] = *(const short8*)(As[cur] + rd_off(wm * 128 + mi * 16 + lr));
#pragma unroll
        for (int ni = 0; ni < 4; ++ni)
            bfv[ni] = *(const short8*)(Bs[cur] + rd_off(wn * 64 + ni * 16 + lr));
        __builtin_amdgcn_s_setprio(1);
#pragma unroll
        for (int mi = 0; mi < 8; ++mi)
#pragma unroll
            for (int ni = 0; ni < 4; ++ni)
                acc[mi][ni] = __builtin_amdgcn_mfma_f32_16x16x32_bf16(
                    af[mi], bfv[ni], acc[mi][ni], 0, 0, 0);
        __builtin_amdgcn_s_setprio(0);
        __builtin_amdgcn_s_barrier();
    }

#pragma unroll
    for (int mi = 0; mi < 8; ++mi) {
        int gmc = m0 + wm * 128 + mi * 16 + lk * 4;
#pragma unroll
        for (int ni = 0; ni < 4; ++ni) {
            int gn = n0 + wn * 64 + ni * 16 + lr;
            float bsv = (EPI == 1 || EPI == 3 || EPI == 4) ? bias[gn] : 0.0f;
#pragma unroll
            for (int e = 0; e < 4; ++e) {
                int rm = gmc + e, grow;
                if (cmap) { int j = rm >> 5; if (j > cntA - 1) j = cntA - 1; grow = (rm & 31) * S + cmap[j]; }
                else grow = rm;
                float v = acc[mi][ni][e] + bsv;
                if (EPI == 3) v = 0.5f * v * (1.0f + erff(v * 0.70710678118654752f));
                if (EPI <= 1) ((float*)Cout)[(size_t)grow * Nd + gn] = v;
                else          ((short*)Cout)[(size_t)grow * Nd + gn] = f2bf(v);
            }
        }
    }
}

// ---------------------------------------------------------------------------
// batched weight transpose+convert, 32x32 tiles, f32 W[Kd][Nd] -> bf16 Wt[Nd][Kd]
// ---------------------------------------------------------------------------
__device__ inline void wtrans_tile(const float* __restrict__ W, short* __restrict__ Wt,
                                   int Kd, int Nd, int n0, int k0, int tid) {
    __shared__ float tile[32][33];
    int tx = tid & 31, ty = tid >> 5; // ty 0..7
#pragma unroll
    for (int r = 0; r < 32; r += 8)
        tile[ty + r][tx] = W[(size_t)(k0 + ty + r) * Nd + n0 + tx];
    __syncthreads();
#pragma unroll
    for (int r = 0; r < 32; r += 8)
        Wt[(size_t)(n0 + ty + r) * Kd + k0 + tx] = f2bf(tile[tx][ty + r]);
}

__launch_bounds__(256)
__global__ void wtrans_qkvo(const float* __restrict__ wq, const float* __restrict__ wk,
                            const float* __restrict__ wv, const float* __restrict__ wo,
                            short* __restrict__ wqkvT, short* __restrict__ woT) {
    int z = blockIdx.z, l = z >> 2, part = z & 3;
    const float* src = (part == 0 ? wq : part == 1 ? wk : part == 2 ? wv : wo)
                       + (size_t)l * D * D;
    short* dst = (part < 3) ? wqkvT + (size_t)l * 3 * D * D + (size_t)part * D * D
                            : woT + (size_t)l * D * D;
    wtrans_tile(src, dst, D, D, blockIdx.x * 32, blockIdx.y * 32, threadIdx.x);
}

__launch_bounds__(256)
__global__ void wtrans_ffn(const float* __restrict__ w1, const float* __restrict__ w2,
                           short* __restrict__ w1T, short* __restrict__ w2T) {
    int z = blockIdx.z, l = z >> 1, part = z & 1;
    int nt = part ? blockIdx.y : blockIdx.x;
    int kt = part ? blockIdx.x : blockIdx.y;
    if (part == 0)
        wtrans_tile(w1 + (size_t)l * D * DFF, w1T + (size_t)l * DFF * D,
                    D, DFF, nt * 32, kt * 32, threadIdx.x);
    else
        wtrans_tile(w2 + (size_t)l * DFF * D, w2T + (size_t)l * D * DFF,
                    DFF, D, nt * 32, kt * 32, threadIdx.x);
}

__launch_bounds__(256)
__global__ void wtrans_one(const float* __restrict__ W, short* __restrict__ Wt,
                           int Kd, int Nd) {
    wtrans_tile(W, Wt, Kd, Nd, blockIdx.x * 32, blockIdx.y * 32, threadIdx.x);
}

// ---------------------------------------------------------------------------
// CSCM prep
// ---------------------------------------------------------------------------
__launch_bounds__(256)
__global__ void cscm_prep(const float* __restrict__ cw, const float* __restrict__ cb,
                          const float* __restrict__ bg, const float* __restrict__ bb,
                          short* __restrict__ cscmT, float* __restrict__ sc,
                          float* __restrict__ sh) {
    int idx = blockIdx.x * 256 + threadIdx.x;
    if (idx < 2 * DBOT * 512) {
        int l = idx >> 16;
        int rem = idx & 65535;
        int oc = rem >> 9, j = rem & 511;
        int r = j >> 7, c = j & 127;
        cscmT[idx] = f2bf(cw[(((size_t)l * DBOT + oc) * DBOT + c) * 4 + r]);
    }
    if (idx < 3 * DBOT) {
        sc[idx] = bg[idx];
        sh[idx] = cb[idx] * bg[idx] + bb[idx];
    }
}

// ---------------------------------------------------------------------------
// Embedding
// ---------------------------------------------------------------------------
__launch_bounds__(256)
__global__ void embed_kernel(const float* __restrict__ x_enc, const float* __restrict__ x_mark,
                             const float* __restrict__ cw, const float* __restrict__ tw,
                             const float* __restrict__ tb, float* __restrict__ emb,
                             short* __restrict__ emb_bf) {
    size_t idx = (size_t)blockIdx.x * 256 + threadIdx.x;
    if (idx >= (size_t)BB * L * D) return;
    int d = idx % D;
    int t = (idx / D) % L;
    int b = idx / ((size_t)D * L);
    float acc = tb[d];
#pragma unroll
    for (int w = 0; w < 3; ++w) {
        int s = t + w - 1;
        if (s < 0) s = L - 1;
        if (s >= L) s = 0;
        const float* xr = x_enc + ((size_t)b * L + s) * CIN;
        const float* wr = cw + (size_t)d * (CIN * 3) + w;
#pragma unroll
        for (int i = 0; i < CIN; ++i) acc += xr[i] * wr[i * 3];
    }
    int e = d & ~1;
    float div = expf(-(float)e * (logf(10000.0f) / (float)D));
    float arg = (float)t * div;
    acc += (d & 1) ? cosf(arg) : sinf(arg);
    const float* mr = x_mark + ((size_t)b * L + t) * MARK;
#pragma unroll
    for (int m = 0; m < MARK; ++m) acc += mr[m] * tw[m * D + d];
    emb[idx] = acc;
    emb_bf[idx] = f2bf(acc);
}

// ---------------------------------------------------------------------------
// CSCM conv level 3 (tiny)
// ---------------------------------------------------------------------------
__launch_bounds__(128)
__global__ void cscm_conv_bf16(const short* __restrict__ in, int inRowsPerB,
                               short* __restrict__ outp, const float* __restrict__ w,
                               const float* __restrict__ cb, const float* __restrict__ bng,
                               const float* __restrict__ bnb, int Lout) {
    int bid = blockIdx.x;
    int to = bid % Lout, b = bid / Lout;
    __shared__ float insh[4 * DBOT];
    int tid = threadIdx.x;
#pragma unroll
    for (int r = 0; r < 4; ++r)
        insh[r * DBOT + tid] = bf2f(in[((size_t)(b * inRowsPerB + to * 4 + r)) * DBOT + tid]);
    __syncthreads();
    float acc = cb[tid];
    const float* wr = w + (size_t)tid * (DBOT * 4);
    for (int c = 0; c < DBOT; ++c) {
#pragma unroll
        for (int r = 0; r < 4; ++r)
            acc += insh[r * DBOT + c] * wr[c * 4 + r];
    }
    acc = acc * bng[tid] + bnb[tid];
    outp[((size_t)(b * Lout + to)) * DBOT + tid] = f2bf(acc > 0.0f ? acc : (expf(acc) - 1.0f));
}

// ---------------------------------------------------------------------------
// concat pyramid outputs (bf16) -> csc [MCAT][128]
// ---------------------------------------------------------------------------
__launch_bounds__(256)
__global__ void concat_cs_kernel(const short* __restrict__ cs1, const short* __restrict__ cs2,
                                 const short* __restrict__ cs3, short* __restrict__ csc) {
    int idx = blockIdx.x * 256 + threadIdx.x;
    if (idx >= MCAT * DBOT) return;
    int m = idx >> 7, c = idx & 127;
    short v = 0;
    if (m < BB * LC) {
        int b = m / LC, t = m % LC;
        if (t < L1)           v = cs1[(size_t)(b * L1 + t) * DBOT + c];
        else if (t < L1 + L2) v = cs2[(size_t)(b * L2 + (t - L1)) * DBOT + c];
        else                  v = cs3[(size_t)(b * L3 + (t - L1 - L2)) * DBOT + c];
    }
    csc[idx] = v;
}

// ---------------------------------------------------------------------------
// sparse neighbor lists from the pyramid mask rules
// ---------------------------------------------------------------------------
__device__ inline void layer_of(int i, int& l, int& p) {
    if (i < 336)      { l = 0; p = i; }
    else if (i < 420) { l = 1; p = i - 336; }
    else if (i < 441) { l = 2; p = i - 420; }
    else              { l = 3; p = i - 441; }
}

__launch_bounds__(64)
__global__ void nbr_kernel(int* __restrict__ nbr) {
    int i = blockIdx.x * 64 + threadIdx.x;
    if (i >= S) return;
    const int sizes[4]  = {336, 84, 21, 5};
    const int starts[4] = {0, 336, 420, 441};
    int li, pi;
    layer_of(i, li, pi);
    int lst[NMAX];
    int cnt = 0;
    for (int d = -2; d <= 2; ++d) {
        int q = pi + d;
        if (q >= 0 && q < sizes[li]) lst[cnt++] = starts[li] + q;
    }
    if (li > 0) {
        int lo = pi * 4;
        int hi = (pi == sizes[li] - 1) ? sizes[li - 1] : (pi + 1) * 4;
        for (int c = lo; c < hi; ++c) lst[cnt++] = starts[li - 1] + c;
    }
    if (li < 3) {
        int q = pi >> 2;
        if (q > sizes[li + 1] - 1) q = sizes[li + 1] - 1;
        lst[cnt++] = starts[li + 1] + q;
    }
    for (int j = 0; j < NMAX; ++j) nbr[i * NMAX + j] = (j < cnt) ? lst[j] : -1;
}

// ---------------------------------------------------------------------------
// active sets: A3 = gather positions {335,419,440,445}; A_{l-1} = U nbr(A_l).
// Layer l computes QKV at A_{l-1}, everything else at A_l.
// idxL[lvl*S + k], cntL[lvl]; deterministic worklist order.
// ---------------------------------------------------------------------------
__launch_bounds__(64)
__global__ void activesets_kernel(const int* __restrict__ nbr, int* __restrict__ idxL,
                                  int* __restrict__ cntL) {
    if (threadIdx.x != 0) return;
    bool mk[S];
    int cur[S], nxt[S];
    cur[0] = 335; cur[1] = 419; cur[2] = 440; cur[3] = 445;
    int cc = 4;
    cntL[3] = 4;
    for (int k = 0; k < 4; ++k) idxL[3 * S + k] = cur[k];
    for (int lvl = 3; lvl >= 1; --lvl) {
        for (int i = 0; i < S; ++i) mk[i] = false;
        int nc = 0;
        for (int k = 0; k < cc; ++k) {
            const int* nr = nbr + cur[k] * NMAX;
            for (int t = 0; t < NMAX; ++t) {
                int v = nr[t];
                if (v >= 0 && !mk[v]) { mk[v] = true; nxt[nc++] = v; }
            }
        }
        cntL[lvl - 1] = nc;
        for (int k = 0; k < nc; ++k) { idxL[(lvl - 1) * S + k] = nxt[k]; cur[k] = nxt[k]; }
        cc = nc;
    }
}

// ---------------------------------------------------------------------------
// sparse attention over the active list: compact wave id = j*32+b;
// Q at orig (b,i=idx[j]); K/V neighbors at orig rows; Ob written COMPACT.
// ---------------------------------------------------------------------------
__launch_bounds__(256)
__global__ void attn_sparse_kernel(const short* __restrict__ QKV, const int* __restrict__ nbr,
                                   short* __restrict__ Ob, const int* __restrict__ idxl,
                                   const int* __restrict__ cntp) {
    int wid  = blockIdx.x * 4 + (threadIdx.x >> 6);
    if (wid >= (*cntp) * 32) return;
    int lane = threadIdx.x & 63;
    int b = wid & 31, j = wid >> 5;
    int i = idxl[j];
    const short8 qv = *(const short8*)(QKV + (size_t)(b * S + i) * 1536 + lane * 8);
    float qf[8];
#pragma unroll
    for (int e = 0; e < 8; ++e) qf[e] = bf2f(qv[e]);
    int nb[NMAX];
    const int* nr = nbr + i * NMAX;
#pragma unroll
    for (int jj = 0; jj < NMAX; ++jj) nb[jj] = nr[jj];
    float sc[NMAX];
#pragma unroll
    for (int jj = 0; jj < NMAX; ++jj) {
        float s = -1e30f;
        if (nb[jj] >= 0) {
            const short8 kv = *(const short8*)(QKV + (size_t)(b * S + nb[jj]) * 1536 + 512 + lane * 8);
            s = 0.0f;
#pragma unroll
            for (int e = 0; e < 8; ++e) s += qf[e] * bf2f(kv[e]);
            s += __shfl_xor(s, 1); s += __shfl_xor(s, 2); s += __shfl_xor(s, 4);
            s *= 0.125f;
        }
        sc[jj] = s;
    }
    float mx = sc[0];
#pragma unroll
    for (int jj = 1; jj < NMAX; ++jj) mx = fmaxf(mx, sc[jj]);
    float sum = 0.0f;
    float accv[8] = {};
#pragma unroll
    for (int jj = 0; jj < NMAX; ++jj) {
        float p = expf(sc[jj] - mx);
        sum += p;
        if (nb[jj] >= 0) {
            const short8 vv = *(const short8*)(QKV + (size_t)(b * S + nb[jj]) * 1536 + 1024 + lane * 8);
#pragma unroll
            for (int e = 0; e < 8; ++e) accv[e] += p * bf2f(vv[e]);
        }
    }
    float inv = 1.0f / sum;
    short8 ov;
#pragma unroll
    for (int e = 0; e < 8; ++e) ov[e] = f2bf(accv[e] * inv);
    *(short8*)(Ob + (size_t)wid * D + lane * 8) = ov;
}

// ---------------------------------------------------------------------------
// concat(emb, coarse) + LayerNorm -> seq (f32) + seq_bf (bf16), all rows
// ---------------------------------------------------------------------------
__launch_bounds__(256)
__global__ void concat_ln_kernel(const float* __restrict__ emb, const float* __restrict__ coarse,
                                 const float* __restrict__ g, const float* __restrict__ bta,
                                 float* __restrict__ seq, short* __restrict__ seq_bf) {
    int row = blockIdx.x;
    int b = row / S, s = row % S;
    const float* src = (s < L) ? emb + ((size_t)b * L + s) * D
                               : coarse + ((size_t)b * LC + (s - L)) * D;
    __shared__ float red[256];
    int tid = threadIdx.x;
    float x0 = src[tid], x1 = src[tid + 256];
    red[tid] = x0 + x1;
    __syncthreads();
    for (int t = 128; t > 0; t >>= 1) { if (tid < t) red[tid] += red[tid + t]; __syncthreads(); }
    float mu = red[0] * (1.0f / D);
    __syncthreads();
    float d0 = x0 - mu, d1 = x1 - mu;
    red[tid] = d0 * d0 + d1 * d1;
    __syncthreads();
    for (int t = 128; t > 0; t >>= 1) { if (tid < t) red[tid] += red[tid + t]; __syncthreads(); }
    float rstd = rsqrtf(red[0] * (1.0f / D) + 1e-5f);
    float v0 = d0 * rstd * g[tid]       + bta[tid];
    float v1 = d1 * rstd * g[tid + 256] + bta[tid + 256];
    float* dst = seq + (size_t)row * D;
    dst[tid] = v0; dst[tid + 256] = v1;
    short* dbf = seq_bf + (size_t)row * D;
    dbf[tid] = f2bf(v0); dbf[tid + 256] = f2bf(v1);
}

// ---------------------------------------------------------------------------
// indexed residual LN: compact row -> orig row b*S+idx[j];
// seq/seq_bf updated at orig; add read compact (bf16)
// ---------------------------------------------------------------------------
__launch_bounds__(256)
__global__ void add_ln_idx(float* __restrict__ seq, const short* __restrict__ add,
                           const float* __restrict__ g, const float* __restrict__ bta,
                           short* __restrict__ seq_bf, const int* __restrict__ idxl,
                           const int* __restrict__ cntp) {
    int row = blockIdx.x;
    if (row >= (*cntp) * 32) return;
    int b = row & 31, j = row >> 5;
    int orig = b * S + idxl[j];
    __shared__ float red[256];
    int tid = threadIdx.x;
    float* srow = seq + (size_t)orig * D;
    const short* arow = add + (size_t)row * D;
    float x0 = srow[tid] + bf2f(arow[tid]);
    float x1 = srow[tid + 256] + bf2f(arow[tid + 256]);
    red[tid] = x0 + x1;
    __syncthreads();
    for (int t = 128; t > 0; t >>= 1) { if (tid < t) red[tid] += red[tid + t]; __syncthreads(); }
    float mu = red[0] * (1.0f / D);
    __syncthreads();
    float d0 = x0 - mu, d1 = x1 - mu;
    red[tid] = d0 * d0 + d1 * d1;
    __syncthreads();
    for (int t = 128; t > 0; t >>= 1) { if (tid < t) red[tid] += red[tid + t]; __syncthreads(); }
    float rstd = rsqrtf(red[0] * (1.0f / D) + 1e-5f);
    float v0 = d0 * rstd * g[tid]       + bta[tid];
    float v1 = d1 * rstd * g[tid + 256] + bta[tid + 256];
    srow[tid] = v0; srow[tid + 256] = v1;
    short* dbf = seq_bf + (size_t)orig * D;
    dbf[tid] = f2bf(v0); dbf[tid + 256] = f2bf(v1);
}

// ---------------------------------------------------------------------------
// prediction head, split-K with fused gather
// ---------------------------------------------------------------------------
__launch_bounds__(256)
__global__ void pred_kernel(const float* __restrict__ seq, const float* __restrict__ w,
                            float* __restrict__ part) {
    __shared__ float es[32][257];
    __shared__ float wsm[256][8];
    int tid = threadIdx.x;
    int n0 = blockIdx.x * 8;
    int ks = blockIdx.y;
    int k0 = ks * 256;
    const int pos[4] = {335, 419, 440, 445};
    int seg = ks >> 1;
    int dbase = (ks & 1) * 256;
#pragma unroll 8
    for (int r = 0; r < 32; ++r)
        es[r][tid] = seq[((size_t)r * S + pos[seg]) * D + dbase + tid];
#pragma unroll
    for (int e = 0; e < 8; ++e)
        wsm[tid][e] = w[(size_t)(k0 + tid) * PRED_N + n0 + e];
    __syncthreads();
    int b = tid >> 3, nn = tid & 7;
    float acc = 0.0f;
#pragma unroll 8
    for (int kk = 0; kk < 256; ++kk)
        acc += es[b][kk] * wsm[kk][nn];
    part[(size_t)ks * (BB * PRED_N) + (size_t)b * PRED_N + n0 + nn] = acc;
}

__launch_bounds__(256)
__global__ void pred_reduce_kernel(const float* __restrict__ part, float* __restrict__ out) {
    int idx = blockIdx.x * 256 + threadIdx.x;
    if (idx >= BB * PRED_N) return;
    float s = 0.0f;
#pragma unroll
    for (int k = 0; k < 8; ++k) s += part[(size_t)k * (BB * PRED_N) + idx];
    out[idx] = s;
}

// ---------------------------------------------------------------------------
extern "C" void kernel_launch(void* const* d_in, const int* in_sizes, int n_in,
                              void* d_out, int out_size, void* d_ws, size_t ws_size,
                              hipStream_t stream) {
    const float* x_enc      = (const float*)d_in[0];
    const float* x_mark_enc = (const float*)d_in[1];
    const float* conv_embed_w = (const float*)d_in[4];
    const float* time_w  = (const float*)d_in[5];
    const float* time_b  = (const float*)d_in[6];
    const float* down_w  = (const float*)d_in[7];
    const float* down_b  = (const float*)d_in[8];
    const float* cscm_w  = (const float*)d_in[9];
    const float* cscm_b  = (const float*)d_in[10];
    const float* bn_g    = (const float*)d_in[11];
    const float* bn_b    = (const float*)d_in[12];
    const float* up_w    = (const float*)d_in[13];
    const float* up_b    = (const float*)d_in[14];
    const float* cln_g   = (const float*)d_in[15];
    const float* cln_b   = (const float*)d_in[16];
    const float* wq      = (const float*)d_in[17];
    const float* wk      = (const float*)d_in[18];
    const float* wv      = (const float*)d_in[19];
    const float* wo      = (const float*)d_in[20];
    const float* ln1_g   = (const float*)d_in[21];
    const float* ln1_b   = (const float*)d_in[22];
    const float* ffn_w1  = (const float*)d_in[23];
    const float* ffn_b1  = (const float*)d_in[24];
    const float* ffn_w2  = (const float*)d_in[25];
    const float* ffn_b2  = (const float*)d_in[26];
    const float* ln2_g   = (const float*)d_in[27];
    const float* ln2_b   = (const float*)d_in[28];
    const float* pred_w  = (const float*)d_in[29];
    float* out = (float*)d_out;

    // ---- workspace layout (bytes, 256-aligned) ----
    char* w8 = (char*)d_ws;
    size_t off = 0;
    auto alloc = [&](size_t bytes) {
        void* p = w8 + off;
        off = (off + bytes + 255) & ~(size_t)255;
        return p;
    };
    float* emb    = (float*)alloc((size_t)BB * L * D * 4);
    short* emb_bf = (short*)alloc((size_t)BB * L * D * 2);
    short* xd_bf  = (short*)alloc((size_t)BB * L * DBOT * 2);
    short* cs1_bf = (short*)alloc((size_t)MCONV2P * 512 * 2);
    short* cs2_bf = (short*)alloc((size_t)MCONV2P * DBOT * 2);
    short* cs3_bf = (short*)alloc((size_t)BB * L3 * DBOT * 2);
    short* csc_bf = (short*)alloc((size_t)MCAT * DBOT * 2);
    float* coarse = (float*)alloc((size_t)MCAT * D * 4);
    float* seq    = (float*)alloc((size_t)BB * S * D * 4);
    short* T1     = (short*)alloc((size_t)MP * D * 2);
    float* part   = (float*)alloc((size_t)8 * BB * PRED_N * 4);
    short* seq_bf = (short*)alloc((size_t)MP * D * 2);
    short* QKV    = (short*)alloc((size_t)MP * 3 * D * 2);  // + Ob contiguous =
    short* Ob     = (short*)alloc((size_t)MP * D * 2);      // hidden [MP][2048]
    short* hidden = QKV;
    short* wqkvT  = (short*)alloc((size_t)NLAYER * 3 * D * D * 2);
    short* woT    = (short*)alloc((size_t)NLAYER * D * D * 2);
    short* w1T    = (short*)alloc((size_t)NLAYER * DFF * D * 2);
    short* w2T    = (short*)alloc((size_t)NLAYER * D * DFF * 2);
    short* downT  = (short*)alloc((size_t)DBOT * D * 2);
    short* upT    = (short*)alloc((size_t)D * DBOT * 2);
    short* cscmT  = (short*)alloc((size_t)2 * DBOT * 512 * 2);
    float* csc_sc = (float*)alloc((size_t)3 * DBOT * 4);
    float* csc_sh = (float*)alloc((size_t)3 * DBOT * 4);
    int*   nbr    = (int*)alloc((size_t)S * NMAX * 4);
    int*   idxL   = (int*)alloc((size_t)4 * S * 4);
    int*   cntL   = (int*)alloc((size_t)4 * 4);
    (void)ws_size; (void)in_sizes; (void)n_in; (void)out_size;

    const int rowsL = BB * L;   // 10752 = 84*128
    const int rowsS = BB * S;   // 14272
    dim3 blk(256);

    // 0. weight convert+transpose
    wtrans_qkvo<<<dim3(16, 16, 4 * NLAYER), blk, 0, stream>>>(wq, wk, wv, wo, wqkvT, woT);
    wtrans_ffn<<<dim3(64, 16, 2 * NLAYER), blk, 0, stream>>>(ffn_w1, ffn_w2, w1T, w2T);
    wtrans_one<<<dim3(DBOT / 32, D / 32), blk, 0, stream>>>(down_w, downT, D, DBOT);
    wtrans_one<<<dim3(D / 32, DBOT / 32), blk, 0, stream>>>(up_w, upT, DBOT, D);
    cscm_prep<<<dim3((2 * DBOT * 512 + 255) / 256), blk, 0, stream>>>(
        cscm_w, cscm_b, bn_g, bn_b, cscmT, csc_sc, csc_sh);
    // 1. embedding + neighbor lists + active sets
    embed_kernel<<<dim3(((size_t)BB * L * D + 255) / 256), blk, 0, stream>>>(
        x_enc, x_mark_enc, conv_embed_w, time_w, time_b, emb, emb_bf);
    nbr_kernel<<<dim3((S + 63) / 64), dim3(64), 0, stream>>>(nbr);
    activesets_kernel<<<dim3(1), dim3(64), 0, stream>>>(nbr, idxL, cntL);
    // 2. down projection -> bf16
    mfma_gemm<4><<<dim3(1, rowsL / 128), blk, 0, stream>>>(
        emb_bf, downT, down_b, nullptr, xd_bf, D, DBOT, nullptr, nullptr, nullptr);
    // 3. CSCM pyramid: conv1/conv2 as GEMM
    mfma_gemm<5><<<dim3(1, MCONV1 / 128), blk, 0, stream>>>(
        xd_bf, cscmT, csc_sc, csc_sh, cs1_bf, 512, DBOT, nullptr, nullptr, nullptr);
    mfma_gemm<5><<<dim3(1, MCONV2P / 128), blk, 0, stream>>>(
        cs1_bf, cscmT + (size_t)DBOT * 512, csc_sc + DBOT, csc_sh + DBOT,
        cs2_bf, 512, DBOT, nullptr, nullptr, nullptr);
    cscm_conv_bf16<<<dim3(BB * L3), dim3(DBOT), 0, stream>>>(
        cs2_bf, L2, cs3_bf, cscm_w + 2 * DBOT * DBOT * 4,
        cscm_b + 2 * DBOT, bn_g + 2 * DBOT, bn_b + 2 * DBOT, L3);
    // 4. up projection
    concat_cs_kernel<<<dim3((MCAT * DBOT + 255) / 256), blk, 0, stream>>>(
        cs1_bf, cs2_bf, cs3_bf, csc_bf);
    mfma_gemm<1><<<dim3(D / 128, MCAT / 128), blk, 0, stream>>>(
        csc_bf, upT, up_b, nullptr, coarse, DBOT, D, nullptr, nullptr, nullptr);
    // 5. concat + LN (all rows)
    concat_ln_kernel<<<dim3(rowsS), blk, 0, stream>>>(emb, coarse, cln_g, cln_b, seq, seq_bf);

    // 6. encoder layers (sparse active sets; layer l: QKV at A_{l-1}=idxL[l-1],
    //    attn/Oproj/LN/FFN at A_l=idxL[l])
    const int gy  = MP / 128;  // 112
    const int gy2 = MP / 256;  // 56
    for (int l = 0; l < NLAYER; ++l) {
        const int* inList  = idxL + (size_t)l * S;       // A_{l-1} (l index 0-based)
        const int* inCnt   = cntL + l;
        const int* outList = idxL + (size_t)(l + 1) * S; // A_l
        const int* outCnt  = cntL + (l + 1);
        mfma_gemm256<2><<<dim3(3 * D / 256, gy2), dim3(512), 0, stream>>>(
            seq_bf, wqkvT + (size_t)l * 3 * D * D, nullptr, QKV, D, 3 * D,
            inList, inList, inCnt);
        attn_sparse_kernel<<<dim3(rowsS / 4), blk, 0, stream>>>(
            QKV, nbr, Ob, outList, outCnt);
        mfma_gemm<2><<<dim3(D / 128, gy), blk, 0, stream>>>(
            Ob, woT + (size_t)l * D * D, nullptr, nullptr, T1, D, D,
            nullptr, nullptr, outCnt);
        add_ln_idx<<<dim3(rowsS), blk, 0, stream>>>(
            seq, T1, ln1_g + (size_t)l * D, ln1_b + (size_t)l * D, seq_bf,
            outList, outCnt);
        mfma_gemm256<3><<<dim3(DFF / 256, gy2), dim3(512), 0, stream>>>(
            seq_bf, w1T + (size_t)l * DFF * D, ffn_b1 + (size_t)l * DFF, hidden, D, DFF,
            outList, nullptr, outCnt);
        mfma_gemm<4><<<dim3(D / 128, gy), blk, 0, stream>>>(
            hidden, w2T + (size_t)l * D * DFF, ffn_b2 + (size_t)l * D, nullptr, T1, DFF, D,
            nullptr, nullptr, outCnt);
        add_ln_idx<<<dim3(rowsS), blk, 0, stream>>>(
            seq, T1, ln2_g + (size_t)l * D, ln2_b + (size_t)l * D, seq_bf,
            outList, outCnt);
    }

    // 7. prediction head (split-K, gather fused) + reduce
    pred_kernel<<<dim3(PRED_N / 8, 8), blk, 0, stream>>>(seq, pred_w, part);
    pred_reduce_kernel<<<dim3((BB * PRED_N + 255) / 256), blk, 0, stream>>>(part, out);
}

// Round 13
// 617.942 us; speedup vs baseline: 1.4665x; 1.4665x over previous
//
#include <hip/hip_runtime.h>
#include <math.h>

// ---- problem constants ----
constexpr int BB   = 32;    // batch
constexpr int L    = 336;   // seq_len
constexpr int CIN  = 7;
constexpr int MARK = 4;
constexpr int D    = 512;   // d_model
constexpr int DFF  = 2048;
constexpr int NH   = 8;
constexpr int HD   = 64;    // dk = dv
constexpr int S    = 446;   // 336+84+21+5
constexpr int DBOT = 128;
constexpr int L1 = 84, L2 = 21, L3 = 5;
constexpr int LC = 110;     // 84+21+5
constexpr int NLAYER = 3;
constexpr int PRED_N = 672; // 96*7
constexpr int MP   = 14336; // BB*S padded
constexpr int NMAX = 12;    // max sparse neighbors (real max 10)
constexpr int MCONV1 = BB * L1;          // 2688 = 21*128 (exact)
constexpr int MCONV2P = 768;             // BB*L2=672 padded to 6*128
constexpr int MCAT  = 3584;              // BB*LC=3520 padded to 28*128

using short8  = __attribute__((ext_vector_type(8))) short;
using float4v = __attribute__((ext_vector_type(4))) float;

// ---------------------------------------------------------------------------
// COMPILE-TIME pyramid structure: neighbor lists + active sets.
// Active sets: A3 = gather positions {335,419,440,445}; A_{l-1} = U nbr(A_l),
// compacted in sorted order (order is internally consistent everywhere).
// Layer l (0-based): QKV at idx[l] (cnt[l]), attn/Oproj/LN/FFN at idx[l+1].
// ---------------------------------------------------------------------------
struct SetsData {
    int nbr[S][NMAX];
    int idx[4][S];
    int cnt[4];
};

constexpr SetsData compute_sets() {
    SetsData sd{};
    constexpr int sizes[4]  = {336, 84, 21, 5};
    constexpr int starts[4] = {0, 336, 420, 441};
    // neighbor lists (same rules as the reference mask)
    for (int i = 0; i < S; ++i) {
        int li = 0, pi = i;
        if (i < 336)      { li = 0; pi = i; }
        else if (i < 420) { li = 1; pi = i - 336; }
        else if (i < 441) { li = 2; pi = i - 420; }
        else              { li = 3; pi = i - 441; }
        int cnt = 0;
        for (int d = -2; d <= 2; ++d) {
            int q = pi + d;
            if (q >= 0 && q < sizes[li]) sd.nbr[i][cnt++] = starts[li] + q;
        }
        if (li > 0) {
            int lo = pi * 4;
            int hi = (pi == sizes[li] - 1) ? sizes[li - 1] : (pi + 1) * 4;
            for (int c = lo; c < hi; ++c) sd.nbr[i][cnt++] = starts[li - 1] + c;
        }
        if (li < 3) {
            int q = pi >> 2;
            if (q > sizes[li + 1] - 1) q = sizes[li + 1] - 1;
            sd.nbr[i][cnt++] = starts[li + 1] + q;
        }
        for (int j = cnt; j < NMAX; ++j) sd.nbr[i][j] = -1;
    }
    // active sets, back-propagated from the 4 gather positions
    sd.cnt[3] = 4;
    sd.idx[3][0] = 335; sd.idx[3][1] = 419; sd.idx[3][2] = 440; sd.idx[3][3] = 445;
    for (int lvl = 3; lvl >= 1; --lvl) {
        bool mk[S] = {};
        for (int k = 0; k < sd.cnt[lvl]; ++k) {
            int i = sd.idx[lvl][k];
            for (int t = 0; t < NMAX; ++t) {
                int v = sd.nbr[i][t];
                if (v >= 0) mk[v] = true;
            }
        }
        int nc = 0;
        for (int i = 0; i < S; ++i)
            if (mk[i]) sd.idx[lvl - 1][nc++] = i;
        sd.cnt[lvl - 1] = nc;
    }
    return sd;
}

constexpr SetsData HS = compute_sets();     // host: grid sizing
__constant__ SetsData d_sets = compute_sets();  // device: row maps + nbr

constexpr int cdiv_c(int a, int b) { return (a + b - 1) / b; }

__device__ inline short f2bf(float f) {
    union { float f; unsigned u; } v; v.f = f;
    unsigned r = v.u + 0x7fffu + ((v.u >> 16) & 1u);
    return (short)(r >> 16);
}
__device__ inline float bf2f(short h) {
    union { unsigned u; float f; } v; v.u = ((unsigned)(unsigned short)h) << 16;
    return v.f;
}

// async global->LDS, 16B per lane, wave-uniform LDS base + lane*16
__device__ inline void gload_lds16(const void* g, void* l) {
    __builtin_amdgcn_global_load_lds(
        (const __attribute__((address_space(1))) void*)g,
        (__attribute__((address_space(3))) void*)l, 16, 0, 0);
}

// Staging map (both GEMM kernels), conflict-free + coalesced (verified r11:
// 0 bank conflicts): LDS 16B-chunk u encodes row=((u>>3)<<1)|((u>>2)&1),
// k-slot s=u&3 holding global kseg kg = s ^ ((u>>3)&3). Reader: rh=row>>1,
// s=lk^(rh&3), chunk=rh*8+(row&1)*4+s.
// Sparse rows: alvl/clvl >= 0 select d_sets.idx[lvl] (pos-major compact:
// compact m -> b=m&31, j=m>>5 clamped to cnt-1, orig row b*S+idx[j]).

// ---------------------------------------------------------------------------
// 128x128 bf16 MFMA GEMM, BK=32, double-buffered, counted vmcnt(4) pipeline.
// EPI: 0 f32; 1 f32+bias; 2 bf16; 3 bf16+bias+gelu; 4 bf16+bias;
//      5 bf16, v = acc*bias[gn]+bias2[gn] then ELU
// ---------------------------------------------------------------------------
template<int EPI>
__launch_bounds__(256, 4)
__global__ void mfma_gemm(const short* __restrict__ A, const short* __restrict__ Bt,
                          const float* __restrict__ bias, const float* __restrict__ bias2,
                          void* __restrict__ Cout, int Kd, int Nd,
                          int alvl, int clvl, int cnt) {
    __shared__ short As[2][128 * 32];
    __shared__ short Bs[2][128 * 32];
    int tid = threadIdx.x;
    int nwg  = gridDim.x * gridDim.y;
    int orig = blockIdx.y * gridDim.x + blockIdx.x;
    int qq = nwg >> 3, rr = nwg & 7;
    int xcd = orig & 7, idx = orig >> 3;
    int wgid = (xcd < rr ? xcd * (qq + 1) : rr * (qq + 1) + (xcd - rr) * qq) + idx;
    int m0 = (wgid / gridDim.x) * 128, n0 = (wgid % gridDim.x) * 128;

    int lane = tid & 63, wid = tid >> 6;
    int wm = wid >> 1, wn = wid & 1;
    int lr = lane & 15, lk = lane >> 4;

    size_t abase[2], bbase[2];
#pragma unroll
    for (int r = 0; r < 2; ++r) {
        int u = r * 256 + tid;
        int row = ((u >> 3) << 1) | ((u >> 2) & 1);
        int kg  = (u & 3) ^ ((u >> 3) & 3);
        int rm = m0 + row, ga;
        if (alvl >= 0) { int j = rm >> 5; if (j > cnt - 1) j = cnt - 1; ga = (rm & 31) * S + d_sets.idx[alvl][j]; }
        else ga = rm;
        abase[r] = (size_t)ga * Kd + kg * 8;
        bbase[r] = (size_t)(n0 + row) * Kd + kg * 8;
    }
    auto stage = [&](int buf, int k0) {
#pragma unroll
        for (int r = 0; r < 2; ++r) {
            short* la = As[buf] + (size_t)(r * 256 + wid * 64) * 8;
            short* lb = Bs[buf] + (size_t)(r * 256 + wid * 64) * 8;
            gload_lds16(A + abase[r] + k0, la);
            gload_lds16(Bt + bbase[r] + k0, lb);
        }
    };
    auto rd_off = [&](int row_) {
        int rh = row_ >> 1;
        int s  = lk ^ (rh & 3);
        return (size_t)(rh * 8 + (row_ & 1) * 4 + s) * 8;
    };

    float4v acc[4][4];
#pragma unroll
    for (int i = 0; i < 4; ++i)
#pragma unroll
        for (int j = 0; j < 4; ++j) acc[i][j] = 0;

    const int nt = Kd >> 5;
    stage(0, 0);
    for (int t = 0; t < nt; ++t) {
        int cur = t & 1;
        if (t + 1 < nt) {
            stage(cur ^ 1, (t + 1) * 32);
            asm volatile("s_waitcnt vmcnt(4)" ::: "memory");
        } else {
            asm volatile("s_waitcnt vmcnt(0)" ::: "memory");
        }
        __builtin_amdgcn_s_barrier();
        short8 af[4], bfv[4];
#pragma unroll
        for (int mi = 0; mi < 4; ++mi)
            af[mi] = *(const short8*)(As[cur] + rd_off(wm * 64 + mi * 16 + lr));
#pragma unroll
        for (int ni = 0; ni < 4; ++ni)
            bfv[ni] = *(const short8*)(Bs[cur] + rd_off(wn * 64 + ni * 16 + lr));
        __builtin_amdgcn_s_setprio(1);
#pragma unroll
        for (int mi = 0; mi < 4; ++mi)
#pragma unroll
            for (int ni = 0; ni < 4; ++ni)
                acc[mi][ni] = __builtin_amdgcn_mfma_f32_16x16x32_bf16(
                    af[mi], bfv[ni], acc[mi][ni], 0, 0, 0);
        __builtin_amdgcn_s_setprio(0);
        __builtin_amdgcn_s_barrier();
    }

#pragma unroll
    for (int mi = 0; mi < 4; ++mi) {
        int gmc = m0 + wm * 64 + mi * 16 + lk * 4;
#pragma unroll
        for (int ni = 0; ni < 4; ++ni) {
            int gn = n0 + wn * 64 + ni * 16 + lr;
            float bsv = (EPI == 1 || EPI == 3 || EPI == 4) ? bias[gn] : 0.0f;
            float sc = (EPI == 5) ? bias[gn]  : 0.0f;
            float sh = (EPI == 5) ? bias2[gn] : 0.0f;
#pragma unroll
            for (int e = 0; e < 4; ++e) {
                int rm = gmc + e, grow;
                if (clvl >= 0) { int j = rm >> 5; if (j > cnt - 1) j = cnt - 1; grow = (rm & 31) * S + d_sets.idx[clvl][j]; }
                else grow = rm;
                float v = acc[mi][ni][e] + bsv;
                if (EPI == 3) v = 0.5f * v * (1.0f + erff(v * 0.70710678118654752f));
                if (EPI == 5) { v = v * sc + sh; v = v > 0.0f ? v : (expf(v) - 1.0f); }
                if (EPI <= 1) ((float*)Cout)[(size_t)grow * Nd + gn] = v;
                else          ((short*)Cout)[(size_t)grow * Nd + gn] = f2bf(v);
            }
        }
    }
}

// ---------------------------------------------------------------------------
// 256x256 bf16 MFMA GEMM (wide-N shapes: FFN1, QKV). Same structure.
// ---------------------------------------------------------------------------
template<int EPI>
__launch_bounds__(512, 2)
__global__ void mfma_gemm256(const short* __restrict__ A, const short* __restrict__ Bt,
                             const float* __restrict__ bias, void* __restrict__ Cout,
                             int Kd, int Nd, int alvl, int clvl, int cnt) {
    __shared__ short As[2][256 * 32];
    __shared__ short Bs[2][256 * 32];
    int tid = threadIdx.x;
    int nwg  = gridDim.x * gridDim.y;
    int orig = blockIdx.y * gridDim.x + blockIdx.x;
    int qq = nwg >> 3, rr = nwg & 7;
    int xcd = orig & 7, idx = orig >> 3;
    int wgid = (xcd < rr ? xcd * (qq + 1) : rr * (qq + 1) + (xcd - rr) * qq) + idx;
    int m0 = (wgid / gridDim.x) * 256, n0 = (wgid % gridDim.x) * 256;

    int lane = tid & 63, wid = tid >> 6;
    int wm = wid >> 2, wn = wid & 3;
    int lr = lane & 15, lk = lane >> 4;

    size_t abase[2], bbase[2];
#pragma unroll
    for (int r = 0; r < 2; ++r) {
        int u = r * 512 + tid;
        int row = ((u >> 3) << 1) | ((u >> 2) & 1);
        int kg  = (u & 3) ^ ((u >> 3) & 3);
        int rm = m0 + row, ga;
        if (alvl >= 0) { int j = rm >> 5; if (j > cnt - 1) j = cnt - 1; ga = (rm & 31) * S + d_sets.idx[alvl][j]; }
        else ga = rm;
        abase[r] = (size_t)ga * Kd + kg * 8;
        bbase[r] = (size_t)(n0 + row) * Kd + kg * 8;
    }
    auto stage = [&](int buf, int k0) {
#pragma unroll
        for (int r = 0; r < 2; ++r) {
            short* la = As[buf] + (size_t)(r * 512 + wid * 64) * 8;
            short* lb = Bs[buf] + (size_t)(r * 512 + wid * 64) * 8;
            gload_lds16(A + abase[r] + k0, la);
            gload_lds16(Bt + bbase[r] + k0, lb);
        }
    };
    auto rd_off = [&](int row_) {
        int rh = row_ >> 1;
        int s  = lk ^ (rh & 3);
        return (size_t)(rh * 8 + (row_ & 1) * 4 + s) * 8;
    };

    float4v acc[8][4];
#pragma unroll
    for (int i = 0; i < 8; ++i)
#pragma unroll
        for (int j = 0; j < 4; ++j) acc[i][j] = 0;

    const int nt = Kd >> 5;
    stage(0, 0);
    for (int t = 0; t < nt; ++t) {
        int cur = t & 1;
        if (t + 1 < nt) {
            stage(cur ^ 1, (t + 1) * 32);
            asm volatile("s_waitcnt vmcnt(4)" ::: "memory");
        } else {
            asm volatile("s_waitcnt vmcnt(0)" ::: "memory");
        }
        __builtin_amdgcn_s_barrier();
        short8 af[8], bfv[4];
#pragma unroll
        for (int mi = 0; mi < 8; ++mi)
            af[mi] = *(const short8*)(As[cur] + rd_off(wm * 128 + mi * 16 + lr));
#pragma unroll
        for (int ni = 0; ni < 4; ++ni)
            bfv[ni] = *(const short8*)(Bs[cur] + rd_off(wn * 64 + ni * 16 + lr));
        __builtin_amdgcn_s_setprio(1);
#pragma unroll
        for (int mi = 0; mi < 8; ++mi)
#pragma unroll
            for (int ni = 0; ni < 4; ++ni)
                acc[mi][ni] = __builtin_amdgcn_mfma_f32_16x16x32_bf16(
                    af[mi], bfv[ni], acc[mi][ni], 0, 0, 0);
        __builtin_amdgcn_s_setprio(0);
        __builtin_amdgcn_s_barrier();
    }

#pragma unroll
    for (int mi = 0; mi < 8; ++mi) {
        int gmc = m0 + wm * 128 + mi * 16 + lk * 4;
#pragma unroll
        for (int ni = 0; ni < 4; ++ni) {
            int gn = n0 + wn * 64 + ni * 16 + lr;
            float bsv = (EPI == 1 || EPI == 3 || EPI == 4) ? bias[gn] : 0.0f;
#pragma unroll
            for (int e = 0; e < 4; ++e) {
                int rm = gmc + e, grow;
                if (clvl >= 0) { int j = rm >> 5; if (j > cnt - 1) j = cnt - 1; grow = (rm & 31) * S + d_sets.idx[clvl][j]; }
                else grow = rm;
                float v = acc[mi][ni][e] + bsv;
                if (EPI == 3) v = 0.5f * v * (1.0f + erff(v * 0.70710678118654752f));
                if (EPI <= 1) ((float*)Cout)[(size_t)grow * Nd + gn] = v;
                else          ((short*)Cout)[(size_t)grow * Nd + gn] = f2bf(v);
            }
        }
    }
}

// ---------------------------------------------------------------------------
// batched weight transpose+convert, 32x32 tiles, f32 W[Kd][Nd] -> bf16 Wt[Nd][Kd]
// ---------------------------------------------------------------------------
__device__ inline void wtrans_tile(const float* __restrict__ W, short* __restrict__ Wt,
                                   int Kd, int Nd, int n0, int k0, int tid) {
    __shared__ float tile[32][33];
    int tx = tid & 31, ty = tid >> 5; // ty 0..7
#pragma unroll
    for (int r = 0; r < 32; r += 8)
        tile[ty + r][tx] = W[(size_t)(k0 + ty + r) * Nd + n0 + tx];
    __syncthreads();
#pragma unroll
    for (int r = 0; r < 32; r += 8)
        Wt[(size_t)(n0 + ty + r) * Kd + k0 + tx] = f2bf(tile[tx][ty + r]);
}

__launch_bounds__(256)
__global__ void wtrans_qkvo(const float* __restrict__ wq, const float* __restrict__ wk,
                            const float* __restrict__ wv, const float* __restrict__ wo,
                            short* __restrict__ wqkvT, short* __restrict__ woT) {
    int z = blockIdx.z, l = z >> 2, part = z & 3;
    const float* src = (part == 0 ? wq : part == 1 ? wk : part == 2 ? wv : wo)
                       + (size_t)l * D * D;
    short* dst = (part < 3) ? wqkvT + (size_t)l * 3 * D * D + (size_t)part * D * D
                            : woT + (size_t)l * D * D;
    wtrans_tile(src, dst, D, D, blockIdx.x * 32, blockIdx.y * 32, threadIdx.x);
}

__launch_bounds__(256)
__global__ void wtrans_ffn(const float* __restrict__ w1, const float* __restrict__ w2,
                           short* __restrict__ w1T, short* __restrict__ w2T) {
    int z = blockIdx.z, l = z >> 1, part = z & 1;
    int nt = part ? blockIdx.y : blockIdx.x;
    int kt = part ? blockIdx.x : blockIdx.y;
    if (part == 0)
        wtrans_tile(w1 + (size_t)l * D * DFF, w1T + (size_t)l * DFF * D,
                    D, DFF, nt * 32, kt * 32, threadIdx.x);
    else
        wtrans_tile(w2 + (size_t)l * DFF * D, w2T + (size_t)l * D * DFF,
                    DFF, D, nt * 32, kt * 32, threadIdx.x);
}

__launch_bounds__(256)
__global__ void wtrans_one(const float* __restrict__ W, short* __restrict__ Wt,
                           int Kd, int Nd) {
    wtrans_tile(W, Wt, Kd, Nd, blockIdx.x * 32, blockIdx.y * 32, threadIdx.x);
}

// ---------------------------------------------------------------------------
// CSCM prep
// ---------------------------------------------------------------------------
__launch_bounds__(256)
__global__ void cscm_prep(const float* __restrict__ cw, const float* __restrict__ cb,
                          const float* __restrict__ bg, const float* __restrict__ bb,
                          short* __restrict__ cscmT, float* __restrict__ sc,
                          float* __restrict__ sh) {
    int idx = blockIdx.x * 256 + threadIdx.x;
    if (idx < 2 * DBOT * 512) {
        int l = idx >> 16;
        int rem = idx & 65535;
        int oc = rem >> 9, j = rem & 511;
        int r = j >> 7, c = j & 127;
        cscmT[idx] = f2bf(cw[(((size_t)l * DBOT + oc) * DBOT + c) * 4 + r]);
    }
    if (idx < 3 * DBOT) {
        sc[idx] = bg[idx];
        sh[idx] = cb[idx] * bg[idx] + bb[idx];
    }
}

// ---------------------------------------------------------------------------
// Embedding
// ---------------------------------------------------------------------------
__launch_bounds__(256)
__global__ void embed_kernel(const float* __restrict__ x_enc, const float* __restrict__ x_mark,
                             const float* __restrict__ cw, const float* __restrict__ tw,
                             const float* __restrict__ tb, float* __restrict__ emb,
                             short* __restrict__ emb_bf) {
    size_t idx = (size_t)blockIdx.x * 256 + threadIdx.x;
    if (idx >= (size_t)BB * L * D) return;
    int d = idx % D;
    int t = (idx / D) % L;
    int b = idx / ((size_t)D * L);
    float acc = tb[d];
#pragma unroll
    for (int w = 0; w < 3; ++w) {
        int s = t + w - 1;
        if (s < 0) s = L - 1;
        if (s >= L) s = 0;
        const float* xr = x_enc + ((size_t)b * L + s) * CIN;
        const float* wr = cw + (size_t)d * (CIN * 3) + w;
#pragma unroll
        for (int i = 0; i < CIN; ++i) acc += xr[i] * wr[i * 3];
    }
    int e = d & ~1;
    float div = expf(-(float)e * (logf(10000.0f) / (float)D));
    float arg = (float)t * div;
    acc += (d & 1) ? cosf(arg) : sinf(arg);
    const float* mr = x_mark + ((size_t)b * L + t) * MARK;
#pragma unroll
    for (int m = 0; m < MARK; ++m) acc += mr[m] * tw[m * D + d];
    emb[idx] = acc;
    emb_bf[idx] = f2bf(acc);
}

// ---------------------------------------------------------------------------
// CSCM conv level 3 (tiny)
// ---------------------------------------------------------------------------
__launch_bounds__(128)
__global__ void cscm_conv_bf16(const short* __restrict__ in, int inRowsPerB,
                               short* __restrict__ outp, const float* __restrict__ w,
                               const float* __restrict__ cb, const float* __restrict__ bng,
                               const float* __restrict__ bnb, int Lout) {
    int bid = blockIdx.x;
    int to = bid % Lout, b = bid / Lout;
    __shared__ float insh[4 * DBOT];
    int tid = threadIdx.x;
#pragma unroll
    for (int r = 0; r < 4; ++r)
        insh[r * DBOT + tid] = bf2f(in[((size_t)(b * inRowsPerB + to * 4 + r)) * DBOT + tid]);
    __syncthreads();
    float acc = cb[tid];
    const float* wr = w + (size_t)tid * (DBOT * 4);
    for (int c = 0; c < DBOT; ++c) {
#pragma unroll
        for (int r = 0; r < 4; ++r)
            acc += insh[r * DBOT + c] * wr[c * 4 + r];
    }
    acc = acc * bng[tid] + bnb[tid];
    outp[((size_t)(b * Lout + to)) * DBOT + tid] = f2bf(acc > 0.0f ? acc : (expf(acc) - 1.0f));
}

// ---------------------------------------------------------------------------
// concat pyramid outputs (bf16) -> csc [MCAT][128]
// ---------------------------------------------------------------------------
__launch_bounds__(256)
__global__ void concat_cs_kernel(const short* __restrict__ cs1, const short* __restrict__ cs2,
                                 const short* __restrict__ cs3, short* __restrict__ csc) {
    int idx = blockIdx.x * 256 + threadIdx.x;
    if (idx >= MCAT * DBOT) return;
    int m = idx >> 7, c = idx & 127;
    short v = 0;
    if (m < BB * LC) {
        int b = m / LC, t = m % LC;
        if (t < L1)           v = cs1[(size_t)(b * L1 + t) * DBOT + c];
        else if (t < L1 + L2) v = cs2[(size_t)(b * L2 + (t - L1)) * DBOT + c];
        else                  v = cs3[(size_t)(b * L3 + (t - L1 - L2)) * DBOT + c];
    }
    csc[idx] = v;
}

// ---------------------------------------------------------------------------
// sparse attention over active level: compact wave id = j*32+b;
// Q at orig (b, idx[lvl][j]); K/V at orig neighbor rows; Ob written COMPACT.
// ---------------------------------------------------------------------------
__launch_bounds__(256)
__global__ void attn_sparse_kernel(const short* __restrict__ QKV, short* __restrict__ Ob,
                                   int lvl, int cnt) {
    int wid  = blockIdx.x * 4 + (threadIdx.x >> 6);
    if (wid >= cnt * 32) return;
    int lane = threadIdx.x & 63;
    int b = wid & 31, j = wid >> 5;
    int i = d_sets.idx[lvl][j];
    const short8 qv = *(const short8*)(QKV + (size_t)(b * S + i) * 1536 + lane * 8);
    float qf[8];
#pragma unroll
    for (int e = 0; e < 8; ++e) qf[e] = bf2f(qv[e]);
    int nb[NMAX];
#pragma unroll
    for (int jj = 0; jj < NMAX; ++jj) nb[jj] = d_sets.nbr[i][jj];
    float sc[NMAX];
#pragma unroll
    for (int jj = 0; jj < NMAX; ++jj) {
        float s = -1e30f;
        if (nb[jj] >= 0) {
            const short8 kv = *(const short8*)(QKV + (size_t)(b * S + nb[jj]) * 1536 + 512 + lane * 8);
            s = 0.0f;
#pragma unroll
            for (int e = 0; e < 8; ++e) s += qf[e] * bf2f(kv[e]);
            s += __shfl_xor(s, 1); s += __shfl_xor(s, 2); s += __shfl_xor(s, 4);
            s *= 0.125f;
        }
        sc[jj] = s;
    }
    float mx = sc[0];
#pragma unroll
    for (int jj = 1; jj < NMAX; ++jj) mx = fmaxf(mx, sc[jj]);
    float sum = 0.0f;
    float accv[8] = {};
#pragma unroll
    for (int jj = 0; jj < NMAX; ++jj) {
        float p = expf(sc[jj] - mx);
        sum += p;
        if (nb[jj] >= 0) {
            const short8 vv = *(const short8*)(QKV + (size_t)(b * S + nb[jj]) * 1536 + 1024 + lane * 8);
#pragma unroll
            for (int e = 0; e < 8; ++e) accv[e] += p * bf2f(vv[e]);
        }
    }
    float inv = 1.0f / sum;
    short8 ov;
#pragma unroll
    for (int e = 0; e < 8; ++e) ov[e] = f2bf(accv[e] * inv);
    *(short8*)(Ob + (size_t)wid * D + lane * 8) = ov;
}

// ---------------------------------------------------------------------------
// concat(emb, coarse) + LayerNorm -> seq (f32) + seq_bf (bf16), all rows
// ---------------------------------------------------------------------------
__launch_bounds__(256)
__global__ void concat_ln_kernel(const float* __restrict__ emb, const float* __restrict__ coarse,
                                 const float* __restrict__ g, const float* __restrict__ bta,
                                 float* __restrict__ seq, short* __restrict__ seq_bf) {
    int row = blockIdx.x;
    int b = row / S, s = row % S;
    const float* src = (s < L) ? emb + ((size_t)b * L + s) * D
                               : coarse + ((size_t)b * LC + (s - L)) * D;
    __shared__ float red[256];
    int tid = threadIdx.x;
    float x0 = src[tid], x1 = src[tid + 256];
    red[tid] = x0 + x1;
    __syncthreads();
    for (int t = 128; t > 0; t >>= 1) { if (tid < t) red[tid] += red[tid + t]; __syncthreads(); }
    float mu = red[0] * (1.0f / D);
    __syncthreads();
    float d0 = x0 - mu, d1 = x1 - mu;
    red[tid] = d0 * d0 + d1 * d1;
    __syncthreads();
    for (int t = 128; t > 0; t >>= 1) { if (tid < t) red[tid] += red[tid + t]; __syncthreads(); }
    float rstd = rsqrtf(red[0] * (1.0f / D) + 1e-5f);
    float v0 = d0 * rstd * g[tid]       + bta[tid];
    float v1 = d1 * rstd * g[tid + 256] + bta[tid + 256];
    float* dst = seq + (size_t)row * D;
    dst[tid] = v0; dst[tid + 256] = v1;
    short* dbf = seq_bf + (size_t)row * D;
    dbf[tid] = f2bf(v0); dbf[tid + 256] = f2bf(v1);
}

// ---------------------------------------------------------------------------
// indexed residual LN: compact row -> orig row b*S+idx[lvl][j]; exact grid
// ---------------------------------------------------------------------------
__launch_bounds__(256)
__global__ void add_ln_idx(float* __restrict__ seq, const short* __restrict__ add,
                           const float* __restrict__ g, const float* __restrict__ bta,
                           short* __restrict__ seq_bf, int lvl) {
    int row = blockIdx.x;
    int b = row & 31, j = row >> 5;
    int orig = b * S + d_sets.idx[lvl][j];
    __shared__ float red[256];
    int tid = threadIdx.x;
    float* srow = seq + (size_t)orig * D;
    const short* arow = add + (size_t)row * D;
    float x0 = srow[tid] + bf2f(arow[tid]);
    float x1 = srow[tid + 256] + bf2f(arow[tid + 256]);
    red[tid] = x0 + x1;
    __syncthreads();
    for (int t = 128; t > 0; t >>= 1) { if (tid < t) red[tid] += red[tid + t]; __syncthreads(); }
    float mu = red[0] * (1.0f / D);
    __syncthreads();
    float d0 = x0 - mu, d1 = x1 - mu;
    red[tid] = d0 * d0 + d1 * d1;
    __syncthreads();
    for (int t = 128; t > 0; t >>= 1) { if (tid < t) red[tid] += red[tid + t]; __syncthreads(); }
    float rstd = rsqrtf(red[0] * (1.0f / D) + 1e-5f);
    float v0 = d0 * rstd * g[tid]       + bta[tid];
    float v1 = d1 * rstd * g[tid + 256] + bta[tid + 256];
    srow[tid] = v0; srow[tid + 256] = v1;
    short* dbf = seq_bf + (size_t)orig * D;
    dbf[tid] = f2bf(v0); dbf[tid + 256] = f2bf(v1);
}

// ---------------------------------------------------------------------------
// prediction head, split-K with fused gather
// ---------------------------------------------------------------------------
__launch_bounds__(256)
__global__ void pred_kernel(const float* __restrict__ seq, const float* __restrict__ w,
                            float* __restrict__ part) {
    __shared__ float es[32][257];
    __shared__ float wsm[256][8];
    int tid = threadIdx.x;
    int n0 = blockIdx.x * 8;
    int ks = blockIdx.y;
    int k0 = ks * 256;
    const int pos[4] = {335, 419, 440, 445};
    int seg = ks >> 1;
    int dbase = (ks & 1) * 256;
#pragma unroll 8
    for (int r = 0; r < 32; ++r)
        es[r][tid] = seq[((size_t)r * S + pos[seg]) * D + dbase + tid];
#pragma unroll
    for (int e = 0; e < 8; ++e)
        wsm[tid][e] = w[(size_t)(k0 + tid) * PRED_N + n0 + e];
    __syncthreads();
    int b = tid >> 3, nn = tid & 7;
    float acc = 0.0f;
#pragma unroll 8
    for (int kk = 0; kk < 256; ++kk)
        acc += es[b][kk] * wsm[kk][nn];
    part[(size_t)ks * (BB * PRED_N) + (size_t)b * PRED_N + n0 + nn] = acc;
}

__launch_bounds__(256)
__global__ void pred_reduce_kernel(const float* __restrict__ part, float* __restrict__ out) {
    int idx = blockIdx.x * 256 + threadIdx.x;
    if (idx >= BB * PRED_N) return;
    float s = 0.0f;
#pragma unroll
    for (int k = 0; k < 8; ++k) s += part[(size_t)k * (BB * PRED_N) + idx];
    out[idx] = s;
}

// ---------------------------------------------------------------------------
extern "C" void kernel_launch(void* const* d_in, const int* in_sizes, int n_in,
                              void* d_out, int out_size, void* d_ws, size_t ws_size,
                              hipStream_t stream) {
    const float* x_enc      = (const float*)d_in[0];
    const float* x_mark_enc = (const float*)d_in[1];
    const float* conv_embed_w = (const float*)d_in[4];
    const float* time_w  = (const float*)d_in[5];
    const float* time_b  = (const float*)d_in[6];
    const float* down_w  = (const float*)d_in[7];
    const float* down_b  = (const float*)d_in[8];
    const float* cscm_w  = (const float*)d_in[9];
    const float* cscm_b  = (const float*)d_in[10];
    const float* bn_g    = (const float*)d_in[11];
    const float* bn_b    = (const float*)d_in[12];
    const float* up_w    = (const float*)d_in[13];
    const float* up_b    = (const float*)d_in[14];
    const float* cln_g   = (const float*)d_in[15];
    const float* cln_b   = (const float*)d_in[16];
    const float* wq      = (const float*)d_in[17];
    const float* wk      = (const float*)d_in[18];
    const float* wv      = (const float*)d_in[19];
    const float* wo      = (const float*)d_in[20];
    const float* ln1_g   = (const float*)d_in[21];
    const float* ln1_b   = (const float*)d_in[22];
    const float* ffn_w1  = (const float*)d_in[23];
    const float* ffn_b1  = (const float*)d_in[24];
    const float* ffn_w2  = (const float*)d_in[25];
    const float* ffn_b2  = (const float*)d_in[26];
    const float* ln2_g   = (const float*)d_in[27];
    const float* ln2_b   = (const float*)d_in[28];
    const float* pred_w  = (const float*)d_in[29];
    float* out = (float*)d_out;

    // ---- workspace layout (bytes, 256-aligned) ----
    char* w8 = (char*)d_ws;
    size_t off = 0;
    auto alloc = [&](size_t bytes) {
        void* p = w8 + off;
        off = (off + bytes + 255) & ~(size_t)255;
        return p;
    };
    float* emb    = (float*)alloc((size_t)BB * L * D * 4);
    short* emb_bf = (short*)alloc((size_t)BB * L * D * 2);
    short* xd_bf  = (short*)alloc((size_t)BB * L * DBOT * 2);
    short* cs1_bf = (short*)alloc((size_t)MCONV2P * 512 * 2);
    short* cs2_bf = (short*)alloc((size_t)MCONV2P * DBOT * 2);
    short* cs3_bf = (short*)alloc((size_t)BB * L3 * DBOT * 2);
    short* csc_bf = (short*)alloc((size_t)MCAT * DBOT * 2);
    float* coarse = (float*)alloc((size_t)MCAT * D * 4);
    float* seq    = (float*)alloc((size_t)BB * S * D * 4);
    short* T1     = (short*)alloc((size_t)MP * D * 2);
    float* part   = (float*)alloc((size_t)8 * BB * PRED_N * 4);
    short* seq_bf = (short*)alloc((size_t)MP * D * 2);
    short* QKV    = (short*)alloc((size_t)MP * 3 * D * 2);  // + Ob contiguous =
    short* Ob     = (short*)alloc((size_t)MP * D * 2);      // hidden region
    short* hidden = QKV;
    short* wqkvT  = (short*)alloc((size_t)NLAYER * 3 * D * D * 2);
    short* woT    = (short*)alloc((size_t)NLAYER * D * D * 2);
    short* w1T    = (short*)alloc((size_t)NLAYER * DFF * D * 2);
    short* w2T    = (short*)alloc((size_t)NLAYER * D * DFF * 2);
    short* downT  = (short*)alloc((size_t)DBOT * D * 2);
    short* upT    = (short*)alloc((size_t)D * DBOT * 2);
    short* cscmT  = (short*)alloc((size_t)2 * DBOT * 512 * 2);
    float* csc_sc = (float*)alloc((size_t)3 * DBOT * 4);
    float* csc_sh = (float*)alloc((size_t)3 * DBOT * 4);
    (void)ws_size; (void)in_sizes; (void)n_in; (void)out_size;

    const int rowsL = BB * L;   // 10752 = 84*128
    const int rowsS = BB * S;   // 14272
    dim3 blk(256);

    // 0. weight convert+transpose
    wtrans_qkvo<<<dim3(16, 16, 4 * NLAYER), blk, 0, stream>>>(wq, wk, wv, wo, wqkvT, woT);
    wtrans_ffn<<<dim3(64, 16, 2 * NLAYER), blk, 0, stream>>>(ffn_w1, ffn_w2, w1T, w2T);
    wtrans_one<<<dim3(DBOT / 32, D / 32), blk, 0, stream>>>(down_w, downT, D, DBOT);
    wtrans_one<<<dim3(D / 32, DBOT / 32), blk, 0, stream>>>(up_w, upT, DBOT, D);
    cscm_prep<<<dim3((2 * DBOT * 512 + 255) / 256), blk, 0, stream>>>(
        cscm_w, cscm_b, bn_g, bn_b, cscmT, csc_sc, csc_sh);
    // 1. embedding
    embed_kernel<<<dim3(((size_t)BB * L * D + 255) / 256), blk, 0, stream>>>(
        x_enc, x_mark_enc, conv_embed_w, time_w, time_b, emb, emb_bf);
    // 2. down projection -> bf16
    mfma_gemm<4><<<dim3(1, rowsL / 128), blk, 0, stream>>>(
        emb_bf, downT, down_b, nullptr, xd_bf, D, DBOT, -1, -1, 0);
    // 3. CSCM pyramid
    mfma_gemm<5><<<dim3(1, MCONV1 / 128), blk, 0, stream>>>(
        xd_bf, cscmT, csc_sc, csc_sh, cs1_bf, 512, DBOT, -1, -1, 0);
    mfma_gemm<5><<<dim3(1, MCONV2P / 128), blk, 0, stream>>>(
        cs1_bf, cscmT + (size_t)DBOT * 512, csc_sc + DBOT, csc_sh + DBOT,
        cs2_bf, 512, DBOT, -1, -1, 0);
    cscm_conv_bf16<<<dim3(BB * L3), dim3(DBOT), 0, stream>>>(
        cs2_bf, L2, cs3_bf, cscm_w + 2 * DBOT * DBOT * 4,
        cscm_b + 2 * DBOT, bn_g + 2 * DBOT, bn_b + 2 * DBOT, L3);
    // 4. up projection
    concat_cs_kernel<<<dim3((MCAT * DBOT + 255) / 256), blk, 0, stream>>>(
        cs1_bf, cs2_bf, cs3_bf, csc_bf);
    mfma_gemm<1><<<dim3(D / 128, MCAT / 128), blk, 0, stream>>>(
        csc_bf, upT, up_b, nullptr, coarse, DBOT, D, -1, -1, 0);
    // 5. concat + LN (all rows)
    concat_ln_kernel<<<dim3(rowsS), blk, 0, stream>>>(emb, coarse, cln_g, cln_b, seq, seq_bf);

    // 6. encoder layers (compile-time sparse active sets; grids exact)
    for (int l = 0; l < NLAYER; ++l) {
        const int inLvl = l, outLvl = l + 1;
        const int inCnt  = HS.cnt[l];
        const int outCnt = HS.cnt[l + 1];
        mfma_gemm256<2><<<dim3(3 * D / 256, cdiv_c(1, 1) * ((inCnt * 32 + 255) / 256)),
                          dim3(512), 0, stream>>>(
            seq_bf, wqkvT + (size_t)l * 3 * D * D, nullptr, QKV, D, 3 * D,
            inLvl, inLvl, inCnt);
        attn_sparse_kernel<<<dim3(outCnt * 8), blk, 0, stream>>>(
            QKV, Ob, outLvl, outCnt);
        mfma_gemm<2><<<dim3(D / 128, (outCnt * 32 + 127) / 128), blk, 0, stream>>>(
            Ob, woT + (size_t)l * D * D, nullptr, nullptr, T1, D, D,
            -1, -1, 0);
        add_ln_idx<<<dim3(outCnt * 32), blk, 0, stream>>>(
            seq, T1, ln1_g + (size_t)l * D, ln1_b + (size_t)l * D, seq_bf, outLvl);
        mfma_gemm256<3><<<dim3(DFF / 256, (outCnt * 32 + 255) / 256), dim3(512), 0, stream>>>(
            seq_bf, w1T + (size_t)l * DFF * D, ffn_b1 + (size_t)l * DFF, hidden, D, DFF,
            outLvl, -1, outCnt);
        mfma_gemm<4><<<dim3(D / 128, (outCnt * 32 + 127) / 128), blk, 0, stream>>>(
            hidden, w2T + (size_t)l * D * DFF, ffn_b2 + (size_t)l * D, nullptr, T1, DFF, D,
            -1, -1, 0);
        add_ln_idx<<<dim3(outCnt * 32), blk, 0, stream>>>(
            seq, T1, ln2_g + (size_t)l * D, ln2_b + (size_t)l * D, seq_bf, outLvl);
    }

    // 7. prediction head (split-K, gather fused) + reduce
    pred_kernel<<<dim3(PRED_N / 8, 8), blk, 0, stream>>>(seq, pred_w, part);
    pred_reduce_kernel<<<dim3((BB * PRED_N + 255) / 256), blk, 0, stream>>>(part, out);
}

// Round 14
// 613.597 us; speedup vs baseline: 1.4769x; 1.0071x over previous
//
#include <hip/hip_runtime.h>
#include <math.h>

// ---- problem constants ----
constexpr int BB   = 32;    // batch
constexpr int L    = 336;   // seq_len
constexpr int CIN  = 7;
constexpr int MARK = 4;
constexpr int D    = 512;   // d_model
constexpr int DFF  = 2048;
constexpr int NH   = 8;
constexpr int HD   = 64;    // dk = dv
constexpr int S    = 446;   // 336+84+21+5
constexpr int DBOT = 128;
constexpr int L1 = 84, L2 = 21, L3 = 5;
constexpr int LC = 110;     // 84+21+5
constexpr int NLAYER = 3;
constexpr int PRED_N = 672; // 96*7
constexpr int MP   = 14336; // BB*S padded
constexpr int NMAX = 12;    // max sparse neighbors (real max 10)
constexpr int MCONV1 = BB * L1;          // 2688 = 21*128 (exact)
constexpr int MCONV2P = 768;             // BB*L2=672 padded to 6*128
constexpr int MCAT  = 3584;              // BB*LC=3520 padded to 28*128

using short8  = __attribute__((ext_vector_type(8))) short;
using float4v = __attribute__((ext_vector_type(4))) float;

// ---------------------------------------------------------------------------
// COMPILE-TIME pyramid structure: neighbor lists + active sets.
// A3 = gather positions {335,419,440,445}; A_{l-1} = U nbr(A_l), sorted.
// Layer l (0-based): QKV at idx[l] (cnt[l]), attn/Oproj/LN/FFN at idx[l+1].
// ---------------------------------------------------------------------------
struct SetsData {
    int nbr[S][NMAX];
    int idx[4][S];
    int cnt[4];
};

constexpr SetsData compute_sets() {
    SetsData sd{};
    constexpr int sizes[4]  = {336, 84, 21, 5};
    constexpr int starts[4] = {0, 336, 420, 441};
    for (int i = 0; i < S; ++i) {
        int li = 0, pi = i;
        if (i < 336)      { li = 0; pi = i; }
        else if (i < 420) { li = 1; pi = i - 336; }
        else if (i < 441) { li = 2; pi = i - 420; }
        else              { li = 3; pi = i - 441; }
        int cnt = 0;
        for (int d = -2; d <= 2; ++d) {
            int q = pi + d;
            if (q >= 0 && q < sizes[li]) sd.nbr[i][cnt++] = starts[li] + q;
        }
        if (li > 0) {
            int lo = pi * 4;
            int hi = (pi == sizes[li] - 1) ? sizes[li - 1] : (pi + 1) * 4;
            for (int c = lo; c < hi; ++c) sd.nbr[i][cnt++] = starts[li - 1] + c;
        }
        if (li < 3) {
            int q = pi >> 2;
            if (q > sizes[li + 1] - 1) q = sizes[li + 1] - 1;
            sd.nbr[i][cnt++] = starts[li + 1] + q;
        }
        for (int j = cnt; j < NMAX; ++j) sd.nbr[i][j] = -1;
    }
    sd.cnt[3] = 4;
    sd.idx[3][0] = 335; sd.idx[3][1] = 419; sd.idx[3][2] = 440; sd.idx[3][3] = 445;
    for (int lvl = 3; lvl >= 1; --lvl) {
        bool mk[S] = {};
        for (int k = 0; k < sd.cnt[lvl]; ++k) {
            int i = sd.idx[lvl][k];
            for (int t = 0; t < NMAX; ++t) {
                int v = sd.nbr[i][t];
                if (v >= 0) mk[v] = true;
            }
        }
        int nc = 0;
        for (int i = 0; i < S; ++i)
            if (mk[i]) sd.idx[lvl - 1][nc++] = i;
        sd.cnt[lvl - 1] = nc;
    }
    return sd;
}

constexpr SetsData HS = compute_sets();         // host: grid sizing
__constant__ SetsData d_sets = compute_sets();  // device: row maps + nbr

__device__ inline short f2bf(float f) {
    union { float f; unsigned u; } v; v.f = f;
    unsigned r = v.u + 0x7fffu + ((v.u >> 16) & 1u);
    return (short)(r >> 16);
}
__device__ inline float bf2f(short h) {
    union { unsigned u; float f; } v; v.u = ((unsigned)(unsigned short)h) << 16;
    return v.f;
}

// async global->LDS, 16B per lane, wave-uniform LDS base + lane*16
__device__ inline void gload_lds16(const void* g, void* l) {
    __builtin_amdgcn_global_load_lds(
        (const __attribute__((address_space(1))) void*)g,
        (__attribute__((address_space(3))) void*)l, 16, 0, 0);
}

// Staging map (both GEMM kernels), conflict-free + coalesced (verified r11:
// 0 bank conflicts): LDS 16B-chunk u encodes row=((u>>3)<<1)|((u>>2)&1),
// k-slot s=u&3 holding global kseg kg = s ^ ((u>>3)&3). Reader: rh=row>>1,
// s=lk^(rh&3), chunk=rh*8+(row&1)*4+s.
// Sparse rows: alvl/clvl >= 0 select d_sets.idx[lvl] (pos-major compact:
// compact m -> b=m&31, j=m>>5 clamped to cnt-1, orig row b*S+idx[j]).

// ---------------------------------------------------------------------------
// 128x128 bf16 MFMA GEMM, BK=32, double-buffered, counted vmcnt(4) pipeline.
// EPI: 0 f32; 1 f32+bias; 2 bf16; 3 bf16+bias+gelu; 4 bf16+bias;
//      5 bf16, v = acc*bias[gn]+bias2[gn] then ELU
// ---------------------------------------------------------------------------
template<int EPI>
__launch_bounds__(256, 4)
__global__ void mfma_gemm(const short* __restrict__ A, const short* __restrict__ Bt,
                          const float* __restrict__ bias, const float* __restrict__ bias2,
                          void* __restrict__ Cout, int Kd, int Nd,
                          int alvl, int clvl, int cnt) {
    __shared__ short As[2][128 * 32];
    __shared__ short Bs[2][128 * 32];
    int tid = threadIdx.x;
    int nwg  = gridDim.x * gridDim.y;
    int orig = blockIdx.y * gridDim.x + blockIdx.x;
    int qq = nwg >> 3, rr = nwg & 7;
    int xcd = orig & 7, idx = orig >> 3;
    int wgid = (xcd < rr ? xcd * (qq + 1) : rr * (qq + 1) + (xcd - rr) * qq) + idx;
    int m0 = (wgid / gridDim.x) * 128, n0 = (wgid % gridDim.x) * 128;

    int lane = tid & 63, wid = tid >> 6;
    int wm = wid >> 1, wn = wid & 1;
    int lr = lane & 15, lk = lane >> 4;

    size_t abase[2], bbase[2];
#pragma unroll
    for (int r = 0; r < 2; ++r) {
        int u = r * 256 + tid;
        int row = ((u >> 3) << 1) | ((u >> 2) & 1);
        int kg  = (u & 3) ^ ((u >> 3) & 3);
        int rm = m0 + row, ga;
        if (alvl >= 0) { int j = rm >> 5; if (j > cnt - 1) j = cnt - 1; ga = (rm & 31) * S + d_sets.idx[alvl][j]; }
        else ga = rm;
        abase[r] = (size_t)ga * Kd + kg * 8;
        bbase[r] = (size_t)(n0 + row) * Kd + kg * 8;
    }
    auto stage = [&](int buf, int k0) {
#pragma unroll
        for (int r = 0; r < 2; ++r) {
            short* la = As[buf] + (size_t)(r * 256 + wid * 64) * 8;
            short* lb = Bs[buf] + (size_t)(r * 256 + wid * 64) * 8;
            gload_lds16(A + abase[r] + k0, la);
            gload_lds16(Bt + bbase[r] + k0, lb);
        }
    };
    auto rd_off = [&](int row_) {
        int rh = row_ >> 1;
        int s  = lk ^ (rh & 3);
        return (size_t)(rh * 8 + (row_ & 1) * 4 + s) * 8;
    };

    float4v acc[4][4];
#pragma unroll
    for (int i = 0; i < 4; ++i)
#pragma unroll
        for (int j = 0; j < 4; ++j) acc[i][j] = 0;

    const int nt = Kd >> 5;
    stage(0, 0);
    for (int t = 0; t < nt; ++t) {
        int cur = t & 1;
        if (t + 1 < nt) {
            stage(cur ^ 1, (t + 1) * 32);
            asm volatile("s_waitcnt vmcnt(4)" ::: "memory");
        } else {
            asm volatile("s_waitcnt vmcnt(0)" ::: "memory");
        }
        __builtin_amdgcn_s_barrier();
        short8 af[4], bfv[4];
#pragma unroll
        for (int mi = 0; mi < 4; ++mi)
            af[mi] = *(const short8*)(As[cur] + rd_off(wm * 64 + mi * 16 + lr));
#pragma unroll
        for (int ni = 0; ni < 4; ++ni)
            bfv[ni] = *(const short8*)(Bs[cur] + rd_off(wn * 64 + ni * 16 + lr));
        __builtin_amdgcn_s_setprio(1);
#pragma unroll
        for (int mi = 0; mi < 4; ++mi)
#pragma unroll
            for (int ni = 0; ni < 4; ++ni)
                acc[mi][ni] = __builtin_amdgcn_mfma_f32_16x16x32_bf16(
                    af[mi], bfv[ni], acc[mi][ni], 0, 0, 0);
        __builtin_amdgcn_s_setprio(0);
        __builtin_amdgcn_s_barrier();
    }

#pragma unroll
    for (int mi = 0; mi < 4; ++mi) {
        int gmc = m0 + wm * 64 + mi * 16 + lk * 4;
#pragma unroll
        for (int ni = 0; ni < 4; ++ni) {
            int gn = n0 + wn * 64 + ni * 16 + lr;
            float bsv = (EPI == 1 || EPI == 3 || EPI == 4) ? bias[gn] : 0.0f;
            float sc = (EPI == 5) ? bias[gn]  : 0.0f;
            float sh = (EPI == 5) ? bias2[gn] : 0.0f;
#pragma unroll
            for (int e = 0; e < 4; ++e) {
                int rm = gmc + e, grow;
                if (clvl >= 0) { int j = rm >> 5; if (j > cnt - 1) j = cnt - 1; grow = (rm & 31) * S + d_sets.idx[clvl][j]; }
                else grow = rm;
                float v = acc[mi][ni][e] + bsv;
                if (EPI == 3) v = 0.5f * v * (1.0f + erff(v * 0.70710678118654752f));
                if (EPI == 5) { v = v * sc + sh; v = v > 0.0f ? v : (expf(v) - 1.0f); }
                if (EPI <= 1) ((float*)Cout)[(size_t)grow * Nd + gn] = v;
                else          ((short*)Cout)[(size_t)grow * Nd + gn] = f2bf(v);
            }
        }
    }
}

// ---------------------------------------------------------------------------
// 256x256 bf16 MFMA GEMM (wide-N shapes: FFN1, QKV). Same structure.
// ---------------------------------------------------------------------------
template<int EPI>
__launch_bounds__(512, 2)
__global__ void mfma_gemm256(const short* __restrict__ A, const short* __restrict__ Bt,
                             const float* __restrict__ bias, void* __restrict__ Cout,
                             int Kd, int Nd, int alvl, int clvl, int cnt) {
    __shared__ short As[2][256 * 32];
    __shared__ short Bs[2][256 * 32];
    int tid = threadIdx.x;
    int nwg  = gridDim.x * gridDim.y;
    int orig = blockIdx.y * gridDim.x + blockIdx.x;
    int qq = nwg >> 3, rr = nwg & 7;
    int xcd = orig & 7, idx = orig >> 3;
    int wgid = (xcd < rr ? xcd * (qq + 1) : rr * (qq + 1) + (xcd - rr) * qq) + idx;
    int m0 = (wgid / gridDim.x) * 256, n0 = (wgid % gridDim.x) * 256;

    int lane = tid & 63, wid = tid >> 6;
    int wm = wid >> 2, wn = wid & 3;
    int lr = lane & 15, lk = lane >> 4;

    size_t abase[2], bbase[2];
#pragma unroll
    for (int r = 0; r < 2; ++r) {
        int u = r * 512 + tid;
        int row = ((u >> 3) << 1) | ((u >> 2) & 1);
        int kg  = (u & 3) ^ ((u >> 3) & 3);
        int rm = m0 + row, ga;
        if (alvl >= 0) { int j = rm >> 5; if (j > cnt - 1) j = cnt - 1; ga = (rm & 31) * S + d_sets.idx[alvl][j]; }
        else ga = rm;
        abase[r] = (size_t)ga * Kd + kg * 8;
        bbase[r] = (size_t)(n0 + row) * Kd + kg * 8;
    }
    auto stage = [&](int buf, int k0) {
#pragma unroll
        for (int r = 0; r < 2; ++r) {
            short* la = As[buf] + (size_t)(r * 512 + wid * 64) * 8;
            short* lb = Bs[buf] + (size_t)(r * 512 + wid * 64) * 8;
            gload_lds16(A + abase[r] + k0, la);
            gload_lds16(Bt + bbase[r] + k0, lb);
        }
    };
    auto rd_off = [&](int row_) {
        int rh = row_ >> 1;
        int s  = lk ^ (rh & 3);
        return (size_t)(rh * 8 + (row_ & 1) * 4 + s) * 8;
    };

    float4v acc[8][4];
#pragma unroll
    for (int i = 0; i < 8; ++i)
#pragma unroll
        for (int j = 0; j < 4; ++j) acc[i][j] = 0;

    const int nt = Kd >> 5;
    stage(0, 0);
    for (int t = 0; t < nt; ++t) {
        int cur = t & 1;
        if (t + 1 < nt) {
            stage(cur ^ 1, (t + 1) * 32);
            asm volatile("s_waitcnt vmcnt(4)" ::: "memory");
        } else {
            asm volatile("s_waitcnt vmcnt(0)" ::: "memory");
        }
        __builtin_amdgcn_s_barrier();
        short8 af[8], bfv[4];
#pragma unroll
        for (int mi = 0; mi < 8; ++mi)
            af[mi] = *(const short8*)(As[cur] + rd_off(wm * 128 + mi * 16 + lr));
#pragma unroll
        for (int ni = 0; ni < 4; ++ni)
            bfv[ni] = *(const short8*)(Bs[cur] + rd_off(wn * 64 + ni * 16 + lr));
        __builtin_amdgcn_s_setprio(1);
#pragma unroll
        for (int mi = 0; mi < 8; ++mi)
#pragma unroll
            for (int ni = 0; ni < 4; ++ni)
                acc[mi][ni] = __builtin_amdgcn_mfma_f32_16x16x32_bf16(
                    af[mi], bfv[ni], acc[mi][ni], 0, 0, 0);
        __builtin_amdgcn_s_setprio(0);
        __builtin_amdgcn_s_barrier();
    }

#pragma unroll
    for (int mi = 0; mi < 8; ++mi) {
        int gmc = m0 + wm * 128 + mi * 16 + lk * 4;
#pragma unroll
        for (int ni = 0; ni < 4; ++ni) {
            int gn = n0 + wn * 64 + ni * 16 + lr;
            float bsv = (EPI == 1 || EPI == 3 || EPI == 4) ? bias[gn] : 0.0f;
#pragma unroll
            for (int e = 0; e < 4; ++e) {
                int rm = gmc + e, grow;
                if (clvl >= 0) { int j = rm >> 5; if (j > cnt - 1) j = cnt - 1; grow = (rm & 31) * S + d_sets.idx[clvl][j]; }
                else grow = rm;
                float v = acc[mi][ni][e] + bsv;
                if (EPI == 3) v = 0.5f * v * (1.0f + erff(v * 0.70710678118654752f));
                if (EPI <= 1) ((float*)Cout)[(size_t)grow * Nd + gn] = v;
                else          ((short*)Cout)[(size_t)grow * Nd + gn] = f2bf(v);
            }
        }
    }
}

// ---------------------------------------------------------------------------
// batched weight transpose+convert, 32x32 tiles, f32 W[Kd][Nd] -> bf16 Wt[Nd][Kd]
// ---------------------------------------------------------------------------
__device__ inline void wtrans_tile(const float* __restrict__ W, short* __restrict__ Wt,
                                   int Kd, int Nd, int n0, int k0, int tid) {
    __shared__ float tile[32][33];
    int tx = tid & 31, ty = tid >> 5; // ty 0..7
#pragma unroll
    for (int r = 0; r < 32; r += 8)
        tile[ty + r][tx] = W[(size_t)(k0 + ty + r) * Nd + n0 + tx];
    __syncthreads();
#pragma unroll
    for (int r = 0; r < 32; r += 8)
        Wt[(size_t)(n0 + ty + r) * Kd + k0 + tx] = f2bf(tile[tx][ty + r]);
}

__launch_bounds__(256)
__global__ void wtrans_qkvo(const float* __restrict__ wq, const float* __restrict__ wk,
                            const float* __restrict__ wv, const float* __restrict__ wo,
                            short* __restrict__ wqkvT, short* __restrict__ woT) {
    int z = blockIdx.z, l = z >> 2, part = z & 3;
    const float* src = (part == 0 ? wq : part == 1 ? wk : part == 2 ? wv : wo)
                       + (size_t)l * D * D;
    short* dst = (part < 3) ? wqkvT + (size_t)l * 3 * D * D + (size_t)part * D * D
                            : woT + (size_t)l * D * D;
    wtrans_tile(src, dst, D, D, blockIdx.x * 32, blockIdx.y * 32, threadIdx.x);
}

__launch_bounds__(256)
__global__ void wtrans_ffn(const float* __restrict__ w1, const float* __restrict__ w2,
                           short* __restrict__ w1T, short* __restrict__ w2T) {
    int z = blockIdx.z, l = z >> 1, part = z & 1;
    int nt = part ? blockIdx.y : blockIdx.x;
    int kt = part ? blockIdx.x : blockIdx.y;
    if (part == 0)
        wtrans_tile(w1 + (size_t)l * D * DFF, w1T + (size_t)l * DFF * D,
                    D, DFF, nt * 32, kt * 32, threadIdx.x);
    else
        wtrans_tile(w2 + (size_t)l * DFF * D, w2T + (size_t)l * D * DFF,
                    DFF, D, nt * 32, kt * 32, threadIdx.x);
}

__launch_bounds__(256)
__global__ void wtrans_one(const float* __restrict__ W, short* __restrict__ Wt,
                           int Kd, int Nd) {
    wtrans_tile(W, Wt, Kd, Nd, blockIdx.x * 32, blockIdx.y * 32, threadIdx.x);
}

// ---------------------------------------------------------------------------
// CSCM prep
// ---------------------------------------------------------------------------
__launch_bounds__(256)
__global__ void cscm_prep(const float* __restrict__ cw, const float* __restrict__ cb,
                          const float* __restrict__ bg, const float* __restrict__ bb,
                          short* __restrict__ cscmT, float* __restrict__ sc,
                          float* __restrict__ sh) {
    int idx = blockIdx.x * 256 + threadIdx.x;
    if (idx < 2 * DBOT * 512) {
        int l = idx >> 16;
        int rem = idx & 65535;
        int oc = rem >> 9, j = rem & 511;
        int r = j >> 7, c = j & 127;
        cscmT[idx] = f2bf(cw[(((size_t)l * DBOT + oc) * DBOT + c) * 4 + r]);
    }
    if (idx < 3 * DBOT) {
        sc[idx] = bg[idx];
        sh[idx] = cb[idx] * bg[idx] + bb[idx];
    }
}

// ---------------------------------------------------------------------------
// positional-encoding table: pe[t][d], computed ONCE (L*D = 172K elements,
// not 32x redundantly inside the embed kernel)
// ---------------------------------------------------------------------------
__launch_bounds__(256)
__global__ void pe_kernel(float* __restrict__ pe) {
    int idx = blockIdx.x * 256 + threadIdx.x;
    if (idx >= L * D) return;
    int d = idx % D, t = idx / D;
    int e = d & ~1;
    float div = expf(-(float)e * (logf(10000.0f) / (float)D));
    float arg = (float)t * div;
    pe[idx] = (d & 1) ? cosf(arg) : sinf(arg);
}

// ---------------------------------------------------------------------------
// Embedding: conv(k=3, circular) + pe table + mark @ time_w + time_b
// ---------------------------------------------------------------------------
__launch_bounds__(256)
__global__ void embed_kernel(const float* __restrict__ x_enc, const float* __restrict__ x_mark,
                             const float* __restrict__ cw, const float* __restrict__ tw,
                             const float* __restrict__ tb, const float* __restrict__ pe,
                             float* __restrict__ emb, short* __restrict__ emb_bf) {
    size_t idx = (size_t)blockIdx.x * 256 + threadIdx.x;
    if (idx >= (size_t)BB * L * D) return;
    int d = idx % D;
    int t = (idx / D) % L;
    int b = idx / ((size_t)D * L);
    float acc = tb[d] + pe[t * D + d];
#pragma unroll
    for (int w = 0; w < 3; ++w) {
        int s = t + w - 1;
        if (s < 0) s = L - 1;
        if (s >= L) s = 0;
        const float* xr = x_enc + ((size_t)b * L + s) * CIN;
        const float* wr = cw + (size_t)d * (CIN * 3) + w;
#pragma unroll
        for (int i = 0; i < CIN; ++i) acc += xr[i] * wr[i * 3];
    }
    const float* mr = x_mark + ((size_t)b * L + t) * MARK;
#pragma unroll
    for (int m = 0; m < MARK; ++m) acc += mr[m] * tw[m * D + d];
    emb[idx] = acc;
    emb_bf[idx] = f2bf(acc);
}

// ---------------------------------------------------------------------------
// CSCM conv level 3 (tiny)
// ---------------------------------------------------------------------------
__launch_bounds__(128)
__global__ void cscm_conv_bf16(const short* __restrict__ in, int inRowsPerB,
                               short* __restrict__ outp, const float* __restrict__ w,
                               const float* __restrict__ cb, const float* __restrict__ bng,
                               const float* __restrict__ bnb, int Lout) {
    int bid = blockIdx.x;
    int to = bid % Lout, b = bid / Lout;
    __shared__ float insh[4 * DBOT];
    int tid = threadIdx.x;
#pragma unroll
    for (int r = 0; r < 4; ++r)
        insh[r * DBOT + tid] = bf2f(in[((size_t)(b * inRowsPerB + to * 4 + r)) * DBOT + tid]);
    __syncthreads();
    float acc = cb[tid];
    const float* wr = w + (size_t)tid * (DBOT * 4);
    for (int c = 0; c < DBOT; ++c) {
#pragma unroll
        for (int r = 0; r < 4; ++r)
            acc += insh[r * DBOT + c] * wr[c * 4 + r];
    }
    acc = acc * bng[tid] + bnb[tid];
    outp[((size_t)(b * Lout + to)) * DBOT + tid] = f2bf(acc > 0.0f ? acc : (expf(acc) - 1.0f));
}

// ---------------------------------------------------------------------------
// concat pyramid outputs (bf16) -> csc [MCAT][128]
// ---------------------------------------------------------------------------
__launch_bounds__(256)
__global__ void concat_cs_kernel(const short* __restrict__ cs1, const short* __restrict__ cs2,
                                 const short* __restrict__ cs3, short* __restrict__ csc) {
    int idx = blockIdx.x * 256 + threadIdx.x;
    if (idx >= MCAT * DBOT) return;
    int m = idx >> 7, c = idx & 127;
    short v = 0;
    if (m < BB * LC) {
        int b = m / LC, t = m % LC;
        if (t < L1)           v = cs1[(size_t)(b * L1 + t) * DBOT + c];
        else if (t < L1 + L2) v = cs2[(size_t)(b * L2 + (t - L1)) * DBOT + c];
        else                  v = cs3[(size_t)(b * L3 + (t - L1 - L2)) * DBOT + c];
    }
    csc[idx] = v;
}

// ---------------------------------------------------------------------------
// sparse attention over active level (compact Ob)
// ---------------------------------------------------------------------------
__launch_bounds__(256)
__global__ void attn_sparse_kernel(const short* __restrict__ QKV, short* __restrict__ Ob,
                                   int lvl, int cnt) {
    int wid  = blockIdx.x * 4 + (threadIdx.x >> 6);
    if (wid >= cnt * 32) return;
    int lane = threadIdx.x & 63;
    int b = wid & 31, j = wid >> 5;
    int i = d_sets.idx[lvl][j];
    const short8 qv = *(const short8*)(QKV + (size_t)(b * S + i) * 1536 + lane * 8);
    float qf[8];
#pragma unroll
    for (int e = 0; e < 8; ++e) qf[e] = bf2f(qv[e]);
    int nb[NMAX];
#pragma unroll
    for (int jj = 0; jj < NMAX; ++jj) nb[jj] = d_sets.nbr[i][jj];
    float sc[NMAX];
#pragma unroll
    for (int jj = 0; jj < NMAX; ++jj) {
        float s = -1e30f;
        if (nb[jj] >= 0) {
            const short8 kv = *(const short8*)(QKV + (size_t)(b * S + nb[jj]) * 1536 + 512 + lane * 8);
            s = 0.0f;
#pragma unroll
            for (int e = 0; e < 8; ++e) s += qf[e] * bf2f(kv[e]);
            s += __shfl_xor(s, 1); s += __shfl_xor(s, 2); s += __shfl_xor(s, 4);
            s *= 0.125f;
        }
        sc[jj] = s;
    }
    float mx = sc[0];
#pragma unroll
    for (int jj = 1; jj < NMAX; ++jj) mx = fmaxf(mx, sc[jj]);
    float sum = 0.0f;
    float accv[8] = {};
#pragma unroll
    for (int jj = 0; jj < NMAX; ++jj) {
        float p = expf(sc[jj] - mx);
        sum += p;
        if (nb[jj] >= 0) {
            const short8 vv = *(const short8*)(QKV + (size_t)(b * S + nb[jj]) * 1536 + 1024 + lane * 8);
#pragma unroll
            for (int e = 0; e < 8; ++e) accv[e] += p * bf2f(vv[e]);
        }
    }
    float inv = 1.0f / sum;
    short8 ov;
#pragma unroll
    for (int e = 0; e < 8; ++e) ov[e] = f2bf(accv[e] * inv);
    *(short8*)(Ob + (size_t)wid * D + lane * 8) = ov;
}

// ---------------------------------------------------------------------------
// wave-shuffle block reduction over 4 waves (256 thr): 2 barriers total
// ---------------------------------------------------------------------------
__device__ inline float blk_reduce(float v, float* ws4, int tid) {
#pragma unroll
    for (int o = 32; o; o >>= 1) v += __shfl_xor(v, o);
    if ((tid & 63) == 0) ws4[tid >> 6] = v;
    __syncthreads();
    return ws4[0] + ws4[1] + ws4[2] + ws4[3];
}

// ---------------------------------------------------------------------------
// concat(emb, coarse) + LayerNorm -> seq (f32) + seq_bf (bf16), all rows
// ---------------------------------------------------------------------------
__launch_bounds__(256)
__global__ void concat_ln_kernel(const float* __restrict__ emb, const float* __restrict__ coarse,
                                 const float* __restrict__ g, const float* __restrict__ bta,
                                 float* __restrict__ seq, short* __restrict__ seq_bf) {
    int row = blockIdx.x;
    int b = row / S, s = row % S;
    const float* src = (s < L) ? emb + ((size_t)b * L + s) * D
                               : coarse + ((size_t)b * LC + (s - L)) * D;
    __shared__ float wsA[4];
    __shared__ float wsB[4];
    int tid = threadIdx.x;
    float x0 = src[tid], x1 = src[tid + 256];
    float mu = blk_reduce(x0 + x1, wsA, tid) * (1.0f / D);
    float d0 = x0 - mu, d1 = x1 - mu;
    float var = blk_reduce(d0 * d0 + d1 * d1, wsB, tid) * (1.0f / D);
    float rstd = rsqrtf(var + 1e-5f);
    float v0 = d0 * rstd * g[tid]       + bta[tid];
    float v1 = d1 * rstd * g[tid + 256] + bta[tid + 256];
    float* dst = seq + (size_t)row * D;
    dst[tid] = v0; dst[tid + 256] = v1;
    short* dbf = seq_bf + (size_t)row * D;
    dbf[tid] = f2bf(v0); dbf[tid + 256] = f2bf(v1);
}

// ---------------------------------------------------------------------------
// indexed residual LN: compact row -> orig row b*S+idx[lvl][j]; exact grid
// ---------------------------------------------------------------------------
__launch_bounds__(256)
__global__ void add_ln_idx(float* __restrict__ seq, const short* __restrict__ add,
                           const float* __restrict__ g, const float* __restrict__ bta,
                           short* __restrict__ seq_bf, int lvl) {
    int row = blockIdx.x;
    int b = row & 31, j = row >> 5;
    int orig = b * S + d_sets.idx[lvl][j];
    __shared__ float wsA[4];
    __shared__ float wsB[4];
    int tid = threadIdx.x;
    float* srow = seq + (size_t)orig * D;
    const short* arow = add + (size_t)row * D;
    float x0 = srow[tid] + bf2f(arow[tid]);
    float x1 = srow[tid + 256] + bf2f(arow[tid + 256]);
    float mu = blk_reduce(x0 + x1, wsA, tid) * (1.0f / D);
    float d0 = x0 - mu, d1 = x1 - mu;
    float var = blk_reduce(d0 * d0 + d1 * d1, wsB, tid) * (1.0f / D);
    float rstd = rsqrtf(var + 1e-5f);
    float v0 = d0 * rstd * g[tid]       + bta[tid];
    float v1 = d1 * rstd * g[tid + 256] + bta[tid + 256];
    srow[tid] = v0; srow[tid + 256] = v1;
    short* dbf = seq_bf + (size_t)orig * D;
    dbf[tid] = f2bf(v0); dbf[tid + 256] = f2bf(v1);
}

// ---------------------------------------------------------------------------
// prediction head, split-K with fused gather
// ---------------------------------------------------------------------------
__launch_bounds__(256)
__global__ void pred_kernel(const float* __restrict__ seq, const float* __restrict__ w,
                            float* __restrict__ part) {
    __shared__ float es[32][257];
    __shared__ float wsm[256][8];
    int tid = threadIdx.x;
    int n0 = blockIdx.x * 8;
    int ks = blockIdx.y;
    int k0 = ks * 256;
    const int pos[4] = {335, 419, 440, 445};
    int seg = ks >> 1;
    int dbase = (ks & 1) * 256;
#pragma unroll 8
    for (int r = 0; r < 32; ++r)
        es[r][tid] = seq[((size_t)r * S + pos[seg]) * D + dbase + tid];
#pragma unroll
    for (int e = 0; e < 8; ++e)
        wsm[tid][e] = w[(size_t)(k0 + tid) * PRED_N + n0 + e];
    __syncthreads();
    int b = tid >> 3, nn = tid & 7;
    float acc = 0.0f;
#pragma unroll 8
    for (int kk = 0; kk < 256; ++kk)
        acc += es[b][kk] * wsm[kk][nn];
    part[(size_t)ks * (BB * PRED_N) + (size_t)b * PRED_N + n0 + nn] = acc;
}

__launch_bounds__(256)
__global__ void pred_reduce_kernel(const float* __restrict__ part, float* __restrict__ out) {
    int idx = blockIdx.x * 256 + threadIdx.x;
    if (idx >= BB * PRED_N) return;
    float s = 0.0f;
#pragma unroll
    for (int k = 0; k < 8; ++k) s += part[(size_t)k * (BB * PRED_N) + idx];
    out[idx] = s;
}

// ---------------------------------------------------------------------------
extern "C" void kernel_launch(void* const* d_in, const int* in_sizes, int n_in,
                              void* d_out, int out_size, void* d_ws, size_t ws_size,
                              hipStream_t stream) {
    const float* x_enc      = (const float*)d_in[0];
    const float* x_mark_enc = (const float*)d_in[1];
    const float* conv_embed_w = (const float*)d_in[4];
    const float* time_w  = (const float*)d_in[5];
    const float* time_b  = (const float*)d_in[6];
    const float* down_w  = (const float*)d_in[7];
    const float* down_b  = (const float*)d_in[8];
    const float* cscm_w  = (const float*)d_in[9];
    const float* cscm_b  = (const float*)d_in[10];
    const float* bn_g    = (const float*)d_in[11];
    const float* bn_b    = (const float*)d_in[12];
    const float* up_w    = (const float*)d_in[13];
    const float* up_b    = (const float*)d_in[14];
    const float* cln_g   = (const float*)d_in[15];
    const float* cln_b   = (const float*)d_in[16];
    const float* wq      = (const float*)d_in[17];
    const float* wk      = (const float*)d_in[18];
    const float* wv      = (const float*)d_in[19];
    const float* wo      = (const float*)d_in[20];
    const float* ln1_g   = (const float*)d_in[21];
    const float* ln1_b   = (const float*)d_in[22];
    const float* ffn_w1  = (const float*)d_in[23];
    const float* ffn_b1  = (const float*)d_in[24];
    const float* ffn_w2  = (const float*)d_in[25];
    const float* ffn_b2  = (const float*)d_in[26];
    const float* ln2_g   = (const float*)d_in[27];
    const float* ln2_b   = (const float*)d_in[28];
    const float* pred_w  = (const float*)d_in[29];
    float* out = (float*)d_out;

    // ---- workspace layout (bytes, 256-aligned) ----
    char* w8 = (char*)d_ws;
    size_t off = 0;
    auto alloc = [&](size_t bytes) {
        void* p = w8 + off;
        off = (off + bytes + 255) & ~(size_t)255;
        return p;
    };
    float* emb    = (float*)alloc((size_t)BB * L * D * 4);
    short* emb_bf = (short*)alloc((size_t)BB * L * D * 2);
    float* pe     = (float*)alloc((size_t)L * D * 4);
    short* xd_bf  = (short*)alloc((size_t)BB * L * DBOT * 2);
    short* cs1_bf = (short*)alloc((size_t)MCONV2P * 512 * 2);
    short* cs2_bf = (short*)alloc((size_t)MCONV2P * DBOT * 2);
    short* cs3_bf = (short*)alloc((size_t)BB * L3 * DBOT * 2);
    short* csc_bf = (short*)alloc((size_t)MCAT * DBOT * 2);
    float* coarse = (float*)alloc((size_t)MCAT * D * 4);
    float* seq    = (float*)alloc((size_t)BB * S * D * 4);
    short* T1     = (short*)alloc((size_t)MP * D * 2);
    float* part   = (float*)alloc((size_t)8 * BB * PRED_N * 4);
    short* seq_bf = (short*)alloc((size_t)MP * D * 2);
    short* QKV    = (short*)alloc((size_t)MP * 3 * D * 2);  // + Ob contiguous
    short* Ob     = (short*)alloc((size_t)MP * D * 2);
    short* hidden = QKV;
    short* wqkvT  = (short*)alloc((size_t)NLAYER * 3 * D * D * 2);
    short* woT    = (short*)alloc((size_t)NLAYER * D * D * 2);
    short* w1T    = (short*)alloc((size_t)NLAYER * DFF * D * 2);
    short* w2T    = (short*)alloc((size_t)NLAYER * D * DFF * 2);
    short* downT  = (short*)alloc((size_t)DBOT * D * 2);
    short* upT    = (short*)alloc((size_t)D * DBOT * 2);
    short* cscmT  = (short*)alloc((size_t)2 * DBOT * 512 * 2);
    float* csc_sc = (float*)alloc((size_t)3 * DBOT * 4);
    float* csc_sh = (float*)alloc((size_t)3 * DBOT * 4);
    (void)ws_size; (void)in_sizes; (void)n_in; (void)out_size;

    const int rowsL = BB * L;   // 10752 = 84*128
    const int rowsS = BB * S;   // 14272
    dim3 blk(256);

    // 0. weight convert+transpose + pe table
    wtrans_qkvo<<<dim3(16, 16, 4 * NLAYER), blk, 0, stream>>>(wq, wk, wv, wo, wqkvT, woT);
    wtrans_ffn<<<dim3(64, 16, 2 * NLAYER), blk, 0, stream>>>(ffn_w1, ffn_w2, w1T, w2T);
    wtrans_one<<<dim3(DBOT / 32, D / 32), blk, 0, stream>>>(down_w, downT, D, DBOT);
    wtrans_one<<<dim3(D / 32, DBOT / 32), blk, 0, stream>>>(up_w, upT, DBOT, D);
    cscm_prep<<<dim3((2 * DBOT * 512 + 255) / 256), blk, 0, stream>>>(
        cscm_w, cscm_b, bn_g, bn_b, cscmT, csc_sc, csc_sh);
    pe_kernel<<<dim3((L * D + 255) / 256), blk, 0, stream>>>(pe);
    // 1. embedding
    embed_kernel<<<dim3(((size_t)BB * L * D + 255) / 256), blk, 0, stream>>>(
        x_enc, x_mark_enc, conv_embed_w, time_w, time_b, pe, emb, emb_bf);
    // 2. down projection -> bf16
    mfma_gemm<4><<<dim3(1, rowsL / 128), blk, 0, stream>>>(
        emb_bf, downT, down_b, nullptr, xd_bf, D, DBOT, -1, -1, 0);
    // 3. CSCM pyramid
    mfma_gemm<5><<<dim3(1, MCONV1 / 128), blk, 0, stream>>>(
        xd_bf, cscmT, csc_sc, csc_sh, cs1_bf, 512, DBOT, -1, -1, 0);
    mfma_gemm<5><<<dim3(1, MCONV2P / 128), blk, 0, stream>>>(
        cs1_bf, cscmT + (size_t)DBOT * 512, csc_sc + DBOT, csc_sh + DBOT,
        cs2_bf, 512, DBOT, -1, -1, 0);
    cscm_conv_bf16<<<dim3(BB * L3), dim3(DBOT), 0, stream>>>(
        cs2_bf, L2, cs3_bf, cscm_w + 2 * DBOT * DBOT * 4,
        cscm_b + 2 * DBOT, bn_g + 2 * DBOT, bn_b + 2 * DBOT, L3);
    // 4. up projection
    concat_cs_kernel<<<dim3((MCAT * DBOT + 255) / 256), blk, 0, stream>>>(
        cs1_bf, cs2_bf, cs3_bf, csc_bf);
    mfma_gemm<1><<<dim3(D / 128, MCAT / 128), blk, 0, stream>>>(
        csc_bf, upT, up_b, nullptr, coarse, DBOT, D, -1, -1, 0);
    // 5. concat + LN (all rows)
    concat_ln_kernel<<<dim3(rowsS), blk, 0, stream>>>(emb, coarse, cln_g, cln_b, seq, seq_bf);

    // 6. encoder layers (compile-time sparse active sets; grids exact)
    for (int l = 0; l < NLAYER; ++l) {
        const int inLvl = l, outLvl = l + 1;
        const int inCnt  = HS.cnt[l];
        const int outCnt = HS.cnt[l + 1];
        mfma_gemm256<2><<<dim3(3 * D / 256, (inCnt * 32 + 255) / 256), dim3(512), 0, stream>>>(
            seq_bf, wqkvT + (size_t)l * 3 * D * D, nullptr, QKV, D, 3 * D,
            inLvl, inLvl, inCnt);
        attn_sparse_kernel<<<dim3(outCnt * 8), blk, 0, stream>>>(
            QKV, Ob, outLvl, outCnt);
        mfma_gemm<2><<<dim3(D / 128, (outCnt * 32 + 127) / 128), blk, 0, stream>>>(
            Ob, woT + (size_t)l * D * D, nullptr, nullptr, T1, D, D,
            -1, -1, 0);
        add_ln_idx<<<dim3(outCnt * 32), blk, 0, stream>>>(
            seq, T1, ln1_g + (size_t)l * D, ln1_b + (size_t)l * D, seq_bf, outLvl);
        mfma_gemm256<3><<<dim3(DFF / 256, (outCnt * 32 + 255) / 256), dim3(512), 0, stream>>>(
            seq_bf, w1T + (size_t)l * DFF * D, ffn_b1 + (size_t)l * DFF, hidden, D, DFF,
            outLvl, -1, outCnt);
        mfma_gemm<4><<<dim3(D / 128, (outCnt * 32 + 127) / 128), blk, 0, stream>>>(
            hidden, w2T + (size_t)l * D * DFF, ffn_b2 + (size_t)l * D, nullptr, T1, DFF, D,
            -1, -1, 0);
        add_ln_idx<<<dim3(outCnt * 32), blk, 0, stream>>>(
            seq, T1, ln2_g + (size_t)l * D, ln2_b + (size_t)l * D, seq_bf, outLvl);
    }

    // 7. prediction head (split-K, gather fused) + reduce
    pred_kernel<<<dim3(PRED_N / 8, 8), blk, 0, stream>>>(seq, pred_w, part);
    pred_reduce_kernel<<<dim3((BB * PRED_N + 255) / 256), blk, 0, stream>>>(part, out);
}

// Round 15
// 579.831 us; speedup vs baseline: 1.5629x; 1.0582x over previous
//
#include <hip/hip_runtime.h>
#include <math.h>

// ---- problem constants ----
constexpr int BB   = 32;    // batch
constexpr int L    = 336;   // seq_len
constexpr int CIN  = 7;
constexpr int MARK = 4;
constexpr int D    = 512;   // d_model
constexpr int DFF  = 2048;
constexpr int NH   = 8;
constexpr int HD   = 64;    // dk = dv
constexpr int S    = 446;   // 336+84+21+5
constexpr int DBOT = 128;
constexpr int L1 = 84, L2 = 21, L3 = 5;
constexpr int LC = 110;     // 84+21+5
constexpr int NLAYER = 3;
constexpr int PRED_N = 672; // 96*7
constexpr int MP   = 14336; // BB*S padded
constexpr int NMAX = 12;    // max sparse neighbors (real max 10)
constexpr int MCONV1 = BB * L1;          // 2688 = 21*128 (exact)
constexpr int MCONV2P = 768;             // BB*L2=672 padded to 6*128
constexpr int MCAT  = 3584;              // BB*LC=3520 padded to 28*128

using short8  = __attribute__((ext_vector_type(8))) short;
using float4v = __attribute__((ext_vector_type(4))) float;

// ---------------------------------------------------------------------------
// COMPILE-TIME pyramid structure: neighbor lists + active sets.
// A3 = gather positions {335,419,440,445}; A_{l-1} = U nbr(A_l), sorted.
// Every node is its own neighbor => A3 <= A2 <= A1 <= A0 (set inclusion).
// Layer l (0-based): QKV at idx[l] (cnt[l]), attn/Oproj/LN/FFN at idx[l+1].
// ---------------------------------------------------------------------------
struct SetsData {
    int nbr[S][NMAX];
    int idx[4][S];
    int cnt[4];
};

constexpr SetsData compute_sets() {
    SetsData sd{};
    constexpr int sizes[4]  = {336, 84, 21, 5};
    constexpr int starts[4] = {0, 336, 420, 441};
    for (int i = 0; i < S; ++i) {
        int li = 0, pi = i;
        if (i < 336)      { li = 0; pi = i; }
        else if (i < 420) { li = 1; pi = i - 336; }
        else if (i < 441) { li = 2; pi = i - 420; }
        else              { li = 3; pi = i - 441; }
        int cnt = 0;
        for (int d = -2; d <= 2; ++d) {
            int q = pi + d;
            if (q >= 0 && q < sizes[li]) sd.nbr[i][cnt++] = starts[li] + q;
        }
        if (li > 0) {
            int lo = pi * 4;
            int hi = (pi == sizes[li] - 1) ? sizes[li - 1] : (pi + 1) * 4;
            for (int c = lo; c < hi; ++c) sd.nbr[i][cnt++] = starts[li - 1] + c;
        }
        if (li < 3) {
            int q = pi >> 2;
            if (q > sizes[li + 1] - 1) q = sizes[li + 1] - 1;
            sd.nbr[i][cnt++] = starts[li + 1] + q;
        }
        for (int j = cnt; j < NMAX; ++j) sd.nbr[i][j] = -1;
    }
    sd.cnt[3] = 4;
    sd.idx[3][0] = 335; sd.idx[3][1] = 419; sd.idx[3][2] = 440; sd.idx[3][3] = 445;
    for (int lvl = 3; lvl >= 1; --lvl) {
        bool mk[S] = {};
        for (int k = 0; k < sd.cnt[lvl]; ++k) {
            int i = sd.idx[lvl][k];
            for (int t = 0; t < NMAX; ++t) {
                int v = sd.nbr[i][t];
                if (v >= 0) mk[v] = true;
            }
        }
        int nc = 0;
        for (int i = 0; i < S; ++i)
            if (mk[i]) sd.idx[lvl - 1][nc++] = i;
        sd.cnt[lvl - 1] = nc;
    }
    return sd;
}

constexpr SetsData HS = compute_sets();         // host: grid sizing
__constant__ SetsData d_sets = compute_sets();  // device: row maps + nbr

__device__ inline short f2bf(float f) {
    union { float f; unsigned u; } v; v.f = f;
    unsigned r = v.u + 0x7fffu + ((v.u >> 16) & 1u);
    return (short)(r >> 16);
}
__device__ inline float bf2f(short h) {
    union { unsigned u; float f; } v; v.u = ((unsigned)(unsigned short)h) << 16;
    return v.f;
}

// async global->LDS, 16B per lane, wave-uniform LDS base + lane*16
__device__ inline void gload_lds16(const void* g, void* l) {
    __builtin_amdgcn_global_load_lds(
        (const __attribute__((address_space(1))) void*)g,
        (__attribute__((address_space(3))) void*)l, 16, 0, 0);
}

// Staging map (both GEMM kernels), conflict-free + coalesced (verified r11:
// 0 bank conflicts): LDS 16B-chunk u encodes row=((u>>3)<<1)|((u>>2)&1),
// k-slot s=u&3 holding global kseg kg = s ^ ((u>>3)&3). Reader: rh=row>>1,
// s=lk^(rh&3), chunk=rh*8+(row&1)*4+s.
// Sparse rows: alvl/clvl >= 0 select d_sets.idx[lvl] (pos-major compact:
// compact m -> b=m&31, j=m>>5 clamped to cnt-1, orig row b*S+idx[j]).

// ---------------------------------------------------------------------------
// 128x128 bf16 MFMA GEMM, BK=32, double-buffered, counted vmcnt(4) pipeline.
// EPI: 0 f32; 1 f32+bias; 2 bf16; 3 bf16+bias+gelu; 4 bf16+bias;
//      5 bf16, v = acc*bias[gn]+bias2[gn] then ELU;
//      6 v = acc + peT[(row%L)*D+gn], write f32 Cout AND bf16 Cout2 (embed)
// ---------------------------------------------------------------------------
template<int EPI>
__launch_bounds__(256, 4)
__global__ void mfma_gemm(const short* __restrict__ A, const short* __restrict__ Bt,
                          const float* __restrict__ bias, const float* __restrict__ bias2,
                          void* __restrict__ Cout, int Kd, int Nd,
                          int alvl, int clvl, int cnt,
                          const float* __restrict__ peT, short* __restrict__ Cout2) {
    __shared__ short As[2][128 * 32];
    __shared__ short Bs[2][128 * 32];
    int tid = threadIdx.x;
    int nwg  = gridDim.x * gridDim.y;
    int orig = blockIdx.y * gridDim.x + blockIdx.x;
    int qq = nwg >> 3, rr = nwg & 7;
    int xcd = orig & 7, idx = orig >> 3;
    int wgid = (xcd < rr ? xcd * (qq + 1) : rr * (qq + 1) + (xcd - rr) * qq) + idx;
    int m0 = (wgid / gridDim.x) * 128, n0 = (wgid % gridDim.x) * 128;

    int lane = tid & 63, wid = tid >> 6;
    int wm = wid >> 1, wn = wid & 1;
    int lr = lane & 15, lk = lane >> 4;

    size_t abase[2], bbase[2];
#pragma unroll
    for (int r = 0; r < 2; ++r) {
        int u = r * 256 + tid;
        int row = ((u >> 3) << 1) | ((u >> 2) & 1);
        int kg  = (u & 3) ^ ((u >> 3) & 3);
        int rm = m0 + row, ga;
        if (alvl >= 0) { int j = rm >> 5; if (j > cnt - 1) j = cnt - 1; ga = (rm & 31) * S + d_sets.idx[alvl][j]; }
        else ga = rm;
        abase[r] = (size_t)ga * Kd + kg * 8;
        bbase[r] = (size_t)(n0 + row) * Kd + kg * 8;
    }
    auto stage = [&](int buf, int k0) {
#pragma unroll
        for (int r = 0; r < 2; ++r) {
            short* la = As[buf] + (size_t)(r * 256 + wid * 64) * 8;
            short* lb = Bs[buf] + (size_t)(r * 256 + wid * 64) * 8;
            gload_lds16(A + abase[r] + k0, la);
            gload_lds16(Bt + bbase[r] + k0, lb);
        }
    };
    auto rd_off = [&](int row_) {
        int rh = row_ >> 1;
        int s  = lk ^ (rh & 3);
        return (size_t)(rh * 8 + (row_ & 1) * 4 + s) * 8;
    };

    float4v acc[4][4];
#pragma unroll
    for (int i = 0; i < 4; ++i)
#pragma unroll
        for (int j = 0; j < 4; ++j) acc[i][j] = 0;

    const int nt = Kd >> 5;
    stage(0, 0);
    for (int t = 0; t < nt; ++t) {
        int cur = t & 1;
        if (t + 1 < nt) {
            stage(cur ^ 1, (t + 1) * 32);
            asm volatile("s_waitcnt vmcnt(4)" ::: "memory");
        } else {
            asm volatile("s_waitcnt vmcnt(0)" ::: "memory");
        }
        __builtin_amdgcn_s_barrier();
        short8 af[4], bfv[4];
#pragma unroll
        for (int mi = 0; mi < 4; ++mi)
            af[mi] = *(const short8*)(As[cur] + rd_off(wm * 64 + mi * 16 + lr));
#pragma unroll
        for (int ni = 0; ni < 4; ++ni)
            bfv[ni] = *(const short8*)(Bs[cur] + rd_off(wn * 64 + ni * 16 + lr));
        __builtin_amdgcn_s_setprio(1);
#pragma unroll
        for (int mi = 0; mi < 4; ++mi)
#pragma unroll
            for (int ni = 0; ni < 4; ++ni)
                acc[mi][ni] = __builtin_amdgcn_mfma_f32_16x16x32_bf16(
                    af[mi], bfv[ni], acc[mi][ni], 0, 0, 0);
        __builtin_amdgcn_s_setprio(0);
        __builtin_amdgcn_s_barrier();
    }

#pragma unroll
    for (int mi = 0; mi < 4; ++mi) {
        int gmc = m0 + wm * 64 + mi * 16 + lk * 4;
#pragma unroll
        for (int ni = 0; ni < 4; ++ni) {
            int gn = n0 + wn * 64 + ni * 16 + lr;
            float bsv = (EPI == 1 || EPI == 3 || EPI == 4) ? bias[gn] : 0.0f;
            float sc = (EPI == 5) ? bias[gn]  : 0.0f;
            float sh = (EPI == 5) ? bias2[gn] : 0.0f;
#pragma unroll
            for (int e = 0; e < 4; ++e) {
                int rm = gmc + e, grow;
                if (clvl >= 0) { int j = rm >> 5; if (j > cnt - 1) j = cnt - 1; grow = (rm & 31) * S + d_sets.idx[clvl][j]; }
                else grow = rm;
                float v = acc[mi][ni][e] + bsv;
                if (EPI == 3) v = 0.5f * v * (1.0f + erff(v * 0.70710678118654752f));
                if (EPI == 5) { v = v * sc + sh; v = v > 0.0f ? v : (expf(v) - 1.0f); }
                if (EPI == 6) {
                    v += peT[(size_t)(grow % L) * D + gn];
                    ((float*)Cout)[(size_t)grow * Nd + gn] = v;
                    Cout2[(size_t)grow * Nd + gn] = f2bf(v);
                } else if (EPI <= 1) {
                    ((float*)Cout)[(size_t)grow * Nd + gn] = v;
                } else {
                    ((short*)Cout)[(size_t)grow * Nd + gn] = f2bf(v);
                }
            }
        }
    }
}

// ---------------------------------------------------------------------------
// 256x256 bf16 MFMA GEMM (wide-N shapes: FFN1, QKV). Same structure.
// ---------------------------------------------------------------------------
template<int EPI>
__launch_bounds__(512, 2)
__global__ void mfma_gemm256(const short* __restrict__ A, const short* __restrict__ Bt,
                             const float* __restrict__ bias, void* __restrict__ Cout,
                             int Kd, int Nd, int alvl, int clvl, int cnt) {
    __shared__ short As[2][256 * 32];
    __shared__ short Bs[2][256 * 32];
    int tid = threadIdx.x;
    int nwg  = gridDim.x * gridDim.y;
    int orig = blockIdx.y * gridDim.x + blockIdx.x;
    int qq = nwg >> 3, rr = nwg & 7;
    int xcd = orig & 7, idx = orig >> 3;
    int wgid = (xcd < rr ? xcd * (qq + 1) : rr * (qq + 1) + (xcd - rr) * qq) + idx;
    int m0 = (wgid / gridDim.x) * 256, n0 = (wgid % gridDim.x) * 256;

    int lane = tid & 63, wid = tid >> 6;
    int wm = wid >> 2, wn = wid & 3;
    int lr = lane & 15, lk = lane >> 4;

    size_t abase[2], bbase[2];
#pragma unroll
    for (int r = 0; r < 2; ++r) {
        int u = r * 512 + tid;
        int row = ((u >> 3) << 1) | ((u >> 2) & 1);
        int kg  = (u & 3) ^ ((u >> 3) & 3);
        int rm = m0 + row, ga;
        if (alvl >= 0) { int j = rm >> 5; if (j > cnt - 1) j = cnt - 1; ga = (rm & 31) * S + d_sets.idx[alvl][j]; }
        else ga = rm;
        abase[r] = (size_t)ga * Kd + kg * 8;
        bbase[r] = (size_t)(n0 + row) * Kd + kg * 8;
    }
    auto stage = [&](int buf, int k0) {
#pragma unroll
        for (int r = 0; r < 2; ++r) {
            short* la = As[buf] + (size_t)(r * 512 + wid * 64) * 8;
            short* lb = Bs[buf] + (size_t)(r * 512 + wid * 64) * 8;
            gload_lds16(A + abase[r] + k0, la);
            gload_lds16(Bt + bbase[r] + k0, lb);
        }
    };
    auto rd_off = [&](int row_) {
        int rh = row_ >> 1;
        int s  = lk ^ (rh & 3);
        return (size_t)(rh * 8 + (row_ & 1) * 4 + s) * 8;
    };

    float4v acc[8][4];
#pragma unroll
    for (int i = 0; i < 8; ++i)
#pragma unroll
        for (int j = 0; j < 4; ++j) acc[i][j] = 0;

    const int nt = Kd >> 5;
    stage(0, 0);
    for (int t = 0; t < nt; ++t) {
        int cur = t & 1;
        if (t + 1 < nt) {
            stage(cur ^ 1, (t + 1) * 32);
            asm volatile("s_waitcnt vmcnt(4)" ::: "memory");
        } else {
            asm volatile("s_waitcnt vmcnt(0)" ::: "memory");
        }
        __builtin_amdgcn_s_barrier();
        short8 af[8], bfv[4];
#pragma unroll
        for (int mi = 0; mi < 8; ++mi)
            af[mi] = *(const short8*)(As[cur] + rd_off(wm * 128 + mi * 16 + lr));
#pragma unroll
        for (int ni = 0; ni < 4; ++ni)
            bfv[ni] = *(const short8*)(Bs[cur] + rd_off(wn * 64 + ni * 16 + lr));
        __builtin_amdgcn_s_setprio(1);
#pragma unroll
        for (int mi = 0; mi < 8; ++mi)
#pragma unroll
            for (int ni = 0; ni < 4; ++ni)
                acc[mi][ni] = __builtin_amdgcn_mfma_f32_16x16x32_bf16(
                    af[mi], bfv[ni], acc[mi][ni], 0, 0, 0);
        __builtin_amdgcn_s_setprio(0);
        __builtin_amdgcn_s_barrier();
    }

#pragma unroll
    for (int mi = 0; mi < 8; ++mi) {
        int gmc = m0 + wm * 128 + mi * 16 + lk * 4;
#pragma unroll
        for (int ni = 0; ni < 4; ++ni) {
            int gn = n0 + wn * 64 + ni * 16 + lr;
            float bsv = (EPI == 1 || EPI == 3 || EPI == 4) ? bias[gn] : 0.0f;
#pragma unroll
            for (int e = 0; e < 4; ++e) {
                int rm = gmc + e, grow;
                if (clvl >= 0) { int j = rm >> 5; if (j > cnt - 1) j = cnt - 1; grow = (rm & 31) * S + d_sets.idx[clvl][j]; }
                else grow = rm;
                float v = acc[mi][ni][e] + bsv;
                if (EPI == 3) v = 0.5f * v * (1.0f + erff(v * 0.70710678118654752f));
                if (EPI <= 1) ((float*)Cout)[(size_t)grow * Nd + gn] = v;
                else          ((short*)Cout)[(size_t)grow * Nd + gn] = f2bf(v);
            }
        }
    }
}

// ---------------------------------------------------------------------------
// batched weight transpose+convert, 32x32 tiles, f32 W[Kd][Nd] -> bf16 Wt[Nd][Kd]
// ---------------------------------------------------------------------------
__device__ inline void wtrans_tile(const float* __restrict__ W, short* __restrict__ Wt,
                                   int Kd, int Nd, int n0, int k0, int tid) {
    __shared__ float tile[32][33];
    int tx = tid & 31, ty = tid >> 5; // ty 0..7
#pragma unroll
    for (int r = 0; r < 32; r += 8)
        tile[ty + r][tx] = W[(size_t)(k0 + ty + r) * Nd + n0 + tx];
    __syncthreads();
#pragma unroll
    for (int r = 0; r < 32; r += 8)
        Wt[(size_t)(n0 + ty + r) * Kd + k0 + tx] = f2bf(tile[tx][ty + r]);
}

__launch_bounds__(256)
__global__ void wtrans_qkvo(const float* __restrict__ wq, const float* __restrict__ wk,
                            const float* __restrict__ wv, const float* __restrict__ wo,
                            short* __restrict__ wqkvT, short* __restrict__ woT) {
    int z = blockIdx.z, l = z >> 2, part = z & 3;
    const float* src = (part == 0 ? wq : part == 1 ? wk : part == 2 ? wv : wo)
                       + (size_t)l * D * D;
    short* dst = (part < 3) ? wqkvT + (size_t)l * 3 * D * D + (size_t)part * D * D
                            : woT + (size_t)l * D * D;
    wtrans_tile(src, dst, D, D, blockIdx.x * 32, blockIdx.y * 32, threadIdx.x);
}

__launch_bounds__(256)
__global__ void wtrans_ffn(const float* __restrict__ w1, const float* __restrict__ w2,
                           short* __restrict__ w1T, short* __restrict__ w2T) {
    int z = blockIdx.z, l = z >> 1, part = z & 1;
    int nt = part ? blockIdx.y : blockIdx.x;
    int kt = part ? blockIdx.x : blockIdx.y;
    if (part == 0)
        wtrans_tile(w1 + (size_t)l * D * DFF, w1T + (size_t)l * DFF * D,
                    D, DFF, nt * 32, kt * 32, threadIdx.x);
    else
        wtrans_tile(w2 + (size_t)l * DFF * D, w2T + (size_t)l * D * DFF,
                    DFF, D, nt * 32, kt * 32, threadIdx.x);
}

__launch_bounds__(256)
__global__ void wtrans_one(const float* __restrict__ W, short* __restrict__ Wt,
                           int Kd, int Nd) {
    wtrans_tile(W, Wt, Kd, Nd, blockIdx.x * 32, blockIdx.y * 32, threadIdx.x);
}

// ---------------------------------------------------------------------------
// CSCM prep
// ---------------------------------------------------------------------------
__launch_bounds__(256)
__global__ void cscm_prep(const float* __restrict__ cw, const float* __restrict__ cb,
                          const float* __restrict__ bg, const float* __restrict__ bb,
                          short* __restrict__ cscmT, float* __restrict__ sc,
                          float* __restrict__ sh) {
    int idx = blockIdx.x * 256 + threadIdx.x;
    if (idx < 2 * DBOT * 512) {
        int l = idx >> 16;
        int rem = idx & 65535;
        int oc = rem >> 9, j = rem & 511;
        int r = j >> 7, c = j & 127;
        cscmT[idx] = f2bf(cw[(((size_t)l * DBOT + oc) * DBOT + c) * 4 + r]);
    }
    if (idx < 3 * DBOT) {
        sc[idx] = bg[idx];
        sh[idx] = cb[idx] * bg[idx] + bb[idx];
    }
}

// ---------------------------------------------------------------------------
// positional-encoding table: pe[t][d], computed ONCE
// ---------------------------------------------------------------------------
__launch_bounds__(256)
__global__ void pe_kernel(float* __restrict__ pe) {
    int idx = blockIdx.x * 256 + threadIdx.x;
    if (idx >= L * D) return;
    int d = idx % D, t = idx / D;
    int e = d & ~1;
    float div = expf(-(float)e * (logf(10000.0f) / (float)D));
    float arg = (float)t * div;
    pe[idx] = (d & 1) ? cosf(arg) : sinf(arg);
}

// ---------------------------------------------------------------------------
// embed as GEMM: im2col matrix xim[BB*L][32] (bf16):
//   k<21: x_enc[b, circ(t+k/7-1), k%7]; k in 21..24: x_mark[b,t,k-21];
//   k==25: 1.0 (bias slot); else 0
// ---------------------------------------------------------------------------
__launch_bounds__(256)
__global__ void im2col_kernel(const float* __restrict__ x_enc, const float* __restrict__ x_mark,
                              short* __restrict__ xim) {
    int idx = blockIdx.x * 256 + threadIdx.x;
    if (idx >= BB * L * 32) return;
    int k = idx & 31, m = idx >> 5;
    int t = m % L, b = m / L;
    float v = 0.0f;
    if (k < 21) {
        int w = k / 7, i = k % 7;
        int s = t + w - 1;
        if (s < 0) s = L - 1;
        if (s >= L) s = 0;
        v = x_enc[((size_t)b * L + s) * CIN + i];
    } else if (k < 25) {
        v = x_mark[(size_t)m * MARK + (k - 21)];
    } else if (k == 25) {
        v = 1.0f;
    }
    xim[idx] = f2bf(v);
}

// embed weight in Bt layout wE[512][32]: k<21 -> cw[d*21 + (k%7)*3 + k/7];
// 21..24 -> time_w[(k-21)*D+d]; 25 -> time_b[d]; else 0
__launch_bounds__(256)
__global__ void wembed_kernel(const float* __restrict__ cw, const float* __restrict__ tw,
                              const float* __restrict__ tb, short* __restrict__ wE) {
    int idx = blockIdx.x * 256 + threadIdx.x;
    if (idx >= D * 32) return;
    int k = idx & 31, d = idx >> 5;
    float v = 0.0f;
    if (k < 21) {
        int w = k / 7, i = k % 7;
        v = cw[(size_t)d * (CIN * 3) + i * 3 + w];
    } else if (k < 25) {
        v = tw[(size_t)(k - 21) * D + d];
    } else if (k == 25) {
        v = tb[d];
    }
    wE[idx] = f2bf(v);
}

// ---------------------------------------------------------------------------
// CSCM conv level 3 (tiny)
// ---------------------------------------------------------------------------
__launch_bounds__(128)
__global__ void cscm_conv_bf16(const short* __restrict__ in, int inRowsPerB,
                               short* __restrict__ outp, const float* __restrict__ w,
                               const float* __restrict__ cb, const float* __restrict__ bng,
                               const float* __restrict__ bnb, int Lout) {
    int bid = blockIdx.x;
    int to = bid % Lout, b = bid / Lout;
    __shared__ float insh[4 * DBOT];
    int tid = threadIdx.x;
#pragma unroll
    for (int r = 0; r < 4; ++r)
        insh[r * DBOT + tid] = bf2f(in[((size_t)(b * inRowsPerB + to * 4 + r)) * DBOT + tid]);
    __syncthreads();
    float acc = cb[tid];
    const float* wr = w + (size_t)tid * (DBOT * 4);
    for (int c = 0; c < DBOT; ++c) {
#pragma unroll
        for (int r = 0; r < 4; ++r)
            acc += insh[r * DBOT + c] * wr[c * 4 + r];
    }
    acc = acc * bng[tid] + bnb[tid];
    outp[((size_t)(b * Lout + to)) * DBOT + tid] = f2bf(acc > 0.0f ? acc : (expf(acc) - 1.0f));
}

// ---------------------------------------------------------------------------
// concat pyramid outputs (bf16) -> csc [MCAT][128]
// ---------------------------------------------------------------------------
__launch_bounds__(256)
__global__ void concat_cs_kernel(const short* __restrict__ cs1, const short* __restrict__ cs2,
                                 const short* __restrict__ cs3, short* __restrict__ csc) {
    int idx = blockIdx.x * 256 + threadIdx.x;
    if (idx >= MCAT * DBOT) return;
    int m = idx >> 7, c = idx & 127;
    short v = 0;
    if (m < BB * LC) {
        int b = m / LC, t = m % LC;
        if (t < L1)           v = cs1[(size_t)(b * L1 + t) * DBOT + c];
        else if (t < L1 + L2) v = cs2[(size_t)(b * L2 + (t - L1)) * DBOT + c];
        else                  v = cs3[(size_t)(b * L3 + (t - L1 - L2)) * DBOT + c];
    }
    csc[idx] = v;
}

// ---------------------------------------------------------------------------
// sparse attention over active level (compact Ob)
// ---------------------------------------------------------------------------
__launch_bounds__(256)
__global__ void attn_sparse_kernel(const short* __restrict__ QKV, short* __restrict__ Ob,
                                   int lvl, int cnt) {
    int wid  = blockIdx.x * 4 + (threadIdx.x >> 6);
    if (wid >= cnt * 32) return;
    int lane = threadIdx.x & 63;
    int b = wid & 31, j = wid >> 5;
    int i = d_sets.idx[lvl][j];
    const short8 qv = *(const short8*)(QKV + (size_t)(b * S + i) * 1536 + lane * 8);
    float qf[8];
#pragma unroll
    for (int e = 0; e < 8; ++e) qf[e] = bf2f(qv[e]);
    int nb[NMAX];
#pragma unroll
    for (int jj = 0; jj < NMAX; ++jj) nb[jj] = d_sets.nbr[i][jj];
    float sc[NMAX];
#pragma unroll
    for (int jj = 0; jj < NMAX; ++jj) {
        float s = -1e30f;
        if (nb[jj] >= 0) {
            const short8 kv = *(const short8*)(QKV + (size_t)(b * S + nb[jj]) * 1536 + 512 + lane * 8);
            s = 0.0f;
#pragma unroll
            for (int e = 0; e < 8; ++e) s += qf[e] * bf2f(kv[e]);
            s += __shfl_xor(s, 1); s += __shfl_xor(s, 2); s += __shfl_xor(s, 4);
            s *= 0.125f;
        }
        sc[jj] = s;
    }
    float mx = sc[0];
#pragma unroll
    for (int jj = 1; jj < NMAX; ++jj) mx = fmaxf(mx, sc[jj]);
    float sum = 0.0f;
    float accv[8] = {};
#pragma unroll
    for (int jj = 0; jj < NMAX; ++jj) {
        float p = expf(sc[jj] - mx);
        sum += p;
        if (nb[jj] >= 0) {
            const short8 vv = *(const short8*)(QKV + (size_t)(b * S + nb[jj]) * 1536 + 1024 + lane * 8);
#pragma unroll
            for (int e = 0; e < 8; ++e) accv[e] += p * bf2f(vv[e]);
        }
    }
    float inv = 1.0f / sum;
    short8 ov;
#pragma unroll
    for (int e = 0; e < 8; ++e) ov[e] = f2bf(accv[e] * inv);
    *(short8*)(Ob + (size_t)wid * D + lane * 8) = ov;
}

// ---------------------------------------------------------------------------
// wave-shuffle block reduction over 4 waves (256 thr)
// ---------------------------------------------------------------------------
__device__ inline float blk_reduce(float v, float* ws4, int tid) {
#pragma unroll
    for (int o = 32; o; o >>= 1) v += __shfl_xor(v, o);
    if ((tid & 63) == 0) ws4[tid >> 6] = v;
    __syncthreads();
    return ws4[0] + ws4[1] + ws4[2] + ws4[3];
}

// ---------------------------------------------------------------------------
// concat(emb, coarse) + LayerNorm at A_0 rows only (A_l subsets of A_0):
// compact row -> (b, s=idx[0][j]) -> orig b*S+s
// ---------------------------------------------------------------------------
__launch_bounds__(256)
__global__ void concat_ln_idx(const float* __restrict__ emb, const float* __restrict__ coarse,
                              const float* __restrict__ g, const float* __restrict__ bta,
                              float* __restrict__ seq, short* __restrict__ seq_bf) {
    int row = blockIdx.x;
    int b = row & 31, j = row >> 5;
    int s = d_sets.idx[0][j];
    int orig = b * S + s;
    const float* src = (s < L) ? emb + ((size_t)b * L + s) * D
                               : coarse + ((size_t)b * LC + (s - L)) * D;
    __shared__ float wsA[4];
    __shared__ float wsB[4];
    int tid = threadIdx.x;
    float x0 = src[tid], x1 = src[tid + 256];
    float mu = blk_reduce(x0 + x1, wsA, tid) * (1.0f / D);
    float d0 = x0 - mu, d1 = x1 - mu;
    float var = blk_reduce(d0 * d0 + d1 * d1, wsB, tid) * (1.0f / D);
    float rstd = rsqrtf(var + 1e-5f);
    float v0 = d0 * rstd * g[tid]       + bta[tid];
    float v1 = d1 * rstd * g[tid + 256] + bta[tid + 256];
    float* dst = seq + (size_t)orig * D;
    dst[tid] = v0; dst[tid + 256] = v1;
    short* dbf = seq_bf + (size_t)orig * D;
    dbf[tid] = f2bf(v0); dbf[tid + 256] = f2bf(v1);
}

// ---------------------------------------------------------------------------
// indexed residual LN: compact row -> orig row b*S+idx[lvl][j]; exact grid
// ---------------------------------------------------------------------------
__launch_bounds__(256)
__global__ void add_ln_idx(float* __restrict__ seq, const short* __restrict__ add,
                           const float* __restrict__ g, const float* __restrict__ bta,
                           short* __restrict__ seq_bf, int lvl) {
    int row = blockIdx.x;
    int b = row & 31, j = row >> 5;
    int orig = b * S + d_sets.idx[lvl][j];
    __shared__ float wsA[4];
    __shared__ float wsB[4];
    int tid = threadIdx.x;
    float* srow = seq + (size_t)orig * D;
    const short* arow = add + (size_t)row * D;
    float x0 = srow[tid] + bf2f(arow[tid]);
    float x1 = srow[tid + 256] + bf2f(arow[tid + 256]);
    float mu = blk_reduce(x0 + x1, wsA, tid) * (1.0f / D);
    float d0 = x0 - mu, d1 = x1 - mu;
    float var = blk_reduce(d0 * d0 + d1 * d1, wsB, tid) * (1.0f / D);
    float rstd = rsqrtf(var + 1e-5f);
    float v0 = d0 * rstd * g[tid]       + bta[tid];
    float v1 = d1 * rstd * g[tid + 256] + bta[tid + 256];
    srow[tid] = v0; srow[tid + 256] = v1;
    short* dbf = seq_bf + (size_t)orig * D;
    dbf[tid] = f2bf(v0); dbf[tid + 256] = f2bf(v1);
}

// ---------------------------------------------------------------------------
// prediction head, split-K with fused gather
// ---------------------------------------------------------------------------
__launch_bounds__(256)
__global__ void pred_kernel(const float* __restrict__ seq, const float* __restrict__ w,
                            float* __restrict__ part) {
    __shared__ float es[32][257];
    __shared__ float wsm[256][8];
    int tid = threadIdx.x;
    int n0 = blockIdx.x * 8;
    int ks = blockIdx.y;
    int k0 = ks * 256;
    const int pos[4] = {335, 419, 440, 445};
    int seg = ks >> 1;
    int dbase = (ks & 1) * 256;
#pragma unroll 8
    for (int r = 0; r < 32; ++r)
        es[r][tid] = seq[((size_t)r * S + pos[seg]) * D + dbase + tid];
#pragma unroll
    for (int e = 0; e < 8; ++e)
        wsm[tid][e] = w[(size_t)(k0 + tid) * PRED_N + n0 + e];
    __syncthreads();
    int b = tid >> 3, nn = tid & 7;
    float acc = 0.0f;
#pragma unroll 8
    for (int kk = 0; kk < 256; ++kk)
        acc += es[b][kk] * wsm[kk][nn];
    part[(size_t)ks * (BB * PRED_N) + (size_t)b * PRED_N + n0 + nn] = acc;
}

__launch_bounds__(256)
__global__ void pred_reduce_kernel(const float* __restrict__ part, float* __restrict__ out) {
    int idx = blockIdx.x * 256 + threadIdx.x;
    if (idx >= BB * PRED_N) return;
    float s = 0.0f;
#pragma unroll
    for (int k = 0; k < 8; ++k) s += part[(size_t)k * (BB * PRED_N) + idx];
    out[idx] = s;
}

// ---------------------------------------------------------------------------
extern "C" void kernel_launch(void* const* d_in, const int* in_sizes, int n_in,
                              void* d_out, int out_size, void* d_ws, size_t ws_size,
                              hipStream_t stream) {
    const float* x_enc      = (const float*)d_in[0];
    const float* x_mark_enc = (const float*)d_in[1];
    const float* conv_embed_w = (const float*)d_in[4];
    const float* time_w  = (const float*)d_in[5];
    const float* time_b  = (const float*)d_in[6];
    const float* down_w  = (const float*)d_in[7];
    const float* down_b  = (const float*)d_in[8];
    const float* cscm_w  = (const float*)d_in[9];
    const float* cscm_b  = (const float*)d_in[10];
    const float* bn_g    = (const float*)d_in[11];
    const float* bn_b    = (const float*)d_in[12];
    const float* up_w    = (const float*)d_in[13];
    const float* up_b    = (const float*)d_in[14];
    const float* cln_g   = (const float*)d_in[15];
    const float* cln_b   = (const float*)d_in[16];
    const float* wq      = (const float*)d_in[17];
    const float* wk      = (const float*)d_in[18];
    const float* wv      = (const float*)d_in[19];
    const float* wo      = (const float*)d_in[20];
    const float* ln1_g   = (const float*)d_in[21];
    const float* ln1_b   = (const float*)d_in[22];
    const float* ffn_w1  = (const float*)d_in[23];
    const float* ffn_b1  = (const float*)d_in[24];
    const float* ffn_w2  = (const float*)d_in[25];
    const float* ffn_b2  = (const float*)d_in[26];
    const float* ln2_g   = (const float*)d_in[27];
    const float* ln2_b   = (const float*)d_in[28];
    const float* pred_w  = (const float*)d_in[29];
    float* out = (float*)d_out;

    // ---- workspace layout (bytes, 256-aligned) ----
    char* w8 = (char*)d_ws;
    size_t off = 0;
    auto alloc = [&](size_t bytes) {
        void* p = w8 + off;
        off = (off + bytes + 255) & ~(size_t)255;
        return p;
    };
    float* emb    = (float*)alloc((size_t)BB * L * D * 4);
    short* emb_bf = (short*)alloc((size_t)BB * L * D * 2);
    float* pe     = (float*)alloc((size_t)L * D * 4);
    short* xim    = (short*)alloc((size_t)BB * L * 32 * 2);
    short* wE     = (short*)alloc((size_t)D * 32 * 2);
    short* xd_bf  = (short*)alloc((size_t)BB * L * DBOT * 2);
    short* cs1_bf = (short*)alloc((size_t)MCONV2P * 512 * 2);
    short* cs2_bf = (short*)alloc((size_t)MCONV2P * DBOT * 2);
    short* cs3_bf = (short*)alloc((size_t)BB * L3 * DBOT * 2);
    short* csc_bf = (short*)alloc((size_t)MCAT * DBOT * 2);
    float* coarse = (float*)alloc((size_t)MCAT * D * 4);
    float* seq    = (float*)alloc((size_t)BB * S * D * 4);
    short* T1     = (short*)alloc((size_t)MP * D * 2);
    float* part   = (float*)alloc((size_t)8 * BB * PRED_N * 4);
    short* seq_bf = (short*)alloc((size_t)MP * D * 2);
    short* QKV    = (short*)alloc((size_t)MP * 3 * D * 2);  // + Ob contiguous
    short* Ob     = (short*)alloc((size_t)MP * D * 2);
    short* hidden = QKV;
    short* wqkvT  = (short*)alloc((size_t)NLAYER * 3 * D * D * 2);
    short* woT    = (short*)alloc((size_t)NLAYER * D * D * 2);
    short* w1T    = (short*)alloc((size_t)NLAYER * DFF * D * 2);
    short* w2T    = (short*)alloc((size_t)NLAYER * D * DFF * 2);
    short* downT  = (short*)alloc((size_t)DBOT * D * 2);
    short* upT    = (short*)alloc((size_t)D * DBOT * 2);
    short* cscmT  = (short*)alloc((size_t)2 * DBOT * 512 * 2);
    float* csc_sc = (float*)alloc((size_t)3 * DBOT * 4);
    float* csc_sh = (float*)alloc((size_t)3 * DBOT * 4);
    (void)ws_size; (void)in_sizes; (void)n_in; (void)out_size;

    const int rowsL = BB * L;   // 10752 = 84*128
    dim3 blk(256);

    // 0. weight convert+transpose + pe table + embed prep
    wtrans_qkvo<<<dim3(16, 16, 4 * NLAYER), blk, 0, stream>>>(wq, wk, wv, wo, wqkvT, woT);
    wtrans_ffn<<<dim3(64, 16, 2 * NLAYER), blk, 0, stream>>>(ffn_w1, ffn_w2, w1T, w2T);
    wtrans_one<<<dim3(DBOT / 32, D / 32), blk, 0, stream>>>(down_w, downT, D, DBOT);
    wtrans_one<<<dim3(D / 32, DBOT / 32), blk, 0, stream>>>(up_w, upT, DBOT, D);
    cscm_prep<<<dim3((2 * DBOT * 512 + 255) / 256), blk, 0, stream>>>(
        cscm_w, cscm_b, bn_g, bn_b, cscmT, csc_sc, csc_sh);
    pe_kernel<<<dim3((L * D + 255) / 256), blk, 0, stream>>>(pe);
    wembed_kernel<<<dim3((D * 32 + 255) / 256), blk, 0, stream>>>(
        conv_embed_w, time_w, time_b, wE);
    im2col_kernel<<<dim3((rowsL * 32 + 255) / 256), blk, 0, stream>>>(
        x_enc, x_mark_enc, xim);
    // 1. embedding as GEMM (M=10752, N=512, K=32) + pe epilogue, dual output
    mfma_gemm<6><<<dim3(D / 128, rowsL / 128), blk, 0, stream>>>(
        xim, wE, nullptr, nullptr, emb, 32, D, -1, -1, 0, pe, emb_bf);
    // 2. down projection -> bf16
    mfma_gemm<4><<<dim3(1, rowsL / 128), blk, 0, stream>>>(
        emb_bf, downT, down_b, nullptr, xd_bf, D, DBOT, -1, -1, 0, nullptr, nullptr);
    // 3. CSCM pyramid
    mfma_gemm<5><<<dim3(1, MCONV1 / 128), blk, 0, stream>>>(
        xd_bf, cscmT, csc_sc, csc_sh, cs1_bf, 512, DBOT, -1, -1, 0, nullptr, nullptr);
    mfma_gemm<5><<<dim3(1, MCONV2P / 128), blk, 0, stream>>>(
        cs1_bf, cscmT + (size_t)DBOT * 512, csc_sc + DBOT, csc_sh + DBOT,
        cs2_bf, 512, DBOT, -1, -1, 0, nullptr, nullptr);
    cscm_conv_bf16<<<dim3(BB * L3), dim3(DBOT), 0, stream>>>(
        cs2_bf, L2, cs3_bf, cscm_w + 2 * DBOT * DBOT * 4,
        cscm_b + 2 * DBOT, bn_g + 2 * DBOT, bn_b + 2 * DBOT, L3);
    // 4. up projection
    concat_cs_kernel<<<dim3((MCAT * DBOT + 255) / 256), blk, 0, stream>>>(
        cs1_bf, cs2_bf, cs3_bf, csc_bf);
    mfma_gemm<1><<<dim3(D / 128, MCAT / 128), blk, 0, stream>>>(
        csc_bf, upT, up_b, nullptr, coarse, DBOT, D, -1, -1, 0, nullptr, nullptr);
    // 5. concat + LN (A_0 rows only; all downstream sets are subsets)
    concat_ln_idx<<<dim3(HS.cnt[0] * 32), blk, 0, stream>>>(
        emb, coarse, cln_g, cln_b, seq, seq_bf);

    // 6. encoder layers (compile-time sparse active sets; grids exact)
    for (int l = 0; l < NLAYER; ++l) {
        const int inLvl = l, outLvl = l + 1;
        const int inCnt  = HS.cnt[l];
        const int outCnt = HS.cnt[l + 1];
        mfma_gemm256<2><<<dim3(3 * D / 256, (inCnt * 32 + 255) / 256), dim3(512), 0, stream>>>(
            seq_bf, wqkvT + (size_t)l * 3 * D * D, nullptr, QKV, D, 3 * D,
            inLvl, inLvl, inCnt);
        attn_sparse_kernel<<<dim3(outCnt * 8), blk, 0, stream>>>(
            QKV, Ob, outLvl, outCnt);
        mfma_gemm<2><<<dim3(D / 128, (outCnt * 32 + 127) / 128), blk, 0, stream>>>(
            Ob, woT + (size_t)l * D * D, nullptr, nullptr, T1, D, D,
            -1, -1, 0, nullptr, nullptr);
        add_ln_idx<<<dim3(outCnt * 32), blk, 0, stream>>>(
            seq, T1, ln1_g + (size_t)l * D, ln1_b + (size_t)l * D, seq_bf, outLvl);
        mfma_gemm256<3><<<dim3(DFF / 256, (outCnt * 32 + 255) / 256), dim3(512), 0, stream>>>(
            seq_bf, w1T + (size_t)l * DFF * D, ffn_b1 + (size_t)l * DFF, hidden, D, DFF,
            outLvl, -1, outCnt);
        mfma_gemm<4><<<dim3(D / 128, (outCnt * 32 + 127) / 128), blk, 0, stream>>>(
            hidden, w2T + (size_t)l * D * DFF, ffn_b2 + (size_t)l * D, nullptr, T1, DFF, D,
            -1, -1, 0, nullptr, nullptr);
        add_ln_idx<<<dim3(outCnt * 32), blk, 0, stream>>>(
            seq, T1, ln2_g + (size_t)l * D, ln2_b + (size_t)l * D, seq_bf, outLvl);
    }

    // 7. prediction head (split-K, gather fused) + reduce
    pred_kernel<<<dim3(PRED_N / 8, 8), blk, 0, stream>>>(seq, pred_w, part);
    pred_reduce_kernel<<<dim3((BB * PRED_N + 255) / 256), blk, 0, stream>>>(part, out);
}

// Round 16
// 473.732 us; speedup vs baseline: 1.9130x; 1.2240x over previous
//
#include <hip/hip_runtime.h>
#include <math.h>

// ---- problem constants ----
constexpr int BB   = 32;    // batch
constexpr int L    = 336;   // seq_len
constexpr int CIN  = 7;
constexpr int MARK = 4;
constexpr int D    = 512;   // d_model
constexpr int DFF  = 2048;
constexpr int NH   = 8;
constexpr int HD   = 64;    // dk = dv
constexpr int S    = 446;   // 336+84+21+5
constexpr int DBOT = 128;
constexpr int L1 = 84, L2 = 21, L3 = 5;
constexpr int LC = 110;     // 84+21+5
constexpr int NLAYER = 3;
constexpr int PRED_N = 672; // 96*7
constexpr int MP   = 14336; // BB*S padded
constexpr int NMAX = 12;    // max sparse neighbors (real max 10)
constexpr int MCONV1 = BB * L1;          // 2688 = 21*128 (exact)
constexpr int MCONV2P = 768;             // BB*L2=672 padded to 6*128
constexpr int MCAT  = 3584;              // BB*LC=3520 padded to 28*128

using short8  = __attribute__((ext_vector_type(8))) short;
using float4v = __attribute__((ext_vector_type(4))) float;

// ---------------------------------------------------------------------------
// COMPILE-TIME pyramid structure: neighbor lists + active sets.
// A3 = gather positions {335,419,440,445}; A_{l-1} = U nbr(A_l), sorted.
// Every node is its own neighbor => A3 <= A2 <= A1 <= A0 (set inclusion).
// Layer l (0-based): QKV at idx[l] (cnt[l]), attn/Oproj/LN/FFN at idx[l+1].
// ---------------------------------------------------------------------------
struct SetsData {
    int nbr[S][NMAX];
    int idx[4][S];
    int cnt[4];
};

constexpr SetsData compute_sets() {
    SetsData sd{};
    constexpr int sizes[4]  = {336, 84, 21, 5};
    constexpr int starts[4] = {0, 336, 420, 441};
    for (int i = 0; i < S; ++i) {
        int li = 0, pi = i;
        if (i < 336)      { li = 0; pi = i; }
        else if (i < 420) { li = 1; pi = i - 336; }
        else if (i < 441) { li = 2; pi = i - 420; }
        else              { li = 3; pi = i - 441; }
        int cnt = 0;
        for (int d = -2; d <= 2; ++d) {
            int q = pi + d;
            if (q >= 0 && q < sizes[li]) sd.nbr[i][cnt++] = starts[li] + q;
        }
        if (li > 0) {
            int lo = pi * 4;
            int hi = (pi == sizes[li] - 1) ? sizes[li - 1] : (pi + 1) * 4;
            for (int c = lo; c < hi; ++c) sd.nbr[i][cnt++] = starts[li - 1] + c;
        }
        if (li < 3) {
            int q = pi >> 2;
            if (q > sizes[li + 1] - 1) q = sizes[li + 1] - 1;
            sd.nbr[i][cnt++] = starts[li + 1] + q;
        }
        for (int j = cnt; j < NMAX; ++j) sd.nbr[i][j] = -1;
    }
    sd.cnt[3] = 4;
    sd.idx[3][0] = 335; sd.idx[3][1] = 419; sd.idx[3][2] = 440; sd.idx[3][3] = 445;
    for (int lvl = 3; lvl >= 1; --lvl) {
        bool mk[S] = {};
        for (int k = 0; k < sd.cnt[lvl]; ++k) {
            int i = sd.idx[lvl][k];
            for (int t = 0; t < NMAX; ++t) {
                int v = sd.nbr[i][t];
                if (v >= 0) mk[v] = true;
            }
        }
        int nc = 0;
        for (int i = 0; i < S; ++i)
            if (mk[i]) sd.idx[lvl - 1][nc++] = i;
        sd.cnt[lvl - 1] = nc;
    }
    return sd;
}

constexpr SetsData HS = compute_sets();         // host: grid sizing
__constant__ SetsData d_sets = compute_sets();  // device: row maps + nbr

__device__ inline short f2bf(float f) {
    union { float f; unsigned u; } v; v.f = f;
    unsigned r = v.u + 0x7fffu + ((v.u >> 16) & 1u);
    return (short)(r >> 16);
}
__device__ inline float bf2f(short h) {
    union { unsigned u; float f; } v; v.u = ((unsigned)(unsigned short)h) << 16;
    return v.f;
}

// async global->LDS, 16B per lane, wave-uniform LDS base + lane*16
__device__ inline void gload_lds16(const void* g, void* l) {
    __builtin_amdgcn_global_load_lds(
        (const __attribute__((address_space(1))) void*)g,
        (__attribute__((address_space(3))) void*)l, 16, 0, 0);
}

// Staging map: conflict-free + coalesced (verified r11: 0 bank conflicts):
// LDS 16B-chunk u encodes row=((u>>3)<<1)|((u>>2)&1), k-slot s=u&3 holding
// global kseg kg = s ^ ((u>>3)&3). Reader: rh=row>>1, s=lk^(rh&3),
// chunk=rh*8+(row&1)*4+s.
// Sparse rows: alvl/clvl >= 0 select d_sets.idx[lvl] (pos-major compact:
// compact m -> b=m&31, j=m>>5 clamped to cnt-1, orig row b*S+idx[j]).

// ---------------------------------------------------------------------------
// 128x128 bf16 MFMA GEMM, BK=32, double-buffered, counted vmcnt(4) pipeline.
// 4 blocks/CU (32KB LDS) — the only GEMM tile now; sparse-M shapes are
// latency-bound, so max blocks/CU beats the 256² tile's byte savings (r15).
// EPI: 0 f32; 1 f32+bias; 2 bf16; 3 bf16+bias+gelu; 4 bf16+bias;
//      5 bf16, v = acc*bias[gn]+bias2[gn] then ELU;
//      6 v = acc + peT[(row%L)*D+gn], write f32 Cout AND bf16 Cout2 (embed)
// ---------------------------------------------------------------------------
template<int EPI>
__launch_bounds__(256, 4)
__global__ void mfma_gemm(const short* __restrict__ A, const short* __restrict__ Bt,
                          const float* __restrict__ bias, const float* __restrict__ bias2,
                          void* __restrict__ Cout, int Kd, int Nd,
                          int alvl, int clvl, int cnt,
                          const float* __restrict__ peT, short* __restrict__ Cout2) {
    __shared__ short As[2][128 * 32];
    __shared__ short Bs[2][128 * 32];
    int tid = threadIdx.x;
    int nwg  = gridDim.x * gridDim.y;
    int orig = blockIdx.y * gridDim.x + blockIdx.x;
    int qq = nwg >> 3, rr = nwg & 7;
    int xcd = orig & 7, idx = orig >> 3;
    int wgid = (xcd < rr ? xcd * (qq + 1) : rr * (qq + 1) + (xcd - rr) * qq) + idx;
    int m0 = (wgid / gridDim.x) * 128, n0 = (wgid % gridDim.x) * 128;

    int lane = tid & 63, wid = tid >> 6;
    int wm = wid >> 1, wn = wid & 1;
    int lr = lane & 15, lk = lane >> 4;

    size_t abase[2], bbase[2];
#pragma unroll
    for (int r = 0; r < 2; ++r) {
        int u = r * 256 + tid;
        int row = ((u >> 3) << 1) | ((u >> 2) & 1);
        int kg  = (u & 3) ^ ((u >> 3) & 3);
        int rm = m0 + row, ga;
        if (alvl >= 0) { int j = rm >> 5; if (j > cnt - 1) j = cnt - 1; ga = (rm & 31) * S + d_sets.idx[alvl][j]; }
        else ga = rm;
        abase[r] = (size_t)ga * Kd + kg * 8;
        bbase[r] = (size_t)(n0 + row) * Kd + kg * 8;
    }
    auto stage = [&](int buf, int k0) {
#pragma unroll
        for (int r = 0; r < 2; ++r) {
            short* la = As[buf] + (size_t)(r * 256 + wid * 64) * 8;
            short* lb = Bs[buf] + (size_t)(r * 256 + wid * 64) * 8;
            gload_lds16(A + abase[r] + k0, la);
            gload_lds16(Bt + bbase[r] + k0, lb);
        }
    };
    auto rd_off = [&](int row_) {
        int rh = row_ >> 1;
        int s  = lk ^ (rh & 3);
        return (size_t)(rh * 8 + (row_ & 1) * 4 + s) * 8;
    };

    float4v acc[4][4];
#pragma unroll
    for (int i = 0; i < 4; ++i)
#pragma unroll
        for (int j = 0; j < 4; ++j) acc[i][j] = 0;

    const int nt = Kd >> 5;
    stage(0, 0);
    for (int t = 0; t < nt; ++t) {
        int cur = t & 1;
        if (t + 1 < nt) {
            stage(cur ^ 1, (t + 1) * 32);
            asm volatile("s_waitcnt vmcnt(4)" ::: "memory");
        } else {
            asm volatile("s_waitcnt vmcnt(0)" ::: "memory");
        }
        __builtin_amdgcn_s_barrier();
        short8 af[4], bfv[4];
#pragma unroll
        for (int mi = 0; mi < 4; ++mi)
            af[mi] = *(const short8*)(As[cur] + rd_off(wm * 64 + mi * 16 + lr));
#pragma unroll
        for (int ni = 0; ni < 4; ++ni)
            bfv[ni] = *(const short8*)(Bs[cur] + rd_off(wn * 64 + ni * 16 + lr));
        __builtin_amdgcn_s_setprio(1);
#pragma unroll
        for (int mi = 0; mi < 4; ++mi)
#pragma unroll
            for (int ni = 0; ni < 4; ++ni)
                acc[mi][ni] = __builtin_amdgcn_mfma_f32_16x16x32_bf16(
                    af[mi], bfv[ni], acc[mi][ni], 0, 0, 0);
        __builtin_amdgcn_s_setprio(0);
        __builtin_amdgcn_s_barrier();
    }

#pragma unroll
    for (int mi = 0; mi < 4; ++mi) {
        int gmc = m0 + wm * 64 + mi * 16 + lk * 4;
#pragma unroll
        for (int ni = 0; ni < 4; ++ni) {
            int gn = n0 + wn * 64 + ni * 16 + lr;
            float bsv = (EPI == 1 || EPI == 3 || EPI == 4) ? bias[gn] : 0.0f;
            float sc = (EPI == 5) ? bias[gn]  : 0.0f;
            float sh = (EPI == 5) ? bias2[gn] : 0.0f;
#pragma unroll
            for (int e = 0; e < 4; ++e) {
                int rm = gmc + e, grow;
                if (clvl >= 0) { int j = rm >> 5; if (j > cnt - 1) j = cnt - 1; grow = (rm & 31) * S + d_sets.idx[clvl][j]; }
                else grow = rm;
                float v = acc[mi][ni][e] + bsv;
                if (EPI == 3) v = 0.5f * v * (1.0f + erff(v * 0.70710678118654752f));
                if (EPI == 5) { v = v * sc + sh; v = v > 0.0f ? v : (expf(v) - 1.0f); }
                if (EPI == 6) {
                    v += peT[(size_t)(grow % L) * D + gn];
                    ((float*)Cout)[(size_t)grow * Nd + gn] = v;
                    Cout2[(size_t)grow * Nd + gn] = f2bf(v);
                } else if (EPI <= 1) {
                    ((float*)Cout)[(size_t)grow * Nd + gn] = v;
                } else {
                    ((short*)Cout)[(size_t)grow * Nd + gn] = f2bf(v);
                }
            }
        }
    }
}

// ---------------------------------------------------------------------------
// batched weight transpose+convert, 32x32 tiles, f32 W[Kd][Nd] -> bf16 Wt[Nd][Kd]
// ---------------------------------------------------------------------------
__device__ inline void wtrans_tile(const float* __restrict__ W, short* __restrict__ Wt,
                                   int Kd, int Nd, int n0, int k0, int tid) {
    __shared__ float tile[32][33];
    int tx = tid & 31, ty = tid >> 5; // ty 0..7
#pragma unroll
    for (int r = 0; r < 32; r += 8)
        tile[ty + r][tx] = W[(size_t)(k0 + ty + r) * Nd + n0 + tx];
    __syncthreads();
#pragma unroll
    for (int r = 0; r < 32; r += 8)
        Wt[(size_t)(n0 + ty + r) * Kd + k0 + tx] = f2bf(tile[tx][ty + r]);
}

__launch_bounds__(256)
__global__ void wtrans_qkvo(const float* __restrict__ wq, const float* __restrict__ wk,
                            const float* __restrict__ wv, const float* __restrict__ wo,
                            short* __restrict__ wqkvT, short* __restrict__ woT) {
    int z = blockIdx.z, l = z >> 2, part = z & 3;
    const float* src = (part == 0 ? wq : part == 1 ? wk : part == 2 ? wv : wo)
                       + (size_t)l * D * D;
    short* dst = (part < 3) ? wqkvT + (size_t)l * 3 * D * D + (size_t)part * D * D
                            : woT + (size_t)l * D * D;
    wtrans_tile(src, dst, D, D, blockIdx.x * 32, blockIdx.y * 32, threadIdx.x);
}

__launch_bounds__(256)
__global__ void wtrans_ffn(const float* __restrict__ w1, const float* __restrict__ w2,
                           short* __restrict__ w1T, short* __restrict__ w2T) {
    int z = blockIdx.z, l = z >> 1, part = z & 1;
    int nt = part ? blockIdx.y : blockIdx.x;
    int kt = part ? blockIdx.x : blockIdx.y;
    if (part == 0)
        wtrans_tile(w1 + (size_t)l * D * DFF, w1T + (size_t)l * DFF * D,
                    D, DFF, nt * 32, kt * 32, threadIdx.x);
    else
        wtrans_tile(w2 + (size_t)l * DFF * D, w2T + (size_t)l * D * DFF,
                    DFF, D, nt * 32, kt * 32, threadIdx.x);
}

__launch_bounds__(256)
__global__ void wtrans_one(const float* __restrict__ W, short* __restrict__ Wt,
                           int Kd, int Nd) {
    wtrans_tile(W, Wt, Kd, Nd, blockIdx.x * 32, blockIdx.y * 32, threadIdx.x);
}

// ---------------------------------------------------------------------------
// CSCM prep
// ---------------------------------------------------------------------------
__launch_bounds__(256)
__global__ void cscm_prep(const float* __restrict__ cw, const float* __restrict__ cb,
                          const float* __restrict__ bg, const float* __restrict__ bb,
                          short* __restrict__ cscmT, float* __restrict__ sc,
                          float* __restrict__ sh) {
    int idx = blockIdx.x * 256 + threadIdx.x;
    if (idx < 2 * DBOT * 512) {
        int l = idx >> 16;
        int rem = idx & 65535;
        int oc = rem >> 9, j = rem & 511;
        int r = j >> 7, c = j & 127;
        cscmT[idx] = f2bf(cw[(((size_t)l * DBOT + oc) * DBOT + c) * 4 + r]);
    }
    if (idx < 3 * DBOT) {
        sc[idx] = bg[idx];
        sh[idx] = cb[idx] * bg[idx] + bb[idx];
    }
}

// ---------------------------------------------------------------------------
// positional-encoding table: pe[t][d], computed ONCE
// ---------------------------------------------------------------------------
__launch_bounds__(256)
__global__ void pe_kernel(float* __restrict__ pe) {
    int idx = blockIdx.x * 256 + threadIdx.x;
    if (idx >= L * D) return;
    int d = idx % D, t = idx / D;
    int e = d & ~1;
    float div = expf(-(float)e * (logf(10000.0f) / (float)D));
    float arg = (float)t * div;
    pe[idx] = (d & 1) ? cosf(arg) : sinf(arg);
}

// ---------------------------------------------------------------------------
// embed as GEMM: im2col matrix xim[BB*L][32] (bf16)
// ---------------------------------------------------------------------------
__launch_bounds__(256)
__global__ void im2col_kernel(const float* __restrict__ x_enc, const float* __restrict__ x_mark,
                              short* __restrict__ xim) {
    int idx = blockIdx.x * 256 + threadIdx.x;
    if (idx >= BB * L * 32) return;
    int k = idx & 31, m = idx >> 5;
    int t = m % L, b = m / L;
    float v = 0.0f;
    if (k < 21) {
        int w = k / 7, i = k % 7;
        int s = t + w - 1;
        if (s < 0) s = L - 1;
        if (s >= L) s = 0;
        v = x_enc[((size_t)b * L + s) * CIN + i];
    } else if (k < 25) {
        v = x_mark[(size_t)m * MARK + (k - 21)];
    } else if (k == 25) {
        v = 1.0f;
    }
    xim[idx] = f2bf(v);
}

// embed weight in Bt layout wE[512][32]
__launch_bounds__(256)
__global__ void wembed_kernel(const float* __restrict__ cw, const float* __restrict__ tw,
                              const float* __restrict__ tb, short* __restrict__ wE) {
    int idx = blockIdx.x * 256 + threadIdx.x;
    if (idx >= D * 32) return;
    int k = idx & 31, d = idx >> 5;
    float v = 0.0f;
    if (k < 21) {
        int w = k / 7, i = k % 7;
        v = cw[(size_t)d * (CIN * 3) + i * 3 + w];
    } else if (k < 25) {
        v = tw[(size_t)(k - 21) * D + d];
    } else if (k == 25) {
        v = tb[d];
    }
    wE[idx] = f2bf(v);
}

// ---------------------------------------------------------------------------
// CSCM conv level 3 (tiny)
// ---------------------------------------------------------------------------
__launch_bounds__(128)
__global__ void cscm_conv_bf16(const short* __restrict__ in, int inRowsPerB,
                               short* __restrict__ outp, const float* __restrict__ w,
                               const float* __restrict__ cb, const float* __restrict__ bng,
                               const float* __restrict__ bnb, int Lout) {
    int bid = blockIdx.x;
    int to = bid % Lout, b = bid / Lout;
    __shared__ float insh[4 * DBOT];
    int tid = threadIdx.x;
#pragma unroll
    for (int r = 0; r < 4; ++r)
        insh[r * DBOT + tid] = bf2f(in[((size_t)(b * inRowsPerB + to * 4 + r)) * DBOT + tid]);
    __syncthreads();
    float acc = cb[tid];
    const float* wr = w + (size_t)tid * (DBOT * 4);
    for (int c = 0; c < DBOT; ++c) {
#pragma unroll
        for (int r = 0; r < 4; ++r)
            acc += insh[r * DBOT + c] * wr[c * 4 + r];
    }
    acc = acc * bng[tid] + bnb[tid];
    outp[((size_t)(b * Lout + to)) * DBOT + tid] = f2bf(acc > 0.0f ? acc : (expf(acc) - 1.0f));
}

// ---------------------------------------------------------------------------
// concat pyramid outputs (bf16) -> csc [MCAT][128]
// ---------------------------------------------------------------------------
__launch_bounds__(256)
__global__ void concat_cs_kernel(const short* __restrict__ cs1, const short* __restrict__ cs2,
                                 const short* __restrict__ cs3, short* __restrict__ csc) {
    int idx = blockIdx.x * 256 + threadIdx.x;
    if (idx >= MCAT * DBOT) return;
    int m = idx >> 7, c = idx & 127;
    short v = 0;
    if (m < BB * LC) {
        int b = m / LC, t = m % LC;
        if (t < L1)           v = cs1[(size_t)(b * L1 + t) * DBOT + c];
        else if (t < L1 + L2) v = cs2[(size_t)(b * L2 + (t - L1)) * DBOT + c];
        else                  v = cs3[(size_t)(b * L3 + (t - L1 - L2)) * DBOT + c];
    }
    csc[idx] = v;
}

// ---------------------------------------------------------------------------
// sparse attention over active level (compact Ob)
// ---------------------------------------------------------------------------
__launch_bounds__(256)
__global__ void attn_sparse_kernel(const short* __restrict__ QKV, short* __restrict__ Ob,
                                   int lvl, int cnt) {
    int wid  = blockIdx.x * 4 + (threadIdx.x >> 6);
    if (wid >= cnt * 32) return;
    int lane = threadIdx.x & 63;
    int b = wid & 31, j = wid >> 5;
    int i = d_sets.idx[lvl][j];
    const short8 qv = *(const short8*)(QKV + (size_t)(b * S + i) * 1536 + lane * 8);
    float qf[8];
#pragma unroll
    for (int e = 0; e < 8; ++e) qf[e] = bf2f(qv[e]);
    int nb[NMAX];
#pragma unroll
    for (int jj = 0; jj < NMAX; ++jj) nb[jj] = d_sets.nbr[i][jj];
    float sc[NMAX];
#pragma unroll
    for (int jj = 0; jj < NMAX; ++jj) {
        float s = -1e30f;
        if (nb[jj] >= 0) {
            const short8 kv = *(const short8*)(QKV + (size_t)(b * S + nb[jj]) * 1536 + 512 + lane * 8);
            s = 0.0f;
#pragma unroll
            for (int e = 0; e < 8; ++e) s += qf[e] * bf2f(kv[e]);
            s += __shfl_xor(s, 1); s += __shfl_xor(s, 2); s += __shfl_xor(s, 4);
            s *= 0.125f;
        }
        sc[jj] = s;
    }
    float mx = sc[0];
#pragma unroll
    for (int jj = 1; jj < NMAX; ++jj) mx = fmaxf(mx, sc[jj]);
    float sum = 0.0f;
    float accv[8] = {};
#pragma unroll
    for (int jj = 0; jj < NMAX; ++jj) {
        float p = expf(sc[jj] - mx);
        sum += p;
        if (nb[jj] >= 0) {
            const short8 vv = *(const short8*)(QKV + (size_t)(b * S + nb[jj]) * 1536 + 1024 + lane * 8);
#pragma unroll
            for (int e = 0; e < 8; ++e) accv[e] += p * bf2f(vv[e]);
        }
    }
    float inv = 1.0f / sum;
    short8 ov;
#pragma unroll
    for (int e = 0; e < 8; ++e) ov[e] = f2bf(accv[e] * inv);
    *(short8*)(Ob + (size_t)wid * D + lane * 8) = ov;
}

// ---------------------------------------------------------------------------
// wave-shuffle block reduction over 4 waves (256 thr)
// ---------------------------------------------------------------------------
__device__ inline float blk_reduce(float v, float* ws4, int tid) {
#pragma unroll
    for (int o = 32; o; o >>= 1) v += __shfl_xor(v, o);
    if ((tid & 63) == 0) ws4[tid >> 6] = v;
    __syncthreads();
    return ws4[0] + ws4[1] + ws4[2] + ws4[3];
}

// ---------------------------------------------------------------------------
// concat(emb, coarse) + LayerNorm at A_0 rows only
// ---------------------------------------------------------------------------
__launch_bounds__(256)
__global__ void concat_ln_idx(const float* __restrict__ emb, const float* __restrict__ coarse,
                              const float* __restrict__ g, const float* __restrict__ bta,
                              float* __restrict__ seq, short* __restrict__ seq_bf) {
    int row = blockIdx.x;
    int b = row & 31, j = row >> 5;
    int s = d_sets.idx[0][j];
    int orig = b * S + s;
    const float* src = (s < L) ? emb + ((size_t)b * L + s) * D
                               : coarse + ((size_t)b * LC + (s - L)) * D;
    __shared__ float wsA[4];
    __shared__ float wsB[4];
    int tid = threadIdx.x;
    float x0 = src[tid], x1 = src[tid + 256];
    float mu = blk_reduce(x0 + x1, wsA, tid) * (1.0f / D);
    float d0 = x0 - mu, d1 = x1 - mu;
    float var = blk_reduce(d0 * d0 + d1 * d1, wsB, tid) * (1.0f / D);
    float rstd = rsqrtf(var + 1e-5f);
    float v0 = d0 * rstd * g[tid]       + bta[tid];
    float v1 = d1 * rstd * g[tid + 256] + bta[tid + 256];
    float* dst = seq + (size_t)orig * D;
    dst[tid] = v0; dst[tid + 256] = v1;
    short* dbf = seq_bf + (size_t)orig * D;
    dbf[tid] = f2bf(v0); dbf[tid + 256] = f2bf(v1);
}

// ---------------------------------------------------------------------------
// indexed residual LN: compact row -> orig row b*S+idx[lvl][j]; exact grid
// ---------------------------------------------------------------------------
__launch_bounds__(256)
__global__ void add_ln_idx(float* __restrict__ seq, const short* __restrict__ add,
                           const float* __restrict__ g, const float* __restrict__ bta,
                           short* __restrict__ seq_bf, int lvl) {
    int row = blockIdx.x;
    int b = row & 31, j = row >> 5;
    int orig = b * S + d_sets.idx[lvl][j];
    __shared__ float wsA[4];
    __shared__ float wsB[4];
    int tid = threadIdx.x;
    float* srow = seq + (size_t)orig * D;
    const short* arow = add + (size_t)row * D;
    float x0 = srow[tid] + bf2f(arow[tid]);
    float x1 = srow[tid + 256] + bf2f(arow[tid + 256]);
    float mu = blk_reduce(x0 + x1, wsA, tid) * (1.0f / D);
    float d0 = x0 - mu, d1 = x1 - mu;
    float var = blk_reduce(d0 * d0 + d1 * d1, wsB, tid) * (1.0f / D);
    float rstd = rsqrtf(var + 1e-5f);
    float v0 = d0 * rstd * g[tid]       + bta[tid];
    float v1 = d1 * rstd * g[tid + 256] + bta[tid + 256];
    srow[tid] = v0; srow[tid + 256] = v1;
    short* dbf = seq_bf + (size_t)orig * D;
    dbf[tid] = f2bf(v0); dbf[tid + 256] = f2bf(v1);
}

// ---------------------------------------------------------------------------
// prediction head, split-K with fused gather
// ---------------------------------------------------------------------------
__launch_bounds__(256)
__global__ void pred_kernel(const float* __restrict__ seq, const float* __restrict__ w,
                            float* __restrict__ part) {
    __shared__ float es[32][257];
    __shared__ float wsm[256][8];
    int tid = threadIdx.x;
    int n0 = blockIdx.x * 8;
    int ks = blockIdx.y;
    int k0 = ks * 256;
    const int pos[4] = {335, 419, 440, 445};
    int seg = ks >> 1;
    int dbase = (ks & 1) * 256;
#pragma unroll 8
    for (int r = 0; r < 32; ++r)
        es[r][tid] = seq[((size_t)r * S + pos[seg]) * D + dbase + tid];
#pragma unroll
    for (int e = 0; e < 8; ++e)
        wsm[tid][e] = w[(size_t)(k0 + tid) * PRED_N + n0 + e];
    __syncthreads();
    int b = tid >> 3, nn = tid & 7;
    float acc = 0.0f;
#pragma unroll 8
    for (int kk = 0; kk < 256; ++kk)
        acc += es[b][kk] * wsm[kk][nn];
    part[(size_t)ks * (BB * PRED_N) + (size_t)b * PRED_N + n0 + nn] = acc;
}

__launch_bounds__(256)
__global__ void pred_reduce_kernel(const float* __restrict__ part, float* __restrict__ out) {
    int idx = blockIdx.x * 256 + threadIdx.x;
    if (idx >= BB * PRED_N) return;
    float s = 0.0f;
#pragma unroll
    for (int k = 0; k < 8; ++k) s += part[(size_t)k * (BB * PRED_N) + idx];
    out[idx] = s;
}

// ---------------------------------------------------------------------------
extern "C" void kernel_launch(void* const* d_in, const int* in_sizes, int n_in,
                              void* d_out, int out_size, void* d_ws, size_t ws_size,
                              hipStream_t stream) {
    const float* x_enc      = (const float*)d_in[0];
    const float* x_mark_enc = (const float*)d_in[1];
    const float* conv_embed_w = (const float*)d_in[4];
    const float* time_w  = (const float*)d_in[5];
    const float* time_b  = (const float*)d_in[6];
    const float* down_w  = (const float*)d_in[7];
    const float* down_b  = (const float*)d_in[8];
    const float* cscm_w  = (const float*)d_in[9];
    const float* cscm_b  = (const float*)d_in[10];
    const float* bn_g    = (const float*)d_in[11];
    const float* bn_b    = (const float*)d_in[12];
    const float* up_w    = (const float*)d_in[13];
    const float* up_b    = (const float*)d_in[14];
    const float* cln_g   = (const float*)d_in[15];
    const float* cln_b   = (const float*)d_in[16];
    const float* wq      = (const float*)d_in[17];
    const float* wk      = (const float*)d_in[18];
    const float* wv      = (const float*)d_in[19];
    const float* wo      = (const float*)d_in[20];
    const float* ln1_g   = (const float*)d_in[21];
    const float* ln1_b   = (const float*)d_in[22];
    const float* ffn_w1  = (const float*)d_in[23];
    const float* ffn_b1  = (const float*)d_in[24];
    const float* ffn_w2  = (const float*)d_in[25];
    const float* ffn_b2  = (const float*)d_in[26];
    const float* ln2_g   = (const float*)d_in[27];
    const float* ln2_b   = (const float*)d_in[28];
    const float* pred_w  = (const float*)d_in[29];
    float* out = (float*)d_out;

    // ---- workspace layout (bytes, 256-aligned) ----
    char* w8 = (char*)d_ws;
    size_t off = 0;
    auto alloc = [&](size_t bytes) {
        void* p = w8 + off;
        off = (off + bytes + 255) & ~(size_t)255;
        return p;
    };
    float* emb    = (float*)alloc((size_t)BB * L * D * 4);
    short* emb_bf = (short*)alloc((size_t)BB * L * D * 2);
    float* pe     = (float*)alloc((size_t)L * D * 4);
    short* xim    = (short*)alloc((size_t)BB * L * 32 * 2);
    short* wE     = (short*)alloc((size_t)D * 32 * 2);
    short* xd_bf  = (short*)alloc((size_t)BB * L * DBOT * 2);
    short* cs1_bf = (short*)alloc((size_t)MCONV2P * 512 * 2);
    short* cs2_bf = (short*)alloc((size_t)MCONV2P * DBOT * 2);
    short* cs3_bf = (short*)alloc((size_t)BB * L3 * DBOT * 2);
    short* csc_bf = (short*)alloc((size_t)MCAT * DBOT * 2);
    float* coarse = (float*)alloc((size_t)MCAT * D * 4);
    float* seq    = (float*)alloc((size_t)BB * S * D * 4);
    short* T1     = (short*)alloc((size_t)MP * D * 2);
    float* part   = (float*)alloc((size_t)8 * BB * PRED_N * 4);
    short* seq_bf = (short*)alloc((size_t)MP * D * 2);
    short* QKV    = (short*)alloc((size_t)MP * 3 * D * 2);  // + Ob contiguous
    short* Ob     = (short*)alloc((size_t)MP * D * 2);
    short* hidden = QKV;
    short* wqkvT  = (short*)alloc((size_t)NLAYER * 3 * D * D * 2);
    short* woT    = (short*)alloc((size_t)NLAYER * D * D * 2);
    short* w1T    = (short*)alloc((size_t)NLAYER * DFF * D * 2);
    short* w2T    = (short*)alloc((size_t)NLAYER * D * DFF * 2);
    short* downT  = (short*)alloc((size_t)DBOT * D * 2);
    short* upT    = (short*)alloc((size_t)D * DBOT * 2);
    short* cscmT  = (short*)alloc((size_t)2 * DBOT * 512 * 2);
    float* csc_sc = (float*)alloc((size_t)3 * DBOT * 4);
    float* csc_sh = (float*)alloc((size_t)3 * DBOT * 4);
    (void)ws_size; (void)in_sizes; (void)n_in; (void)out_size;

    const int rowsL = BB * L;   // 10752 = 84*128
    dim3 blk(256);

    // 0. weight convert+transpose + pe table + embed prep
    wtrans_qkvo<<<dim3(16, 16, 4 * NLAYER), blk, 0, stream>>>(wq, wk, wv, wo, wqkvT, woT);
    wtrans_ffn<<<dim3(64, 16, 2 * NLAYER), blk, 0, stream>>>(ffn_w1, ffn_w2, w1T, w2T);
    wtrans_one<<<dim3(DBOT / 32, D / 32), blk, 0, stream>>>(down_w, downT, D, DBOT);
    wtrans_one<<<dim3(D / 32, DBOT / 32), blk, 0, stream>>>(up_w, upT, DBOT, D);
    cscm_prep<<<dim3((2 * DBOT * 512 + 255) / 256), blk, 0, stream>>>(
        cscm_w, cscm_b, bn_g, bn_b, cscmT, csc_sc, csc_sh);
    pe_kernel<<<dim3((L * D + 255) / 256), blk, 0, stream>>>(pe);
    wembed_kernel<<<dim3((D * 32 + 255) / 256), blk, 0, stream>>>(
        conv_embed_w, time_w, time_b, wE);
    im2col_kernel<<<dim3((rowsL * 32 + 255) / 256), blk, 0, stream>>>(
        x_enc, x_mark_enc, xim);
    // 1. embedding as GEMM (M=10752, N=512, K=32) + pe epilogue, dual output
    mfma_gemm<6><<<dim3(D / 128, rowsL / 128), blk, 0, stream>>>(
        xim, wE, nullptr, nullptr, emb, 32, D, -1, -1, 0, pe, emb_bf);
    // 2. down projection -> bf16
    mfma_gemm<4><<<dim3(1, rowsL / 128), blk, 0, stream>>>(
        emb_bf, downT, down_b, nullptr, xd_bf, D, DBOT, -1, -1, 0, nullptr, nullptr);
    // 3. CSCM pyramid
    mfma_gemm<5><<<dim3(1, MCONV1 / 128), blk, 0, stream>>>(
        xd_bf, cscmT, csc_sc, csc_sh, cs1_bf, 512, DBOT, -1, -1, 0, nullptr, nullptr);
    mfma_gemm<5><<<dim3(1, MCONV2P / 128), blk, 0, stream>>>(
        cs1_bf, cscmT + (size_t)DBOT * 512, csc_sc + DBOT, csc_sh + DBOT,
        cs2_bf, 512, DBOT, -1, -1, 0, nullptr, nullptr);
    cscm_conv_bf16<<<dim3(BB * L3), dim3(DBOT), 0, stream>>>(
        cs2_bf, L2, cs3_bf, cscm_w + 2 * DBOT * DBOT * 4,
        cscm_b + 2 * DBOT, bn_g + 2 * DBOT, bn_b + 2 * DBOT, L3);
    // 4. up projection
    concat_cs_kernel<<<dim3((MCAT * DBOT + 255) / 256), blk, 0, stream>>>(
        cs1_bf, cs2_bf, cs3_bf, csc_bf);
    mfma_gemm<1><<<dim3(D / 128, MCAT / 128), blk, 0, stream>>>(
        csc_bf, upT, up_b, nullptr, coarse, DBOT, D, -1, -1, 0, nullptr, nullptr);
    // 5. concat + LN (A_0 rows only; all downstream sets are subsets)
    concat_ln_idx<<<dim3(HS.cnt[0] * 32), blk, 0, stream>>>(
        emb, coarse, cln_g, cln_b, seq, seq_bf);

    // 6. encoder layers (compile-time sparse active sets; 128^2 tile for
    //    max blocks/CU — sparse-M shapes are latency-bound, r15)
    for (int l = 0; l < NLAYER; ++l) {
        const int inLvl = l, outLvl = l + 1;
        const int inCnt  = HS.cnt[l];
        const int outCnt = HS.cnt[l + 1];
        mfma_gemm<2><<<dim3(3 * D / 128, (inCnt * 32 + 127) / 128), blk, 0, stream>>>(
            seq_bf, wqkvT + (size_t)l * 3 * D * D, nullptr, nullptr, QKV, D, 3 * D,
            inLvl, inLvl, inCnt, nullptr, nullptr);
        attn_sparse_kernel<<<dim3(outCnt * 8), blk, 0, stream>>>(
            QKV, Ob, outLvl, outCnt);
        mfma_gemm<2><<<dim3(D / 128, (outCnt * 32 + 127) / 128), blk, 0, stream>>>(
            Ob, woT + (size_t)l * D * D, nullptr, nullptr, T1, D, D,
            -1, -1, 0, nullptr, nullptr);
        add_ln_idx<<<dim3(outCnt * 32), blk, 0, stream>>>(
            seq, T1, ln1_g + (size_t)l * D, ln1_b + (size_t)l * D, seq_bf, outLvl);
        mfma_gemm<3><<<dim3(DFF / 128, (outCnt * 32 + 127) / 128), blk, 0, stream>>>(
            seq_bf, w1T + (size_t)l * DFF * D, ffn_b1 + (size_t)l * DFF, nullptr, hidden, D, DFF,
            outLvl, -1, outCnt, nullptr, nullptr);
        mfma_gemm<4><<<dim3(D / 128, (outCnt * 32 + 127) / 128), blk, 0, stream>>>(
            hidden, w2T + (size_t)l * D * DFF, ffn_b2 + (size_t)l * D, nullptr, T1, DFF, D,
            -1, -1, 0, nullptr, nullptr);
        add_ln_idx<<<dim3(outCnt * 32), blk, 0, stream>>>(
            seq, T1, ln2_g + (size_t)l * D, ln2_b + (size_t)l * D, seq_bf, outLvl);
    }

    // 7. prediction head (split-K, gather fused) + reduce
    pred_kernel<<<dim3(PRED_N / 8, 8), blk, 0, stream>>>(seq, pred_w, part);
    pred_reduce_kernel<<<dim3((BB * PRED_N + 255) / 256), blk, 0, stream>>>(part, out);
}

// Round 18
// 377.678 us; speedup vs baseline: 2.3995x; 1.2543x over previous
//
#include <hip/hip_runtime.h>
#include <math.h>

// ---- problem constants ----
constexpr int BB   = 32;    // batch
constexpr int L    = 336;   // seq_len
constexpr int CIN  = 7;
constexpr int MARK = 4;
constexpr int D    = 512;   // d_model
constexpr int DFF  = 2048;
constexpr int NH   = 8;
constexpr int HD   = 64;    // dk = dv
constexpr int S    = 446;   // 336+84+21+5
constexpr int DBOT = 128;
constexpr int L1 = 84, L2 = 21, L3 = 5;
constexpr int LC = 110;     // 84+21+5
constexpr int NLAYER = 3;
constexpr int PRED_N = 672; // 96*7
constexpr int MP   = 14336; // BB*S padded
constexpr int NMAX = 12;    // max sparse neighbors (real max 10)
constexpr int MCONV1 = BB * L1;          // 2688 = 21*128 (exact)
constexpr int MCONV2P = 768;             // BB*L2=672 padded to 6*128
constexpr int MCAT  = 3584;              // BB*LC=3520 padded to 28*128

using short8  = __attribute__((ext_vector_type(8))) short;
using float4v = __attribute__((ext_vector_type(4))) float;

// ---------------------------------------------------------------------------
// COMPILE-TIME pyramid structure: neighbor lists + active sets.
// ---------------------------------------------------------------------------
struct SetsData {
    int nbr[S][NMAX];
    int idx[4][S];
    int cnt[4];
};

constexpr SetsData compute_sets() {
    SetsData sd{};
    constexpr int sizes[4]  = {336, 84, 21, 5};
    constexpr int starts[4] = {0, 336, 420, 441};
    for (int i = 0; i < S; ++i) {
        int li = 0, pi = i;
        if (i < 336)      { li = 0; pi = i; }
        else if (i < 420) { li = 1; pi = i - 336; }
        else if (i < 441) { li = 2; pi = i - 420; }
        else              { li = 3; pi = i - 441; }
        int cnt = 0;
        for (int d = -2; d <= 2; ++d) {
            int q = pi + d;
            if (q >= 0 && q < sizes[li]) sd.nbr[i][cnt++] = starts[li] + q;
        }
        if (li > 0) {
            int lo = pi * 4;
            int hi = (pi == sizes[li] - 1) ? sizes[li - 1] : (pi + 1) * 4;
            for (int c = lo; c < hi; ++c) sd.nbr[i][cnt++] = starts[li - 1] + c;
        }
        if (li < 3) {
            int q = pi >> 2;
            if (q > sizes[li + 1] - 1) q = sizes[li + 1] - 1;
            sd.nbr[i][cnt++] = starts[li + 1] + q;
        }
        for (int j = cnt; j < NMAX; ++j) sd.nbr[i][j] = -1;
    }
    sd.cnt[3] = 4;
    sd.idx[3][0] = 335; sd.idx[3][1] = 419; sd.idx[3][2] = 440; sd.idx[3][3] = 445;
    for (int lvl = 3; lvl >= 1; --lvl) {
        bool mk[S] = {};
        for (int k = 0; k < sd.cnt[lvl]; ++k) {
            int i = sd.idx[lvl][k];
            for (int t = 0; t < NMAX; ++t) {
                int v = sd.nbr[i][t];
                if (v >= 0) mk[v] = true;
            }
        }
        int nc = 0;
        for (int i = 0; i < S; ++i)
            if (mk[i]) sd.idx[lvl - 1][nc++] = i;
        sd.cnt[lvl - 1] = nc;
    }
    return sd;
}

constexpr SetsData HS = compute_sets();         // host: grid sizing
__constant__ SetsData d_sets = compute_sets();  // device: row maps + nbr

// exact split-K partial buffer size (elements), from compile-time counts
constexpr size_t psk_elems() {
    size_t mx = 0;
    for (int l = 0; l < NLAYER; ++l) {
        size_t Mc = (size_t)HS.cnt[l + 1] * 32;
        size_t Mpad = ((Mc + 127) / 128) * 128;
        if (Mc <= 512) { size_t v = 4 * Mpad * 512;  if (v > mx) mx = v; }   // wo
        if (Mc <= 128) { size_t v = 4 * Mpad * 2048; if (v > mx) mx = v; }   // ffn1
        size_t ks = (Mc <= 512) ? 8 : 4;
        size_t v = ks * Mpad * 512; if (v > mx) mx = v;                      // ffn2
    }
    return mx;
}

__device__ inline short f2bf(float f) {
    union { float f; unsigned u; } v; v.f = f;
    unsigned r = v.u + 0x7fffu + ((v.u >> 16) & 1u);
    return (short)(r >> 16);
}
__device__ inline float bf2f(short h) {
    union { unsigned u; float f; } v; v.u = ((unsigned)(unsigned short)h) << 16;
    return v.f;
}

// async global->LDS, 16B per lane, wave-uniform LDS base + lane*16
__device__ inline void gload_lds16(const void* g, void* l) {
    __builtin_amdgcn_global_load_lds(
        (const __attribute__((address_space(1))) void*)g,
        (__attribute__((address_space(3))) void*)l, 16, 0, 0);
}

// Staging map: conflict-free + coalesced (verified r11: 0 bank conflicts).
// Sparse rows: alvl/clvl >= 0 select d_sets.idx[lvl] (pos-major compact:
// compact m -> b=m&31, j=m>>5 clamped to cnt-1, orig row b*S+idx[j]).

// ---------------------------------------------------------------------------
// 128x128 bf16 MFMA GEMM, BK=32, double-buffered, counted vmcnt(4) pipeline.
// EPI: 0 f32; 1 f32+bias; 2 bf16; 3 bf16+bias+gelu; 4 bf16+bias;
//      5 bf16, v = acc*bias[gn]+bias2[gn] then ELU;
//      6 v = acc + peT[(row%L)*D+gn], write f32 Cout AND bf16 Cout2 (embed)
// ---------------------------------------------------------------------------
template<int EPI>
__launch_bounds__(256, 4)
__global__ void mfma_gemm(const short* __restrict__ A, const short* __restrict__ Bt,
                          const float* __restrict__ bias, const float* __restrict__ bias2,
                          void* __restrict__ Cout, int Kd, int Nd,
                          int alvl, int clvl, int cnt,
                          const float* __restrict__ peT, short* __restrict__ Cout2) {
    __shared__ short As[2][128 * 32];
    __shared__ short Bs[2][128 * 32];
    int tid = threadIdx.x;
    int nwg  = gridDim.x * gridDim.y;
    int orig = blockIdx.y * gridDim.x + blockIdx.x;
    int qq = nwg >> 3, rr = nwg & 7;
    int xcd = orig & 7, idx = orig >> 3;
    int wgid = (xcd < rr ? xcd * (qq + 1) : rr * (qq + 1) + (xcd - rr) * qq) + idx;
    int m0 = (wgid / gridDim.x) * 128, n0 = (wgid % gridDim.x) * 128;

    int lane = tid & 63, wid = tid >> 6;
    int wm = wid >> 1, wn = wid & 1;
    int lr = lane & 15, lk = lane >> 4;

    size_t abase[2], bbase[2];
#pragma unroll
    for (int r = 0; r < 2; ++r) {
        int u = r * 256 + tid;
        int row = ((u >> 3) << 1) | ((u >> 2) & 1);
        int kg  = (u & 3) ^ ((u >> 3) & 3);
        int rm = m0 + row, ga;
        if (alvl >= 0) { int j = rm >> 5; if (j > cnt - 1) j = cnt - 1; ga = (rm & 31) * S + d_sets.idx[alvl][j]; }
        else ga = rm;
        abase[r] = (size_t)ga * Kd + kg * 8;
        bbase[r] = (size_t)(n0 + row) * Kd + kg * 8;
    }
    auto stage = [&](int buf, int k0) {
#pragma unroll
        for (int r = 0; r < 2; ++r) {
            short* la = As[buf] + (size_t)(r * 256 + wid * 64) * 8;
            short* lb = Bs[buf] + (size_t)(r * 256 + wid * 64) * 8;
            gload_lds16(A + abase[r] + k0, la);
            gload_lds16(Bt + bbase[r] + k0, lb);
        }
    };
    auto rd_off = [&](int row_) {
        int rh = row_ >> 1;
        int s  = lk ^ (rh & 3);
        return (size_t)(rh * 8 + (row_ & 1) * 4 + s) * 8;
    };

    float4v acc[4][4];
#pragma unroll
    for (int i = 0; i < 4; ++i)
#pragma unroll
        for (int j = 0; j < 4; ++j) acc[i][j] = 0;

    const int nt = Kd >> 5;
    stage(0, 0);
    for (int t = 0; t < nt; ++t) {
        int cur = t & 1;
        if (t + 1 < nt) {
            stage(cur ^ 1, (t + 1) * 32);
            asm volatile("s_waitcnt vmcnt(4)" ::: "memory");
        } else {
            asm volatile("s_waitcnt vmcnt(0)" ::: "memory");
        }
        __builtin_amdgcn_s_barrier();
        short8 af[4], bfv[4];
#pragma unroll
        for (int mi = 0; mi < 4; ++mi)
            af[mi] = *(const short8*)(As[cur] + rd_off(wm * 64 + mi * 16 + lr));
#pragma unroll
        for (int ni = 0; ni < 4; ++ni)
            bfv[ni] = *(const short8*)(Bs[cur] + rd_off(wn * 64 + ni * 16 + lr));
        __builtin_amdgcn_s_setprio(1);
#pragma unroll
        for (int mi = 0; mi < 4; ++mi)
#pragma unroll
            for (int ni = 0; ni < 4; ++ni)
                acc[mi][ni] = __builtin_amdgcn_mfma_f32_16x16x32_bf16(
                    af[mi], bfv[ni], acc[mi][ni], 0, 0, 0);
        __builtin_amdgcn_s_setprio(0);
        __builtin_amdgcn_s_barrier();
    }

#pragma unroll
    for (int mi = 0; mi < 4; ++mi) {
        int gmc = m0 + wm * 64 + mi * 16 + lk * 4;
#pragma unroll
        for (int ni = 0; ni < 4; ++ni) {
            int gn = n0 + wn * 64 + ni * 16 + lr;
            float bsv = (EPI == 1 || EPI == 3 || EPI == 4) ? bias[gn] : 0.0f;
            float sc = (EPI == 5) ? bias[gn]  : 0.0f;
            float sh = (EPI == 5) ? bias2[gn] : 0.0f;
#pragma unroll
            for (int e = 0; e < 4; ++e) {
                int rm = gmc + e, grow;
                if (clvl >= 0) { int j = rm >> 5; if (j > cnt - 1) j = cnt - 1; grow = (rm & 31) * S + d_sets.idx[clvl][j]; }
                else grow = rm;
                float v = acc[mi][ni][e] + bsv;
                if (EPI == 3) v = 0.5f * v * (1.0f + erff(v * 0.70710678118654752f));
                if (EPI == 5) { v = v * sc + sh; v = v > 0.0f ? v : (expf(v) - 1.0f); }
                if (EPI == 6) {
                    v += peT[(size_t)(grow % L) * D + gn];
                    ((float*)Cout)[(size_t)grow * Nd + gn] = v;
                    Cout2[(size_t)grow * Nd + gn] = f2bf(v);
                } else if (EPI <= 1) {
                    ((float*)Cout)[(size_t)grow * Nd + gn] = v;
                } else {
                    ((short*)Cout)[(size_t)grow * Nd + gn] = f2bf(v);
                }
            }
        }
    }
}

// ---------------------------------------------------------------------------
// SPLIT-K variant: gridDim.z = KS slices; slice kz covers K range
// [kz*Kd/KS, (kz+1)*Kd/KS); writes f32 partial part[kz][Mpad][Nd].
// For serial-K-latency-bound shapes (r16: FFN2-l3 was 4 blocks x 64 K-steps
// = 42.7us at 0.15% occupancy).
// ---------------------------------------------------------------------------
__launch_bounds__(256, 4)
__global__ void mfma_gemm_sk(const short* __restrict__ A, const short* __restrict__ Bt,
                             float* __restrict__ part, int Kd, int Nd,
                             int alvl, int cnt) {
    __shared__ short As[2][128 * 32];
    __shared__ short Bs[2][128 * 32];
    int tid = threadIdx.x;
    int nwg  = gridDim.x * gridDim.y;
    int orig = blockIdx.y * gridDim.x + blockIdx.x;
    int qq = nwg >> 3, rr = nwg & 7;
    int xcd = orig & 7, idx = orig >> 3;
    int wgid = (xcd < rr ? xcd * (qq + 1) : rr * (qq + 1) + (xcd - rr) * qq) + idx;
    int m0 = (wgid / gridDim.x) * 128, n0 = (wgid % gridDim.x) * 128;
    int Mpad = gridDim.y * 128;
    int kz = blockIdx.z;
    int kb = Kd / gridDim.z;          // slice length (multiple of 32)
    int kbase = kz * kb;

    int lane = tid & 63, wid = tid >> 6;
    int wm = wid >> 1, wn = wid & 1;
    int lr = lane & 15, lk = lane >> 4;

    size_t abase[2], bbase[2];
#pragma unroll
    for (int r = 0; r < 2; ++r) {
        int u = r * 256 + tid;
        int row = ((u >> 3) << 1) | ((u >> 2) & 1);
        int kg  = (u & 3) ^ ((u >> 3) & 3);
        int rm = m0 + row, ga;
        if (alvl >= 0) { int j = rm >> 5; if (j > cnt - 1) j = cnt - 1; ga = (rm & 31) * S + d_sets.idx[alvl][j]; }
        else ga = rm;
        abase[r] = (size_t)ga * Kd + kbase + kg * 8;
        bbase[r] = (size_t)(n0 + row) * Kd + kbase + kg * 8;
    }
    auto stage = [&](int buf, int k0) {
#pragma unroll
        for (int r = 0; r < 2; ++r) {
            short* la = As[buf] + (size_t)(r * 256 + wid * 64) * 8;
            short* lb = Bs[buf] + (size_t)(r * 256 + wid * 64) * 8;
            gload_lds16(A + abase[r] + k0, la);
            gload_lds16(Bt + bbase[r] + k0, lb);
        }
    };
    auto rd_off = [&](int row_) {
        int rh = row_ >> 1;
        int s  = lk ^ (rh & 3);
        return (size_t)(rh * 8 + (row_ & 1) * 4 + s) * 8;
    };

    float4v acc[4][4];
#pragma unroll
    for (int i = 0; i < 4; ++i)
#pragma unroll
        for (int j = 0; j < 4; ++j) acc[i][j] = 0;

    const int nt = kb >> 5;
    stage(0, 0);
    for (int t = 0; t < nt; ++t) {
        int cur = t & 1;
        if (t + 1 < nt) {
            stage(cur ^ 1, (t + 1) * 32);
            asm volatile("s_waitcnt vmcnt(4)" ::: "memory");
        } else {
            asm volatile("s_waitcnt vmcnt(0)" ::: "memory");
        }
        __builtin_amdgcn_s_barrier();
        short8 af[4], bfv[4];
#pragma unroll
        for (int mi = 0; mi < 4; ++mi)
            af[mi] = *(const short8*)(As[cur] + rd_off(wm * 64 + mi * 16 + lr));
#pragma unroll
        for (int ni = 0; ni < 4; ++ni)
            bfv[ni] = *(const short8*)(Bs[cur] + rd_off(wn * 64 + ni * 16 + lr));
        __builtin_amdgcn_s_setprio(1);
#pragma unroll
        for (int mi = 0; mi < 4; ++mi)
#pragma unroll
            for (int ni = 0; ni < 4; ++ni)
                acc[mi][ni] = __builtin_amdgcn_mfma_f32_16x16x32_bf16(
                    af[mi], bfv[ni], acc[mi][ni], 0, 0, 0);
        __builtin_amdgcn_s_setprio(0);
        __builtin_amdgcn_s_barrier();
    }

#pragma unroll
    for (int mi = 0; mi < 4; ++mi) {
        int gmc = m0 + wm * 64 + mi * 16 + lk * 4;
#pragma unroll
        for (int ni = 0; ni < 4; ++ni) {
            int gn = n0 + wn * 64 + ni * 16 + lr;
#pragma unroll
            for (int e = 0; e < 4; ++e)
                part[((size_t)kz * Mpad + gmc + e) * Nd + gn] = acc[mi][ni][e];
        }
    }
}

// sum KS partials + epilogue -> bf16 compact output
// EPI: 2 plain; 3 +bias+gelu; 4 +bias
template<int EPI>
__launch_bounds__(256)
__global__ void reduce_sk(const float* __restrict__ part, const float* __restrict__ bias,
                          short* __restrict__ Cout, int Mpad, int Nd, int KS) {
    int idx = blockIdx.x * 256 + threadIdx.x;
    if (idx >= Mpad * Nd) return;
    float s = 0.0f;
    for (int k = 0; k < KS; ++k)
        s += part[(size_t)k * Mpad * Nd + idx];
    if (EPI == 3 || EPI == 4) s += bias[idx % Nd];
    if (EPI == 3) s = 0.5f * s * (1.0f + erff(s * 0.70710678118654752f));
    Cout[idx] = f2bf(s);
}

// ---------------------------------------------------------------------------
// batched weight transpose+convert, 32x32 tiles, f32 W[Kd][Nd] -> bf16 Wt[Nd][Kd]
// ---------------------------------------------------------------------------
__device__ inline void wtrans_tile(const float* __restrict__ W, short* __restrict__ Wt,
                                   int Kd, int Nd, int n0, int k0, int tid) {
    __shared__ float tile[32][33];
    int tx = tid & 31, ty = tid >> 5; // ty 0..7
#pragma unroll
    for (int r = 0; r < 32; r += 8)
        tile[ty + r][tx] = W[(size_t)(k0 + ty + r) * Nd + n0 + tx];
    __syncthreads();
#pragma unroll
    for (int r = 0; r < 32; r += 8)
        Wt[(size_t)(n0 + ty + r) * Kd + k0 + tx] = f2bf(tile[tx][ty + r]);
}

__launch_bounds__(256)
__global__ void wtrans_qkvo(const float* __restrict__ wq, const float* __restrict__ wk,
                            const float* __restrict__ wv, const float* __restrict__ wo,
                            short* __restrict__ wqkvT, short* __restrict__ woT) {
    int z = blockIdx.z, l = z >> 2, part = z & 3;
    const float* src = (part == 0 ? wq : part == 1 ? wk : part == 2 ? wv : wo)
                       + (size_t)l * D * D;
    short* dst = (part < 3) ? wqkvT + (size_t)l * 3 * D * D + (size_t)part * D * D
                            : woT + (size_t)l * D * D;
    wtrans_tile(src, dst, D, D, blockIdx.x * 32, blockIdx.y * 32, threadIdx.x);
}

__launch_bounds__(256)
__global__ void wtrans_ffn(const float* __restrict__ w1, const float* __restrict__ w2,
                           short* __restrict__ w1T, short* __restrict__ w2T) {
    int z = blockIdx.z, l = z >> 1, part = z & 1;
    int nt = part ? blockIdx.y : blockIdx.x;
    int kt = part ? blockIdx.x : blockIdx.y;
    if (part == 0)
        wtrans_tile(w1 + (size_t)l * D * DFF, w1T + (size_t)l * DFF * D,
                    D, DFF, nt * 32, kt * 32, threadIdx.x);
    else
        wtrans_tile(w2 + (size_t)l * DFF * D, w2T + (size_t)l * D * DFF,
                    DFF, D, nt * 32, kt * 32, threadIdx.x);
}

__launch_bounds__(256)
__global__ void wtrans_one(const float* __restrict__ W, short* __restrict__ Wt,
                           int Kd, int Nd) {
    wtrans_tile(W, Wt, Kd, Nd, blockIdx.x * 32, blockIdx.y * 32, threadIdx.x);
}

// ---------------------------------------------------------------------------
// CSCM prep
// ---------------------------------------------------------------------------
__launch_bounds__(256)
__global__ void cscm_prep(const float* __restrict__ cw, const float* __restrict__ cb,
                          const float* __restrict__ bg, const float* __restrict__ bb,
                          short* __restrict__ cscmT, float* __restrict__ sc,
                          float* __restrict__ sh) {
    int idx = blockIdx.x * 256 + threadIdx.x;
    if (idx < 2 * DBOT * 512) {
        int l = idx >> 16;
        int rem = idx & 65535;
        int oc = rem >> 9, j = rem & 511;
        int r = j >> 7, c = j & 127;
        cscmT[idx] = f2bf(cw[(((size_t)l * DBOT + oc) * DBOT + c) * 4 + r]);
    }
    if (idx < 3 * DBOT) {
        sc[idx] = bg[idx];
        sh[idx] = cb[idx] * bg[idx] + bb[idx];
    }
}

// ---------------------------------------------------------------------------
// positional-encoding table: pe[t][d], computed ONCE
// ---------------------------------------------------------------------------
__launch_bounds__(256)
__global__ void pe_kernel(float* __restrict__ pe) {
    int idx = blockIdx.x * 256 + threadIdx.x;
    if (idx >= L * D) return;
    int d = idx % D, t = idx / D;
    int e = d & ~1;
    float div = expf(-(float)e * (logf(10000.0f) / (float)D));
    float arg = (float)t * div;
    pe[idx] = (d & 1) ? cosf(arg) : sinf(arg);
}

// ---------------------------------------------------------------------------
// embed as GEMM: im2col matrix xim[BB*L][32] (bf16)
// ---------------------------------------------------------------------------
__launch_bounds__(256)
__global__ void im2col_kernel(const float* __restrict__ x_enc, const float* __restrict__ x_mark,
                              short* __restrict__ xim) {
    int idx = blockIdx.x * 256 + threadIdx.x;
    if (idx >= BB * L * 32) return;
    int k = idx & 31, m = idx >> 5;
    int t = m % L, b = m / L;
    float v = 0.0f;
    if (k < 21) {
        int w = k / 7, i = k % 7;
        int s = t + w - 1;
        if (s < 0) s = L - 1;
        if (s >= L) s = 0;
        v = x_enc[((size_t)b * L + s) * CIN + i];
    } else if (k < 25) {
        v = x_mark[(size_t)m * MARK + (k - 21)];
    } else if (k == 25) {
        v = 1.0f;
    }
    xim[idx] = f2bf(v);
}

// embed weight in Bt layout wE[512][32]
__launch_bounds__(256)
__global__ void wembed_kernel(const float* __restrict__ cw, const float* __restrict__ tw,
                              const float* __restrict__ tb, short* __restrict__ wE) {
    int idx = blockIdx.x * 256 + threadIdx.x;
    if (idx >= D * 32) return;
    int k = idx & 31, d = idx >> 5;
    float v = 0.0f;
    if (k < 21) {
        int w = k / 7, i = k % 7;
        v = cw[(size_t)d * (CIN * 3) + i * 3 + w];
    } else if (k < 25) {
        v = tw[(size_t)(k - 21) * D + d];
    } else if (k == 25) {
        v = tb[d];
    }
    wE[idx] = f2bf(v);
}

// ---------------------------------------------------------------------------
// CSCM conv level 3 (tiny)
// ---------------------------------------------------------------------------
__launch_bounds__(128)
__global__ void cscm_conv_bf16(const short* __restrict__ in, int inRowsPerB,
                               short* __restrict__ outp, const float* __restrict__ w,
                               const float* __restrict__ cb, const float* __restrict__ bng,
                               const float* __restrict__ bnb, int Lout) {
    int bid = blockIdx.x;
    int to = bid % Lout, b = bid / Lout;
    __shared__ float insh[4 * DBOT];
    int tid = threadIdx.x;
#pragma unroll
    for (int r = 0; r < 4; ++r)
        insh[r * DBOT + tid] = bf2f(in[((size_t)(b * inRowsPerB + to * 4 + r)) * DBOT + tid]);
    __syncthreads();
    float acc = cb[tid];
    const float* wr = w + (size_t)tid * (DBOT * 4);
    for (int c = 0; c < DBOT; ++c) {
#pragma unroll
        for (int r = 0; r < 4; ++r)
            acc += insh[r * DBOT + c] * wr[c * 4 + r];
    }
    acc = acc * bng[tid] + bnb[tid];
    outp[((size_t)(b * Lout + to)) * DBOT + tid] = f2bf(acc > 0.0f ? acc : (expf(acc) - 1.0f));
}

// ---------------------------------------------------------------------------
// concat pyramid outputs (bf16) -> csc [MCAT][128]
// ---------------------------------------------------------------------------
__launch_bounds__(256)
__global__ void concat_cs_kernel(const short* __restrict__ cs1, const short* __restrict__ cs2,
                                 const short* __restrict__ cs3, short* __restrict__ csc) {
    int idx = blockIdx.x * 256 + threadIdx.x;
    if (idx >= MCAT * DBOT) return;
    int m = idx >> 7, c = idx & 127;
    short v = 0;
    if (m < BB * LC) {
        int b = m / LC, t = m % LC;
        if (t < L1)           v = cs1[(size_t)(b * L1 + t) * DBOT + c];
        else if (t < L1 + L2) v = cs2[(size_t)(b * L2 + (t - L1)) * DBOT + c];
        else                  v = cs3[(size_t)(b * L3 + (t - L1 - L2)) * DBOT + c];
    }
    csc[idx] = v;
}

// ---------------------------------------------------------------------------
// sparse attention over active level (compact Ob)
// ---------------------------------------------------------------------------
__launch_bounds__(256)
__global__ void attn_sparse_kernel(const short* __restrict__ QKV, short* __restrict__ Ob,
                                   int lvl, int cnt) {
    int wid  = blockIdx.x * 4 + (threadIdx.x >> 6);
    if (wid >= cnt * 32) return;
    int lane = threadIdx.x & 63;
    int b = wid & 31, j = wid >> 5;
    int i = d_sets.idx[lvl][j];
    const short8 qv = *(const short8*)(QKV + (size_t)(b * S + i) * 1536 + lane * 8);
    float qf[8];
#pragma unroll
    for (int e = 0; e < 8; ++e) qf[e] = bf2f(qv[e]);
    int nb[NMAX];
#pragma unroll
    for (int jj = 0; jj < NMAX; ++jj) nb[jj] = d_sets.nbr[i][jj];
    float sc[NMAX];
#pragma unroll
    for (int jj = 0; jj < NMAX; ++jj) {
        float s = -1e30f;
        if (nb[jj] >= 0) {
            const short8 kv = *(const short8*)(QKV + (size_t)(b * S + nb[jj]) * 1536 + 512 + lane * 8);
            s = 0.0f;
#pragma unroll
            for (int e = 0; e < 8; ++e) s += qf[e] * bf2f(kv[e]);
            s += __shfl_xor(s, 1); s += __shfl_xor(s, 2); s += __shfl_xor(s, 4);
            s *= 0.125f;
        }
        sc[jj] = s;
    }
    float mx = sc[0];
#pragma unroll
    for (int jj = 1; jj < NMAX; ++jj) mx = fmaxf(mx, sc[jj]);
    float sum = 0.0f;
    float accv[8] = {};
#pragma unroll
    for (int jj = 0; jj < NMAX; ++jj) {
        float p = expf(sc[jj] - mx);
        sum += p;
        if (nb[jj] >= 0) {
            const short8 vv = *(const short8*)(QKV + (size_t)(b * S + nb[jj]) * 1536 + 1024 + lane * 8);
#pragma unroll
            for (int e = 0; e < 8; ++e) accv[e] += p * bf2f(vv[e]);
        }
    }
    float inv = 1.0f / sum;
    short8 ov;
#pragma unroll
    for (int e = 0; e < 8; ++e) ov[e] = f2bf(accv[e] * inv);
    *(short8*)(Ob + (size_t)wid * D + lane * 8) = ov;
}

// ---------------------------------------------------------------------------
// wave-shuffle block reduction over 4 waves (256 thr)
// ---------------------------------------------------------------------------
__device__ inline float blk_reduce(float v, float* ws4, int tid) {
#pragma unroll
    for (int o = 32; o; o >>= 1) v += __shfl_xor(v, o);
    if ((tid & 63) == 0) ws4[tid >> 6] = v;
    __syncthreads();
    return ws4[0] + ws4[1] + ws4[2] + ws4[3];
}

// ---------------------------------------------------------------------------
// concat(emb, coarse) + LayerNorm at A_0 rows only
// ---------------------------------------------------------------------------
__launch_bounds__(256)
__global__ void concat_ln_idx(const float* __restrict__ emb, const float* __restrict__ coarse,
                              const float* __restrict__ g, const float* __restrict__ bta,
                              float* __restrict__ seq, short* __restrict__ seq_bf) {
    int row = blockIdx.x;
    int b = row & 31, j = row >> 5;
    int s = d_sets.idx[0][j];
    int orig = b * S + s;
    const float* src = (s < L) ? emb + ((size_t)b * L + s) * D
                               : coarse + ((size_t)b * LC + (s - L)) * D;
    __shared__ float wsA[4];
    __shared__ float wsB[4];
    int tid = threadIdx.x;
    float x0 = src[tid], x1 = src[tid + 256];
    float mu = blk_reduce(x0 + x1, wsA, tid) * (1.0f / D);
    float d0 = x0 - mu, d1 = x1 - mu;
    float var = blk_reduce(d0 * d0 + d1 * d1, wsB, tid) * (1.0f / D);
    float rstd = rsqrtf(var + 1e-5f);
    float v0 = d0 * rstd * g[tid]       + bta[tid];
    float v1 = d1 * rstd * g[tid + 256] + bta[tid + 256];
    float* dst = seq + (size_t)orig * D;
    dst[tid] = v0; dst[tid + 256] = v1;
    short* dbf = seq_bf + (size_t)orig * D;
    dbf[tid] = f2bf(v0); dbf[tid + 256] = f2bf(v1);
}

// ---------------------------------------------------------------------------
// indexed residual LN: compact row -> orig row b*S+idx[lvl][j]; exact grid
// ---------------------------------------------------------------------------
__launch_bounds__(256)
__global__ void add_ln_idx(float* __restrict__ seq, const short* __restrict__ add,
                           const float* __restrict__ g, const float* __restrict__ bta,
                           short* __restrict__ seq_bf, int lvl) {
    int row = blockIdx.x;
    int b = row & 31, j = row >> 5;
    int orig = b * S + d_sets.idx[lvl][j];
    __shared__ float wsA[4];
    __shared__ float wsB[4];
    int tid = threadIdx.x;
    float* srow = seq + (size_t)orig * D;
    const short* arow = add + (size_t)row * D;
    float x0 = srow[tid] + bf2f(arow[tid]);
    float x1 = srow[tid + 256] + bf2f(arow[tid + 256]);
    float mu = blk_reduce(x0 + x1, wsA, tid) * (1.0f / D);
    float d0 = x0 - mu, d1 = x1 - mu;
    float var = blk_reduce(d0 * d0 + d1 * d1, wsB, tid) * (1.0f / D);
    float rstd = rsqrtf(var + 1e-5f);
    float v0 = d0 * rstd * g[tid]       + bta[tid];
    float v1 = d1 * rstd * g[tid + 256] + bta[tid + 256];
    srow[tid] = v0; srow[tid + 256] = v1;
    short* dbf = seq_bf + (size_t)orig * D;
    dbf[tid] = f2bf(v0); dbf[tid + 256] = f2bf(v1);
}

// ---------------------------------------------------------------------------
// prediction head, split-K with fused gather
// ---------------------------------------------------------------------------
__launch_bounds__(256)
__global__ void pred_kernel(const float* __restrict__ seq, const float* __restrict__ w,
                            float* __restrict__ part) {
    __shared__ float es[32][257];
    __shared__ float wsm[256][8];
    int tid = threadIdx.x;
    int n0 = blockIdx.x * 8;
    int ks = blockIdx.y;
    int k0 = ks * 256;
    const int pos[4] = {335, 419, 440, 445};
    int seg = ks >> 1;
    int dbase = (ks & 1) * 256;
#pragma unroll 8
    for (int r = 0; r < 32; ++r)
        es[r][tid] = seq[((size_t)r * S + pos[seg]) * D + dbase + tid];
#pragma unroll
    for (int e = 0; e < 8; ++e)
        wsm[tid][e] = w[(size_t)(k0 + tid) * PRED_N + n0 + e];
    __syncthreads();
    int b = tid >> 3, nn = tid & 7;
    float acc = 0.0f;
#pragma unroll 8
    for (int kk = 0; kk < 256; ++kk)
        acc += es[b][kk] * wsm[kk][nn];
    part[(size_t)ks * (BB * PRED_N) + (size_t)b * PRED_N + n0 + nn] = acc;
}

__launch_bounds__(256)
__global__ void pred_reduce_kernel(const float* __restrict__ part, float* __restrict__ out) {
    int idx = blockIdx.x * 256 + threadIdx.x;
    if (idx >= BB * PRED_N) return;
    float s = 0.0f;
#pragma unroll
    for (int k = 0; k < 8; ++k) s += part[(size_t)k * (BB * PRED_N) + idx];
    out[idx] = s;
}

// ---------------------------------------------------------------------------
extern "C" void kernel_launch(void* const* d_in, const int* in_sizes, int n_in,
                              void* d_out, int out_size, void* d_ws, size_t ws_size,
                              hipStream_t stream) {
    const float* x_enc      = (const float*)d_in[0];
    const float* x_mark_enc = (const float*)d_in[1];
    const float* conv_embed_w = (const float*)d_in[4];
    const float* time_w  = (const float*)d_in[5];
    const float* time_b  = (const float*)d_in[6];
    const float* down_w  = (const float*)d_in[7];
    const float* down_b  = (const float*)d_in[8];
    const float* cscm_w  = (const float*)d_in[9];
    const float* cscm_b  = (const float*)d_in[10];
    const float* bn_g    = (const float*)d_in[11];
    const float* bn_b    = (const float*)d_in[12];
    const float* up_w    = (const float*)d_in[13];
    const float* up_b    = (const float*)d_in[14];
    const float* cln_g   = (const float*)d_in[15];
    const float* cln_b   = (const float*)d_in[16];
    const float* wq      = (const float*)d_in[17];
    const float* wk      = (const float*)d_in[18];
    const float* wv      = (const float*)d_in[19];
    const float* wo      = (const float*)d_in[20];
    const float* ln1_g   = (const float*)d_in[21];
    const float* ln1_b   = (const float*)d_in[22];
    const float* ffn_w1  = (const float*)d_in[23];
    const float* ffn_b1  = (const float*)d_in[24];
    const float* ffn_w2  = (const float*)d_in[25];
    const float* ffn_b2  = (const float*)d_in[26];
    const float* ln2_g   = (const float*)d_in[27];
    const float* ln2_b   = (const float*)d_in[28];
    const float* pred_w  = (const float*)d_in[29];
    float* out = (float*)d_out;

    // ---- workspace layout (bytes, 256-aligned) ----
    char* w8 = (char*)d_ws;
    size_t off = 0;
    auto alloc = [&](size_t bytes) {
        void* p = w8 + off;
        off = (off + bytes + 255) & ~(size_t)255;
        return p;
    };
    float* emb    = (float*)alloc((size_t)BB * L * D * 4);
    short* emb_bf = (short*)alloc((size_t)BB * L * D * 2);
    float* pe     = (float*)alloc((size_t)L * D * 4);
    short* xim    = (short*)alloc((size_t)BB * L * 32 * 2);
    short* wE     = (short*)alloc((size_t)D * 32 * 2);
    short* xd_bf  = (short*)alloc((size_t)BB * L * DBOT * 2);
    short* cs1_bf = (short*)alloc((size_t)MCONV2P * 512 * 2);
    short* cs2_bf = (short*)alloc((size_t)MCONV2P * DBOT * 2);
    short* cs3_bf = (short*)alloc((size_t)BB * L3 * DBOT * 2);
    short* csc_bf = (short*)alloc((size_t)MCAT * DBOT * 2);
    float* coarse = (float*)alloc((size_t)MCAT * D * 4);
    float* seq    = (float*)alloc((size_t)BB * S * D * 4);
    short* T1     = (short*)alloc((size_t)MP * D * 2);
    float* part   = (float*)alloc((size_t)8 * BB * PRED_N * 4);
    float* partsk = (float*)alloc(psk_elems() * 4);   // split-K partials (exact, ~16MB)
    short* seq_bf = (short*)alloc((size_t)MP * D * 2);
    short* QKV    = (short*)alloc((size_t)MP * 3 * D * 2);  // + Ob contiguous
    short* Ob     = (short*)alloc((size_t)MP * D * 2);
    short* hidden = QKV;
    short* wqkvT  = (short*)alloc((size_t)NLAYER * 3 * D * D * 2);
    short* woT    = (short*)alloc((size_t)NLAYER * D * D * 2);
    short* w1T    = (short*)alloc((size_t)NLAYER * DFF * D * 2);
    short* w2T    = (short*)alloc((size_t)NLAYER * D * DFF * 2);
    short* downT  = (short*)alloc((size_t)DBOT * D * 2);
    short* upT    = (short*)alloc((size_t)D * DBOT * 2);
    short* cscmT  = (short*)alloc((size_t)2 * DBOT * 512 * 2);
    float* csc_sc = (float*)alloc((size_t)3 * DBOT * 4);
    float* csc_sh = (float*)alloc((size_t)3 * DBOT * 4);
    (void)ws_size; (void)in_sizes; (void)n_in; (void)out_size;

    const int rowsL = BB * L;   // 10752 = 84*128
    dim3 blk(256);

    // 0. weight convert+transpose + pe table + embed prep
    wtrans_qkvo<<<dim3(16, 16, 4 * NLAYER), blk, 0, stream>>>(wq, wk, wv, wo, wqkvT, woT);
    wtrans_ffn<<<dim3(64, 16, 2 * NLAYER), blk, 0, stream>>>(ffn_w1, ffn_w2, w1T, w2T);
    wtrans_one<<<dim3(DBOT / 32, D / 32), blk, 0, stream>>>(down_w, downT, D, DBOT);
    wtrans_one<<<dim3(D / 32, DBOT / 32), blk, 0, stream>>>(up_w, upT, DBOT, D);
    cscm_prep<<<dim3((2 * DBOT * 512 + 255) / 256), blk, 0, stream>>>(
        cscm_w, cscm_b, bn_g, bn_b, cscmT, csc_sc, csc_sh);
    pe_kernel<<<dim3((L * D + 255) / 256), blk, 0, stream>>>(pe);
    wembed_kernel<<<dim3((D * 32 + 255) / 256), blk, 0, stream>>>(
        conv_embed_w, time_w, time_b, wE);
    im2col_kernel<<<dim3((rowsL * 32 + 255) / 256), blk, 0, stream>>>(
        x_enc, x_mark_enc, xim);
    // 1. embedding as GEMM (M=10752, N=512, K=32) + pe epilogue, dual output
    mfma_gemm<6><<<dim3(D / 128, rowsL / 128), blk, 0, stream>>>(
        xim, wE, nullptr, nullptr, emb, 32, D, -1, -1, 0, pe, emb_bf);
    // 2. down projection -> bf16
    mfma_gemm<4><<<dim3(1, rowsL / 128), blk, 0, stream>>>(
        emb_bf, downT, down_b, nullptr, xd_bf, D, DBOT, -1, -1, 0, nullptr, nullptr);
    // 3. CSCM pyramid
    mfma_gemm<5><<<dim3(1, MCONV1 / 128), blk, 0, stream>>>(
        xd_bf, cscmT, csc_sc, csc_sh, cs1_bf, 512, DBOT, -1, -1, 0, nullptr, nullptr);
    mfma_gemm<5><<<dim3(1, MCONV2P / 128), blk, 0, stream>>>(
        cs1_bf, cscmT + (size_t)DBOT * 512, csc_sc + DBOT, csc_sh + DBOT,
        cs2_bf, 512, DBOT, -1, -1, 0, nullptr, nullptr);
    cscm_conv_bf16<<<dim3(BB * L3), dim3(DBOT), 0, stream>>>(
        cs2_bf, L2, cs3_bf, cscm_w + 2 * DBOT * DBOT * 4,
        cscm_b + 2 * DBOT, bn_g + 2 * DBOT, bn_b + 2 * DBOT, L3);
    // 4. up projection
    concat_cs_kernel<<<dim3((MCAT * DBOT + 255) / 256), blk, 0, stream>>>(
        cs1_bf, cs2_bf, cs3_bf, csc_bf);
    mfma_gemm<1><<<dim3(D / 128, MCAT / 128), blk, 0, stream>>>(
        csc_bf, upT, up_b, nullptr, coarse, DBOT, D, -1, -1, 0, nullptr, nullptr);
    // 5. concat + LN (A_0 rows only)
    concat_ln_idx<<<dim3(HS.cnt[0] * 32), blk, 0, stream>>>(
        emb, coarse, cln_g, cln_b, seq, seq_bf);

    // 6. encoder layers (compile-time sparse active sets; 128^2 tile;
    //    split-K for serial-K-latency-bound shapes, r16)
    for (int l = 0; l < NLAYER; ++l) {
        const int inLvl = l, outLvl = l + 1;
        const int inCnt  = HS.cnt[l];
        const int outCnt = HS.cnt[l + 1];
        const int Mc   = outCnt * 32;
        const int Mpad = ((Mc + 127) / 128) * 128;
        mfma_gemm<2><<<dim3(3 * D / 128, (inCnt * 32 + 127) / 128), blk, 0, stream>>>(
            seq_bf, wqkvT + (size_t)l * 3 * D * D, nullptr, nullptr, QKV, D, 3 * D,
            inLvl, inLvl, inCnt, nullptr, nullptr);
        attn_sparse_kernel<<<dim3(outCnt * 8), blk, 0, stream>>>(
            QKV, Ob, outLvl, outCnt);
        // O-projection: split-K when M small (K=512, KS=4)
        if (Mc <= 512) {
            mfma_gemm_sk<<<dim3(D / 128, Mpad / 128, 4), blk, 0, stream>>>(
                Ob, woT + (size_t)l * D * D, partsk, D, D, -1, 0);
            reduce_sk<2><<<dim3((Mpad * D + 255) / 256), blk, 0, stream>>>(
                partsk, nullptr, T1, Mpad, D, 4);
        } else {
            mfma_gemm<2><<<dim3(D / 128, Mpad / 128), blk, 0, stream>>>(
                Ob, woT + (size_t)l * D * D, nullptr, nullptr, T1, D, D,
                -1, -1, 0, nullptr, nullptr);
        }
        add_ln_idx<<<dim3(Mc), blk, 0, stream>>>(
            seq, T1, ln1_g + (size_t)l * D, ln1_b + (size_t)l * D, seq_bf, outLvl);
        // FFN1: split-K only for tiny M (K=512, KS=4)
        if (Mc <= 128) {
            mfma_gemm_sk<<<dim3(DFF / 128, Mpad / 128, 4), blk, 0, stream>>>(
                seq_bf, w1T + (size_t)l * DFF * D, partsk, D, DFF, outLvl, outCnt);
            reduce_sk<3><<<dim3((Mpad * DFF + 255) / 256), blk, 0, stream>>>(
                partsk, ffn_b1 + (size_t)l * DFF, hidden, Mpad, DFF, 4);
        } else {
            mfma_gemm<3><<<dim3(DFF / 128, Mpad / 128), blk, 0, stream>>>(
                seq_bf, w1T + (size_t)l * DFF * D, ffn_b1 + (size_t)l * DFF, nullptr,
                hidden, D, DFF, outLvl, -1, outCnt, nullptr, nullptr);
        }
        // FFN2: K=2048, always split (KS=8 small M, else 4)
        {
            int KS = (Mc <= 512) ? 8 : 4;
            mfma_gemm_sk<<<dim3(D / 128, Mpad / 128, KS), blk, 0, stream>>>(
                hidden, w2T + (size_t)l * D * DFF, partsk, DFF, D, -1, 0);
            reduce_sk<4><<<dim3((Mpad * D + 255) / 256), blk, 0, stream>>>(
                partsk, ffn_b2 + (size_t)l * D, T1, Mpad, D, KS);
        }
        add_ln_idx<<<dim3(Mc), blk, 0, stream>>>(
            seq, T1, ln2_g + (size_t)l * D, ln2_b + (size_t)l * D, seq_bf, outLvl);
    }

    // 7. prediction head (split-K, gather fused) + reduce
    pred_kernel<<<dim3(PRED_N / 8, 8), blk, 0, stream>>>(seq, pred_w, part);
    pred_reduce_kernel<<<dim3((BB * PRED_N + 255) / 256), blk, 0, stream>>>(part, out);
}

// Round 19
// 360.362 us; speedup vs baseline: 2.5148x; 1.0480x over previous
//
#include <hip/hip_runtime.h>
#include <math.h>

// ---- problem constants ----
constexpr int BB   = 32;    // batch
constexpr int L    = 336;   // seq_len
constexpr int CIN  = 7;
constexpr int MARK = 4;
constexpr int D    = 512;   // d_model
constexpr int DFF  = 2048;
constexpr int NH   = 8;
constexpr int HD   = 64;    // dk = dv
constexpr int S    = 446;   // 336+84+21+5
constexpr int DBOT = 128;
constexpr int L1 = 84, L2 = 21, L3 = 5;
constexpr int LC = 110;     // 84+21+5
constexpr int NLAYER = 3;
constexpr int PRED_N = 672; // 96*7
constexpr int MP   = 14336; // BB*S padded
constexpr int NMAX = 12;    // max sparse neighbors (real max 10)
constexpr int MCONV1 = BB * L1;          // 2688 = 21*128 (exact)
constexpr int MCONV2P = 768;             // BB*L2=672 padded to 6*128
constexpr int MCAT  = 3584;              // BB*LC=3520 padded to 28*128

using short8  = __attribute__((ext_vector_type(8))) short;
using float4v = __attribute__((ext_vector_type(4))) float;

// ---------------------------------------------------------------------------
// COMPILE-TIME pyramid structure: neighbor lists + active sets.
// ---------------------------------------------------------------------------
struct SetsData {
    int nbr[S][NMAX];
    int idx[4][S];
    int cnt[4];
};

constexpr SetsData compute_sets() {
    SetsData sd{};
    constexpr int sizes[4]  = {336, 84, 21, 5};
    constexpr int starts[4] = {0, 336, 420, 441};
    for (int i = 0; i < S; ++i) {
        int li = 0, pi = i;
        if (i < 336)      { li = 0; pi = i; }
        else if (i < 420) { li = 1; pi = i - 336; }
        else if (i < 441) { li = 2; pi = i - 420; }
        else              { li = 3; pi = i - 441; }
        int cnt = 0;
        for (int d = -2; d <= 2; ++d) {
            int q = pi + d;
            if (q >= 0 && q < sizes[li]) sd.nbr[i][cnt++] = starts[li] + q;
        }
        if (li > 0) {
            int lo = pi * 4;
            int hi = (pi == sizes[li] - 1) ? sizes[li - 1] : (pi + 1) * 4;
            for (int c = lo; c < hi; ++c) sd.nbr[i][cnt++] = starts[li - 1] + c;
        }
        if (li < 3) {
            int q = pi >> 2;
            if (q > sizes[li + 1] - 1) q = sizes[li + 1] - 1;
            sd.nbr[i][cnt++] = starts[li + 1] + q;
        }
        for (int j = cnt; j < NMAX; ++j) sd.nbr[i][j] = -1;
    }
    sd.cnt[3] = 4;
    sd.idx[3][0] = 335; sd.idx[3][1] = 419; sd.idx[3][2] = 440; sd.idx[3][3] = 445;
    for (int lvl = 3; lvl >= 1; --lvl) {
        bool mk[S] = {};
        for (int k = 0; k < sd.cnt[lvl]; ++k) {
            int i = sd.idx[lvl][k];
            for (int t = 0; t < NMAX; ++t) {
                int v = sd.nbr[i][t];
                if (v >= 0) mk[v] = true;
            }
        }
        int nc = 0;
        for (int i = 0; i < S; ++i)
            if (mk[i]) sd.idx[lvl - 1][nc++] = i;
        sd.cnt[lvl - 1] = nc;
    }
    return sd;
}

constexpr SetsData HS = compute_sets();         // host: grid sizing
__constant__ SetsData d_sets = compute_sets();  // device: row maps + nbr

// exact split-K partial buffer size (elements), from compile-time counts
constexpr size_t psk_elems() {
    size_t mx = 0;
    for (int l = 0; l < NLAYER; ++l) {
        size_t Mc = (size_t)HS.cnt[l + 1] * 32;
        size_t Mpad = ((Mc + 127) / 128) * 128;
        if (Mc <= 512) { size_t v = 4 * Mpad * 512;  if (v > mx) mx = v; }   // wo
        if (Mc <= 128) { size_t v = 4 * Mpad * 2048; if (v > mx) mx = v; }   // ffn1
        size_t ks = (Mc <= 512) ? 8 : 4;
        size_t v = ks * Mpad * 512; if (v > mx) mx = v;                      // ffn2
    }
    return mx;
}

__device__ inline short f2bf(float f) {
    union { float f; unsigned u; } v; v.f = f;
    unsigned r = v.u + 0x7fffu + ((v.u >> 16) & 1u);
    return (short)(r >> 16);
}
__device__ inline float bf2f(short h) {
    union { unsigned u; float f; } v; v.u = ((unsigned)(unsigned short)h) << 16;
    return v.f;
}

// async global->LDS, 16B per lane, wave-uniform LDS base + lane*16
__device__ inline void gload_lds16(const void* g, void* l) {
    __builtin_amdgcn_global_load_lds(
        (const __attribute__((address_space(1))) void*)g,
        (__attribute__((address_space(3))) void*)l, 16, 0, 0);
}

// Staging map: conflict-free + coalesced (verified r11: 0 bank conflicts).
// Sparse rows: alvl/clvl >= 0 select d_sets.idx[lvl] (pos-major compact:
// compact m -> b=m&31, j=m>>5 clamped to cnt-1, orig row b*S+idx[j]).

// ---------------------------------------------------------------------------
// 128x128 bf16 MFMA GEMM, BK=32, double-buffered, counted vmcnt(4) pipeline.
// EPI: 0 f32; 1 f32+bias; 2 bf16; 3 bf16+bias+gelu; 4 bf16+bias;
//      5 bf16, v = acc*bias[gn]+bias2[gn] then ELU;
//      6 v = acc + peT[(row%L)*D+gn], write f32 Cout AND bf16 Cout2 (embed)
// ---------------------------------------------------------------------------
template<int EPI>
__launch_bounds__(256, 4)
__global__ void mfma_gemm(const short* __restrict__ A, const short* __restrict__ Bt,
                          const float* __restrict__ bias, const float* __restrict__ bias2,
                          void* __restrict__ Cout, int Kd, int Nd,
                          int alvl, int clvl, int cnt,
                          const float* __restrict__ peT, short* __restrict__ Cout2) {
    __shared__ short As[2][128 * 32];
    __shared__ short Bs[2][128 * 32];
    int tid = threadIdx.x;
    int nwg  = gridDim.x * gridDim.y;
    int orig = blockIdx.y * gridDim.x + blockIdx.x;
    int qq = nwg >> 3, rr = nwg & 7;
    int xcd = orig & 7, idx = orig >> 3;
    int wgid = (xcd < rr ? xcd * (qq + 1) : rr * (qq + 1) + (xcd - rr) * qq) + idx;
    int m0 = (wgid / gridDim.x) * 128, n0 = (wgid % gridDim.x) * 128;

    int lane = tid & 63, wid = tid >> 6;
    int wm = wid >> 1, wn = wid & 1;
    int lr = lane & 15, lk = lane >> 4;

    size_t abase[2], bbase[2];
#pragma unroll
    for (int r = 0; r < 2; ++r) {
        int u = r * 256 + tid;
        int row = ((u >> 3) << 1) | ((u >> 2) & 1);
        int kg  = (u & 3) ^ ((u >> 3) & 3);
        int rm = m0 + row, ga;
        if (alvl >= 0) { int j = rm >> 5; if (j > cnt - 1) j = cnt - 1; ga = (rm & 31) * S + d_sets.idx[alvl][j]; }
        else ga = rm;
        abase[r] = (size_t)ga * Kd + kg * 8;
        bbase[r] = (size_t)(n0 + row) * Kd + kg * 8;
    }
    auto stage = [&](int buf, int k0) {
#pragma unroll
        for (int r = 0; r < 2; ++r) {
            short* la = As[buf] + (size_t)(r * 256 + wid * 64) * 8;
            short* lb = Bs[buf] + (size_t)(r * 256 + wid * 64) * 8;
            gload_lds16(A + abase[r] + k0, la);
            gload_lds16(Bt + bbase[r] + k0, lb);
        }
    };
    auto rd_off = [&](int row_) {
        int rh = row_ >> 1;
        int s  = lk ^ (rh & 3);
        return (size_t)(rh * 8 + (row_ & 1) * 4 + s) * 8;
    };

    float4v acc[4][4];
#pragma unroll
    for (int i = 0; i < 4; ++i)
#pragma unroll
        for (int j = 0; j < 4; ++j) acc[i][j] = 0;

    const int nt = Kd >> 5;
    stage(0, 0);
    for (int t = 0; t < nt; ++t) {
        int cur = t & 1;
        if (t + 1 < nt) {
            stage(cur ^ 1, (t + 1) * 32);
            asm volatile("s_waitcnt vmcnt(4)" ::: "memory");
        } else {
            asm volatile("s_waitcnt vmcnt(0)" ::: "memory");
        }
        __builtin_amdgcn_s_barrier();
        short8 af[4], bfv[4];
#pragma unroll
        for (int mi = 0; mi < 4; ++mi)
            af[mi] = *(const short8*)(As[cur] + rd_off(wm * 64 + mi * 16 + lr));
#pragma unroll
        for (int ni = 0; ni < 4; ++ni)
            bfv[ni] = *(const short8*)(Bs[cur] + rd_off(wn * 64 + ni * 16 + lr));
        __builtin_amdgcn_s_setprio(1);
#pragma unroll
        for (int mi = 0; mi < 4; ++mi)
#pragma unroll
            for (int ni = 0; ni < 4; ++ni)
                acc[mi][ni] = __builtin_amdgcn_mfma_f32_16x16x32_bf16(
                    af[mi], bfv[ni], acc[mi][ni], 0, 0, 0);
        __builtin_amdgcn_s_setprio(0);
        __builtin_amdgcn_s_barrier();
    }

#pragma unroll
    for (int mi = 0; mi < 4; ++mi) {
        int gmc = m0 + wm * 64 + mi * 16 + lk * 4;
#pragma unroll
        for (int ni = 0; ni < 4; ++ni) {
            int gn = n0 + wn * 64 + ni * 16 + lr;
            float bsv = (EPI == 1 || EPI == 3 || EPI == 4) ? bias[gn] : 0.0f;
            float sc = (EPI == 5) ? bias[gn]  : 0.0f;
            float sh = (EPI == 5) ? bias2[gn] : 0.0f;
#pragma unroll
            for (int e = 0; e < 4; ++e) {
                int rm = gmc + e, grow;
                if (clvl >= 0) { int j = rm >> 5; if (j > cnt - 1) j = cnt - 1; grow = (rm & 31) * S + d_sets.idx[clvl][j]; }
                else grow = rm;
                float v = acc[mi][ni][e] + bsv;
                if (EPI == 3) v = 0.5f * v * (1.0f + erff(v * 0.70710678118654752f));
                if (EPI == 5) { v = v * sc + sh; v = v > 0.0f ? v : (expf(v) - 1.0f); }
                if (EPI == 6) {
                    v += peT[(size_t)(grow % L) * D + gn];
                    ((float*)Cout)[(size_t)grow * Nd + gn] = v;
                    Cout2[(size_t)grow * Nd + gn] = f2bf(v);
                } else if (EPI <= 1) {
                    ((float*)Cout)[(size_t)grow * Nd + gn] = v;
                } else {
                    ((short*)Cout)[(size_t)grow * Nd + gn] = f2bf(v);
                }
            }
        }
    }
}

// ---------------------------------------------------------------------------
// SPLIT-K variant: gridDim.z = KS slices; writes f32 partial part[kz][Mpad][Nd].
// ---------------------------------------------------------------------------
__launch_bounds__(256, 4)
__global__ void mfma_gemm_sk(const short* __restrict__ A, const short* __restrict__ Bt,
                             float* __restrict__ part, int Kd, int Nd,
                             int alvl, int cnt) {
    __shared__ short As[2][128 * 32];
    __shared__ short Bs[2][128 * 32];
    int tid = threadIdx.x;
    int nwg  = gridDim.x * gridDim.y;
    int orig = blockIdx.y * gridDim.x + blockIdx.x;
    int qq = nwg >> 3, rr = nwg & 7;
    int xcd = orig & 7, idx = orig >> 3;
    int wgid = (xcd < rr ? xcd * (qq + 1) : rr * (qq + 1) + (xcd - rr) * qq) + idx;
    int m0 = (wgid / gridDim.x) * 128, n0 = (wgid % gridDim.x) * 128;
    int Mpad = gridDim.y * 128;
    int kz = blockIdx.z;
    int kb = Kd / gridDim.z;          // slice length (multiple of 32)
    int kbase = kz * kb;

    int lane = tid & 63, wid = tid >> 6;
    int wm = wid >> 1, wn = wid & 1;
    int lr = lane & 15, lk = lane >> 4;

    size_t abase[2], bbase[2];
#pragma unroll
    for (int r = 0; r < 2; ++r) {
        int u = r * 256 + tid;
        int row = ((u >> 3) << 1) | ((u >> 2) & 1);
        int kg  = (u & 3) ^ ((u >> 3) & 3);
        int rm = m0 + row, ga;
        if (alvl >= 0) { int j = rm >> 5; if (j > cnt - 1) j = cnt - 1; ga = (rm & 31) * S + d_sets.idx[alvl][j]; }
        else ga = rm;
        abase[r] = (size_t)ga * Kd + kbase + kg * 8;
        bbase[r] = (size_t)(n0 + row) * Kd + kbase + kg * 8;
    }
    auto stage = [&](int buf, int k0) {
#pragma unroll
        for (int r = 0; r < 2; ++r) {
            short* la = As[buf] + (size_t)(r * 256 + wid * 64) * 8;
            short* lb = Bs[buf] + (size_t)(r * 256 + wid * 64) * 8;
            gload_lds16(A + abase[r] + k0, la);
            gload_lds16(Bt + bbase[r] + k0, lb);
        }
    };
    auto rd_off = [&](int row_) {
        int rh = row_ >> 1;
        int s  = lk ^ (rh & 3);
        return (size_t)(rh * 8 + (row_ & 1) * 4 + s) * 8;
    };

    float4v acc[4][4];
#pragma unroll
    for (int i = 0; i < 4; ++i)
#pragma unroll
        for (int j = 0; j < 4; ++j) acc[i][j] = 0;

    const int nt = kb >> 5;
    stage(0, 0);
    for (int t = 0; t < nt; ++t) {
        int cur = t & 1;
        if (t + 1 < nt) {
            stage(cur ^ 1, (t + 1) * 32);
            asm volatile("s_waitcnt vmcnt(4)" ::: "memory");
        } else {
            asm volatile("s_waitcnt vmcnt(0)" ::: "memory");
        }
        __builtin_amdgcn_s_barrier();
        short8 af[4], bfv[4];
#pragma unroll
        for (int mi = 0; mi < 4; ++mi)
            af[mi] = *(const short8*)(As[cur] + rd_off(wm * 64 + mi * 16 + lr));
#pragma unroll
        for (int ni = 0; ni < 4; ++ni)
            bfv[ni] = *(const short8*)(Bs[cur] + rd_off(wn * 64 + ni * 16 + lr));
        __builtin_amdgcn_s_setprio(1);
#pragma unroll
        for (int mi = 0; mi < 4; ++mi)
#pragma unroll
            for (int ni = 0; ni < 4; ++ni)
                acc[mi][ni] = __builtin_amdgcn_mfma_f32_16x16x32_bf16(
                    af[mi], bfv[ni], acc[mi][ni], 0, 0, 0);
        __builtin_amdgcn_s_setprio(0);
        __builtin_amdgcn_s_barrier();
    }

#pragma unroll
    for (int mi = 0; mi < 4; ++mi) {
        int gmc = m0 + wm * 64 + mi * 16 + lk * 4;
#pragma unroll
        for (int ni = 0; ni < 4; ++ni) {
            int gn = n0 + wn * 64 + ni * 16 + lr;
#pragma unroll
            for (int e = 0; e < 4; ++e)
                part[((size_t)kz * Mpad + gmc + e) * Nd + gn] = acc[mi][ni][e];
        }
    }
}

// sum KS partials + epilogue -> bf16 compact output (only FFN1 uses this now)
// EPI: 3 +bias+gelu
template<int EPI>
__launch_bounds__(256)
__global__ void reduce_sk(const float* __restrict__ part, const float* __restrict__ bias,
                          short* __restrict__ Cout, int Mpad, int Nd, int KS) {
    int idx = blockIdx.x * 256 + threadIdx.x;
    if (idx >= Mpad * Nd) return;
    float s = 0.0f;
    for (int k = 0; k < KS; ++k)
        s += part[(size_t)k * Mpad * Nd + idx];
    if (EPI == 3 || EPI == 4) s += bias[idx % Nd];
    if (EPI == 3) s = 0.5f * s * (1.0f + erff(s * 0.70710678118654752f));
    Cout[idx] = f2bf(s);
}

// ---------------------------------------------------------------------------
// batched weight transpose+convert, 32x32 tiles, f32 W[Kd][Nd] -> bf16 Wt[Nd][Kd]
// ---------------------------------------------------------------------------
__device__ inline void wtrans_tile(const float* __restrict__ W, short* __restrict__ Wt,
                                   int Kd, int Nd, int n0, int k0, int tid) {
    __shared__ float tile[32][33];
    int tx = tid & 31, ty = tid >> 5; // ty 0..7
#pragma unroll
    for (int r = 0; r < 32; r += 8)
        tile[ty + r][tx] = W[(size_t)(k0 + ty + r) * Nd + n0 + tx];
    __syncthreads();
#pragma unroll
    for (int r = 0; r < 32; r += 8)
        Wt[(size_t)(n0 + ty + r) * Kd + k0 + tx] = f2bf(tile[tx][ty + r]);
}

__launch_bounds__(256)
__global__ void wtrans_qkvo(const float* __restrict__ wq, const float* __restrict__ wk,
                            const float* __restrict__ wv, const float* __restrict__ wo,
                            short* __restrict__ wqkvT, short* __restrict__ woT) {
    int z = blockIdx.z, l = z >> 2, part = z & 3;
    const float* src = (part == 0 ? wq : part == 1 ? wk : part == 2 ? wv : wo)
                       + (size_t)l * D * D;
    short* dst = (part < 3) ? wqkvT + (size_t)l * 3 * D * D + (size_t)part * D * D
                            : woT + (size_t)l * D * D;
    wtrans_tile(src, dst, D, D, blockIdx.x * 32, blockIdx.y * 32, threadIdx.x);
}

__launch_bounds__(256)
__global__ void wtrans_ffn(const float* __restrict__ w1, const float* __restrict__ w2,
                           short* __restrict__ w1T, short* __restrict__ w2T) {
    int z = blockIdx.z, l = z >> 1, part = z & 1;
    int nt = part ? blockIdx.y : blockIdx.x;
    int kt = part ? blockIdx.x : blockIdx.y;
    if (part == 0)
        wtrans_tile(w1 + (size_t)l * D * DFF, w1T + (size_t)l * DFF * D,
                    D, DFF, nt * 32, kt * 32, threadIdx.x);
    else
        wtrans_tile(w2 + (size_t)l * DFF * D, w2T + (size_t)l * D * DFF,
                    DFF, D, nt * 32, kt * 32, threadIdx.x);
}

// ---------------------------------------------------------------------------
// fused small-weight prep: blocks 0..63 down_w^T; 64..127 up_w^T;
// 128..639 cscm GEMM-layout + BN coefficient fold
// ---------------------------------------------------------------------------
__launch_bounds__(256)
__global__ void wtrans_small(const float* __restrict__ down_w, short* __restrict__ downT,
                             const float* __restrict__ up_w, short* __restrict__ upT,
                             const float* __restrict__ cw, const float* __restrict__ cb,
                             const float* __restrict__ bg, const float* __restrict__ bb,
                             short* __restrict__ cscmT, float* __restrict__ sc,
                             float* __restrict__ sh) {
    int b = blockIdx.x;
    if (b < 64) {
        wtrans_tile(down_w, downT, D, DBOT, (b & 3) * 32, (b >> 2) * 32, threadIdx.x);
    } else if (b < 128) {
        int b2 = b - 64;
        wtrans_tile(up_w, upT, DBOT, D, (b2 & 15) * 32, (b2 >> 4) * 32, threadIdx.x);
    } else {
        int idx = (b - 128) * 256 + threadIdx.x;
        if (idx < 2 * DBOT * 512) {
            int l = idx >> 16;
            int rem = idx & 65535;
            int oc = rem >> 9, j = rem & 511;
            int r = j >> 7, c = j & 127;
            cscmT[idx] = f2bf(cw[(((size_t)l * DBOT + oc) * DBOT + c) * 4 + r]);
        }
        if (idx < 3 * DBOT) {
            sc[idx] = bg[idx];
            sh[idx] = cb[idx] * bg[idx] + bb[idx];
        }
    }
}

// ---------------------------------------------------------------------------
// fused misc prep: pe table | embed weight wE | im2col xim  (range-partitioned)
// ---------------------------------------------------------------------------
constexpr int PE_N  = L * D;           // 172032
constexpr int WE_N  = D * 32;          // 16384
constexpr int XIM_N = BB * L * 32;     // 344064
constexpr int MISC_N = PE_N + WE_N + XIM_N;

__launch_bounds__(256)
__global__ void prep_misc(const float* __restrict__ x_enc, const float* __restrict__ x_mark,
                          const float* __restrict__ cw, const float* __restrict__ tw,
                          const float* __restrict__ tb, float* __restrict__ pe,
                          short* __restrict__ wE, short* __restrict__ xim) {
    int idx = blockIdx.x * 256 + threadIdx.x;
    if (idx < PE_N) {
        int d = idx % D, t = idx / D;
        int e = d & ~1;
        float div = expf(-(float)e * (logf(10000.0f) / (float)D));
        float arg = (float)t * div;
        pe[idx] = (d & 1) ? cosf(arg) : sinf(arg);
        return;
    }
    int i2 = idx - PE_N;
    if (i2 < WE_N) {
        int k = i2 & 31, d = i2 >> 5;
        float v = 0.0f;
        if (k < 21) {
            int w = k / 7, i = k % 7;
            v = cw[(size_t)d * (CIN * 3) + i * 3 + w];
        } else if (k < 25) {
            v = tw[(size_t)(k - 21) * D + d];
        } else if (k == 25) {
            v = tb[d];
        }
        wE[i2] = f2bf(v);
        return;
    }
    int i3 = i2 - WE_N;
    if (i3 < XIM_N) {
        int k = i3 & 31, m = i3 >> 5;
        int t = m % L, b = m / L;
        float v = 0.0f;
        if (k < 21) {
            int w = k / 7, i = k % 7;
            int s = t + w - 1;
            if (s < 0) s = L - 1;
            if (s >= L) s = 0;
            v = x_enc[((size_t)b * L + s) * CIN + i];
        } else if (k < 25) {
            v = x_mark[(size_t)m * MARK + (k - 21)];
        } else if (k == 25) {
            v = 1.0f;
        }
        xim[i3] = f2bf(v);
    }
}

// ---------------------------------------------------------------------------
// CSCM conv level 3 (tiny)
// ---------------------------------------------------------------------------
__launch_bounds__(128)
__global__ void cscm_conv_bf16(const short* __restrict__ in, int inRowsPerB,
                               short* __restrict__ outp, const float* __restrict__ w,
                               const float* __restrict__ cb, const float* __restrict__ bng,
                               const float* __restrict__ bnb, int Lout) {
    int bid = blockIdx.x;
    int to = bid % Lout, b = bid / Lout;
    __shared__ float insh[4 * DBOT];
    int tid = threadIdx.x;
#pragma unroll
    for (int r = 0; r < 4; ++r)
        insh[r * DBOT + tid] = bf2f(in[((size_t)(b * inRowsPerB + to * 4 + r)) * DBOT + tid]);
    __syncthreads();
    float acc = cb[tid];
    const float* wr = w + (size_t)tid * (DBOT * 4);
    for (int c = 0; c < DBOT; ++c) {
#pragma unroll
        for (int r = 0; r < 4; ++r)
            acc += insh[r * DBOT + c] * wr[c * 4 + r];
    }
    acc = acc * bng[tid] + bnb[tid];
    outp[((size_t)(b * Lout + to)) * DBOT + tid] = f2bf(acc > 0.0f ? acc : (expf(acc) - 1.0f));
}

// ---------------------------------------------------------------------------
// concat pyramid outputs (bf16) -> csc [MCAT][128]
// ---------------------------------------------------------------------------
__launch_bounds__(256)
__global__ void concat_cs_kernel(const short* __restrict__ cs1, const short* __restrict__ cs2,
                                 const short* __restrict__ cs3, short* __restrict__ csc) {
    int idx = blockIdx.x * 256 + threadIdx.x;
    if (idx >= MCAT * DBOT) return;
    int m = idx >> 7, c = idx & 127;
    short v = 0;
    if (m < BB * LC) {
        int b = m / LC, t = m % LC;
        if (t < L1)           v = cs1[(size_t)(b * L1 + t) * DBOT + c];
        else if (t < L1 + L2) v = cs2[(size_t)(b * L2 + (t - L1)) * DBOT + c];
        else                  v = cs3[(size_t)(b * L3 + (t - L1 - L2)) * DBOT + c];
    }
    csc[idx] = v;
}

// ---------------------------------------------------------------------------
// sparse attention over active level (compact Ob)
// ---------------------------------------------------------------------------
__launch_bounds__(256)
__global__ void attn_sparse_kernel(const short* __restrict__ QKV, short* __restrict__ Ob,
                                   int lvl, int cnt) {
    int wid  = blockIdx.x * 4 + (threadIdx.x >> 6);
    if (wid >= cnt * 32) return;
    int lane = threadIdx.x & 63;
    int b = wid & 31, j = wid >> 5;
    int i = d_sets.idx[lvl][j];
    const short8 qv = *(const short8*)(QKV + (size_t)(b * S + i) * 1536 + lane * 8);
    float qf[8];
#pragma unroll
    for (int e = 0; e < 8; ++e) qf[e] = bf2f(qv[e]);
    int nb[NMAX];
#pragma unroll
    for (int jj = 0; jj < NMAX; ++jj) nb[jj] = d_sets.nbr[i][jj];
    float sc[NMAX];
#pragma unroll
    for (int jj = 0; jj < NMAX; ++jj) {
        float s = -1e30f;
        if (nb[jj] >= 0) {
            const short8 kv = *(const short8*)(QKV + (size_t)(b * S + nb[jj]) * 1536 + 512 + lane * 8);
            s = 0.0f;
#pragma unroll
            for (int e = 0; e < 8; ++e) s += qf[e] * bf2f(kv[e]);
            s += __shfl_xor(s, 1); s += __shfl_xor(s, 2); s += __shfl_xor(s, 4);
            s *= 0.125f;
        }
        sc[jj] = s;
    }
    float mx = sc[0];
#pragma unroll
    for (int jj = 1; jj < NMAX; ++jj) mx = fmaxf(mx, sc[jj]);
    float sum = 0.0f;
    float accv[8] = {};
#pragma unroll
    for (int jj = 0; jj < NMAX; ++jj) {
        float p = expf(sc[jj] - mx);
        sum += p;
        if (nb[jj] >= 0) {
            const short8 vv = *(const short8*)(QKV + (size_t)(b * S + nb[jj]) * 1536 + 1024 + lane * 8);
#pragma unroll
            for (int e = 0; e < 8; ++e) accv[e] += p * bf2f(vv[e]);
        }
    }
    float inv = 1.0f / sum;
    short8 ov;
#pragma unroll
    for (int e = 0; e < 8; ++e) ov[e] = f2bf(accv[e] * inv);
    *(short8*)(Ob + (size_t)wid * D + lane * 8) = ov;
}

// ---------------------------------------------------------------------------
// wave-shuffle block reduction over 4 waves (256 thr)
// ---------------------------------------------------------------------------
__device__ inline float blk_reduce(float v, float* ws4, int tid) {
#pragma unroll
    for (int o = 32; o; o >>= 1) v += __shfl_xor(v, o);
    if ((tid & 63) == 0) ws4[tid >> 6] = v;
    __syncthreads();
    return ws4[0] + ws4[1] + ws4[2] + ws4[3];
}

// ---------------------------------------------------------------------------
// concat(emb, coarse) + LayerNorm at A_0 rows only
// ---------------------------------------------------------------------------
__launch_bounds__(256)
__global__ void concat_ln_idx(const float* __restrict__ emb, const float* __restrict__ coarse,
                              const float* __restrict__ g, const float* __restrict__ bta,
                              float* __restrict__ seq, short* __restrict__ seq_bf) {
    int row = blockIdx.x;
    int b = row & 31, j = row >> 5;
    int s = d_sets.idx[0][j];
    int orig = b * S + s;
    const float* src = (s < L) ? emb + ((size_t)b * L + s) * D
                               : coarse + ((size_t)b * LC + (s - L)) * D;
    __shared__ float wsA[4];
    __shared__ float wsB[4];
    int tid = threadIdx.x;
    float x0 = src[tid], x1 = src[tid + 256];
    float mu = blk_reduce(x0 + x1, wsA, tid) * (1.0f / D);
    float d0 = x0 - mu, d1 = x1 - mu;
    float var = blk_reduce(d0 * d0 + d1 * d1, wsB, tid) * (1.0f / D);
    float rstd = rsqrtf(var + 1e-5f);
    float v0 = d0 * rstd * g[tid]       + bta[tid];
    float v1 = d1 * rstd * g[tid + 256] + bta[tid + 256];
    float* dst = seq + (size_t)orig * D;
    dst[tid] = v0; dst[tid + 256] = v1;
    short* dbf = seq_bf + (size_t)orig * D;
    dbf[tid] = f2bf(v0); dbf[tid + 256] = f2bf(v1);
}

// ---------------------------------------------------------------------------
// indexed residual LN (bf16 add input)
// ---------------------------------------------------------------------------
__launch_bounds__(256)
__global__ void add_ln_idx(float* __restrict__ seq, const short* __restrict__ add,
                           const float* __restrict__ g, const float* __restrict__ bta,
                           short* __restrict__ seq_bf, int lvl) {
    int row = blockIdx.x;
    int b = row & 31, j = row >> 5;
    int orig = b * S + d_sets.idx[lvl][j];
    __shared__ float wsA[4];
    __shared__ float wsB[4];
    int tid = threadIdx.x;
    float* srow = seq + (size_t)orig * D;
    const short* arow = add + (size_t)row * D;
    float x0 = srow[tid] + bf2f(arow[tid]);
    float x1 = srow[tid + 256] + bf2f(arow[tid + 256]);
    float mu = blk_reduce(x0 + x1, wsA, tid) * (1.0f / D);
    float d0 = x0 - mu, d1 = x1 - mu;
    float var = blk_reduce(d0 * d0 + d1 * d1, wsB, tid) * (1.0f / D);
    float rstd = rsqrtf(var + 1e-5f);
    float v0 = d0 * rstd * g[tid]       + bta[tid];
    float v1 = d1 * rstd * g[tid + 256] + bta[tid + 256];
    srow[tid] = v0; srow[tid + 256] = v1;
    short* dbf = seq_bf + (size_t)orig * D;
    dbf[tid] = f2bf(v0); dbf[tid + 256] = f2bf(v1);
}

// ---------------------------------------------------------------------------
// fused split-K reduce + residual LN: add = sum_k partsk[k][row][d] (+bias)
// replaces reduce_sk + add_ln_idx for the wo/FFN2 split-K sites (r18 fusion)
// ---------------------------------------------------------------------------
__launch_bounds__(256)
__global__ void add_ln_sk(float* __restrict__ seq, const float* __restrict__ part,
                          const float* __restrict__ bias, const float* __restrict__ g,
                          const float* __restrict__ bta, short* __restrict__ seq_bf,
                          int lvl, int Mpad, int KS) {
    int row = blockIdx.x;
    int b = row & 31, j = row >> 5;
    int orig = b * S + d_sets.idx[lvl][j];
    __shared__ float wsA[4];
    __shared__ float wsB[4];
    int tid = threadIdx.x;
    float a0 = 0.0f, a1 = 0.0f;
    for (int k = 0; k < KS; ++k) {
        const float* pr = part + ((size_t)k * Mpad + row) * D;
        a0 += pr[tid];
        a1 += pr[tid + 256];
    }
    if (bias) { a0 += bias[tid]; a1 += bias[tid + 256]; }
    float* srow = seq + (size_t)orig * D;
    float x0 = srow[tid] + a0;
    float x1 = srow[tid + 256] + a1;
    float mu = blk_reduce(x0 + x1, wsA, tid) * (1.0f / D);
    float d0 = x0 - mu, d1 = x1 - mu;
    float var = blk_reduce(d0 * d0 + d1 * d1, wsB, tid) * (1.0f / D);
    float rstd = rsqrtf(var + 1e-5f);
    float v0 = d0 * rstd * g[tid]       + bta[tid];
    float v1 = d1 * rstd * g[tid + 256] + bta[tid + 256];
    srow[tid] = v0; srow[tid + 256] = v1;
    short* dbf = seq_bf + (size_t)orig * D;
    dbf[tid] = f2bf(v0); dbf[tid + 256] = f2bf(v1);
}

// ---------------------------------------------------------------------------
// prediction head, split-K with fused gather
// ---------------------------------------------------------------------------
__launch_bounds__(256)
__global__ void pred_kernel(const float* __restrict__ seq, const float* __restrict__ w,
                            float* __restrict__ part) {
    __shared__ float es[32][257];
    __shared__ float wsm[256][8];
    int tid = threadIdx.x;
    int n0 = blockIdx.x * 8;
    int ks = blockIdx.y;
    int k0 = ks * 256;
    const int pos[4] = {335, 419, 440, 445};
    int seg = ks >> 1;
    int dbase = (ks & 1) * 256;
#pragma unroll 8
    for (int r = 0; r < 32; ++r)
        es[r][tid] = seq[((size_t)r * S + pos[seg]) * D + dbase + tid];
#pragma unroll
    for (int e = 0; e < 8; ++e)
        wsm[tid][e] = w[(size_t)(k0 + tid) * PRED_N + n0 + e];
    __syncthreads();
    int b = tid >> 3, nn = tid & 7;
    float acc = 0.0f;
#pragma unroll 8
    for (int kk = 0; kk < 256; ++kk)
        acc += es[b][kk] * wsm[kk][nn];
    part[(size_t)ks * (BB * PRED_N) + (size_t)b * PRED_N + n0 + nn] = acc;
}

__launch_bounds__(256)
__global__ void pred_reduce_kernel(const float* __restrict__ part, float* __restrict__ out) {
    int idx = blockIdx.x * 256 + threadIdx.x;
    if (idx >= BB * PRED_N) return;
    float s = 0.0f;
#pragma unroll
    for (int k = 0; k < 8; ++k) s += part[(size_t)k * (BB * PRED_N) + idx];
    out[idx] = s;
}

// ---------------------------------------------------------------------------
extern "C" void kernel_launch(void* const* d_in, const int* in_sizes, int n_in,
                              void* d_out, int out_size, void* d_ws, size_t ws_size,
                              hipStream_t stream) {
    const float* x_enc      = (const float*)d_in[0];
    const float* x_mark_enc = (const float*)d_in[1];
    const float* conv_embed_w = (const float*)d_in[4];
    const float* time_w  = (const float*)d_in[5];
    const float* time_b  = (const float*)d_in[6];
    const float* down_w  = (const float*)d_in[7];
    const float* down_b  = (const float*)d_in[8];
    const float* cscm_w  = (const float*)d_in[9];
    const float* cscm_b  = (const float*)d_in[10];
    const float* bn_g    = (const float*)d_in[11];
    const float* bn_b    = (const float*)d_in[12];
    const float* up_w    = (const float*)d_in[13];
    const float* up_b    = (const float*)d_in[14];
    const float* cln_g   = (const float*)d_in[15];
    const float* cln_b   = (const float*)d_in[16];
    const float* wq      = (const float*)d_in[17];
    const float* wk      = (const float*)d_in[18];
    const float* wv      = (const float*)d_in[19];
    const float* wo      = (const float*)d_in[20];
    const float* ln1_g   = (const float*)d_in[21];
    const float* ln1_b   = (const float*)d_in[22];
    const float* ffn_w1  = (const float*)d_in[23];
    const float* ffn_b1  = (const float*)d_in[24];
    const float* ffn_w2  = (const float*)d_in[25];
    const float* ffn_b2  = (const float*)d_in[26];
    const float* ln2_g   = (const float*)d_in[27];
    const float* ln2_b   = (const float*)d_in[28];
    const float* pred_w  = (const float*)d_in[29];
    float* out = (float*)d_out;

    // ---- workspace layout (bytes, 256-aligned) ----
    char* w8 = (char*)d_ws;
    size_t off = 0;
    auto alloc = [&](size_t bytes) {
        void* p = w8 + off;
        off = (off + bytes + 255) & ~(size_t)255;
        return p;
    };
    float* emb    = (float*)alloc((size_t)BB * L * D * 4);
    short* emb_bf = (short*)alloc((size_t)BB * L * D * 2);
    float* pe     = (float*)alloc((size_t)L * D * 4);
    short* xim    = (short*)alloc((size_t)BB * L * 32 * 2);
    short* wE     = (short*)alloc((size_t)D * 32 * 2);
    short* xd_bf  = (short*)alloc((size_t)BB * L * DBOT * 2);
    short* cs1_bf = (short*)alloc((size_t)MCONV2P * 512 * 2);
    short* cs2_bf = (short*)alloc((size_t)MCONV2P * DBOT * 2);
    short* cs3_bf = (short*)alloc((size_t)BB * L3 * DBOT * 2);
    short* csc_bf = (short*)alloc((size_t)MCAT * DBOT * 2);
    float* coarse = (float*)alloc((size_t)MCAT * D * 4);
    float* seq    = (float*)alloc((size_t)BB * S * D * 4);
    short* T1     = (short*)alloc((size_t)MP * D * 2);
    float* part   = (float*)alloc((size_t)8 * BB * PRED_N * 4);
    float* partsk = (float*)alloc(psk_elems() * 4);   // split-K partials (exact)
    short* seq_bf = (short*)alloc((size_t)MP * D * 2);
    short* QKV    = (short*)alloc((size_t)MP * 3 * D * 2);  // + Ob contiguous
    short* Ob     = (short*)alloc((size_t)MP * D * 2);
    short* hidden = QKV;
    short* wqkvT  = (short*)alloc((size_t)NLAYER * 3 * D * D * 2);
    short* woT    = (short*)alloc((size_t)NLAYER * D * D * 2);
    short* w1T    = (short*)alloc((size_t)NLAYER * DFF * D * 2);
    short* w2T    = (short*)alloc((size_t)NLAYER * D * DFF * 2);
    short* downT  = (short*)alloc((size_t)DBOT * D * 2);
    short* upT    = (short*)alloc((size_t)D * DBOT * 2);
    short* cscmT  = (short*)alloc((size_t)2 * DBOT * 512 * 2);
    float* csc_sc = (float*)alloc((size_t)3 * DBOT * 4);
    float* csc_sh = (float*)alloc((size_t)3 * DBOT * 4);
    (void)ws_size; (void)in_sizes; (void)n_in; (void)out_size;

    const int rowsL = BB * L;   // 10752 = 84*128
    dim3 blk(256);

    // 0. fused prep: weight transposes + pe/wE/xim + small weights
    wtrans_qkvo<<<dim3(16, 16, 4 * NLAYER), blk, 0, stream>>>(wq, wk, wv, wo, wqkvT, woT);
    wtrans_ffn<<<dim3(64, 16, 2 * NLAYER), blk, 0, stream>>>(ffn_w1, ffn_w2, w1T, w2T);
    wtrans_small<<<dim3(128 + 512), blk, 0, stream>>>(
        down_w, downT, up_w, upT, cscm_w, cscm_b, bn_g, bn_b, cscmT, csc_sc, csc_sh);
    prep_misc<<<dim3((MISC_N + 255) / 256), blk, 0, stream>>>(
        x_enc, x_mark_enc, conv_embed_w, time_w, time_b, pe, wE, xim);
    // 1. embedding as GEMM (M=10752, N=512, K=32) + pe epilogue, dual output
    mfma_gemm<6><<<dim3(D / 128, rowsL / 128), blk, 0, stream>>>(
        xim, wE, nullptr, nullptr, emb, 32, D, -1, -1, 0, pe, emb_bf);
    // 2. down projection -> bf16
    mfma_gemm<4><<<dim3(1, rowsL / 128), blk, 0, stream>>>(
        emb_bf, downT, down_b, nullptr, xd_bf, D, DBOT, -1, -1, 0, nullptr, nullptr);
    // 3. CSCM pyramid
    mfma_gemm<5><<<dim3(1, MCONV1 / 128), blk, 0, stream>>>(
        xd_bf, cscmT, csc_sc, csc_sh, cs1_bf, 512, DBOT, -1, -1, 0, nullptr, nullptr);
    mfma_gemm<5><<<dim3(1, MCONV2P / 128), blk, 0, stream>>>(
        cs1_bf, cscmT + (size_t)DBOT * 512, csc_sc + DBOT, csc_sh + DBOT,
        cs2_bf, 512, DBOT, -1, -1, 0, nullptr, nullptr);
    cscm_conv_bf16<<<dim3(BB * L3), dim3(DBOT), 0, stream>>>(
        cs2_bf, L2, cs3_bf, cscm_w + 2 * DBOT * DBOT * 4,
        cscm_b + 2 * DBOT, bn_g + 2 * DBOT, bn_b + 2 * DBOT, L3);
    // 4. up projection
    concat_cs_kernel<<<dim3((MCAT * DBOT + 255) / 256), blk, 0, stream>>>(
        cs1_bf, cs2_bf, cs3_bf, csc_bf);
    mfma_gemm<1><<<dim3(D / 128, MCAT / 128), blk, 0, stream>>>(
        csc_bf, upT, up_b, nullptr, coarse, DBOT, D, -1, -1, 0, nullptr, nullptr);
    // 5. concat + LN (A_0 rows only)
    concat_ln_idx<<<dim3(HS.cnt[0] * 32), blk, 0, stream>>>(
        emb, coarse, cln_g, cln_b, seq, seq_bf);

    // 6. encoder layers (sparse active sets; split-K + fused reduce/LN)
    for (int l = 0; l < NLAYER; ++l) {
        const int inLvl = l, outLvl = l + 1;
        const int inCnt  = HS.cnt[l];
        const int outCnt = HS.cnt[l + 1];
        const int Mc   = outCnt * 32;
        const int Mpad = ((Mc + 127) / 128) * 128;
        mfma_gemm<2><<<dim3(3 * D / 128, (inCnt * 32 + 127) / 128), blk, 0, stream>>>(
            seq_bf, wqkvT + (size_t)l * 3 * D * D, nullptr, nullptr, QKV, D, 3 * D,
            inLvl, inLvl, inCnt, nullptr, nullptr);
        attn_sparse_kernel<<<dim3(outCnt * 8), blk, 0, stream>>>(
            QKV, Ob, outLvl, outCnt);
        // O-projection + LN1 (split-K fused into LN when M small)
        if (Mc <= 512) {
            mfma_gemm_sk<<<dim3(D / 128, Mpad / 128, 4), blk, 0, stream>>>(
                Ob, woT + (size_t)l * D * D, partsk, D, D, -1, 0);
            add_ln_sk<<<dim3(Mc), blk, 0, stream>>>(
                seq, partsk, nullptr, ln1_g + (size_t)l * D, ln1_b + (size_t)l * D,
                seq_bf, outLvl, Mpad, 4);
        } else {
            mfma_gemm<2><<<dim3(D / 128, Mpad / 128), blk, 0, stream>>>(
                Ob, woT + (size_t)l * D * D, nullptr, nullptr, T1, D, D,
                -1, -1, 0, nullptr, nullptr);
            add_ln_idx<<<dim3(Mc), blk, 0, stream>>>(
                seq, T1, ln1_g + (size_t)l * D, ln1_b + (size_t)l * D, seq_bf, outLvl);
        }
        // FFN1: split-K only for tiny M (K=512, KS=4)
        if (Mc <= 128) {
            mfma_gemm_sk<<<dim3(DFF / 128, Mpad / 128, 4), blk, 0, stream>>>(
                seq_bf, w1T + (size_t)l * DFF * D, partsk, D, DFF, outLvl, outCnt);
            reduce_sk<3><<<dim3((Mpad * DFF + 255) / 256), blk, 0, stream>>>(
                partsk, ffn_b1 + (size_t)l * DFF, hidden, Mpad, DFF, 4);
        } else {
            mfma_gemm<3><<<dim3(DFF / 128, Mpad / 128), blk, 0, stream>>>(
                seq_bf, w1T + (size_t)l * DFF * D, ffn_b1 + (size_t)l * DFF, nullptr,
                hidden, D, DFF, outLvl, -1, outCnt, nullptr, nullptr);
        }
        // FFN2 + LN2: split-K, reduce fused into LN
        {
            int KS = (Mc <= 512) ? 8 : 4;
            mfma_gemm_sk<<<dim3(D / 128, Mpad / 128, KS), blk, 0, stream>>>(
                hidden, w2T + (size_t)l * D * DFF, partsk, DFF, D, -1, 0);
            add_ln_sk<<<dim3(Mc), blk, 0, stream>>>(
                seq, partsk, ffn_b2 + (size_t)l * D, ln2_g + (size_t)l * D,
                ln2_b + (size_t)l * D, seq_bf, outLvl, Mpad, KS);
        }
    }

    // 7. prediction head (split-K, gather fused) + reduce
    pred_kernel<<<dim3(PRED_N / 8, 8), blk, 0, stream>>>(seq, pred_w, part);
    pred_reduce_kernel<<<dim3((BB * PRED_N + 255) / 256), blk, 0, stream>>>(part, out);
}

// Round 20
// 347.055 us; speedup vs baseline: 2.6112x; 1.0383x over previous
//
#include <hip/hip_runtime.h>
#include <math.h>

// ---- problem constants ----
constexpr int BB   = 32;    // batch
constexpr int L    = 336;   // seq_len
constexpr int CIN  = 7;
constexpr int MARK = 4;
constexpr int D    = 512;   // d_model
constexpr int DFF  = 2048;
constexpr int NH   = 8;
constexpr int HD   = 64;    // dk = dv
constexpr int S    = 446;   // 336+84+21+5
constexpr int DBOT = 128;
constexpr int L1 = 84, L2 = 21, L3 = 5;
constexpr int LC = 110;     // 84+21+5
constexpr int NLAYER = 3;
constexpr int PRED_N = 672; // 96*7
constexpr int MP   = 14336; // BB*S padded
constexpr int NMAX = 12;    // max sparse neighbors (real max 10)
constexpr int MCONV1 = BB * L1;          // 2688 = 21*128 (exact)
constexpr int MCONV2P = 768;             // BB*L2=672 padded to 6*128
constexpr int MCAT  = 3584;              // BB*LC=3520 padded to 28*128

using short8  = __attribute__((ext_vector_type(8))) short;
using float4v = __attribute__((ext_vector_type(4))) float;

// ---------------------------------------------------------------------------
// COMPILE-TIME pyramid structure: neighbor lists + active sets.
// ---------------------------------------------------------------------------
struct SetsData {
    int nbr[S][NMAX];
    int idx[4][S];
    int cnt[4];
};

constexpr SetsData compute_sets() {
    SetsData sd{};
    constexpr int sizes[4]  = {336, 84, 21, 5};
    constexpr int starts[4] = {0, 336, 420, 441};
    for (int i = 0; i < S; ++i) {
        int li = 0, pi = i;
        if (i < 336)      { li = 0; pi = i; }
        else if (i < 420) { li = 1; pi = i - 336; }
        else if (i < 441) { li = 2; pi = i - 420; }
        else              { li = 3; pi = i - 441; }
        int cnt = 0;
        for (int d = -2; d <= 2; ++d) {
            int q = pi + d;
            if (q >= 0 && q < sizes[li]) sd.nbr[i][cnt++] = starts[li] + q;
        }
        if (li > 0) {
            int lo = pi * 4;
            int hi = (pi == sizes[li] - 1) ? sizes[li - 1] : (pi + 1) * 4;
            for (int c = lo; c < hi; ++c) sd.nbr[i][cnt++] = starts[li - 1] + c;
        }
        if (li < 3) {
            int q = pi >> 2;
            if (q > sizes[li + 1] - 1) q = sizes[li + 1] - 1;
            sd.nbr[i][cnt++] = starts[li + 1] + q;
        }
        for (int j = cnt; j < NMAX; ++j) sd.nbr[i][j] = -1;
    }
    sd.cnt[3] = 4;
    sd.idx[3][0] = 335; sd.idx[3][1] = 419; sd.idx[3][2] = 440; sd.idx[3][3] = 445;
    for (int lvl = 3; lvl >= 1; --lvl) {
        bool mk[S] = {};
        for (int k = 0; k < sd.cnt[lvl]; ++k) {
            int i = sd.idx[lvl][k];
            for (int t = 0; t < NMAX; ++t) {
                int v = sd.nbr[i][t];
                if (v >= 0) mk[v] = true;
            }
        }
        int nc = 0;
        for (int i = 0; i < S; ++i)
            if (mk[i]) sd.idx[lvl - 1][nc++] = i;
        sd.cnt[lvl - 1] = nc;
    }
    return sd;
}

constexpr SetsData HS = compute_sets();         // host: grid sizing
__constant__ SetsData d_sets = compute_sets();  // device: row maps + nbr

// exact split-K partial buffer size (elements), from compile-time counts
constexpr size_t psk_elems() {
    size_t mx = 4 * (size_t)BB * L * DBOT;      // down-proj split-K (5.5M)
    {
        size_t v = 4 * (size_t)MCONV1 * DBOT; if (v > mx) mx = v;   // conv1
        v = 4 * (size_t)MCONV2P * DBOT;       if (v > mx) mx = v;   // conv2
    }
    for (int l = 0; l < NLAYER; ++l) {
        size_t Mc = (size_t)HS.cnt[l + 1] * 32;
        size_t Mpad = ((Mc + 127) / 128) * 128;
        if (Mc <= 512) { size_t v = 4 * Mpad * 512;  if (v > mx) mx = v; }   // wo
        if (Mc <= 128) { size_t v = 4 * Mpad * 2048; if (v > mx) mx = v; }   // ffn1
        size_t ks = (Mc <= 512) ? 8 : 4;
        size_t v = ks * Mpad * 512; if (v > mx) mx = v;                      // ffn2
    }
    return mx;
}

__device__ inline short f2bf(float f) {
    union { float f; unsigned u; } v; v.f = f;
    unsigned r = v.u + 0x7fffu + ((v.u >> 16) & 1u);
    return (short)(r >> 16);
}
__device__ inline float bf2f(short h) {
    union { unsigned u; float f; } v; v.u = ((unsigned)(unsigned short)h) << 16;
    return v.f;
}

// async global->LDS, 16B per lane, wave-uniform LDS base + lane*16
__device__ inline void gload_lds16(const void* g, void* l) {
    __builtin_amdgcn_global_load_lds(
        (const __attribute__((address_space(1))) void*)g,
        (__attribute__((address_space(3))) void*)l, 16, 0, 0);
}

// Staging map: conflict-free + coalesced (verified r11: 0 bank conflicts).
// Sparse rows: alvl/clvl >= 0 select d_sets.idx[lvl] (pos-major compact:
// compact m -> b=m&31, j=m>>5 clamped to cnt-1, orig row b*S+idx[j]).

// ---------------------------------------------------------------------------
// 128x128 bf16 MFMA GEMM, BK=32, double-buffered, counted vmcnt(4) pipeline.
// EPI: 0 f32; 1 f32+bias; 2 bf16; 3 bf16+bias+gelu; 4 bf16+bias;
//      5 bf16, v = acc*bias[gn]+bias2[gn] then ELU;
//      6 v = acc + peT[(row%L)*D+gn] -> bf16 Cout2 only (embed)
// ---------------------------------------------------------------------------
template<int EPI>
__launch_bounds__(256, 4)
__global__ void mfma_gemm(const short* __restrict__ A, const short* __restrict__ Bt,
                          const float* __restrict__ bias, const float* __restrict__ bias2,
                          void* __restrict__ Cout, int Kd, int Nd,
                          int alvl, int clvl, int cnt,
                          const float* __restrict__ peT, short* __restrict__ Cout2) {
    __shared__ short As[2][128 * 32];
    __shared__ short Bs[2][128 * 32];
    int tid = threadIdx.x;
    int nwg  = gridDim.x * gridDim.y;
    int orig = blockIdx.y * gridDim.x + blockIdx.x;
    int qq = nwg >> 3, rr = nwg & 7;
    int xcd = orig & 7, idx = orig >> 3;
    int wgid = (xcd < rr ? xcd * (qq + 1) : rr * (qq + 1) + (xcd - rr) * qq) + idx;
    int m0 = (wgid / gridDim.x) * 128, n0 = (wgid % gridDim.x) * 128;

    int lane = tid & 63, wid = tid >> 6;
    int wm = wid >> 1, wn = wid & 1;
    int lr = lane & 15, lk = lane >> 4;

    size_t abase[2], bbase[2];
#pragma unroll
    for (int r = 0; r < 2; ++r) {
        int u = r * 256 + tid;
        int row = ((u >> 3) << 1) | ((u >> 2) & 1);
        int kg  = (u & 3) ^ ((u >> 3) & 3);
        int rm = m0 + row, ga;
        if (alvl >= 0) { int j = rm >> 5; if (j > cnt - 1) j = cnt - 1; ga = (rm & 31) * S + d_sets.idx[alvl][j]; }
        else ga = rm;
        abase[r] = (size_t)ga * Kd + kg * 8;
        bbase[r] = (size_t)(n0 + row) * Kd + kg * 8;
    }
    auto stage = [&](int buf, int k0) {
#pragma unroll
        for (int r = 0; r < 2; ++r) {
            short* la = As[buf] + (size_t)(r * 256 + wid * 64) * 8;
            short* lb = Bs[buf] + (size_t)(r * 256 + wid * 64) * 8;
            gload_lds16(A + abase[r] + k0, la);
            gload_lds16(Bt + bbase[r] + k0, lb);
        }
    };
    auto rd_off = [&](int row_) {
        int rh = row_ >> 1;
        int s  = lk ^ (rh & 3);
        return (size_t)(rh * 8 + (row_ & 1) * 4 + s) * 8;
    };

    float4v acc[4][4];
#pragma unroll
    for (int i = 0; i < 4; ++i)
#pragma unroll
        for (int j = 0; j < 4; ++j) acc[i][j] = 0;

    const int nt = Kd >> 5;
    stage(0, 0);
    for (int t = 0; t < nt; ++t) {
        int cur = t & 1;
        if (t + 1 < nt) {
            stage(cur ^ 1, (t + 1) * 32);
            asm volatile("s_waitcnt vmcnt(4)" ::: "memory");
        } else {
            asm volatile("s_waitcnt vmcnt(0)" ::: "memory");
        }
        __builtin_amdgcn_s_barrier();
        short8 af[4], bfv[4];
#pragma unroll
        for (int mi = 0; mi < 4; ++mi)
            af[mi] = *(const short8*)(As[cur] + rd_off(wm * 64 + mi * 16 + lr));
#pragma unroll
        for (int ni = 0; ni < 4; ++ni)
            bfv[ni] = *(const short8*)(Bs[cur] + rd_off(wn * 64 + ni * 16 + lr));
        __builtin_amdgcn_s_setprio(1);
#pragma unroll
        for (int mi = 0; mi < 4; ++mi)
#pragma unroll
            for (int ni = 0; ni < 4; ++ni)
                acc[mi][ni] = __builtin_amdgcn_mfma_f32_16x16x32_bf16(
                    af[mi], bfv[ni], acc[mi][ni], 0, 0, 0);
        __builtin_amdgcn_s_setprio(0);
        __builtin_amdgcn_s_barrier();
    }

#pragma unroll
    for (int mi = 0; mi < 4; ++mi) {
        int gmc = m0 + wm * 64 + mi * 16 + lk * 4;
#pragma unroll
        for (int ni = 0; ni < 4; ++ni) {
            int gn = n0 + wn * 64 + ni * 16 + lr;
            float bsv = (EPI == 1 || EPI == 3 || EPI == 4) ? bias[gn] : 0.0f;
            float sc = (EPI == 5) ? bias[gn]  : 0.0f;
            float sh = (EPI == 5) ? bias2[gn] : 0.0f;
#pragma unroll
            for (int e = 0; e < 4; ++e) {
                int rm = gmc + e, grow;
                if (clvl >= 0) { int j = rm >> 5; if (j > cnt - 1) j = cnt - 1; grow = (rm & 31) * S + d_sets.idx[clvl][j]; }
                else grow = rm;
                float v = acc[mi][ni][e] + bsv;
                if (EPI == 3) v = 0.5f * v * (1.0f + erff(v * 0.70710678118654752f));
                if (EPI == 5) { v = v * sc + sh; v = v > 0.0f ? v : (expf(v) - 1.0f); }
                if (EPI == 6) {
                    v += peT[(size_t)(grow % L) * D + gn];
                    Cout2[(size_t)grow * Nd + gn] = f2bf(v);
                } else if (EPI <= 1) {
                    ((float*)Cout)[(size_t)grow * Nd + gn] = v;
                } else {
                    ((short*)Cout)[(size_t)grow * Nd + gn] = f2bf(v);
                }
            }
        }
    }
}

// ---------------------------------------------------------------------------
// SPLIT-K variant: gridDim.z = KS slices; writes f32 partial part[kz][Mpad][Nd].
// ---------------------------------------------------------------------------
__launch_bounds__(256, 4)
__global__ void mfma_gemm_sk(const short* __restrict__ A, const short* __restrict__ Bt,
                             float* __restrict__ part, int Kd, int Nd,
                             int alvl, int cnt) {
    __shared__ short As[2][128 * 32];
    __shared__ short Bs[2][128 * 32];
    int tid = threadIdx.x;
    int nwg  = gridDim.x * gridDim.y;
    int orig = blockIdx.y * gridDim.x + blockIdx.x;
    int qq = nwg >> 3, rr = nwg & 7;
    int xcd = orig & 7, idx = orig >> 3;
    int wgid = (xcd < rr ? xcd * (qq + 1) : rr * (qq + 1) + (xcd - rr) * qq) + idx;
    int m0 = (wgid / gridDim.x) * 128, n0 = (wgid % gridDim.x) * 128;
    int Mpad = gridDim.y * 128;
    int kz = blockIdx.z;
    int kb = Kd / gridDim.z;          // slice length (multiple of 32)
    int kbase = kz * kb;

    int lane = tid & 63, wid = tid >> 6;
    int wm = wid >> 1, wn = wid & 1;
    int lr = lane & 15, lk = lane >> 4;

    size_t abase[2], bbase[2];
#pragma unroll
    for (int r = 0; r < 2; ++r) {
        int u = r * 256 + tid;
        int row = ((u >> 3) << 1) | ((u >> 2) & 1);
        int kg  = (u & 3) ^ ((u >> 3) & 3);
        int rm = m0 + row, ga;
        if (alvl >= 0) { int j = rm >> 5; if (j > cnt - 1) j = cnt - 1; ga = (rm & 31) * S + d_sets.idx[alvl][j]; }
        else ga = rm;
        abase[r] = (size_t)ga * Kd + kbase + kg * 8;
        bbase[r] = (size_t)(n0 + row) * Kd + kbase + kg * 8;
    }
    auto stage = [&](int buf, int k0) {
#pragma unroll
        for (int r = 0; r < 2; ++r) {
            short* la = As[buf] + (size_t)(r * 256 + wid * 64) * 8;
            short* lb = Bs[buf] + (size_t)(r * 256 + wid * 64) * 8;
            gload_lds16(A + abase[r] + k0, la);
            gload_lds16(Bt + bbase[r] + k0, lb);
        }
    };
    auto rd_off = [&](int row_) {
        int rh = row_ >> 1;
        int s  = lk ^ (rh & 3);
        return (size_t)(rh * 8 + (row_ & 1) * 4 + s) * 8;
    };

    float4v acc[4][4];
#pragma unroll
    for (int i = 0; i < 4; ++i)
#pragma unroll
        for (int j = 0; j < 4; ++j) acc[i][j] = 0;

    const int nt = kb >> 5;
    stage(0, 0);
    for (int t = 0; t < nt; ++t) {
        int cur = t & 1;
        if (t + 1 < nt) {
            stage(cur ^ 1, (t + 1) * 32);
            asm volatile("s_waitcnt vmcnt(4)" ::: "memory");
        } else {
            asm volatile("s_waitcnt vmcnt(0)" ::: "memory");
        }
        __builtin_amdgcn_s_barrier();
        short8 af[4], bfv[4];
#pragma unroll
        for (int mi = 0; mi < 4; ++mi)
            af[mi] = *(const short8*)(As[cur] + rd_off(wm * 64 + mi * 16 + lr));
#pragma unroll
        for (int ni = 0; ni < 4; ++ni)
            bfv[ni] = *(const short8*)(Bs[cur] + rd_off(wn * 64 + ni * 16 + lr));
        __builtin_amdgcn_s_setprio(1);
#pragma unroll
        for (int mi = 0; mi < 4; ++mi)
#pragma unroll
            for (int ni = 0; ni < 4; ++ni)
                acc[mi][ni] = __builtin_amdgcn_mfma_f32_16x16x32_bf16(
                    af[mi], bfv[ni], acc[mi][ni], 0, 0, 0);
        __builtin_amdgcn_s_setprio(0);
        __builtin_amdgcn_s_barrier();
    }

#pragma unroll
    for (int mi = 0; mi < 4; ++mi) {
        int gmc = m0 + wm * 64 + mi * 16 + lk * 4;
#pragma unroll
        for (int ni = 0; ni < 4; ++ni) {
            int gn = n0 + wn * 64 + ni * 16 + lr;
#pragma unroll
            for (int e = 0; e < 4; ++e)
                part[((size_t)kz * Mpad + gmc + e) * Nd + gn] = acc[mi][ni][e];
        }
    }
}

// sum KS partials + epilogue -> bf16 compact output
// EPI: 3 +bias+gelu; 4 +bias; 5 *bias+bias2 then ELU (conv BN fold)
template<int EPI>
__launch_bounds__(256)
__global__ void reduce_sk(const float* __restrict__ part, const float* __restrict__ bias,
                          const float* __restrict__ bias2, short* __restrict__ Cout,
                          int Mpad, int Nd, int KS) {
    int idx = blockIdx.x * 256 + threadIdx.x;
    if (idx >= Mpad * Nd) return;
    float s = 0.0f;
    for (int k = 0; k < KS; ++k)
        s += part[(size_t)k * Mpad * Nd + idx];
    int n = idx % Nd;
    if (EPI == 3 || EPI == 4) s += bias[n];
    if (EPI == 3) s = 0.5f * s * (1.0f + erff(s * 0.70710678118654752f));
    if (EPI == 5) { s = s * bias[n] + bias2[n]; s = s > 0.0f ? s : (expf(s) - 1.0f); }
    Cout[idx] = f2bf(s);
}

// ---------------------------------------------------------------------------
// batched weight transpose+convert, 32x32 tiles, f32 W[Kd][Nd] -> bf16 Wt[Nd][Kd]
// ---------------------------------------------------------------------------
__device__ inline void wtrans_tile(const float* __restrict__ W, short* __restrict__ Wt,
                                   int Kd, int Nd, int n0, int k0, int tid) {
    __shared__ float tile[32][33];
    int tx = tid & 31, ty = tid >> 5; // ty 0..7
#pragma unroll
    for (int r = 0; r < 32; r += 8)
        tile[ty + r][tx] = W[(size_t)(k0 + ty + r) * Nd + n0 + tx];
    __syncthreads();
#pragma unroll
    for (int r = 0; r < 32; r += 8)
        Wt[(size_t)(n0 + ty + r) * Kd + k0 + tx] = f2bf(tile[tx][ty + r]);
}

__launch_bounds__(256)
__global__ void wtrans_qkvo(const float* __restrict__ wq, const float* __restrict__ wk,
                            const float* __restrict__ wv, const float* __restrict__ wo,
                            short* __restrict__ wqkvT, short* __restrict__ woT) {
    int z = blockIdx.z, l = z >> 2, part = z & 3;
    const float* src = (part == 0 ? wq : part == 1 ? wk : part == 2 ? wv : wo)
                       + (size_t)l * D * D;
    short* dst = (part < 3) ? wqkvT + (size_t)l * 3 * D * D + (size_t)part * D * D
                            : woT + (size_t)l * D * D;
    wtrans_tile(src, dst, D, D, blockIdx.x * 32, blockIdx.y * 32, threadIdx.x);
}

__launch_bounds__(256)
__global__ void wtrans_ffn(const float* __restrict__ w1, const float* __restrict__ w2,
                           short* __restrict__ w1T, short* __restrict__ w2T) {
    int z = blockIdx.z, l = z >> 1, part = z & 1;
    int nt = part ? blockIdx.y : blockIdx.x;
    int kt = part ? blockIdx.x : blockIdx.y;
    if (part == 0)
        wtrans_tile(w1 + (size_t)l * D * DFF, w1T + (size_t)l * DFF * D,
                    D, DFF, nt * 32, kt * 32, threadIdx.x);
    else
        wtrans_tile(w2 + (size_t)l * DFF * D, w2T + (size_t)l * D * DFF,
                    DFF, D, nt * 32, kt * 32, threadIdx.x);
}

// ---------------------------------------------------------------------------
// fused small-weight prep: blocks 0..63 down_w^T; 64..127 up_w^T;
// 128..639 cscm GEMM-layout + BN coefficient fold
// ---------------------------------------------------------------------------
__launch_bounds__(256)
__global__ void wtrans_small(const float* __restrict__ down_w, short* __restrict__ downT,
                             const float* __restrict__ up_w, short* __restrict__ upT,
                             const float* __restrict__ cw, const float* __restrict__ cb,
                             const float* __restrict__ bg, const float* __restrict__ bb,
                             short* __restrict__ cscmT, float* __restrict__ sc,
                             float* __restrict__ sh) {
    int b = blockIdx.x;
    if (b < 64) {
        wtrans_tile(down_w, downT, D, DBOT, (b & 3) * 32, (b >> 2) * 32, threadIdx.x);
    } else if (b < 128) {
        int b2 = b - 64;
        wtrans_tile(up_w, upT, DBOT, D, (b2 & 15) * 32, (b2 >> 4) * 32, threadIdx.x);
    } else {
        int idx = (b - 128) * 256 + threadIdx.x;
        if (idx < 2 * DBOT * 512) {
            int l = idx >> 16;
            int rem = idx & 65535;
            int oc = rem >> 9, j = rem & 511;
            int r = j >> 7, c = j & 127;
            cscmT[idx] = f2bf(cw[(((size_t)l * DBOT + oc) * DBOT + c) * 4 + r]);
        }
        if (idx < 3 * DBOT) {
            sc[idx] = bg[idx];
            sh[idx] = cb[idx] * bg[idx] + bb[idx];
        }
    }
}

// ---------------------------------------------------------------------------
// fused misc prep: pe table | embed weight wE | im2col xim  (range-partitioned)
// ---------------------------------------------------------------------------
constexpr int PE_N  = L * D;           // 172032
constexpr int WE_N  = D * 32;          // 16384
constexpr int XIM_N = BB * L * 32;     // 344064
constexpr int MISC_N = PE_N + WE_N + XIM_N;

__launch_bounds__(256)
__global__ void prep_misc(const float* __restrict__ x_enc, const float* __restrict__ x_mark,
                          const float* __restrict__ cw, const float* __restrict__ tw,
                          const float* __restrict__ tb, float* __restrict__ pe,
                          short* __restrict__ wE, short* __restrict__ xim) {
    int idx = blockIdx.x * 256 + threadIdx.x;
    if (idx < PE_N) {
        int d = idx % D, t = idx / D;
        int e = d & ~1;
        float div = expf(-(float)e * (logf(10000.0f) / (float)D));
        float arg = (float)t * div;
        pe[idx] = (d & 1) ? cosf(arg) : sinf(arg);
        return;
    }
    int i2 = idx - PE_N;
    if (i2 < WE_N) {
        int k = i2 & 31, d = i2 >> 5;
        float v = 0.0f;
        if (k < 21) {
            int w = k / 7, i = k % 7;
            v = cw[(size_t)d * (CIN * 3) + i * 3 + w];
        } else if (k < 25) {
            v = tw[(size_t)(k - 21) * D + d];
        } else if (k == 25) {
            v = tb[d];
        }
        wE[i2] = f2bf(v);
        return;
    }
    int i3 = i2 - WE_N;
    if (i3 < XIM_N) {
        int k = i3 & 31, m = i3 >> 5;
        int t = m % L, b = m / L;
        float v = 0.0f;
        if (k < 21) {
            int w = k / 7, i = k % 7;
            int s = t + w - 1;
            if (s < 0) s = L - 1;
            if (s >= L) s = 0;
            v = x_enc[((size_t)b * L + s) * CIN + i];
        } else if (k < 25) {
            v = x_mark[(size_t)m * MARK + (k - 21)];
        } else if (k == 25) {
            v = 1.0f;
        }
        xim[i3] = f2bf(v);
    }
}

// ---------------------------------------------------------------------------
// CSCM conv level 3 (tiny)
// ---------------------------------------------------------------------------
__launch_bounds__(128)
__global__ void cscm_conv_bf16(const short* __restrict__ in, int inRowsPerB,
                               short* __restrict__ outp, const float* __restrict__ w,
                               const float* __restrict__ cb, const float* __restrict__ bng,
                               const float* __restrict__ bnb, int Lout) {
    int bid = blockIdx.x;
    int to = bid % Lout, b = bid / Lout;
    __shared__ float insh[4 * DBOT];
    int tid = threadIdx.x;
#pragma unroll
    for (int r = 0; r < 4; ++r)
        insh[r * DBOT + tid] = bf2f(in[((size_t)(b * inRowsPerB + to * 4 + r)) * DBOT + tid]);
    __syncthreads();
    float acc = cb[tid];
    const float* wr = w + (size_t)tid * (DBOT * 4);
    for (int c = 0; c < DBOT; ++c) {
#pragma unroll
        for (int r = 0; r < 4; ++r)
            acc += insh[r * DBOT + c] * wr[c * 4 + r];
    }
    acc = acc * bng[tid] + bnb[tid];
    outp[((size_t)(b * Lout + to)) * DBOT + tid] = f2bf(acc > 0.0f ? acc : (expf(acc) - 1.0f));
}

// ---------------------------------------------------------------------------
// concat pyramid outputs (bf16) -> csc [MCAT][128]
// ---------------------------------------------------------------------------
__launch_bounds__(256)
__global__ void concat_cs_kernel(const short* __restrict__ cs1, const short* __restrict__ cs2,
                                 const short* __restrict__ cs3, short* __restrict__ csc) {
    int idx = blockIdx.x * 256 + threadIdx.x;
    if (idx >= MCAT * DBOT) return;
    int m = idx >> 7, c = idx & 127;
    short v = 0;
    if (m < BB * LC) {
        int b = m / LC, t = m % LC;
        if (t < L1)           v = cs1[(size_t)(b * L1 + t) * DBOT + c];
        else if (t < L1 + L2) v = cs2[(size_t)(b * L2 + (t - L1)) * DBOT + c];
        else                  v = cs3[(size_t)(b * L3 + (t - L1 - L2)) * DBOT + c];
    }
    csc[idx] = v;
}

// ---------------------------------------------------------------------------
// sparse attention over active level (compact Ob)
// ---------------------------------------------------------------------------
__launch_bounds__(256)
__global__ void attn_sparse_kernel(const short* __restrict__ QKV, short* __restrict__ Ob,
                                   int lvl, int cnt) {
    int wid  = blockIdx.x * 4 + (threadIdx.x >> 6);
    if (wid >= cnt * 32) return;
    int lane = threadIdx.x & 63;
    int b = wid & 31, j = wid >> 5;
    int i = d_sets.idx[lvl][j];
    const short8 qv = *(const short8*)(QKV + (size_t)(b * S + i) * 1536 + lane * 8);
    float qf[8];
#pragma unroll
    for (int e = 0; e < 8; ++e) qf[e] = bf2f(qv[e]);
    int nb[NMAX];
#pragma unroll
    for (int jj = 0; jj < NMAX; ++jj) nb[jj] = d_sets.nbr[i][jj];
    float sc[NMAX];
#pragma unroll
    for (int jj = 0; jj < NMAX; ++jj) {
        float s = -1e30f;
        if (nb[jj] >= 0) {
            const short8 kv = *(const short8*)(QKV + (size_t)(b * S + nb[jj]) * 1536 + 512 + lane * 8);
            s = 0.0f;
#pragma unroll
            for (int e = 0; e < 8; ++e) s += qf[e] * bf2f(kv[e]);
            s += __shfl_xor(s, 1); s += __shfl_xor(s, 2); s += __shfl_xor(s, 4);
            s *= 0.125f;
        }
        sc[jj] = s;
    }
    float mx = sc[0];
#pragma unroll
    for (int jj = 1; jj < NMAX; ++jj) mx = fmaxf(mx, sc[jj]);
    float sum = 0.0f;
    float accv[8] = {};
#pragma unroll
    for (int jj = 0; jj < NMAX; ++jj) {
        float p = expf(sc[jj] - mx);
        sum += p;
        if (nb[jj] >= 0) {
            const short8 vv = *(const short8*)(QKV + (size_t)(b * S + nb[jj]) * 1536 + 1024 + lane * 8);
#pragma unroll
            for (int e = 0; e < 8; ++e) accv[e] += p * bf2f(vv[e]);
        }
    }
    float inv = 1.0f / sum;
    short8 ov;
#pragma unroll
    for (int e = 0; e < 8; ++e) ov[e] = f2bf(accv[e] * inv);
    *(short8*)(Ob + (size_t)wid * D + lane * 8) = ov;
}

// ---------------------------------------------------------------------------
// wave-shuffle block reduction over 4 waves (256 thr)
// ---------------------------------------------------------------------------
__device__ inline float blk_reduce(float v, float* ws4, int tid) {
#pragma unroll
    for (int o = 32; o; o >>= 1) v += __shfl_xor(v, o);
    if ((tid & 63) == 0) ws4[tid >> 6] = v;
    __syncthreads();
    return ws4[0] + ws4[1] + ws4[2] + ws4[3];
}

// ---------------------------------------------------------------------------
// concat(emb_bf, coarse) + LayerNorm at A_0 rows only (fine rows read bf16)
// ---------------------------------------------------------------------------
__launch_bounds__(256)
__global__ void concat_ln_idx(const short* __restrict__ emb_bf, const float* __restrict__ coarse,
                              const float* __restrict__ g, const float* __restrict__ bta,
                              float* __restrict__ seq, short* __restrict__ seq_bf) {
    int row = blockIdx.x;
    int b = row & 31, j = row >> 5;
    int s = d_sets.idx[0][j];
    int orig = b * S + s;
    __shared__ float wsA[4];
    __shared__ float wsB[4];
    int tid = threadIdx.x;
    float x0, x1;
    if (s < L) {
        const short* src = emb_bf + ((size_t)b * L + s) * D;
        x0 = bf2f(src[tid]); x1 = bf2f(src[tid + 256]);
    } else {
        const float* src = coarse + ((size_t)b * LC + (s - L)) * D;
        x0 = src[tid]; x1 = src[tid + 256];
    }
    float mu = blk_reduce(x0 + x1, wsA, tid) * (1.0f / D);
    float d0 = x0 - mu, d1 = x1 - mu;
    float var = blk_reduce(d0 * d0 + d1 * d1, wsB, tid) * (1.0f / D);
    float rstd = rsqrtf(var + 1e-5f);
    float v0 = d0 * rstd * g[tid]       + bta[tid];
    float v1 = d1 * rstd * g[tid + 256] + bta[tid + 256];
    float* dst = seq + (size_t)orig * D;
    dst[tid] = v0; dst[tid + 256] = v1;
    short* dbf = seq_bf + (size_t)orig * D;
    dbf[tid] = f2bf(v0); dbf[tid + 256] = f2bf(v1);
}

// ---------------------------------------------------------------------------
// indexed residual LN (bf16 add input)
// ---------------------------------------------------------------------------
__launch_bounds__(256)
__global__ void add_ln_idx(float* __restrict__ seq, const short* __restrict__ add,
                           const float* __restrict__ g, const float* __restrict__ bta,
                           short* __restrict__ seq_bf, int lvl) {
    int row = blockIdx.x;
    int b = row & 31, j = row >> 5;
    int orig = b * S + d_sets.idx[lvl][j];
    __shared__ float wsA[4];
    __shared__ float wsB[4];
    int tid = threadIdx.x;
    float* srow = seq + (size_t)orig * D;
    const short* arow = add + (size_t)row * D;
    float x0 = srow[tid] + bf2f(arow[tid]);
    float x1 = srow[tid + 256] + bf2f(arow[tid + 256]);
    float mu = blk_reduce(x0 + x1, wsA, tid) * (1.0f / D);
    float d0 = x0 - mu, d1 = x1 - mu;
    float var = blk_reduce(d0 * d0 + d1 * d1, wsB, tid) * (1.0f / D);
    float rstd = rsqrtf(var + 1e-5f);
    float v0 = d0 * rstd * g[tid]       + bta[tid];
    float v1 = d1 * rstd * g[tid + 256] + bta[tid + 256];
    srow[tid] = v0; srow[tid + 256] = v1;
    short* dbf = seq_bf + (size_t)orig * D;
    dbf[tid] = f2bf(v0); dbf[tid + 256] = f2bf(v1);
}

// ---------------------------------------------------------------------------
// fused split-K reduce + residual LN
// ---------------------------------------------------------------------------
__launch_bounds__(256)
__global__ void add_ln_sk(float* __restrict__ seq, const float* __restrict__ part,
                          const float* __restrict__ bias, const float* __restrict__ g,
                          const float* __restrict__ bta, short* __restrict__ seq_bf,
                          int lvl, int Mpad, int KS) {
    int row = blockIdx.x;
    int b = row & 31, j = row >> 5;
    int orig = b * S + d_sets.idx[lvl][j];
    __shared__ float wsA[4];
    __shared__ float wsB[4];
    int tid = threadIdx.x;
    float a0 = 0.0f, a1 = 0.0f;
    for (int k = 0; k < KS; ++k) {
        const float* pr = part + ((size_t)k * Mpad + row) * D;
        a0 += pr[tid];
        a1 += pr[tid + 256];
    }
    if (bias) { a0 += bias[tid]; a1 += bias[tid + 256]; }
    float* srow = seq + (size_t)orig * D;
    float x0 = srow[tid] + a0;
    float x1 = srow[tid + 256] + a1;
    float mu = blk_reduce(x0 + x1, wsA, tid) * (1.0f / D);
    float d0 = x0 - mu, d1 = x1 - mu;
    float var = blk_reduce(d0 * d0 + d1 * d1, wsB, tid) * (1.0f / D);
    float rstd = rsqrtf(var + 1e-5f);
    float v0 = d0 * rstd * g[tid]       + bta[tid];
    float v1 = d1 * rstd * g[tid + 256] + bta[tid + 256];
    srow[tid] = v0; srow[tid + 256] = v1;
    short* dbf = seq_bf + (size_t)orig * D;
    dbf[tid] = f2bf(v0); dbf[tid + 256] = f2bf(v1);
}

// ---------------------------------------------------------------------------
// prediction head, split-K with fused gather
// ---------------------------------------------------------------------------
__launch_bounds__(256)
__global__ void pred_kernel(const float* __restrict__ seq, const float* __restrict__ w,
                            float* __restrict__ part) {
    __shared__ float es[32][257];
    __shared__ float wsm[256][8];
    int tid = threadIdx.x;
    int n0 = blockIdx.x * 8;
    int ks = blockIdx.y;
    int k0 = ks * 256;
    const int pos[4] = {335, 419, 440, 445};
    int seg = ks >> 1;
    int dbase = (ks & 1) * 256;
#pragma unroll 8
    for (int r = 0; r < 32; ++r)
        es[r][tid] = seq[((size_t)r * S + pos[seg]) * D + dbase + tid];
#pragma unroll
    for (int e = 0; e < 8; ++e)
        wsm[tid][e] = w[(size_t)(k0 + tid) * PRED_N + n0 + e];
    __syncthreads();
    int b = tid >> 3, nn = tid & 7;
    float acc = 0.0f;
#pragma unroll 8
    for (int kk = 0; kk < 256; ++kk)
        acc += es[b][kk] * wsm[kk][nn];
    part[(size_t)ks * (BB * PRED_N) + (size_t)b * PRED_N + n0 + nn] = acc;
}

__launch_bounds__(256)
__global__ void pred_reduce_kernel(const float* __restrict__ part, float* __restrict__ out) {
    int idx = blockIdx.x * 256 + threadIdx.x;
    if (idx >= BB * PRED_N) return;
    float s = 0.0f;
#pragma unroll
    for (int k = 0; k < 8; ++k) s += part[(size_t)k * (BB * PRED_N) + idx];
    out[idx] = s;
}

// ---------------------------------------------------------------------------
extern "C" void kernel_launch(void* const* d_in, const int* in_sizes, int n_in,
                              void* d_out, int out_size, void* d_ws, size_t ws_size,
                              hipStream_t stream) {
    const float* x_enc      = (const float*)d_in[0];
    const float* x_mark_enc = (const float*)d_in[1];
    const float* conv_embed_w = (const float*)d_in[4];
    const float* time_w  = (const float*)d_in[5];
    const float* time_b  = (const float*)d_in[6];
    const float* down_w  = (const float*)d_in[7];
    const float* down_b  = (const float*)d_in[8];
    const float* cscm_w  = (const float*)d_in[9];
    const float* cscm_b  = (const float*)d_in[10];
    const float* bn_g    = (const float*)d_in[11];
    const float* bn_b    = (const float*)d_in[12];
    const float* up_w    = (const float*)d_in[13];
    const float* up_b    = (const float*)d_in[14];
    const float* cln_g   = (const float*)d_in[15];
    const float* cln_b   = (const float*)d_in[16];
    const float* wq      = (const float*)d_in[17];
    const float* wk      = (const float*)d_in[18];
    const float* wv      = (const float*)d_in[19];
    const float* wo      = (const float*)d_in[20];
    const float* ln1_g   = (const float*)d_in[21];
    const float* ln1_b   = (const float*)d_in[22];
    const float* ffn_w1  = (const float*)d_in[23];
    const float* ffn_b1  = (const float*)d_in[24];
    const float* ffn_w2  = (const float*)d_in[25];
    const float* ffn_b2  = (const float*)d_in[26];
    const float* ln2_g   = (const float*)d_in[27];
    const float* ln2_b   = (const float*)d_in[28];
    const float* pred_w  = (const float*)d_in[29];
    float* out = (float*)d_out;

    // ---- workspace layout (bytes, 256-aligned) ----
    char* w8 = (char*)d_ws;
    size_t off = 0;
    auto alloc = [&](size_t bytes) {
        void* p = w8 + off;
        off = (off + bytes + 255) & ~(size_t)255;
        return p;
    };
    short* emb_bf = (short*)alloc((size_t)BB * L * D * 2);
    float* pe     = (float*)alloc((size_t)L * D * 4);
    short* xim    = (short*)alloc((size_t)BB * L * 32 * 2);
    short* wE     = (short*)alloc((size_t)D * 32 * 2);
    short* xd_bf  = (short*)alloc((size_t)BB * L * DBOT * 2);
    short* cs1_bf = (short*)alloc((size_t)MCONV2P * 512 * 2);
    short* cs2_bf = (short*)alloc((size_t)MCONV2P * DBOT * 2);
    short* cs3_bf = (short*)alloc((size_t)BB * L3 * DBOT * 2);
    short* csc_bf = (short*)alloc((size_t)MCAT * DBOT * 2);
    float* coarse = (float*)alloc((size_t)MCAT * D * 4);
    float* seq    = (float*)alloc((size_t)BB * S * D * 4);
    short* T1     = (short*)alloc((size_t)MP * D * 2);
    float* part   = (float*)alloc((size_t)8 * BB * PRED_N * 4);
    float* partsk = (float*)alloc(psk_elems() * 4);   // split-K partials (exact)
    short* seq_bf = (short*)alloc((size_t)MP * D * 2);
    short* QKV    = (short*)alloc((size_t)MP * 3 * D * 2);  // + Ob contiguous
    short* Ob     = (short*)alloc((size_t)MP * D * 2);
    short* hidden = QKV;
    short* wqkvT  = (short*)alloc((size_t)NLAYER * 3 * D * D * 2);
    short* woT    = (short*)alloc((size_t)NLAYER * D * D * 2);
    short* w1T    = (short*)alloc((size_t)NLAYER * DFF * D * 2);
    short* w2T    = (short*)alloc((size_t)NLAYER * D * DFF * 2);
    short* downT  = (short*)alloc((size_t)DBOT * D * 2);
    short* upT    = (short*)alloc((size_t)D * DBOT * 2);
    short* cscmT  = (short*)alloc((size_t)2 * DBOT * 512 * 2);
    float* csc_sc = (float*)alloc((size_t)3 * DBOT * 4);
    float* csc_sh = (float*)alloc((size_t)3 * DBOT * 4);
    (void)ws_size; (void)in_sizes; (void)n_in; (void)out_size;

    const int rowsL = BB * L;   // 10752 = 84*128
    dim3 blk(256);

    // 0. fused prep
    wtrans_qkvo<<<dim3(16, 16, 4 * NLAYER), blk, 0, stream>>>(wq, wk, wv, wo, wqkvT, woT);
    wtrans_ffn<<<dim3(64, 16, 2 * NLAYER), blk, 0, stream>>>(ffn_w1, ffn_w2, w1T, w2T);
    wtrans_small<<<dim3(128 + 512), blk, 0, stream>>>(
        down_w, downT, up_w, upT, cscm_w, cscm_b, bn_g, bn_b, cscmT, csc_sc, csc_sh);
    prep_misc<<<dim3((MISC_N + 255) / 256), blk, 0, stream>>>(
        x_enc, x_mark_enc, conv_embed_w, time_w, time_b, pe, wE, xim);
    // 1. embedding as GEMM (M=10752, N=512, K=32) + pe epilogue, bf16 out
    mfma_gemm<6><<<dim3(D / 128, rowsL / 128), blk, 0, stream>>>(
        xim, wE, nullptr, nullptr, nullptr, 32, D, -1, -1, 0, pe, emb_bf);
    // 2. down projection -> bf16 (split-K: 84 blocks x 16 serial steps was a
    //    latency straggler; KS=4 -> 336 blocks x 4 steps + reduce)
    mfma_gemm_sk<<<dim3(1, rowsL / 128, 4), blk, 0, stream>>>(
        emb_bf, downT, partsk, D, DBOT, -1, 0);
    reduce_sk<4><<<dim3((rowsL * DBOT + 255) / 256), blk, 0, stream>>>(
        partsk, down_b, nullptr, xd_bf, rowsL, DBOT, 4);
    // 3. CSCM pyramid (conv1/conv2 split-K, same rationale)
    mfma_gemm_sk<<<dim3(1, MCONV1 / 128, 4), blk, 0, stream>>>(
        xd_bf, cscmT, partsk, 512, DBOT, -1, 0);
    reduce_sk<5><<<dim3((MCONV1 * DBOT + 255) / 256), blk, 0, stream>>>(
        partsk, csc_sc, csc_sh, cs1_bf, MCONV1, DBOT, 4);
    mfma_gemm_sk<<<dim3(1, MCONV2P / 128, 4), blk, 0, stream>>>(
        cs1_bf, cscmT + (size_t)DBOT * 512, partsk, 512, DBOT, -1, 0);
    reduce_sk<5><<<dim3((MCONV2P * DBOT + 255) / 256), blk, 0, stream>>>(
        partsk, csc_sc + DBOT, csc_sh + DBOT, cs2_bf, MCONV2P, DBOT, 4);
    cscm_conv_bf16<<<dim3(BB * L3), dim3(DBOT), 0, stream>>>(
        cs2_bf, L2, cs3_bf, cscm_w + 2 * DBOT * DBOT * 4,
        cscm_b + 2 * DBOT, bn_g + 2 * DBOT, bn_b + 2 * DBOT, L3);
    // 4. up projection
    concat_cs_kernel<<<dim3((MCAT * DBOT + 255) / 256), blk, 0, stream>>>(
        cs1_bf, cs2_bf, cs3_bf, csc_bf);
    mfma_gemm<1><<<dim3(D / 128, MCAT / 128), blk, 0, stream>>>(
        csc_bf, upT, up_b, nullptr, coarse, DBOT, D, -1, -1, 0, nullptr, nullptr);
    // 5. concat + LN (A_0 rows only; fine rows from bf16 shadow)
    concat_ln_idx<<<dim3(HS.cnt[0] * 32), blk, 0, stream>>>(
        emb_bf, coarse, cln_g, cln_b, seq, seq_bf);

    // 6. encoder layers (sparse active sets; split-K + fused reduce/LN)
    for (int l = 0; l < NLAYER; ++l) {
        const int inLvl = l, outLvl = l + 1;
        const int inCnt  = HS.cnt[l];
        const int outCnt = HS.cnt[l + 1];
        const int Mc   = outCnt * 32;
        const int Mpad = ((Mc + 127) / 128) * 128;
        mfma_gemm<2><<<dim3(3 * D / 128, (inCnt * 32 + 127) / 128), blk, 0, stream>>>(
            seq_bf, wqkvT + (size_t)l * 3 * D * D, nullptr, nullptr, QKV, D, 3 * D,
            inLvl, inLvl, inCnt, nullptr, nullptr);
        attn_sparse_kernel<<<dim3(outCnt * 8), blk, 0, stream>>>(
            QKV, Ob, outLvl, outCnt);
        // O-projection + LN1 (split-K fused into LN when M small)
        if (Mc <= 512) {
            mfma_gemm_sk<<<dim3(D / 128, Mpad / 128, 4), blk, 0, stream>>>(
                Ob, woT + (size_t)l * D * D, partsk, D, D, -1, 0);
            add_ln_sk<<<dim3(Mc), blk, 0, stream>>>(
                seq, partsk, nullptr, ln1_g + (size_t)l * D, ln1_b + (size_t)l * D,
                seq_bf, outLvl, Mpad, 4);
        } else {
            mfma_gemm<2><<<dim3(D / 128, Mpad / 128), blk, 0, stream>>>(
                Ob, woT + (size_t)l * D * D, nullptr, nullptr, T1, D, D,
                -1, -1, 0, nullptr, nullptr);
            add_ln_idx<<<dim3(Mc), blk, 0, stream>>>(
                seq, T1, ln1_g + (size_t)l * D, ln1_b + (size_t)l * D, seq_bf, outLvl);
        }
        // FFN1: split-K only for tiny M (K=512, KS=4)
        if (Mc <= 128) {
            mfma_gemm_sk<<<dim3(DFF / 128, Mpad / 128, 4), blk, 0, stream>>>(
                seq_bf, w1T + (size_t)l * DFF * D, partsk, D, DFF, outLvl, outCnt);
            reduce_sk<3><<<dim3((Mpad * DFF + 255) / 256), blk, 0, stream>>>(
                partsk, ffn_b1 + (size_t)l * DFF, nullptr, hidden, Mpad, DFF, 4);
        } else {
            mfma_gemm<3><<<dim3(DFF / 128, Mpad / 128), blk, 0, stream>>>(
                seq_bf, w1T + (size_t)l * DFF * D, ffn_b1 + (size_t)l * DFF, nullptr,
                hidden, D, DFF, outLvl, -1, outCnt, nullptr, nullptr);
        }
        // FFN2 + LN2: split-K, reduce fused into LN
        {
            int KS = (Mc <= 512) ? 8 : 4;
            mfma_gemm_sk<<<dim3(D / 128, Mpad / 128, KS), blk, 0, stream>>>(
                hidden, w2T + (size_t)l * D * DFF, partsk, DFF, D, -1, 0);
            add_ln_sk<<<dim3(Mc), blk, 0, stream>>>(
                seq, partsk, ffn_b2 + (size_t)l * D, ln2_g + (size_t)l * D,
                ln2_b + (size_t)l * D, seq_bf, outLvl, Mpad, KS);
        }
    }

    // 7. prediction head (split-K, gather fused) + reduce
    pred_kernel<<<dim3(PRED_N / 8, 8), blk, 0, stream>>>(seq, pred_w, part);
    pred_reduce_kernel<<<dim3((BB * PRED_N + 255) / 256), blk, 0, stream>>>(part, out);
}

// Round 21
// 336.804 us; speedup vs baseline: 2.6907x; 1.0304x over previous
//
#include <hip/hip_runtime.h>
#include <math.h>

// ---- problem constants ----
constexpr int BB   = 32;    // batch
constexpr int L    = 336;   // seq_len
constexpr int CIN  = 7;
constexpr int MARK = 4;
constexpr int D    = 512;   // d_model
constexpr int DFF  = 2048;
constexpr int NH   = 8;
constexpr int HD   = 64;    // dk = dv
constexpr int S    = 446;   // 336+84+21+5
constexpr int DBOT = 128;
constexpr int L1 = 84, L2 = 21, L3 = 5;
constexpr int LC = 110;     // 84+21+5
constexpr int NLAYER = 3;
constexpr int PRED_N = 672; // 96*7
constexpr int MP   = 14336; // BB*S padded
constexpr int NMAX = 12;    // max sparse neighbors (real max 10)
constexpr int MCONV1 = BB * L1;          // 2688 = 21*128 (exact)
constexpr int MCONV2P = 768;             // BB*L2=672 padded to 6*128
constexpr int MCAT  = 3584;              // BB*LC=3520 padded to 28*128

using short8  = __attribute__((ext_vector_type(8))) short;
using float4v = __attribute__((ext_vector_type(4))) float;

// ---------------------------------------------------------------------------
// COMPILE-TIME pyramid structure: neighbor lists + active sets.
// ---------------------------------------------------------------------------
struct SetsData {
    int nbr[S][NMAX];
    int idx[4][S];
    int cnt[4];
};

constexpr SetsData compute_sets() {
    SetsData sd{};
    constexpr int sizes[4]  = {336, 84, 21, 5};
    constexpr int starts[4] = {0, 336, 420, 441};
    for (int i = 0; i < S; ++i) {
        int li = 0, pi = i;
        if (i < 336)      { li = 0; pi = i; }
        else if (i < 420) { li = 1; pi = i - 336; }
        else if (i < 441) { li = 2; pi = i - 420; }
        else              { li = 3; pi = i - 441; }
        int cnt = 0;
        for (int d = -2; d <= 2; ++d) {
            int q = pi + d;
            if (q >= 0 && q < sizes[li]) sd.nbr[i][cnt++] = starts[li] + q;
        }
        if (li > 0) {
            int lo = pi * 4;
            int hi = (pi == sizes[li] - 1) ? sizes[li - 1] : (pi + 1) * 4;
            for (int c = lo; c < hi; ++c) sd.nbr[i][cnt++] = starts[li - 1] + c;
        }
        if (li < 3) {
            int q = pi >> 2;
            if (q > sizes[li + 1] - 1) q = sizes[li + 1] - 1;
            sd.nbr[i][cnt++] = starts[li + 1] + q;
        }
        for (int j = cnt; j < NMAX; ++j) sd.nbr[i][j] = -1;
    }
    sd.cnt[3] = 4;
    sd.idx[3][0] = 335; sd.idx[3][1] = 419; sd.idx[3][2] = 440; sd.idx[3][3] = 445;
    for (int lvl = 3; lvl >= 1; --lvl) {
        bool mk[S] = {};
        for (int k = 0; k < sd.cnt[lvl]; ++k) {
            int i = sd.idx[lvl][k];
            for (int t = 0; t < NMAX; ++t) {
                int v = sd.nbr[i][t];
                if (v >= 0) mk[v] = true;
            }
        }
        int nc = 0;
        for (int i = 0; i < S; ++i)
            if (mk[i]) sd.idx[lvl - 1][nc++] = i;
        sd.cnt[lvl - 1] = nc;
    }
    return sd;
}

constexpr SetsData HS = compute_sets();         // host: grid sizing
__constant__ SetsData d_sets = compute_sets();  // device: row maps + nbr

// exact split-K partial buffer size (elements), from compile-time counts
constexpr size_t psk_elems() {
    size_t mx = 4 * (size_t)BB * L * DBOT;      // down-proj split-K (5.5M)
    {
        size_t v = 4 * (size_t)MCONV1 * DBOT; if (v > mx) mx = v;   // conv1
        v = 4 * (size_t)MCONV2P * DBOT;       if (v > mx) mx = v;   // conv2
    }
    for (int l = 0; l < NLAYER; ++l) {
        size_t Mc = (size_t)HS.cnt[l + 1] * 32;
        size_t Mpad = ((Mc + 127) / 128) * 128;
        if (Mc <= 512) { size_t v = 4 * Mpad * 512;  if (v > mx) mx = v; }   // wo
        if (Mc <= 128) { size_t v = 4 * Mpad * 2048; if (v > mx) mx = v; }   // ffn1
        size_t ks = (Mc <= 512) ? 8 : 4;
        size_t v = ks * Mpad * 512; if (v > mx) mx = v;                      // ffn2
    }
    return mx;
}

__device__ inline short f2bf(float f) {
    union { float f; unsigned u; } v; v.f = f;
    unsigned r = v.u + 0x7fffu + ((v.u >> 16) & 1u);
    return (short)(r >> 16);
}
__device__ inline float bf2f(short h) {
    union { unsigned u; float f; } v; v.u = ((unsigned)(unsigned short)h) << 16;
    return v.f;
}

// async global->LDS, 16B per lane, wave-uniform LDS base + lane*16
__device__ inline void gload_lds16(const void* g, void* l) {
    __builtin_amdgcn_global_load_lds(
        (const __attribute__((address_space(1))) void*)g,
        (__attribute__((address_space(3))) void*)l, 16, 0, 0);
}

// Staging map: conflict-free + coalesced (verified r11: 0 bank conflicts).
// Sparse rows: alvl/clvl >= 0 select d_sets.idx[lvl] (pos-major compact:
// compact m -> b=m&31, j=m>>5 clamped to cnt-1, orig row b*S+idx[j]).

// ---------------------------------------------------------------------------
// 128x128 bf16 MFMA GEMM, BK=32, double-buffered, counted vmcnt(4) pipeline.
// EPI: 0 f32; 1 f32+bias; 2 bf16; 3 bf16+bias+gelu; 4 bf16+bias;
//      5 bf16, v = acc*bias[gn]+bias2[gn] then ELU;
//      6 v = acc + peT[(row%L)*D+gn] -> bf16 Cout2 only (embed)
// ---------------------------------------------------------------------------
template<int EPI>
__launch_bounds__(256, 4)
__global__ void mfma_gemm(const short* __restrict__ A, const short* __restrict__ Bt,
                          const float* __restrict__ bias, const float* __restrict__ bias2,
                          void* __restrict__ Cout, int Kd, int Nd,
                          int alvl, int clvl, int cnt,
                          const float* __restrict__ peT, short* __restrict__ Cout2) {
    __shared__ short As[2][128 * 32];
    __shared__ short Bs[2][128 * 32];
    int tid = threadIdx.x;
    int nwg  = gridDim.x * gridDim.y;
    int orig = blockIdx.y * gridDim.x + blockIdx.x;
    int qq = nwg >> 3, rr = nwg & 7;
    int xcd = orig & 7, idx = orig >> 3;
    int wgid = (xcd < rr ? xcd * (qq + 1) : rr * (qq + 1) + (xcd - rr) * qq) + idx;
    int m0 = (wgid / gridDim.x) * 128, n0 = (wgid % gridDim.x) * 128;

    int lane = tid & 63, wid = tid >> 6;
    int wm = wid >> 1, wn = wid & 1;
    int lr = lane & 15, lk = lane >> 4;

    size_t abase[2], bbase[2];
#pragma unroll
    for (int r = 0; r < 2; ++r) {
        int u = r * 256 + tid;
        int row = ((u >> 3) << 1) | ((u >> 2) & 1);
        int kg  = (u & 3) ^ ((u >> 3) & 3);
        int rm = m0 + row, ga;
        if (alvl >= 0) { int j = rm >> 5; if (j > cnt - 1) j = cnt - 1; ga = (rm & 31) * S + d_sets.idx[alvl][j]; }
        else ga = rm;
        abase[r] = (size_t)ga * Kd + kg * 8;
        bbase[r] = (size_t)(n0 + row) * Kd + kg * 8;
    }
    auto stage = [&](int buf, int k0) {
#pragma unroll
        for (int r = 0; r < 2; ++r) {
            short* la = As[buf] + (size_t)(r * 256 + wid * 64) * 8;
            short* lb = Bs[buf] + (size_t)(r * 256 + wid * 64) * 8;
            gload_lds16(A + abase[r] + k0, la);
            gload_lds16(Bt + bbase[r] + k0, lb);
        }
    };
    auto rd_off = [&](int row_) {
        int rh = row_ >> 1;
        int s  = lk ^ (rh & 3);
        return (size_t)(rh * 8 + (row_ & 1) * 4 + s) * 8;
    };

    float4v acc[4][4];
#pragma unroll
    for (int i = 0; i < 4; ++i)
#pragma unroll
        for (int j = 0; j < 4; ++j) acc[i][j] = 0;

    const int nt = Kd >> 5;
    stage(0, 0);
    for (int t = 0; t < nt; ++t) {
        int cur = t & 1;
        if (t + 1 < nt) {
            stage(cur ^ 1, (t + 1) * 32);
            asm volatile("s_waitcnt vmcnt(4)" ::: "memory");
        } else {
            asm volatile("s_waitcnt vmcnt(0)" ::: "memory");
        }
        __builtin_amdgcn_s_barrier();
        short8 af[4], bfv[4];
#pragma unroll
        for (int mi = 0; mi < 4; ++mi)
            af[mi] = *(const short8*)(As[cur] + rd_off(wm * 64 + mi * 16 + lr));
#pragma unroll
        for (int ni = 0; ni < 4; ++ni)
            bfv[ni] = *(const short8*)(Bs[cur] + rd_off(wn * 64 + ni * 16 + lr));
        __builtin_amdgcn_s_setprio(1);
#pragma unroll
        for (int mi = 0; mi < 4; ++mi)
#pragma unroll
            for (int ni = 0; ni < 4; ++ni)
                acc[mi][ni] = __builtin_amdgcn_mfma_f32_16x16x32_bf16(
                    af[mi], bfv[ni], acc[mi][ni], 0, 0, 0);
        __builtin_amdgcn_s_setprio(0);
        __builtin_amdgcn_s_barrier();
    }

#pragma unroll
    for (int mi = 0; mi < 4; ++mi) {
        int gmc = m0 + wm * 64 + mi * 16 + lk * 4;
#pragma unroll
        for (int ni = 0; ni < 4; ++ni) {
            int gn = n0 + wn * 64 + ni * 16 + lr;
            float bsv = (EPI == 1 || EPI == 3 || EPI == 4) ? bias[gn] : 0.0f;
            float sc = (EPI == 5) ? bias[gn]  : 0.0f;
            float sh = (EPI == 5) ? bias2[gn] : 0.0f;
#pragma unroll
            for (int e = 0; e < 4; ++e) {
                int rm = gmc + e, grow;
                if (clvl >= 0) { int j = rm >> 5; if (j > cnt - 1) j = cnt - 1; grow = (rm & 31) * S + d_sets.idx[clvl][j]; }
                else grow = rm;
                float v = acc[mi][ni][e] + bsv;
                if (EPI == 3) v = 0.5f * v * (1.0f + erff(v * 0.70710678118654752f));
                if (EPI == 5) { v = v * sc + sh; v = v > 0.0f ? v : (expf(v) - 1.0f); }
                if (EPI == 6) {
                    v += peT[(size_t)(grow % L) * D + gn];
                    Cout2[(size_t)grow * Nd + gn] = f2bf(v);
                } else if (EPI <= 1) {
                    ((float*)Cout)[(size_t)grow * Nd + gn] = v;
                } else {
                    ((short*)Cout)[(size_t)grow * Nd + gn] = f2bf(v);
                }
            }
        }
    }
}

// ---------------------------------------------------------------------------
// up-projection GEMM with INLINE concat gather (r21): A row m -> one of
// cs1/cs2/cs3 at computed offset (rows are contiguous 128 bf16, so
// global_load_lds stays legal). K=128 fixed. f32 out + bias to coarse.
// ---------------------------------------------------------------------------
__launch_bounds__(256, 4)
__global__ void mfma_gemm_up(const short* __restrict__ cs1, const short* __restrict__ cs2,
                             const short* __restrict__ cs3, const short* __restrict__ Bt,
                             const float* __restrict__ bias, float* __restrict__ Cout) {
    __shared__ short As[2][128 * 32];
    __shared__ short Bs[2][128 * 32];
    int tid = threadIdx.x;
    int nwg  = gridDim.x * gridDim.y;
    int orig = blockIdx.y * gridDim.x + blockIdx.x;
    int qq = nwg >> 3, rr = nwg & 7;
    int xcd = orig & 7, idx = orig >> 3;
    int wgid = (xcd < rr ? xcd * (qq + 1) : rr * (qq + 1) + (xcd - rr) * qq) + idx;
    int m0 = (wgid / gridDim.x) * 128, n0 = (wgid % gridDim.x) * 128;
    const int Kd = DBOT, Nd = D;

    int lane = tid & 63, wid = tid >> 6;
    int wm = wid >> 1, wn = wid & 1;
    int lr = lane & 15, lk = lane >> 4;

    const short* aad[2];
    size_t bbase[2];
#pragma unroll
    for (int r = 0; r < 2; ++r) {
        int u = r * 256 + tid;
        int row = ((u >> 3) << 1) | ((u >> 2) & 1);
        int kg  = (u & 3) ^ ((u >> 3) & 3);
        int rm = m0 + row;
        const short* base;
        if (rm < BB * LC) {
            int b = rm / LC, t = rm % LC;
            if (t < L1)           base = cs1 + (size_t)(b * L1 + t) * DBOT;
            else if (t < L1 + L2) base = cs2 + (size_t)(b * L2 + (t - L1)) * DBOT;
            else                  base = cs3 + (size_t)(b * L3 + (t - L1 - L2)) * DBOT;
        } else {
            base = cs1;   // pad row: garbage computed, never read
        }
        aad[r] = base + kg * 8;
        bbase[r] = (size_t)(n0 + row) * Kd + kg * 8;
    }
    auto stage = [&](int buf, int k0) {
#pragma unroll
        for (int r = 0; r < 2; ++r) {
            short* la = As[buf] + (size_t)(r * 256 + wid * 64) * 8;
            short* lb = Bs[buf] + (size_t)(r * 256 + wid * 64) * 8;
            gload_lds16(aad[r] + k0, la);
            gload_lds16(Bt + bbase[r] + k0, lb);
        }
    };
    auto rd_off = [&](int row_) {
        int rh = row_ >> 1;
        int s  = lk ^ (rh & 3);
        return (size_t)(rh * 8 + (row_ & 1) * 4 + s) * 8;
    };

    float4v acc[4][4];
#pragma unroll
    for (int i = 0; i < 4; ++i)
#pragma unroll
        for (int j = 0; j < 4; ++j) acc[i][j] = 0;

    const int nt = Kd >> 5;   // 4
    stage(0, 0);
    for (int t = 0; t < nt; ++t) {
        int cur = t & 1;
        if (t + 1 < nt) {
            stage(cur ^ 1, (t + 1) * 32);
            asm volatile("s_waitcnt vmcnt(4)" ::: "memory");
        } else {
            asm volatile("s_waitcnt vmcnt(0)" ::: "memory");
        }
        __builtin_amdgcn_s_barrier();
        short8 af[4], bfv[4];
#pragma unroll
        for (int mi = 0; mi < 4; ++mi)
            af[mi] = *(const short8*)(As[cur] + rd_off(wm * 64 + mi * 16 + lr));
#pragma unroll
        for (int ni = 0; ni < 4; ++ni)
            bfv[ni] = *(const short8*)(Bs[cur] + rd_off(wn * 64 + ni * 16 + lr));
        __builtin_amdgcn_s_setprio(1);
#pragma unroll
        for (int mi = 0; mi < 4; ++mi)
#pragma unroll
            for (int ni = 0; ni < 4; ++ni)
                acc[mi][ni] = __builtin_amdgcn_mfma_f32_16x16x32_bf16(
                    af[mi], bfv[ni], acc[mi][ni], 0, 0, 0);
        __builtin_amdgcn_s_setprio(0);
        __builtin_amdgcn_s_barrier();
    }

#pragma unroll
    for (int mi = 0; mi < 4; ++mi) {
        int gmc = m0 + wm * 64 + mi * 16 + lk * 4;
#pragma unroll
        for (int ni = 0; ni < 4; ++ni) {
            int gn = n0 + wn * 64 + ni * 16 + lr;
            float bsv = bias[gn];
#pragma unroll
            for (int e = 0; e < 4; ++e)
                Cout[(size_t)(gmc + e) * Nd + gn] = acc[mi][ni][e] + bsv;
        }
    }
}

// ---------------------------------------------------------------------------
// SPLIT-K variant: gridDim.z = KS slices; writes f32 partial part[kz][Mpad][Nd].
// ---------------------------------------------------------------------------
__launch_bounds__(256, 4)
__global__ void mfma_gemm_sk(const short* __restrict__ A, const short* __restrict__ Bt,
                             float* __restrict__ part, int Kd, int Nd,
                             int alvl, int cnt) {
    __shared__ short As[2][128 * 32];
    __shared__ short Bs[2][128 * 32];
    int tid = threadIdx.x;
    int nwg  = gridDim.x * gridDim.y;
    int orig = blockIdx.y * gridDim.x + blockIdx.x;
    int qq = nwg >> 3, rr = nwg & 7;
    int xcd = orig & 7, idx = orig >> 3;
    int wgid = (xcd < rr ? xcd * (qq + 1) : rr * (qq + 1) + (xcd - rr) * qq) + idx;
    int m0 = (wgid / gridDim.x) * 128, n0 = (wgid % gridDim.x) * 128;
    int Mpad = gridDim.y * 128;
    int kz = blockIdx.z;
    int kb = Kd / gridDim.z;          // slice length (multiple of 32)
    int kbase = kz * kb;

    int lane = tid & 63, wid = tid >> 6;
    int wm = wid >> 1, wn = wid & 1;
    int lr = lane & 15, lk = lane >> 4;

    size_t abase[2], bbase[2];
#pragma unroll
    for (int r = 0; r < 2; ++r) {
        int u = r * 256 + tid;
        int row = ((u >> 3) << 1) | ((u >> 2) & 1);
        int kg  = (u & 3) ^ ((u >> 3) & 3);
        int rm = m0 + row, ga;
        if (alvl >= 0) { int j = rm >> 5; if (j > cnt - 1) j = cnt - 1; ga = (rm & 31) * S + d_sets.idx[alvl][j]; }
        else ga = rm;
        abase[r] = (size_t)ga * Kd + kbase + kg * 8;
        bbase[r] = (size_t)(n0 + row) * Kd + kbase + kg * 8;
    }
    auto stage = [&](int buf, int k0) {
#pragma unroll
        for (int r = 0; r < 2; ++r) {
            short* la = As[buf] + (size_t)(r * 256 + wid * 64) * 8;
            short* lb = Bs[buf] + (size_t)(r * 256 + wid * 64) * 8;
            gload_lds16(A + abase[r] + k0, la);
            gload_lds16(Bt + bbase[r] + k0, lb);
        }
    };
    auto rd_off = [&](int row_) {
        int rh = row_ >> 1;
        int s  = lk ^ (rh & 3);
        return (size_t)(rh * 8 + (row_ & 1) * 4 + s) * 8;
    };

    float4v acc[4][4];
#pragma unroll
    for (int i = 0; i < 4; ++i)
#pragma unroll
        for (int j = 0; j < 4; ++j) acc[i][j] = 0;

    const int nt = kb >> 5;
    stage(0, 0);
    for (int t = 0; t < nt; ++t) {
        int cur = t & 1;
        if (t + 1 < nt) {
            stage(cur ^ 1, (t + 1) * 32);
            asm volatile("s_waitcnt vmcnt(4)" ::: "memory");
        } else {
            asm volatile("s_waitcnt vmcnt(0)" ::: "memory");
        }
        __builtin_amdgcn_s_barrier();
        short8 af[4], bfv[4];
#pragma unroll
        for (int mi = 0; mi < 4; ++mi)
            af[mi] = *(const short8*)(As[cur] + rd_off(wm * 64 + mi * 16 + lr));
#pragma unroll
        for (int ni = 0; ni < 4; ++ni)
            bfv[ni] = *(const short8*)(Bs[cur] + rd_off(wn * 64 + ni * 16 + lr));
        __builtin_amdgcn_s_setprio(1);
#pragma unroll
        for (int mi = 0; mi < 4; ++mi)
#pragma unroll
            for (int ni = 0; ni < 4; ++ni)
                acc[mi][ni] = __builtin_amdgcn_mfma_f32_16x16x32_bf16(
                    af[mi], bfv[ni], acc[mi][ni], 0, 0, 0);
        __builtin_amdgcn_s_setprio(0);
        __builtin_amdgcn_s_barrier();
    }

#pragma unroll
    for (int mi = 0; mi < 4; ++mi) {
        int gmc = m0 + wm * 64 + mi * 16 + lk * 4;
#pragma unroll
        for (int ni = 0; ni < 4; ++ni) {
            int gn = n0 + wn * 64 + ni * 16 + lr;
#pragma unroll
            for (int e = 0; e < 4; ++e)
                part[((size_t)kz * Mpad + gmc + e) * Nd + gn] = acc[mi][ni][e];
        }
    }
}

// sum KS partials + epilogue -> bf16 compact output
// EPI: 3 +bias+gelu; 4 +bias; 5 *bias+bias2 then ELU (conv BN fold)
template<int EPI>
__launch_bounds__(256)
__global__ void reduce_sk(const float* __restrict__ part, const float* __restrict__ bias,
                          const float* __restrict__ bias2, short* __restrict__ Cout,
                          int Mpad, int Nd, int KS) {
    int idx = blockIdx.x * 256 + threadIdx.x;
    if (idx >= Mpad * Nd) return;
    float s = 0.0f;
    for (int k = 0; k < KS; ++k)
        s += part[(size_t)k * Mpad * Nd + idx];
    int n = idx % Nd;
    if (EPI == 3 || EPI == 4) s += bias[n];
    if (EPI == 3) s = 0.5f * s * (1.0f + erff(s * 0.70710678118654752f));
    if (EPI == 5) { s = s * bias[n] + bias2[n]; s = s > 0.0f ? s : (expf(s) - 1.0f); }
    Cout[idx] = f2bf(s);
}

// ---------------------------------------------------------------------------
// weight transpose tile helper
// ---------------------------------------------------------------------------
__device__ inline void wtrans_tile(const float* __restrict__ W, short* __restrict__ Wt,
                                   int Kd, int Nd, int n0, int k0, int tid) {
    __shared__ float tile[32][33];
    int tx = tid & 31, ty = tid >> 5; // ty 0..7
#pragma unroll
    for (int r = 0; r < 32; r += 8)
        tile[ty + r][tx] = W[(size_t)(k0 + ty + r) * Nd + n0 + tx];
    __syncthreads();
#pragma unroll
    for (int r = 0; r < 32; r += 8)
        Wt[(size_t)(n0 + ty + r) * Kd + k0 + tx] = f2bf(tile[tx][ty + r]);
}

// ---------------------------------------------------------------------------
// ONE fused prep kernel (r21): all weight transposes + small prep + pe/wE/xim.
// Block-range partitioned; all portions independent -> run concurrently.
//   [0, 3072)        qkvo transposes (16x16x12)
//   [3072, 9216)     ffn transposes (64x16x6)
//   [9216, 9856)     down/up/cscm small prep (640)
//   [9856, 11936)    pe | wE | xim elementwise (2080)
// ---------------------------------------------------------------------------
constexpr int PE_N  = L * D;           // 172032
constexpr int WE_N  = D * 32;          // 16384
constexpr int XIM_N = BB * L * 32;     // 344064
constexpr int MISC_N = PE_N + WE_N + XIM_N;
constexpr int PREP_BLKS = 3072 + 6144 + 640 + (MISC_N + 255) / 256;

__launch_bounds__(256)
__global__ void prep_all(const float* __restrict__ wq, const float* __restrict__ wk,
                         const float* __restrict__ wv, const float* __restrict__ wo,
                         short* __restrict__ wqkvT, short* __restrict__ woT,
                         const float* __restrict__ w1, const float* __restrict__ w2,
                         short* __restrict__ w1T, short* __restrict__ w2T,
                         const float* __restrict__ down_w, short* __restrict__ downT,
                         const float* __restrict__ up_w, short* __restrict__ upT,
                         const float* __restrict__ cw, const float* __restrict__ cb,
                         const float* __restrict__ bg, const float* __restrict__ bb,
                         short* __restrict__ cscmT, float* __restrict__ sc,
                         float* __restrict__ sh,
                         const float* __restrict__ x_enc, const float* __restrict__ x_mark,
                         const float* __restrict__ cew, const float* __restrict__ tw,
                         const float* __restrict__ tb, float* __restrict__ pe,
                         short* __restrict__ wE, short* __restrict__ xim) {
    int blk = blockIdx.x;
    int tid = threadIdx.x;
    if (blk < 3072) {
        int z = blk >> 8, rem = blk & 255;
        int l = z >> 2, part = z & 3;
        const float* src = (part == 0 ? wq : part == 1 ? wk : part == 2 ? wv : wo)
                           + (size_t)l * D * D;
        short* dst = (part < 3) ? wqkvT + (size_t)l * 3 * D * D + (size_t)part * D * D
                                : woT + (size_t)l * D * D;
        wtrans_tile(src, dst, D, D, (rem & 15) * 32, (rem >> 4) * 32, tid);
        return;
    }
    blk -= 3072;
    if (blk < 6144) {
        int z = blk >> 10, rem = blk & 1023;
        int l = z >> 1, part = z & 1;
        int bx = rem & 63, by = rem >> 6;
        int nt = part ? by : bx;
        int kt = part ? bx : by;
        if (part == 0)
            wtrans_tile(w1 + (size_t)l * D * DFF, w1T + (size_t)l * DFF * D,
                        D, DFF, nt * 32, kt * 32, tid);
        else
            wtrans_tile(w2 + (size_t)l * DFF * D, w2T + (size_t)l * D * DFF,
                        DFF, D, nt * 32, kt * 32, tid);
        return;
    }
    blk -= 6144;
    if (blk < 640) {
        if (blk < 64) {
            wtrans_tile(down_w, downT, D, DBOT, (blk & 3) * 32, (blk >> 2) * 32, tid);
        } else if (blk < 128) {
            int b2 = blk - 64;
            wtrans_tile(up_w, upT, DBOT, D, (b2 & 15) * 32, (b2 >> 4) * 32, tid);
        } else {
            int idx = (blk - 128) * 256 + tid;
            if (idx < 2 * DBOT * 512) {
                int l = idx >> 16;
                int rem = idx & 65535;
                int oc = rem >> 9, j = rem & 511;
                int r = j >> 7, c = j & 127;
                cscmT[idx] = f2bf(cw[(((size_t)l * DBOT + oc) * DBOT + c) * 4 + r]);
            }
            if (idx < 3 * DBOT) {
                sc[idx] = bg[idx];
                sh[idx] = cb[idx] * bg[idx] + bb[idx];
            }
        }
        return;
    }
    blk -= 640;
    {
        int idx = blk * 256 + tid;
        if (idx < PE_N) {
            int d = idx % D, t = idx / D;
            int e = d & ~1;
            float div = expf(-(float)e * (logf(10000.0f) / (float)D));
            float arg = (float)t * div;
            pe[idx] = (d & 1) ? cosf(arg) : sinf(arg);
            return;
        }
        int i2 = idx - PE_N;
        if (i2 < WE_N) {
            int k = i2 & 31, d = i2 >> 5;
            float v = 0.0f;
            if (k < 21) {
                int w = k / 7, i = k % 7;
                v = cew[(size_t)d * (CIN * 3) + i * 3 + w];
            } else if (k < 25) {
                v = tw[(size_t)(k - 21) * D + d];
            } else if (k == 25) {
                v = tb[d];
            }
            wE[i2] = f2bf(v);
            return;
        }
        int i3 = i2 - WE_N;
        if (i3 < XIM_N) {
            int k = i3 & 31, m = i3 >> 5;
            int t = m % L, b = m / L;
            float v = 0.0f;
            if (k < 21) {
                int w = k / 7, i = k % 7;
                int s = t + w - 1;
                if (s < 0) s = L - 1;
                if (s >= L) s = 0;
                v = x_enc[((size_t)b * L + s) * CIN + i];
            } else if (k < 25) {
                v = x_mark[(size_t)m * MARK + (k - 21)];
            } else if (k == 25) {
                v = 1.0f;
            }
            xim[i3] = f2bf(v);
        }
    }
}

// ---------------------------------------------------------------------------
// CSCM conv level 3 (tiny)
// ---------------------------------------------------------------------------
__launch_bounds__(128)
__global__ void cscm_conv_bf16(const short* __restrict__ in, int inRowsPerB,
                               short* __restrict__ outp, const float* __restrict__ w,
                               const float* __restrict__ cb, const float* __restrict__ bng,
                               const float* __restrict__ bnb, int Lout) {
    int bid = blockIdx.x;
    int to = bid % Lout, b = bid / Lout;
    __shared__ float insh[4 * DBOT];
    int tid = threadIdx.x;
#pragma unroll
    for (int r = 0; r < 4; ++r)
        insh[r * DBOT + tid] = bf2f(in[((size_t)(b * inRowsPerB + to * 4 + r)) * DBOT + tid]);
    __syncthreads();
    float acc = cb[tid];
    const float* wr = w + (size_t)tid * (DBOT * 4);
    for (int c = 0; c < DBOT; ++c) {
#pragma unroll
        for (int r = 0; r < 4; ++r)
            acc += insh[r * DBOT + c] * wr[c * 4 + r];
    }
    acc = acc * bng[tid] + bnb[tid];
    outp[((size_t)(b * Lout + to)) * DBOT + tid] = f2bf(acc > 0.0f ? acc : (expf(acc) - 1.0f));
}

// ---------------------------------------------------------------------------
// sparse attention over active level (compact Ob)
// ---------------------------------------------------------------------------
__launch_bounds__(256)
__global__ void attn_sparse_kernel(const short* __restrict__ QKV, short* __restrict__ Ob,
                                   int lvl, int cnt) {
    int wid  = blockIdx.x * 4 + (threadIdx.x >> 6);
    if (wid >= cnt * 32) return;
    int lane = threadIdx.x & 63;
    int b = wid & 31, j = wid >> 5;
    int i = d_sets.idx[lvl][j];
    const short8 qv = *(const short8*)(QKV + (size_t)(b * S + i) * 1536 + lane * 8);
    float qf[8];
#pragma unroll
    for (int e = 0; e < 8; ++e) qf[e] = bf2f(qv[e]);
    int nb[NMAX];
#pragma unroll
    for (int jj = 0; jj < NMAX; ++jj) nb[jj] = d_sets.nbr[i][jj];
    float sc[NMAX];
#pragma unroll
    for (int jj = 0; jj < NMAX; ++jj) {
        float s = -1e30f;
        if (nb[jj] >= 0) {
            const short8 kv = *(const short8*)(QKV + (size_t)(b * S + nb[jj]) * 1536 + 512 + lane * 8);
            s = 0.0f;
#pragma unroll
            for (int e = 0; e < 8; ++e) s += qf[e] * bf2f(kv[e]);
            s += __shfl_xor(s, 1); s += __shfl_xor(s, 2); s += __shfl_xor(s, 4);
            s *= 0.125f;
        }
        sc[jj] = s;
    }
    float mx = sc[0];
#pragma unroll
    for (int jj = 1; jj < NMAX; ++jj) mx = fmaxf(mx, sc[jj]);
    float sum = 0.0f;
    float accv[8] = {};
#pragma unroll
    for (int jj = 0; jj < NMAX; ++jj) {
        float p = expf(sc[jj] - mx);
        sum += p;
        if (nb[jj] >= 0) {
            const short8 vv = *(const short8*)(QKV + (size_t)(b * S + nb[jj]) * 1536 + 1024 + lane * 8);
#pragma unroll
            for (int e = 0; e < 8; ++e) accv[e] += p * bf2f(vv[e]);
        }
    }
    float inv = 1.0f / sum;
    short8 ov;
#pragma unroll
    for (int e = 0; e < 8; ++e) ov[e] = f2bf(accv[e] * inv);
    *(short8*)(Ob + (size_t)wid * D + lane * 8) = ov;
}

// ---------------------------------------------------------------------------
// wave-shuffle block reduction over 4 waves (256 thr)
// ---------------------------------------------------------------------------
__device__ inline float blk_reduce(float v, float* ws4, int tid) {
#pragma unroll
    for (int o = 32; o; o >>= 1) v += __shfl_xor(v, o);
    if ((tid & 63) == 0) ws4[tid >> 6] = v;
    __syncthreads();
    return ws4[0] + ws4[1] + ws4[2] + ws4[3];
}

// ---------------------------------------------------------------------------
// concat(emb_bf, coarse) + LayerNorm at A_0 rows only (fine rows read bf16)
// ---------------------------------------------------------------------------
__launch_bounds__(256)
__global__ void concat_ln_idx(const short* __restrict__ emb_bf, const float* __restrict__ coarse,
                              const float* __restrict__ g, const float* __restrict__ bta,
                              float* __restrict__ seq, short* __restrict__ seq_bf) {
    int row = blockIdx.x;
    int b = row & 31, j = row >> 5;
    int s = d_sets.idx[0][j];
    int orig = b * S + s;
    __shared__ float wsA[4];
    __shared__ float wsB[4];
    int tid = threadIdx.x;
    float x0, x1;
    if (s < L) {
        const short* src = emb_bf + ((size_t)b * L + s) * D;
        x0 = bf2f(src[tid]); x1 = bf2f(src[tid + 256]);
    } else {
        const float* src = coarse + ((size_t)b * LC + (s - L)) * D;
        x0 = src[tid]; x1 = src[tid + 256];
    }
    float mu = blk_reduce(x0 + x1, wsA, tid) * (1.0f / D);
    float d0 = x0 - mu, d1 = x1 - mu;
    float var = blk_reduce(d0 * d0 + d1 * d1, wsB, tid) * (1.0f / D);
    float rstd = rsqrtf(var + 1e-5f);
    float v0 = d0 * rstd * g[tid]       + bta[tid];
    float v1 = d1 * rstd * g[tid + 256] + bta[tid + 256];
    float* dst = seq + (size_t)orig * D;
    dst[tid] = v0; dst[tid + 256] = v1;
    short* dbf = seq_bf + (size_t)orig * D;
    dbf[tid] = f2bf(v0); dbf[tid + 256] = f2bf(v1);
}

// ---------------------------------------------------------------------------
// indexed residual LN (bf16 add input)
// ---------------------------------------------------------------------------
__launch_bounds__(256)
__global__ void add_ln_idx(float* __restrict__ seq, const short* __restrict__ add,
                           const float* __restrict__ g, const float* __restrict__ bta,
                           short* __restrict__ seq_bf, int lvl) {
    int row = blockIdx.x;
    int b = row & 31, j = row >> 5;
    int orig = b * S + d_sets.idx[lvl][j];
    __shared__ float wsA[4];
    __shared__ float wsB[4];
    int tid = threadIdx.x;
    float* srow = seq + (size_t)orig * D;
    const short* arow = add + (size_t)row * D;
    float x0 = srow[tid] + bf2f(arow[tid]);
    float x1 = srow[tid + 256] + bf2f(arow[tid + 256]);
    float mu = blk_reduce(x0 + x1, wsA, tid) * (1.0f / D);
    float d0 = x0 - mu, d1 = x1 - mu;
    float var = blk_reduce(d0 * d0 + d1 * d1, wsB, tid) * (1.0f / D);
    float rstd = rsqrtf(var + 1e-5f);
    float v0 = d0 * rstd * g[tid]       + bta[tid];
    float v1 = d1 * rstd * g[tid + 256] + bta[tid + 256];
    srow[tid] = v0; srow[tid + 256] = v1;
    short* dbf = seq_bf + (size_t)orig * D;
    dbf[tid] = f2bf(v0); dbf[tid + 256] = f2bf(v1);
}

// ---------------------------------------------------------------------------
// fused split-K reduce + residual LN
// ---------------------------------------------------------------------------
__launch_bounds__(256)
__global__ void add_ln_sk(float* __restrict__ seq, const float* __restrict__ part,
                          const float* __restrict__ bias, const float* __restrict__ g,
                          const float* __restrict__ bta, short* __restrict__ seq_bf,
                          int lvl, int Mpad, int KS) {
    int row = blockIdx.x;
    int b = row & 31, j = row >> 5;
    int orig = b * S + d_sets.idx[lvl][j];
    __shared__ float wsA[4];
    __shared__ float wsB[4];
    int tid = threadIdx.x;
    float a0 = 0.0f, a1 = 0.0f;
    for (int k = 0; k < KS; ++k) {
        const float* pr = part + ((size_t)k * Mpad + row) * D;
        a0 += pr[tid];
        a1 += pr[tid + 256];
    }
    if (bias) { a0 += bias[tid]; a1 += bias[tid + 256]; }
    float* srow = seq + (size_t)orig * D;
    float x0 = srow[tid] + a0;
    float x1 = srow[tid + 256] + a1;
    float mu = blk_reduce(x0 + x1, wsA, tid) * (1.0f / D);
    float d0 = x0 - mu, d1 = x1 - mu;
    float var = blk_reduce(d0 * d0 + d1 * d1, wsB, tid) * (1.0f / D);
    float rstd = rsqrtf(var + 1e-5f);
    float v0 = d0 * rstd * g[tid]       + bta[tid];
    float v1 = d1 * rstd * g[tid + 256] + bta[tid + 256];
    srow[tid] = v0; srow[tid + 256] = v1;
    short* dbf = seq_bf + (size_t)orig * D;
    dbf[tid] = f2bf(v0); dbf[tid + 256] = f2bf(v1);
}

// ---------------------------------------------------------------------------
// prediction head, split-K with fused gather
// ---------------------------------------------------------------------------
__launch_bounds__(256)
__global__ void pred_kernel(const float* __restrict__ seq, const float* __restrict__ w,
                            float* __restrict__ part) {
    __shared__ float es[32][257];
    __shared__ float wsm[256][8];
    int tid = threadIdx.x;
    int n0 = blockIdx.x * 8;
    int ks = blockIdx.y;
    int k0 = ks * 256;
    const int pos[4] = {335, 419, 440, 445};
    int seg = ks >> 1;
    int dbase = (ks & 1) * 256;
#pragma unroll 8
    for (int r = 0; r < 32; ++r)
        es[r][tid] = seq[((size_t)r * S + pos[seg]) * D + dbase + tid];
#pragma unroll
    for (int e = 0; e < 8; ++e)
        wsm[tid][e] = w[(size_t)(k0 + tid) * PRED_N + n0 + e];
    __syncthreads();
    int b = tid >> 3, nn = tid & 7;
    float acc = 0.0f;
#pragma unroll 8
    for (int kk = 0; kk < 256; ++kk)
        acc += es[b][kk] * wsm[kk][nn];
    part[(size_t)ks * (BB * PRED_N) + (size_t)b * PRED_N + n0 + nn] = acc;
}

__launch_bounds__(256)
__global__ void pred_reduce_kernel(const float* __restrict__ part, float* __restrict__ out) {
    int idx = blockIdx.x * 256 + threadIdx.x;
    if (idx >= BB * PRED_N) return;
    float s = 0.0f;
#pragma unroll
    for (int k = 0; k < 8; ++k) s += part[(size_t)k * (BB * PRED_N) + idx];
    out[idx] = s;
}

// ---------------------------------------------------------------------------
extern "C" void kernel_launch(void* const* d_in, const int* in_sizes, int n_in,
                              void* d_out, int out_size, void* d_ws, size_t ws_size,
                              hipStream_t stream) {
    const float* x_enc      = (const float*)d_in[0];
    const float* x_mark_enc = (const float*)d_in[1];
    const float* conv_embed_w = (const float*)d_in[4];
    const float* time_w  = (const float*)d_in[5];
    const float* time_b  = (const float*)d_in[6];
    const float* down_w  = (const float*)d_in[7];
    const float* down_b  = (const float*)d_in[8];
    const float* cscm_w  = (const float*)d_in[9];
    const float* cscm_b  = (const float*)d_in[10];
    const float* bn_g    = (const float*)d_in[11];
    const float* bn_b    = (const float*)d_in[12];
    const float* up_w    = (const float*)d_in[13];
    const float* up_b    = (const float*)d_in[14];
    const float* cln_g   = (const float*)d_in[15];
    const float* cln_b   = (const float*)d_in[16];
    const float* wq      = (const float*)d_in[17];
    const float* wk      = (const float*)d_in[18];
    const float* wv      = (const float*)d_in[19];
    const float* wo      = (const float*)d_in[20];
    const float* ln1_g   = (const float*)d_in[21];
    const float* ln1_b   = (const float*)d_in[22];
    const float* ffn_w1  = (const float*)d_in[23];
    const float* ffn_b1  = (const float*)d_in[24];
    const float* ffn_w2  = (const float*)d_in[25];
    const float* ffn_b2  = (const float*)d_in[26];
    const float* ln2_g   = (const float*)d_in[27];
    const float* ln2_b   = (const float*)d_in[28];
    const float* pred_w  = (const float*)d_in[29];
    float* out = (float*)d_out;

    // ---- workspace layout (bytes, 256-aligned) ----
    char* w8 = (char*)d_ws;
    size_t off = 0;
    auto alloc = [&](size_t bytes) {
        void* p = w8 + off;
        off = (off + bytes + 255) & ~(size_t)255;
        return p;
    };
    short* emb_bf = (short*)alloc((size_t)BB * L * D * 2);
    float* pe     = (float*)alloc((size_t)L * D * 4);
    short* xim    = (short*)alloc((size_t)BB * L * 32 * 2);
    short* wE     = (short*)alloc((size_t)D * 32 * 2);
    short* xd_bf  = (short*)alloc((size_t)BB * L * DBOT * 2);
    short* cs1_bf = (short*)alloc((size_t)MCONV2P * 512 * 2);
    short* cs2_bf = (short*)alloc((size_t)MCONV2P * DBOT * 2);
    short* cs3_bf = (short*)alloc((size_t)BB * L3 * DBOT * 2);
    float* coarse = (float*)alloc((size_t)MCAT * D * 4);
    float* seq    = (float*)alloc((size_t)BB * S * D * 4);
    short* T1     = (short*)alloc((size_t)MP * D * 2);
    float* part   = (float*)alloc((size_t)8 * BB * PRED_N * 4);
    float* partsk = (float*)alloc(psk_elems() * 4);   // split-K partials (exact)
    short* seq_bf = (short*)alloc((size_t)MP * D * 2);
    short* QKV    = (short*)alloc((size_t)MP * 3 * D * 2);  // + Ob contiguous
    short* Ob     = (short*)alloc((size_t)MP * D * 2);
    short* hidden = QKV;
    short* wqkvT  = (short*)alloc((size_t)NLAYER * 3 * D * D * 2);
    short* woT    = (short*)alloc((size_t)NLAYER * D * D * 2);
    short* w1T    = (short*)alloc((size_t)NLAYER * DFF * D * 2);
    short* w2T    = (short*)alloc((size_t)NLAYER * D * DFF * 2);
    short* downT  = (short*)alloc((size_t)DBOT * D * 2);
    short* upT    = (short*)alloc((size_t)D * DBOT * 2);
    short* cscmT  = (short*)alloc((size_t)2 * DBOT * 512 * 2);
    float* csc_sc = (float*)alloc((size_t)3 * DBOT * 4);
    float* csc_sh = (float*)alloc((size_t)3 * DBOT * 4);
    (void)ws_size; (void)in_sizes; (void)n_in; (void)out_size;

    const int rowsL = BB * L;   // 10752 = 84*128
    dim3 blk(256);

    // 0. ONE fused prep kernel (all independent workloads run concurrently)
    prep_all<<<dim3(PREP_BLKS), blk, 0, stream>>>(
        wq, wk, wv, wo, wqkvT, woT,
        ffn_w1, ffn_w2, w1T, w2T,
        down_w, downT, up_w, upT,
        cscm_w, cscm_b, bn_g, bn_b, cscmT, csc_sc, csc_sh,
        x_enc, x_mark_enc, conv_embed_w, time_w, time_b, pe, wE, xim);
    // 1. embedding as GEMM (M=10752, N=512, K=32) + pe epilogue, bf16 out
    mfma_gemm<6><<<dim3(D / 128, rowsL / 128), blk, 0, stream>>>(
        xim, wE, nullptr, nullptr, nullptr, 32, D, -1, -1, 0, pe, emb_bf);
    // 2. down projection -> bf16 (split-K)
    mfma_gemm_sk<<<dim3(1, rowsL / 128, 4), blk, 0, stream>>>(
        emb_bf, downT, partsk, D, DBOT, -1, 0);
    reduce_sk<4><<<dim3((rowsL * DBOT + 255) / 256), blk, 0, stream>>>(
        partsk, down_b, nullptr, xd_bf, rowsL, DBOT, 4);
    // 3. CSCM pyramid (conv1/conv2 split-K)
    mfma_gemm_sk<<<dim3(1, MCONV1 / 128, 4), blk, 0, stream>>>(
        xd_bf, cscmT, partsk, 512, DBOT, -1, 0);
    reduce_sk<5><<<dim3((MCONV1 * DBOT + 255) / 256), blk, 0, stream>>>(
        partsk, csc_sc, csc_sh, cs1_bf, MCONV1, DBOT, 4);
    mfma_gemm_sk<<<dim3(1, MCONV2P / 128, 4), blk, 0, stream>>>(
        cs1_bf, cscmT + (size_t)DBOT * 512, partsk, 512, DBOT, -1, 0);
    reduce_sk<5><<<dim3((MCONV2P * DBOT + 255) / 256), blk, 0, stream>>>(
        partsk, csc_sc + DBOT, csc_sh + DBOT, cs2_bf, MCONV2P, DBOT, 4);
    cscm_conv_bf16<<<dim3(BB * L3), dim3(DBOT), 0, stream>>>(
        cs2_bf, L2, cs3_bf, cscm_w + 2 * DBOT * DBOT * 4,
        cscm_b + 2 * DBOT, bn_g + 2 * DBOT, bn_b + 2 * DBOT, L3);
    // 4. up projection with inline concat gather (concat_cs deleted, r21)
    mfma_gemm_up<<<dim3(D / 128, MCAT / 128), blk, 0, stream>>>(
        cs1_bf, cs2_bf, cs3_bf, upT, up_b, coarse);
    // 5. concat + LN (A_0 rows only; fine rows from bf16 shadow)
    concat_ln_idx<<<dim3(HS.cnt[0] * 32), blk, 0, stream>>>(
        emb_bf, coarse, cln_g, cln_b, seq, seq_bf);

    // 6. encoder layers (sparse active sets; split-K + fused reduce/LN)
    for (int l = 0; l < NLAYER; ++l) {
        const int inLvl = l, outLvl = l + 1;
        const int inCnt  = HS.cnt[l];
        const int outCnt = HS.cnt[l + 1];
        const int Mc   = outCnt * 32;
        const int Mpad = ((Mc + 127) / 128) * 128;
        mfma_gemm<2><<<dim3(3 * D / 128, (inCnt * 32 + 127) / 128), blk, 0, stream>>>(
            seq_bf, wqkvT + (size_t)l * 3 * D * D, nullptr, nullptr, QKV, D, 3 * D,
            inLvl, inLvl, inCnt, nullptr, nullptr);
        attn_sparse_kernel<<<dim3(outCnt * 8), blk, 0, stream>>>(
            QKV, Ob, outLvl, outCnt);
        // O-projection + LN1 (split-K fused into LN when M small)
        if (Mc <= 512) {
            mfma_gemm_sk<<<dim3(D / 128, Mpad / 128, 4), blk, 0, stream>>>(
                Ob, woT + (size_t)l * D * D, partsk, D, D, -1, 0);
            add_ln_sk<<<dim3(Mc), blk, 0, stream>>>(
                seq, partsk, nullptr, ln1_g + (size_t)l * D, ln1_b + (size_t)l * D,
                seq_bf, outLvl, Mpad, 4);
        } else {
            mfma_gemm<2><<<dim3(D / 128, Mpad / 128), blk, 0, stream>>>(
                Ob, woT + (size_t)l * D * D, nullptr, nullptr, T1, D, D,
                -1, -1, 0, nullptr, nullptr);
            add_ln_idx<<<dim3(Mc), blk, 0, stream>>>(
                seq, T1, ln1_g + (size_t)l * D, ln1_b + (size_t)l * D, seq_bf, outLvl);
        }
        // FFN1: split-K only for tiny M (K=512, KS=4)
        if (Mc <= 128) {
            mfma_gemm_sk<<<dim3(DFF / 128, Mpad / 128, 4), blk, 0, stream>>>(
                seq_bf, w1T + (size_t)l * DFF * D, partsk, D, DFF, outLvl, outCnt);
            reduce_sk<3><<<dim3((Mpad * DFF + 255) / 256), blk, 0, stream>>>(
                partsk, ffn_b1 + (size_t)l * DFF, nullptr, hidden, Mpad, DFF, 4);
        } else {
            mfma_gemm<3><<<dim3(DFF / 128, Mpad / 128), blk, 0, stream>>>(
                seq_bf, w1T + (size_t)l * DFF * D, ffn_b1 + (size_t)l * DFF, nullptr,
                hidden, D, DFF, outLvl, -1, outCnt, nullptr, nullptr);
        }
        // FFN2 + LN2: split-K, reduce fused into LN
        {
            int KS = (Mc <= 512) ? 8 : 4;
            mfma_gemm_sk<<<dim3(D / 128, Mpad / 128, KS), blk, 0, stream>>>(
                hidden, w2T + (size_t)l * D * DFF, partsk, DFF, D, -1, 0);
            add_ln_sk<<<dim3(Mc), blk, 0, stream>>>(
                seq, partsk, ffn_b2 + (size_t)l * D, ln2_g + (size_t)l * D,
                ln2_b + (size_t)l * D, seq_bf, outLvl, Mpad, KS);
        }
    }

    // 7. prediction head (split-K, gather fused) + reduce
    pred_kernel<<<dim3(PRED_N / 8, 8), blk, 0, stream>>>(seq, pred_w, part);
    pred_reduce_kernel<<<dim3((BB * PRED_N + 255) / 256), blk, 0, stream>>>(part, out);
}

// Round 22
// 328.642 us; speedup vs baseline: 2.7575x; 1.0248x over previous
//
#include <hip/hip_runtime.h>
#include <math.h>

// ---- problem constants ----
constexpr int BB   = 32;    // batch
constexpr int L    = 336;   // seq_len
constexpr int CIN  = 7;
constexpr int MARK = 4;
constexpr int D    = 512;   // d_model
constexpr int DFF  = 2048;
constexpr int NH   = 8;
constexpr int HD   = 64;    // dk = dv
constexpr int S    = 446;   // 336+84+21+5
constexpr int DBOT = 128;
constexpr int L1 = 84, L2 = 21, L3 = 5;
constexpr int LC = 110;     // 84+21+5
constexpr int NLAYER = 3;
constexpr int PRED_N = 672; // 96*7
constexpr int MP   = 14336; // BB*S padded
constexpr int NMAX = 12;    // max sparse neighbors (real max 10)
constexpr int MCONV1 = BB * L1;          // 2688 = 21*128 (exact)
constexpr int MCONV2P = 768;             // BB*L2=672 padded to 6*128
constexpr int MCAT  = 3584;              // BB*LC=3520 padded to 28*128

using short8  = __attribute__((ext_vector_type(8))) short;
using float4v = __attribute__((ext_vector_type(4))) float;

// ---------------------------------------------------------------------------
// COMPILE-TIME pyramid structure: neighbor lists + active sets.
// ---------------------------------------------------------------------------
struct SetsData {
    int nbr[S][NMAX];
    int idx[4][S];
    int cnt[4];
};

constexpr SetsData compute_sets() {
    SetsData sd{};
    constexpr int sizes[4]  = {336, 84, 21, 5};
    constexpr int starts[4] = {0, 336, 420, 441};
    for (int i = 0; i < S; ++i) {
        int li = 0, pi = i;
        if (i < 336)      { li = 0; pi = i; }
        else if (i < 420) { li = 1; pi = i - 336; }
        else if (i < 441) { li = 2; pi = i - 420; }
        else              { li = 3; pi = i - 441; }
        int cnt = 0;
        for (int d = -2; d <= 2; ++d) {
            int q = pi + d;
            if (q >= 0 && q < sizes[li]) sd.nbr[i][cnt++] = starts[li] + q;
        }
        if (li > 0) {
            int lo = pi * 4;
            int hi = (pi == sizes[li] - 1) ? sizes[li - 1] : (pi + 1) * 4;
            for (int c = lo; c < hi; ++c) sd.nbr[i][cnt++] = starts[li - 1] + c;
        }
        if (li < 3) {
            int q = pi >> 2;
            if (q > sizes[li + 1] - 1) q = sizes[li + 1] - 1;
            sd.nbr[i][cnt++] = starts[li + 1] + q;
        }
        for (int j = cnt; j < NMAX; ++j) sd.nbr[i][j] = -1;
    }
    sd.cnt[3] = 4;
    sd.idx[3][0] = 335; sd.idx[3][1] = 419; sd.idx[3][2] = 440; sd.idx[3][3] = 445;
    for (int lvl = 3; lvl >= 1; --lvl) {
        bool mk[S] = {};
        for (int k = 0; k < sd.cnt[lvl]; ++k) {
            int i = sd.idx[lvl][k];
            for (int t = 0; t < NMAX; ++t) {
                int v = sd.nbr[i][t];
                if (v >= 0) mk[v] = true;
            }
        }
        int nc = 0;
        for (int i = 0; i < S; ++i)
            if (mk[i]) sd.idx[lvl - 1][nc++] = i;
        sd.cnt[lvl - 1] = nc;
    }
    return sd;
}

constexpr SetsData HS = compute_sets();         // host: grid sizing
__constant__ SetsData d_sets = compute_sets();  // device: row maps + nbr

// exact split-K partial buffer size (elements), from compile-time counts
// (r22 thresholds: wo always split-K; ffn1 split-K for Mc<=512)
constexpr size_t psk_elems() {
    size_t mx = 4 * (size_t)BB * L * DBOT;      // down-proj split-K (5.5M)
    {
        size_t v = 4 * (size_t)MCONV1 * DBOT; if (v > mx) mx = v;   // conv1
        v = 4 * (size_t)MCONV2P * DBOT;       if (v > mx) mx = v;   // conv2
    }
    for (int l = 0; l < NLAYER; ++l) {
        size_t Mc = (size_t)HS.cnt[l + 1] * 32;
        size_t Mpad = ((Mc + 127) / 128) * 128;
        { size_t v = 4 * Mpad * 512;  if (v > mx) mx = v; }                  // wo (always)
        if (Mc <= 512) { size_t v = 4 * Mpad * 2048; if (v > mx) mx = v; }   // ffn1
        size_t ks = (Mc <= 512) ? 8 : 4;
        size_t v = ks * Mpad * 512; if (v > mx) mx = v;                      // ffn2
    }
    return mx;
}

__device__ inline short f2bf(float f) {
    union { float f; unsigned u; } v; v.f = f;
    unsigned r = v.u + 0x7fffu + ((v.u >> 16) & 1u);
    return (short)(r >> 16);
}
__device__ inline float bf2f(short h) {
    union { unsigned u; float f; } v; v.u = ((unsigned)(unsigned short)h) << 16;
    return v.f;
}

// async global->LDS, 16B per lane, wave-uniform LDS base + lane*16
__device__ inline void gload_lds16(const void* g, void* l) {
    __builtin_amdgcn_global_load_lds(
        (const __attribute__((address_space(1))) void*)g,
        (__attribute__((address_space(3))) void*)l, 16, 0, 0);
}

// Staging map: conflict-free + coalesced (verified r11: 0 bank conflicts).
// Sparse rows: alvl/clvl >= 0 select d_sets.idx[lvl] (pos-major compact:
// compact m -> b=m&31, j=m>>5 clamped to cnt-1, orig row b*S+idx[j]).

// ---------------------------------------------------------------------------
// 128x128 bf16 MFMA GEMM, BK=32, double-buffered, counted vmcnt(4) pipeline.
// EPI: 0 f32; 1 f32+bias; 2 bf16; 3 bf16+bias+gelu; 4 bf16+bias;
//      5 bf16, v = acc*bias[gn]+bias2[gn] then ELU;
//      6 v = acc + peT[(row%L)*D+gn] -> bf16 Cout2 only (embed)
// ---------------------------------------------------------------------------
template<int EPI>
__launch_bounds__(256, 4)
__global__ void mfma_gemm(const short* __restrict__ A, const short* __restrict__ Bt,
                          const float* __restrict__ bias, const float* __restrict__ bias2,
                          void* __restrict__ Cout, int Kd, int Nd,
                          int alvl, int clvl, int cnt,
                          const float* __restrict__ peT, short* __restrict__ Cout2) {
    __shared__ short As[2][128 * 32];
    __shared__ short Bs[2][128 * 32];
    int tid = threadIdx.x;
    int nwg  = gridDim.x * gridDim.y;
    int orig = blockIdx.y * gridDim.x + blockIdx.x;
    int qq = nwg >> 3, rr = nwg & 7;
    int xcd = orig & 7, idx = orig >> 3;
    int wgid = (xcd < rr ? xcd * (qq + 1) : rr * (qq + 1) + (xcd - rr) * qq) + idx;
    int m0 = (wgid / gridDim.x) * 128, n0 = (wgid % gridDim.x) * 128;

    int lane = tid & 63, wid = tid >> 6;
    int wm = wid >> 1, wn = wid & 1;
    int lr = lane & 15, lk = lane >> 4;

    size_t abase[2], bbase[2];
#pragma unroll
    for (int r = 0; r < 2; ++r) {
        int u = r * 256 + tid;
        int row = ((u >> 3) << 1) | ((u >> 2) & 1);
        int kg  = (u & 3) ^ ((u >> 3) & 3);
        int rm = m0 + row, ga;
        if (alvl >= 0) { int j = rm >> 5; if (j > cnt - 1) j = cnt - 1; ga = (rm & 31) * S + d_sets.idx[alvl][j]; }
        else ga = rm;
        abase[r] = (size_t)ga * Kd + kg * 8;
        bbase[r] = (size_t)(n0 + row) * Kd + kg * 8;
    }
    auto stage = [&](int buf, int k0) {
#pragma unroll
        for (int r = 0; r < 2; ++r) {
            short* la = As[buf] + (size_t)(r * 256 + wid * 64) * 8;
            short* lb = Bs[buf] + (size_t)(r * 256 + wid * 64) * 8;
            gload_lds16(A + abase[r] + k0, la);
            gload_lds16(Bt + bbase[r] + k0, lb);
        }
    };
    auto rd_off = [&](int row_) {
        int rh = row_ >> 1;
        int s  = lk ^ (rh & 3);
        return (size_t)(rh * 8 + (row_ & 1) * 4 + s) * 8;
    };

    float4v acc[4][4];
#pragma unroll
    for (int i = 0; i < 4; ++i)
#pragma unroll
        for (int j = 0; j < 4; ++j) acc[i][j] = 0;

    const int nt = Kd >> 5;
    stage(0, 0);
    for (int t = 0; t < nt; ++t) {
        int cur = t & 1;
        if (t + 1 < nt) {
            stage(cur ^ 1, (t + 1) * 32);
            asm volatile("s_waitcnt vmcnt(4)" ::: "memory");
        } else {
            asm volatile("s_waitcnt vmcnt(0)" ::: "memory");
        }
        __builtin_amdgcn_s_barrier();
        short8 af[4], bfv[4];
#pragma unroll
        for (int mi = 0; mi < 4; ++mi)
            af[mi] = *(const short8*)(As[cur] + rd_off(wm * 64 + mi * 16 + lr));
#pragma unroll
        for (int ni = 0; ni < 4; ++ni)
            bfv[ni] = *(const short8*)(Bs[cur] + rd_off(wn * 64 + ni * 16 + lr));
        __builtin_amdgcn_s_setprio(1);
#pragma unroll
        for (int mi = 0; mi < 4; ++mi)
#pragma unroll
            for (int ni = 0; ni < 4; ++ni)
                acc[mi][ni] = __builtin_amdgcn_mfma_f32_16x16x32_bf16(
                    af[mi], bfv[ni], acc[mi][ni], 0, 0, 0);
        __builtin_amdgcn_s_setprio(0);
        __builtin_amdgcn_s_barrier();
    }

#pragma unroll
    for (int mi = 0; mi < 4; ++mi) {
        int gmc = m0 + wm * 64 + mi * 16 + lk * 4;
#pragma unroll
        for (int ni = 0; ni < 4; ++ni) {
            int gn = n0 + wn * 64 + ni * 16 + lr;
            float bsv = (EPI == 1 || EPI == 3 || EPI == 4) ? bias[gn] : 0.0f;
            float sc = (EPI == 5) ? bias[gn]  : 0.0f;
            float sh = (EPI == 5) ? bias2[gn] : 0.0f;
#pragma unroll
            for (int e = 0; e < 4; ++e) {
                int rm = gmc + e, grow;
                if (clvl >= 0) { int j = rm >> 5; if (j > cnt - 1) j = cnt - 1; grow = (rm & 31) * S + d_sets.idx[clvl][j]; }
                else grow = rm;
                float v = acc[mi][ni][e] + bsv;
                if (EPI == 3) v = 0.5f * v * (1.0f + erff(v * 0.70710678118654752f));
                if (EPI == 5) { v = v * sc + sh; v = v > 0.0f ? v : (expf(v) - 1.0f); }
                if (EPI == 6) {
                    v += peT[(size_t)(grow % L) * D + gn];
                    Cout2[(size_t)grow * Nd + gn] = f2bf(v);
                } else if (EPI <= 1) {
                    ((float*)Cout)[(size_t)grow * Nd + gn] = v;
                } else {
                    ((short*)Cout)[(size_t)grow * Nd + gn] = f2bf(v);
                }
            }
        }
    }
}

// ---------------------------------------------------------------------------
// up-projection GEMM with INLINE concat gather (r21)
// ---------------------------------------------------------------------------
__launch_bounds__(256, 4)
__global__ void mfma_gemm_up(const short* __restrict__ cs1, const short* __restrict__ cs2,
                             const short* __restrict__ cs3, const short* __restrict__ Bt,
                             const float* __restrict__ bias, float* __restrict__ Cout) {
    __shared__ short As[2][128 * 32];
    __shared__ short Bs[2][128 * 32];
    int tid = threadIdx.x;
    int nwg  = gridDim.x * gridDim.y;
    int orig = blockIdx.y * gridDim.x + blockIdx.x;
    int qq = nwg >> 3, rr = nwg & 7;
    int xcd = orig & 7, idx = orig >> 3;
    int wgid = (xcd < rr ? xcd * (qq + 1) : rr * (qq + 1) + (xcd - rr) * qq) + idx;
    int m0 = (wgid / gridDim.x) * 128, n0 = (wgid % gridDim.x) * 128;
    const int Kd = DBOT, Nd = D;

    int lane = tid & 63, wid = tid >> 6;
    int wm = wid >> 1, wn = wid & 1;
    int lr = lane & 15, lk = lane >> 4;

    const short* aad[2];
    size_t bbase[2];
#pragma unroll
    for (int r = 0; r < 2; ++r) {
        int u = r * 256 + tid;
        int row = ((u >> 3) << 1) | ((u >> 2) & 1);
        int kg  = (u & 3) ^ ((u >> 3) & 3);
        int rm = m0 + row;
        const short* base;
        if (rm < BB * LC) {
            int b = rm / LC, t = rm % LC;
            if (t < L1)           base = cs1 + (size_t)(b * L1 + t) * DBOT;
            else if (t < L1 + L2) base = cs2 + (size_t)(b * L2 + (t - L1)) * DBOT;
            else                  base = cs3 + (size_t)(b * L3 + (t - L1 - L2)) * DBOT;
        } else {
            base = cs1;   // pad row: garbage computed, never read
        }
        aad[r] = base + kg * 8;
        bbase[r] = (size_t)(n0 + row) * Kd + kg * 8;
    }
    auto stage = [&](int buf, int k0) {
#pragma unroll
        for (int r = 0; r < 2; ++r) {
            short* la = As[buf] + (size_t)(r * 256 + wid * 64) * 8;
            short* lb = Bs[buf] + (size_t)(r * 256 + wid * 64) * 8;
            gload_lds16(aad[r] + k0, la);
            gload_lds16(Bt + bbase[r] + k0, lb);
        }
    };
    auto rd_off = [&](int row_) {
        int rh = row_ >> 1;
        int s  = lk ^ (rh & 3);
        return (size_t)(rh * 8 + (row_ & 1) * 4 + s) * 8;
    };

    float4v acc[4][4];
#pragma unroll
    for (int i = 0; i < 4; ++i)
#pragma unroll
        for (int j = 0; j < 4; ++j) acc[i][j] = 0;

    const int nt = Kd >> 5;   // 4
    stage(0, 0);
    for (int t = 0; t < nt; ++t) {
        int cur = t & 1;
        if (t + 1 < nt) {
            stage(cur ^ 1, (t + 1) * 32);
            asm volatile("s_waitcnt vmcnt(4)" ::: "memory");
        } else {
            asm volatile("s_waitcnt vmcnt(0)" ::: "memory");
        }
        __builtin_amdgcn_s_barrier();
        short8 af[4], bfv[4];
#pragma unroll
        for (int mi = 0; mi < 4; ++mi)
            af[mi] = *(const short8*)(As[cur] + rd_off(wm * 64 + mi * 16 + lr));
#pragma unroll
        for (int ni = 0; ni < 4; ++ni)
            bfv[ni] = *(const short8*)(Bs[cur] + rd_off(wn * 64 + ni * 16 + lr));
        __builtin_amdgcn_s_setprio(1);
#pragma unroll
        for (int mi = 0; mi < 4; ++mi)
#pragma unroll
            for (int ni = 0; ni < 4; ++ni)
                acc[mi][ni] = __builtin_amdgcn_mfma_f32_16x16x32_bf16(
                    af[mi], bfv[ni], acc[mi][ni], 0, 0, 0);
        __builtin_amdgcn_s_setprio(0);
        __builtin_amdgcn_s_barrier();
    }

#pragma unroll
    for (int mi = 0; mi < 4; ++mi) {
        int gmc = m0 + wm * 64 + mi * 16 + lk * 4;
#pragma unroll
        for (int ni = 0; ni < 4; ++ni) {
            int gn = n0 + wn * 64 + ni * 16 + lr;
            float bsv = bias[gn];
#pragma unroll
            for (int e = 0; e < 4; ++e)
                Cout[(size_t)(gmc + e) * Nd + gn] = acc[mi][ni][e] + bsv;
        }
    }
}

// ---------------------------------------------------------------------------
// SPLIT-K variant: gridDim.z = KS slices; writes f32 partial part[kz][Mpad][Nd].
// ---------------------------------------------------------------------------
__launch_bounds__(256, 4)
__global__ void mfma_gemm_sk(const short* __restrict__ A, const short* __restrict__ Bt,
                             float* __restrict__ part, int Kd, int Nd,
                             int alvl, int cnt) {
    __shared__ short As[2][128 * 32];
    __shared__ short Bs[2][128 * 32];
    int tid = threadIdx.x;
    int nwg  = gridDim.x * gridDim.y;
    int orig = blockIdx.y * gridDim.x + blockIdx.x;
    int qq = nwg >> 3, rr = nwg & 7;
    int xcd = orig & 7, idx = orig >> 3;
    int wgid = (xcd < rr ? xcd * (qq + 1) : rr * (qq + 1) + (xcd - rr) * qq) + idx;
    int m0 = (wgid / gridDim.x) * 128, n0 = (wgid % gridDim.x) * 128;
    int Mpad = gridDim.y * 128;
    int kz = blockIdx.z;
    int kb = Kd / gridDim.z;          // slice length (multiple of 32)
    int kbase = kz * kb;

    int lane = tid & 63, wid = tid >> 6;
    int wm = wid >> 1, wn = wid & 1;
    int lr = lane & 15, lk = lane >> 4;

    size_t abase[2], bbase[2];
#pragma unroll
    for (int r = 0; r < 2; ++r) {
        int u = r * 256 + tid;
        int row = ((u >> 3) << 1) | ((u >> 2) & 1);
        int kg  = (u & 3) ^ ((u >> 3) & 3);
        int rm = m0 + row, ga;
        if (alvl >= 0) { int j = rm >> 5; if (j > cnt - 1) j = cnt - 1; ga = (rm & 31) * S + d_sets.idx[alvl][j]; }
        else ga = rm;
        abase[r] = (size_t)ga * Kd + kbase + kg * 8;
        bbase[r] = (size_t)(n0 + row) * Kd + kbase + kg * 8;
    }
    auto stage = [&](int buf, int k0) {
#pragma unroll
        for (int r = 0; r < 2; ++r) {
            short* la = As[buf] + (size_t)(r * 256 + wid * 64) * 8;
            short* lb = Bs[buf] + (size_t)(r * 256 + wid * 64) * 8;
            gload_lds16(A + abase[r] + k0, la);
            gload_lds16(Bt + bbase[r] + k0, lb);
        }
    };
    auto rd_off = [&](int row_) {
        int rh = row_ >> 1;
        int s  = lk ^ (rh & 3);
        return (size_t)(rh * 8 + (row_ & 1) * 4 + s) * 8;
    };

    float4v acc[4][4];
#pragma unroll
    for (int i = 0; i < 4; ++i)
#pragma unroll
        for (int j = 0; j < 4; ++j) acc[i][j] = 0;

    const int nt = kb >> 5;
    stage(0, 0);
    for (int t = 0; t < nt; ++t) {
        int cur = t & 1;
        if (t + 1 < nt) {
            stage(cur ^ 1, (t + 1) * 32);
            asm volatile("s_waitcnt vmcnt(4)" ::: "memory");
        } else {
            asm volatile("s_waitcnt vmcnt(0)" ::: "memory");
        }
        __builtin_amdgcn_s_barrier();
        short8 af[4], bfv[4];
#pragma unroll
        for (int mi = 0; mi < 4; ++mi)
            af[mi] = *(const short8*)(As[cur] + rd_off(wm * 64 + mi * 16 + lr));
#pragma unroll
        for (int ni = 0; ni < 4; ++ni)
            bfv[ni] = *(const short8*)(Bs[cur] + rd_off(wn * 64 + ni * 16 + lr));
        __builtin_amdgcn_s_setprio(1);
#pragma unroll
        for (int mi = 0; mi < 4; ++mi)
#pragma unroll
            for (int ni = 0; ni < 4; ++ni)
                acc[mi][ni] = __builtin_amdgcn_mfma_f32_16x16x32_bf16(
                    af[mi], bfv[ni], acc[mi][ni], 0, 0, 0);
        __builtin_amdgcn_s_setprio(0);
        __builtin_amdgcn_s_barrier();
    }

#pragma unroll
    for (int mi = 0; mi < 4; ++mi) {
        int gmc = m0 + wm * 64 + mi * 16 + lk * 4;
#pragma unroll
        for (int ni = 0; ni < 4; ++ni) {
            int gn = n0 + wn * 64 + ni * 16 + lr;
#pragma unroll
            for (int e = 0; e < 4; ++e)
                part[((size_t)kz * Mpad + gmc + e) * Nd + gn] = acc[mi][ni][e];
        }
    }
}

// sum KS partials + epilogue -> bf16 compact output
// EPI: 3 +bias+gelu; 4 +bias; 5 *bias+bias2 then ELU (conv BN fold)
template<int EPI>
__launch_bounds__(256)
__global__ void reduce_sk(const float* __restrict__ part, const float* __restrict__ bias,
                          const float* __restrict__ bias2, short* __restrict__ Cout,
                          int Mpad, int Nd, int KS) {
    int idx = blockIdx.x * 256 + threadIdx.x;
    if (idx >= Mpad * Nd) return;
    float s = 0.0f;
    for (int k = 0; k < KS; ++k)
        s += part[(size_t)k * Mpad * Nd + idx];
    int n = idx % Nd;
    if (EPI == 3 || EPI == 4) s += bias[n];
    if (EPI == 3) s = 0.5f * s * (1.0f + erff(s * 0.70710678118654752f));
    if (EPI == 5) { s = s * bias[n] + bias2[n]; s = s > 0.0f ? s : (expf(s) - 1.0f); }
    Cout[idx] = f2bf(s);
}

// ---------------------------------------------------------------------------
// weight transpose tile helper
// ---------------------------------------------------------------------------
__device__ inline void wtrans_tile(const float* __restrict__ W, short* __restrict__ Wt,
                                   int Kd, int Nd, int n0, int k0, int tid) {
    __shared__ float tile[32][33];
    int tx = tid & 31, ty = tid >> 5; // ty 0..7
#pragma unroll
    for (int r = 0; r < 32; r += 8)
        tile[ty + r][tx] = W[(size_t)(k0 + ty + r) * Nd + n0 + tx];
    __syncthreads();
#pragma unroll
    for (int r = 0; r < 32; r += 8)
        Wt[(size_t)(n0 + ty + r) * Kd + k0 + tx] = f2bf(tile[tx][ty + r]);
}

// ---------------------------------------------------------------------------
// ONE fused prep kernel: all weight transposes + small prep + pe/wE/xim.
// ---------------------------------------------------------------------------
constexpr int PE_N  = L * D;           // 172032
constexpr int WE_N  = D * 32;          // 16384
constexpr int XIM_N = BB * L * 32;     // 344064
constexpr int MISC_N = PE_N + WE_N + XIM_N;
constexpr int PREP_BLKS = 3072 + 6144 + 640 + (MISC_N + 255) / 256;

__launch_bounds__(256)
__global__ void prep_all(const float* __restrict__ wq, const float* __restrict__ wk,
                         const float* __restrict__ wv, const float* __restrict__ wo,
                         short* __restrict__ wqkvT, short* __restrict__ woT,
                         const float* __restrict__ w1, const float* __restrict__ w2,
                         short* __restrict__ w1T, short* __restrict__ w2T,
                         const float* __restrict__ down_w, short* __restrict__ downT,
                         const float* __restrict__ up_w, short* __restrict__ upT,
                         const float* __restrict__ cw, const float* __restrict__ cb,
                         const float* __restrict__ bg, const float* __restrict__ bb,
                         short* __restrict__ cscmT, float* __restrict__ sc,
                         float* __restrict__ sh,
                         const float* __restrict__ x_enc, const float* __restrict__ x_mark,
                         const float* __restrict__ cew, const float* __restrict__ tw,
                         const float* __restrict__ tb, float* __restrict__ pe,
                         short* __restrict__ wE, short* __restrict__ xim) {
    int blk = blockIdx.x;
    int tid = threadIdx.x;
    if (blk < 3072) {
        int z = blk >> 8, rem = blk & 255;
        int l = z >> 2, part = z & 3;
        const float* src = (part == 0 ? wq : part == 1 ? wk : part == 2 ? wv : wo)
                           + (size_t)l * D * D;
        short* dst = (part < 3) ? wqkvT + (size_t)l * 3 * D * D + (size_t)part * D * D
                                : woT + (size_t)l * D * D;
        wtrans_tile(src, dst, D, D, (rem & 15) * 32, (rem >> 4) * 32, tid);
        return;
    }
    blk -= 3072;
    if (blk < 6144) {
        int z = blk >> 10, rem = blk & 1023;
        int l = z >> 1, part = z & 1;
        int bx = rem & 63, by = rem >> 6;
        int nt = part ? by : bx;
        int kt = part ? bx : by;
        if (part == 0)
            wtrans_tile(w1 + (size_t)l * D * DFF, w1T + (size_t)l * DFF * D,
                        D, DFF, nt * 32, kt * 32, tid);
        else
            wtrans_tile(w2 + (size_t)l * DFF * D, w2T + (size_t)l * D * DFF,
                        DFF, D, nt * 32, kt * 32, tid);
        return;
    }
    blk -= 6144;
    if (blk < 640) {
        if (blk < 64) {
            wtrans_tile(down_w, downT, D, DBOT, (blk & 3) * 32, (blk >> 2) * 32, tid);
        } else if (blk < 128) {
            int b2 = blk - 64;
            wtrans_tile(up_w, upT, DBOT, D, (b2 & 15) * 32, (b2 >> 4) * 32, tid);
        } else {
            int idx = (blk - 128) * 256 + tid;
            if (idx < 2 * DBOT * 512) {
                int l = idx >> 16;
                int rem = idx & 65535;
                int oc = rem >> 9, j = rem & 511;
                int r = j >> 7, c = j & 127;
                cscmT[idx] = f2bf(cw[(((size_t)l * DBOT + oc) * DBOT + c) * 4 + r]);
            }
            if (idx < 3 * DBOT) {
                sc[idx] = bg[idx];
                sh[idx] = cb[idx] * bg[idx] + bb[idx];
            }
        }
        return;
    }
    blk -= 640;
    {
        int idx = blk * 256 + tid;
        if (idx < PE_N) {
            int d = idx % D, t = idx / D;
            int e = d & ~1;
            float div = expf(-(float)e * (logf(10000.0f) / (float)D));
            float arg = (float)t * div;
            pe[idx] = (d & 1) ? cosf(arg) : sinf(arg);
            return;
        }
        int i2 = idx - PE_N;
        if (i2 < WE_N) {
            int k = i2 & 31, d = i2 >> 5;
            float v = 0.0f;
            if (k < 21) {
                int w = k / 7, i = k % 7;
                v = cew[(size_t)d * (CIN * 3) + i * 3 + w];
            } else if (k < 25) {
                v = tw[(size_t)(k - 21) * D + d];
            } else if (k == 25) {
                v = tb[d];
            }
            wE[i2] = f2bf(v);
            return;
        }
        int i3 = i2 - WE_N;
        if (i3 < XIM_N) {
            int k = i3 & 31, m = i3 >> 5;
            int t = m % L, b = m / L;
            float v = 0.0f;
            if (k < 21) {
                int w = k / 7, i = k % 7;
                int s = t + w - 1;
                if (s < 0) s = L - 1;
                if (s >= L) s = 0;
                v = x_enc[((size_t)b * L + s) * CIN + i];
            } else if (k < 25) {
                v = x_mark[(size_t)m * MARK + (k - 21)];
            } else if (k == 25) {
                v = 1.0f;
            }
            xim[i3] = f2bf(v);
        }
    }
}

// ---------------------------------------------------------------------------
// CSCM conv level 3 (tiny)
// ---------------------------------------------------------------------------
__launch_bounds__(128)
__global__ void cscm_conv_bf16(const short* __restrict__ in, int inRowsPerB,
                               short* __restrict__ outp, const float* __restrict__ w,
                               const float* __restrict__ cb, const float* __restrict__ bng,
                               const float* __restrict__ bnb, int Lout) {
    int bid = blockIdx.x;
    int to = bid % Lout, b = bid / Lout;
    __shared__ float insh[4 * DBOT];
    int tid = threadIdx.x;
#pragma unroll
    for (int r = 0; r < 4; ++r)
        insh[r * DBOT + tid] = bf2f(in[((size_t)(b * inRowsPerB + to * 4 + r)) * DBOT + tid]);
    __syncthreads();
    float acc = cb[tid];
    const float* wr = w + (size_t)tid * (DBOT * 4);
    for (int c = 0; c < DBOT; ++c) {
#pragma unroll
        for (int r = 0; r < 4; ++r)
            acc += insh[r * DBOT + c] * wr[c * 4 + r];
    }
    acc = acc * bng[tid] + bnb[tid];
    outp[((size_t)(b * Lout + to)) * DBOT + tid] = f2bf(acc > 0.0f ? acc : (expf(acc) - 1.0f));
}

// ---------------------------------------------------------------------------
// sparse attention over active level (compact Ob)
// ---------------------------------------------------------------------------
__launch_bounds__(256)
__global__ void attn_sparse_kernel(const short* __restrict__ QKV, short* __restrict__ Ob,
                                   int lvl, int cnt) {
    int wid  = blockIdx.x * 4 + (threadIdx.x >> 6);
    if (wid >= cnt * 32) return;
    int lane = threadIdx.x & 63;
    int b = wid & 31, j = wid >> 5;
    int i = d_sets.idx[lvl][j];
    const short8 qv = *(const short8*)(QKV + (size_t)(b * S + i) * 1536 + lane * 8);
    float qf[8];
#pragma unroll
    for (int e = 0; e < 8; ++e) qf[e] = bf2f(qv[e]);
    int nb[NMAX];
#pragma unroll
    for (int jj = 0; jj < NMAX; ++jj) nb[jj] = d_sets.nbr[i][jj];
    float sc[NMAX];
#pragma unroll
    for (int jj = 0; jj < NMAX; ++jj) {
        float s = -1e30f;
        if (nb[jj] >= 0) {
            const short8 kv = *(const short8*)(QKV + (size_t)(b * S + nb[jj]) * 1536 + 512 + lane * 8);
            s = 0.0f;
#pragma unroll
            for (int e = 0; e < 8; ++e) s += qf[e] * bf2f(kv[e]);
            s += __shfl_xor(s, 1); s += __shfl_xor(s, 2); s += __shfl_xor(s, 4);
            s *= 0.125f;
        }
        sc[jj] = s;
    }
    float mx = sc[0];
#pragma unroll
    for (int jj = 1; jj < NMAX; ++jj) mx = fmaxf(mx, sc[jj]);
    float sum = 0.0f;
    float accv[8] = {};
#pragma unroll
    for (int jj = 0; jj < NMAX; ++jj) {
        float p = expf(sc[jj] - mx);
        sum += p;
        if (nb[jj] >= 0) {
            const short8 vv = *(const short8*)(QKV + (size_t)(b * S + nb[jj]) * 1536 + 1024 + lane * 8);
#pragma unroll
            for (int e = 0; e < 8; ++e) accv[e] += p * bf2f(vv[e]);
        }
    }
    float inv = 1.0f / sum;
    short8 ov;
#pragma unroll
    for (int e = 0; e < 8; ++e) ov[e] = f2bf(accv[e] * inv);
    *(short8*)(Ob + (size_t)wid * D + lane * 8) = ov;
}

// ---------------------------------------------------------------------------
// wave-shuffle block reduction over 4 waves (256 thr)
// ---------------------------------------------------------------------------
__device__ inline float blk_reduce(float v, float* ws4, int tid) {
#pragma unroll
    for (int o = 32; o; o >>= 1) v += __shfl_xor(v, o);
    if ((tid & 63) == 0) ws4[tid >> 6] = v;
    __syncthreads();
    return ws4[0] + ws4[1] + ws4[2] + ws4[3];
}

// ---------------------------------------------------------------------------
// concat(emb_bf, coarse) + LayerNorm at A_0 rows only
// ---------------------------------------------------------------------------
__launch_bounds__(256)
__global__ void concat_ln_idx(const short* __restrict__ emb_bf, const float* __restrict__ coarse,
                              const float* __restrict__ g, const float* __restrict__ bta,
                              float* __restrict__ seq, short* __restrict__ seq_bf) {
    int row = blockIdx.x;
    int b = row & 31, j = row >> 5;
    int s = d_sets.idx[0][j];
    int orig = b * S + s;
    __shared__ float wsA[4];
    __shared__ float wsB[4];
    int tid = threadIdx.x;
    float x0, x1;
    if (s < L) {
        const short* src = emb_bf + ((size_t)b * L + s) * D;
        x0 = bf2f(src[tid]); x1 = bf2f(src[tid + 256]);
    } else {
        const float* src = coarse + ((size_t)b * LC + (s - L)) * D;
        x0 = src[tid]; x1 = src[tid + 256];
    }
    float mu = blk_reduce(x0 + x1, wsA, tid) * (1.0f / D);
    float d0 = x0 - mu, d1 = x1 - mu;
    float var = blk_reduce(d0 * d0 + d1 * d1, wsB, tid) * (1.0f / D);
    float rstd = rsqrtf(var + 1e-5f);
    float v0 = d0 * rstd * g[tid]       + bta[tid];
    float v1 = d1 * rstd * g[tid + 256] + bta[tid + 256];
    float* dst = seq + (size_t)orig * D;
    dst[tid] = v0; dst[tid + 256] = v1;
    short* dbf = seq_bf + (size_t)orig * D;
    dbf[tid] = f2bf(v0); dbf[tid + 256] = f2bf(v1);
}

// ---------------------------------------------------------------------------
// fused split-K reduce + residual LN
// ---------------------------------------------------------------------------
__launch_bounds__(256)
__global__ void add_ln_sk(float* __restrict__ seq, const float* __restrict__ part,
                          const float* __restrict__ bias, const float* __restrict__ g,
                          const float* __restrict__ bta, short* __restrict__ seq_bf,
                          int lvl, int Mpad, int KS) {
    int row = blockIdx.x;
    int b = row & 31, j = row >> 5;
    int orig = b * S + d_sets.idx[lvl][j];
    __shared__ float wsA[4];
    __shared__ float wsB[4];
    int tid = threadIdx.x;
    float a0 = 0.0f, a1 = 0.0f;
    for (int k = 0; k < KS; ++k) {
        const float* pr = part + ((size_t)k * Mpad + row) * D;
        a0 += pr[tid];
        a1 += pr[tid + 256];
    }
    if (bias) { a0 += bias[tid]; a1 += bias[tid + 256]; }
    float* srow = seq + (size_t)orig * D;
    float x0 = srow[tid] + a0;
    float x1 = srow[tid + 256] + a1;
    float mu = blk_reduce(x0 + x1, wsA, tid) * (1.0f / D);
    float d0 = x0 - mu, d1 = x1 - mu;
    float var = blk_reduce(d0 * d0 + d1 * d1, wsB, tid) * (1.0f / D);
    float rstd = rsqrtf(var + 1e-5f);
    float v0 = d0 * rstd * g[tid]       + bta[tid];
    float v1 = d1 * rstd * g[tid + 256] + bta[tid + 256];
    srow[tid] = v0; srow[tid + 256] = v1;
    short* dbf = seq_bf + (size_t)orig * D;
    dbf[tid] = f2bf(v0); dbf[tid + 256] = f2bf(v1);
}

// ---------------------------------------------------------------------------
// prediction head, split-K with fused gather
// ---------------------------------------------------------------------------
__launch_bounds__(256)
__global__ void pred_kernel(const float* __restrict__ seq, const float* __restrict__ w,
                            float* __restrict__ part) {
    __shared__ float es[32][257];
    __shared__ float wsm[256][8];
    int tid = threadIdx.x;
    int n0 = blockIdx.x * 8;
    int ks = blockIdx.y;
    int k0 = ks * 256;
    const int pos[4] = {335, 419, 440, 445};
    int seg = ks >> 1;
    int dbase = (ks & 1) * 256;
#pragma unroll 8
    for (int r = 0; r < 32; ++r)
        es[r][tid] = seq[((size_t)r * S + pos[seg]) * D + dbase + tid];
#pragma unroll
    for (int e = 0; e < 8; ++e)
        wsm[tid][e] = w[(size_t)(k0 + tid) * PRED_N + n0 + e];
    __syncthreads();
    int b = tid >> 3, nn = tid & 7;
    float acc = 0.0f;
#pragma unroll 8
    for (int kk = 0; kk < 256; ++kk)
        acc += es[b][kk] * wsm[kk][nn];
    part[(size_t)ks * (BB * PRED_N) + (size_t)b * PRED_N + n0 + nn] = acc;
}

__launch_bounds__(256)
__global__ void pred_reduce_kernel(const float* __restrict__ part, float* __restrict__ out) {
    int idx = blockIdx.x * 256 + threadIdx.x;
    if (idx >= BB * PRED_N) return;
    float s = 0.0f;
#pragma unroll
    for (int k = 0; k < 8; ++k) s += part[(size_t)k * (BB * PRED_N) + idx];
    out[idx] = s;
}

// ---------------------------------------------------------------------------
extern "C" void kernel_launch(void* const* d_in, const int* in_sizes, int n_in,
                              void* d_out, int out_size, void* d_ws, size_t ws_size,
                              hipStream_t stream) {
    const float* x_enc      = (const float*)d_in[0];
    const float* x_mark_enc = (const float*)d_in[1];
    const float* conv_embed_w = (const float*)d_in[4];
    const float* time_w  = (const float*)d_in[5];
    const float* time_b  = (const float*)d_in[6];
    const float* down_w  = (const float*)d_in[7];
    const float* down_b  = (const float*)d_in[8];
    const float* cscm_w  = (const float*)d_in[9];
    const float* cscm_b  = (const float*)d_in[10];
    const float* bn_g    = (const float*)d_in[11];
    const float* bn_b    = (const float*)d_in[12];
    const float* up_w    = (const float*)d_in[13];
    const float* up_b    = (const float*)d_in[14];
    const float* cln_g   = (const float*)d_in[15];
    const float* cln_b   = (const float*)d_in[16];
    const float* wq      = (const float*)d_in[17];
    const float* wk      = (const float*)d_in[18];
    const float* wv      = (const float*)d_in[19];
    const float* wo      = (const float*)d_in[20];
    const float* ln1_g   = (const float*)d_in[21];
    const float* ln1_b   = (const float*)d_in[22];
    const float* ffn_w1  = (const float*)d_in[23];
    const float* ffn_b1  = (const float*)d_in[24];
    const float* ffn_w2  = (const float*)d_in[25];
    const float* ffn_b2  = (const float*)d_in[26];
    const float* ln2_g   = (const float*)d_in[27];
    const float* ln2_b   = (const float*)d_in[28];
    const float* pred_w  = (const float*)d_in[29];
    float* out = (float*)d_out;

    // ---- workspace layout (bytes, 256-aligned) ----
    char* w8 = (char*)d_ws;
    size_t off = 0;
    auto alloc = [&](size_t bytes) {
        void* p = w8 + off;
        off = (off + bytes + 255) & ~(size_t)255;
        return p;
    };
    short* emb_bf = (short*)alloc((size_t)BB * L * D * 2);
    float* pe     = (float*)alloc((size_t)L * D * 4);
    short* xim    = (short*)alloc((size_t)BB * L * 32 * 2);
    short* wE     = (short*)alloc((size_t)D * 32 * 2);
    short* xd_bf  = (short*)alloc((size_t)BB * L * DBOT * 2);
    short* cs1_bf = (short*)alloc((size_t)MCONV2P * 512 * 2);
    short* cs2_bf = (short*)alloc((size_t)MCONV2P * DBOT * 2);
    short* cs3_bf = (short*)alloc((size_t)BB * L3 * DBOT * 2);
    float* coarse = (float*)alloc((size_t)MCAT * D * 4);
    float* seq    = (float*)alloc((size_t)BB * S * D * 4);
    float* part   = (float*)alloc((size_t)8 * BB * PRED_N * 4);
    float* partsk = (float*)alloc(psk_elems() * 4);   // split-K partials (exact)
    short* seq_bf = (short*)alloc((size_t)MP * D * 2);
    short* QKV    = (short*)alloc((size_t)MP * 3 * D * 2);  // + Ob contiguous
    short* Ob     = (short*)alloc((size_t)MP * D * 2);
    short* hidden = QKV;
    short* wqkvT  = (short*)alloc((size_t)NLAYER * 3 * D * D * 2);
    short* woT    = (short*)alloc((size_t)NLAYER * D * D * 2);
    short* w1T    = (short*)alloc((size_t)NLAYER * DFF * D * 2);
    short* w2T    = (short*)alloc((size_t)NLAYER * D * DFF * 2);
    short* downT  = (short*)alloc((size_t)DBOT * D * 2);
    short* upT    = (short*)alloc((size_t)D * DBOT * 2);
    short* cscmT  = (short*)alloc((size_t)2 * DBOT * 512 * 2);
    float* csc_sc = (float*)alloc((size_t)3 * DBOT * 4);
    float* csc_sh = (float*)alloc((size_t)3 * DBOT * 4);
    (void)ws_size; (void)in_sizes; (void)n_in; (void)out_size;

    const int rowsL = BB * L;   // 10752 = 84*128
    dim3 blk(256);

    // 0. ONE fused prep kernel
    prep_all<<<dim3(PREP_BLKS), blk, 0, stream>>>(
        wq, wk, wv, wo, wqkvT, woT,
        ffn_w1, ffn_w2, w1T, w2T,
        down_w, downT, up_w, upT,
        cscm_w, cscm_b, bn_g, bn_b, cscmT, csc_sc, csc_sh,
        x_enc, x_mark_enc, conv_embed_w, time_w, time_b, pe, wE, xim);
    // 1. embedding as GEMM + pe epilogue, bf16 out
    mfma_gemm<6><<<dim3(D / 128, rowsL / 128), blk, 0, stream>>>(
        xim, wE, nullptr, nullptr, nullptr, 32, D, -1, -1, 0, pe, emb_bf);
    // 2. down projection -> bf16 (split-K)
    mfma_gemm_sk<<<dim3(1, rowsL / 128, 4), blk, 0, stream>>>(
        emb_bf, downT, partsk, D, DBOT, -1, 0);
    reduce_sk<4><<<dim3((rowsL * DBOT + 255) / 256), blk, 0, stream>>>(
        partsk, down_b, nullptr, xd_bf, rowsL, DBOT, 4);
    // 3. CSCM pyramid (conv1/conv2 split-K)
    mfma_gemm_sk<<<dim3(1, MCONV1 / 128, 4), blk, 0, stream>>>(
        xd_bf, cscmT, partsk, 512, DBOT, -1, 0);
    reduce_sk<5><<<dim3((MCONV1 * DBOT + 255) / 256), blk, 0, stream>>>(
        partsk, csc_sc, csc_sh, cs1_bf, MCONV1, DBOT, 4);
    mfma_gemm_sk<<<dim3(1, MCONV2P / 128, 4), blk, 0, stream>>>(
        cs1_bf, cscmT + (size_t)DBOT * 512, partsk, 512, DBOT, -1, 0);
    reduce_sk<5><<<dim3((MCONV2P * DBOT + 255) / 256), blk, 0, stream>>>(
        partsk, csc_sc + DBOT, csc_sh + DBOT, cs2_bf, MCONV2P, DBOT, 4);
    cscm_conv_bf16<<<dim3(BB * L3), dim3(DBOT), 0, stream>>>(
        cs2_bf, L2, cs3_bf, cscm_w + 2 * DBOT * DBOT * 4,
        cscm_b + 2 * DBOT, bn_g + 2 * DBOT, bn_b + 2 * DBOT, L3);
    // 4. up projection with inline concat gather
    mfma_gemm_up<<<dim3(D / 128, MCAT / 128), blk, 0, stream>>>(
        cs1_bf, cs2_bf, cs3_bf, upT, up_b, coarse);
    // 5. concat + LN (A_0 rows only)
    concat_ln_idx<<<dim3(HS.cnt[0] * 32), blk, 0, stream>>>(
        emb_bf, coarse, cln_g, cln_b, seq, seq_bf);

    // 6. encoder layers (sparse active sets; split-K everywhere it pays)
    for (int l = 0; l < NLAYER; ++l) {
        const int inLvl = l, outLvl = l + 1;
        const int inCnt  = HS.cnt[l];
        const int outCnt = HS.cnt[l + 1];
        const int Mc   = outCnt * 32;
        const int Mpad = ((Mc + 127) / 128) * 128;
        mfma_gemm<2><<<dim3(3 * D / 128, (inCnt * 32 + 127) / 128), blk, 0, stream>>>(
            seq_bf, wqkvT + (size_t)l * 3 * D * D, nullptr, nullptr, QKV, D, 3 * D,
            inLvl, inLvl, inCnt, nullptr, nullptr);
        attn_sparse_kernel<<<dim3(outCnt * 8), blk, 0, stream>>>(
            QKV, Ob, outLvl, outCnt);
        // O-projection + LN1: ALWAYS split-K + fused reduce/LN (r22)
        mfma_gemm_sk<<<dim3(D / 128, Mpad / 128, 4), blk, 0, stream>>>(
            Ob, woT + (size_t)l * D * D, partsk, D, D, -1, 0);
        add_ln_sk<<<dim3(Mc), blk, 0, stream>>>(
            seq, partsk, nullptr, ln1_g + (size_t)l * D, ln1_b + (size_t)l * D,
            seq_bf, outLvl, Mpad, 4);
        // FFN1: split-K for Mc<=512 (r22: covers l1, l2)
        if (Mc <= 512) {
            mfma_gemm_sk<<<dim3(DFF / 128, Mpad / 128, 4), blk, 0, stream>>>(
                seq_bf, w1T + (size_t)l * DFF * D, partsk, D, DFF, outLvl, outCnt);
            reduce_sk<3><<<dim3((Mpad * DFF + 255) / 256), blk, 0, stream>>>(
                partsk, ffn_b1 + (size_t)l * DFF, nullptr, hidden, Mpad, DFF, 4);
        } else {
            mfma_gemm<3><<<dim3(DFF / 128, Mpad / 128), blk, 0, stream>>>(
                seq_bf, w1T + (size_t)l * DFF * D, ffn_b1 + (size_t)l * DFF, nullptr,
                hidden, D, DFF, outLvl, -1, outCnt, nullptr, nullptr);
        }
        // FFN2 + LN2: split-K, reduce fused into LN
        {
            int KS = (Mc <= 512) ? 8 : 4;
            mfma_gemm_sk<<<dim3(D / 128, Mpad / 128, KS), blk, 0, stream>>>(
                hidden, w2T + (size_t)l * D * DFF, partsk, DFF, D, -1, 0);
            add_ln_sk<<<dim3(Mc), blk, 0, stream>>>(
                seq, partsk, ffn_b2 + (size_t)l * D, ln2_g + (size_t)l * D,
                ln2_b + (size_t)l * D, seq_bf, outLvl, Mpad, KS);
        }
    }

    // 7. prediction head (split-K, gather fused) + reduce
    pred_kernel<<<dim3(PRED_N / 8, 8), blk, 0, stream>>>(seq, pred_w, part);
    pred_reduce_kernel<<<dim3((BB * PRED_N + 255) / 256), blk, 0, stream>>>(part, out);
}